// Round 1
// 1803.838 us; speedup vs baseline: 2.0510x; 2.0510x over previous
//
#include <hip/hip_runtime.h>

#define LAMBDA_INIT 0.2f
#define SCALING 0.17677669529663687f   // 1/sqrt(32)
#define EPS_DEF 1.1920928955078125e-07f
#define EPS_ATTN 1e-5f

typedef unsigned short us4 __attribute__((ext_vector_type(4)));
typedef float f32x4 __attribute__((ext_vector_type(4)));
typedef float f32x2 __attribute__((ext_vector_type(2)));

__device__ __forceinline__ float bf2f(unsigned short u) {
    unsigned int x = ((unsigned int)u) << 16;
    return __builtin_bit_cast(float, x);
}
__device__ __forceinline__ unsigned short f2bf(float f) {
    unsigned int x = __builtin_bit_cast(unsigned int, f);
    x += 0x7fffu + ((x >> 16) & 1u);
    return (unsigned short)(x >> 16);
}
__device__ __forceinline__ float dot4(f32x4 a, f32x4 b) {
    return fmaf(a[0], b[0], fmaf(a[1], b[1], fmaf(a[2], b[2], a[3] * b[3])));
}

__device__ __forceinline__ float wave_sum(float v) {
#pragma unroll
    for (int o = 32; o > 0; o >>= 1) v += __shfl_down(v, o);
    return v;
}
__device__ __forceinline__ float block_sum(float v, float* red4) {
    int wv = threadIdx.x >> 6;
    float w = wave_sum(v);
    __syncthreads();
    if ((threadIdx.x & 63) == 0) red4[wv] = w;
    __syncthreads();
    return red4[0] + red4[1] + red4[2] + red4[3];
}

// ---------------- prep: zero G, compute lambda ----------------
__global__ __launch_bounds__(256) void prep(float* __restrict__ G, float* __restrict__ lamp,
                                            const float* lq1, const float* lk1,
                                            const float* lq2, const float* lk2) {
    int i = (blockIdx.x * 256 + threadIdx.x) * 4;
    G[i] = 0.f; G[i + 1] = 0.f; G[i + 2] = 0.f; G[i + 3] = 0.f;
    if (blockIdx.x == 0 && threadIdx.x == 0) {
        float a = 0.f, c = 0.f;
        for (int d = 0; d < 32; d++) {
            a += lq1[d] * lk1[d];
            c += lq2[d] * lk2[d];
        }
        *lamp = expf(a) - expf(c) + LAMBDA_INIT;
    }
}

// ---------------- RMSNorm: fp32 in, fp32 weight, fp32 or bf16 out ----------------
template <int OUTBF>
__global__ __launch_bounds__(256) void rms_kernel(const float* __restrict__ x,
                                                  const float* __restrict__ w,
                                                  void* __restrict__ out, float eps) {
    int row = blockIdx.x;
    int tid = threadIdx.x;
    size_t base = (size_t)row * 1024 + tid * 4;
    f32x4 v = *(const f32x4*)(x + base);
    float ss = v[0]*v[0] + v[1]*v[1] + v[2]*v[2] + v[3]*v[3];
    __shared__ float red4[4];
    float tot = block_sum(ss, red4);
    float r = rsqrtf(tot * (1.0f / 1024.f) + eps);
    f32x4 wv = *(const f32x4*)(w + tid * 4);
#pragma unroll
    for (int i = 0; i < 4; i++) {
        float val = v[i] * r * wv[i];
        if (OUTBF) ((unsigned short*)out)[base + i] = f2bf(val);
        else ((float*)out)[base + i] = val;
    }
}

// ---------------- VALU fp32 GEMM: C[M,N] = A[M,K] @ Bt[N,K]^T + bias ----------------
template <typename AT, int MODE>
__global__ __launch_bounds__(256) void gemm_v(const AT* __restrict__ A,
                                              const float* __restrict__ Bt,
                                              const float* __restrict__ bias,
                                              const float* __restrict__ res,
                                              float* __restrict__ out, int M, int N, int K) {
    __shared__ __align__(16) float As[16][68];
    __shared__ __align__(16) float Bs[16][68];
    const int tid = threadIdx.x;
    const int bm = blockIdx.x, bn = blockIdx.y;
    const int tx = tid & 15, ty = tid >> 4;
    const int r = tid >> 2, c = (tid & 3) * 4;
    const AT* Ap = A + (size_t)(bm * 64 + r) * K + c;
    const float* Bp = Bt + (size_t)(bn * 64 + r) * K + c;
    float acc[4][4] = {{0.f}};
    for (int k0 = 0; k0 < K; k0 += 16) {
        float a0, a1, a2, a3;
        if constexpr (sizeof(AT) == 2) {
            us4 av = *(const us4*)(Ap + k0);
            a0 = bf2f(av[0]); a1 = bf2f(av[1]); a2 = bf2f(av[2]); a3 = bf2f(av[3]);
        } else {
            f32x4 av = *(const f32x4*)(Ap + k0);
            a0 = av[0]; a1 = av[1]; a2 = av[2]; a3 = av[3];
        }
        f32x4 bv4 = *(const f32x4*)(Bp + k0);
        __syncthreads();
        As[c + 0][r] = a0; As[c + 1][r] = a1; As[c + 2][r] = a2; As[c + 3][r] = a3;
        Bs[c + 0][r] = bv4[0]; Bs[c + 1][r] = bv4[1]; Bs[c + 2][r] = bv4[2]; Bs[c + 3][r] = bv4[3];
        __syncthreads();
#pragma unroll
        for (int kk = 0; kk < 16; kk++) {
            f32x4 av = *(const f32x4*)&As[kk][ty * 4];
            f32x4 bv = *(const f32x4*)&Bs[kk][tx * 4];
#pragma unroll
            for (int i = 0; i < 4; i++)
#pragma unroll
                for (int j = 0; j < 4; j++)
                    acc[i][j] = fmaf(av[i], bv[j], acc[i][j]);
        }
    }
#pragma unroll
    for (int i = 0; i < 4; i++) {
        int m = bm * 64 + ty * 4 + i;
#pragma unroll
        for (int j = 0; j < 4; j++) {
            int n = bn * 64 + tx * 4 + j;
            size_t oi = (size_t)m * N + n;
            float v = acc[i][j] + bias[n];
            if (MODE == 0) out[oi] = v;
            else out[oi] = v + res[oi];
        }
    }
}

// ---------------- fused gate GEMM: mlp = (h2@Wu^T+bu) * silu(h2@Wv^T+bv) ----------------
__global__ __launch_bounds__(256) void gemm_gate_v(const unsigned short* __restrict__ A,
                                                   const float* __restrict__ Wg,
                                                   const float* __restrict__ bg,
                                                   unsigned short* __restrict__ mlp) {
    __shared__ __align__(16) float As[16][68];
    __shared__ __align__(16) float BsU[16][68];
    __shared__ __align__(16) float BsV[16][68];
    const int tid = threadIdx.x;
    const int bm = blockIdx.x, bn = blockIdx.y;
    const int tx = tid & 15, ty = tid >> 4;
    const int r = tid >> 2, c = (tid & 3) * 4;
    const unsigned short* Ap = A + (size_t)(bm * 64 + r) * 1024 + c;
    const float* BpU = Wg + (size_t)(bn * 64 + r) * 1024 + c;
    const float* BpV = Wg + (size_t)(4096 + bn * 64 + r) * 1024 + c;
    float accU[4][4] = {{0.f}}, accV[4][4] = {{0.f}};
    for (int k0 = 0; k0 < 1024; k0 += 16) {
        us4 avw = *(const us4*)(Ap + k0);
        f32x4 u4 = *(const f32x4*)(BpU + k0);
        f32x4 v4 = *(const f32x4*)(BpV + k0);
        __syncthreads();
        As[c + 0][r] = bf2f(avw[0]); As[c + 1][r] = bf2f(avw[1]);
        As[c + 2][r] = bf2f(avw[2]); As[c + 3][r] = bf2f(avw[3]);
        BsU[c + 0][r] = u4[0]; BsU[c + 1][r] = u4[1]; BsU[c + 2][r] = u4[2]; BsU[c + 3][r] = u4[3];
        BsV[c + 0][r] = v4[0]; BsV[c + 1][r] = v4[1]; BsV[c + 2][r] = v4[2]; BsV[c + 3][r] = v4[3];
        __syncthreads();
#pragma unroll
        for (int kk = 0; kk < 16; kk++) {
            f32x4 av = *(const f32x4*)&As[kk][ty * 4];
            f32x4 uv = *(const f32x4*)&BsU[kk][tx * 4];
            f32x4 vv = *(const f32x4*)&BsV[kk][tx * 4];
#pragma unroll
            for (int i = 0; i < 4; i++)
#pragma unroll
                for (int j = 0; j < 4; j++) {
                    accU[i][j] = fmaf(av[i], uv[j], accU[i][j]);
                    accV[i][j] = fmaf(av[i], vv[j], accV[i][j]);
                }
        }
    }
#pragma unroll
    for (int i = 0; i < 4; i++) {
        int m = bm * 64 + ty * 4 + i;
#pragma unroll
        for (int j = 0; j < 4; j++) {
            int n = bn * 64 + tx * 4 + j;
            float u = accU[i][j] + bg[n];
            float v = accV[i][j] + bg[4096 + n];
            float s = v / (1.f + __expf(-v));
            mlp[(size_t)m * 4096 + n] = f2bf(u * s);
        }
    }
}

// ---------------- RoPE in place, token order ----------------
__global__ __launch_bounds__(256) void rope_inplace(float* __restrict__ Y,
                                                    const float* __restrict__ fc) {
    int t = blockIdx.x;
    int s = t & 1023;
    int p = s >> 2;
    if (p == 0) return;
    int c0 = threadIdx.x * 4;
    float* y = Y + (size_t)t * 1024 + c0;
    int d4 = (c0 & 31) >> 1;
    f32x4 f = *(const f32x4*)(fc + ((size_t)(p - 1) * 16 + d4) * 2);  // [cos,sin,cos,sin]
    float v0 = y[0], v1 = y[1], v2 = y[2], v3 = y[3];
    y[0] = v0 * f[0] - v1 * f[1];
    y[1] = v0 * f[1] + v1 * f[0];
    y[2] = v2 * f[2] - v3 * f[3];
    y[3] = v2 * f[3] + v3 * f[2];
}

// =====================================================================
// Tiled attention. Block = 64 consecutive TOKENS of Q (= 16 positions x
// 4 interleaved sequences) for one (b,h). Thread t: q-row r = t>>2,
// sub = t&3. K/V staged per 64-token chunk in LDS.
// Softmax uses NO max subtraction: |s|*scale is bounded (<~40) so
// e^{|s|}/sum e^{|s|} is safe in fp32 and identical math to the ref.
// pass_a_t: sweep1 -> Z1,Z2 per row (written to MZ), sweep2 -> G.
// pass_b_t: combined weight a = sg1*e1/Z1 - lam*sg2*e2/Z2 + (lam/1024)*G[k]
//           in one LDS tile, single AV accumulation, fused RMS + store.
// =====================================================================

// ---------------- pass A (tiled): denominators Z1/Z2 + G ----------------
__global__ __launch_bounds__(256) void pass_a_t(const float* __restrict__ Yq,
                                                const float* __restrict__ Yk,
                                                float* __restrict__ G,
                                                float* __restrict__ MZ) {
    const int qc = blockIdx.x, h = blockIdx.y, b = blockIdx.z;
    const int t = threadIdx.x;
    const int r = t >> 2, sub = t & 3;
    const int cs = sub << 4;
    const int tq = qc * 64 + r;          // token index of this thread's q-row
    const int pq = tq >> 2;              // position within 256-period
    const int nsq = tq & 3;              // sequence id
    const int qrow = (nsq << 8) + pq;    // attention row index q'

    __shared__ __align__(16) float Ks[64][68];
    __shared__ float At[64][65];
    __shared__ float Pc[4][64];
    __shared__ float Gacc[1024];

    for (int i = t; i < 1024; i += 256) Gacc[i] = 0.f;

    f32x4 q[16];
    const f32x4* qp = (const f32x4*)(Yq + (((size_t)(b * 1024 + tq)) << 10) + h * 64);
#pragma unroll
    for (int i = 0; i < 16; i++) q[i] = qp[i];

    const float* Ykb = Yk + ((size_t)b << 20) + h * 64;

    float z1 = 0.f, z2 = 0.f;
    // -------- sweep 1: denominators (both halves) --------
    for (int kc = 0; kc <= qc; kc++) {
        __syncthreads();
        {
            const float* kp_ = Ykb + (((size_t)(kc * 64 + r)) << 10) + cs;
            *(f32x4*)&Ks[r][cs]      = *(const f32x4*)(kp_);
            *(f32x4*)&Ks[r][cs + 4]  = *(const f32x4*)(kp_ + 4);
            *(f32x4*)&Ks[r][cs + 8]  = *(const f32x4*)(kp_ + 8);
            *(f32x4*)&Ks[r][cs + 12] = *(const f32x4*)(kp_ + 12);
        }
        __syncthreads();
        const int kp0 = kc * 16;
#pragma unroll 4
        for (int i = 0; i < 16; i++) {
            const int ltk = (sub << 4) + i;
            const f32x4* kr = (const f32x4*)&Ks[ltk][0];
            float s1 = 0.f, s2 = 0.f;
#pragma unroll
            for (int c8 = 0; c8 < 8; c8++) {
                s1 += dot4(q[c8], kr[c8]);
                s2 += dot4(q[8 + c8], kr[8 + c8]);
            }
            if ((kp0 + (ltk >> 2)) <= pq) {
                z1 += __expf(fabsf(s1 * SCALING));
                z2 += __expf(fabsf(s2 * SCALING));
            }
        }
    }
    float Z1 = z1; Z1 += __shfl_xor(Z1, 1); Z1 += __shfl_xor(Z1, 2);
    float Z2 = z2; Z2 += __shfl_xor(Z2, 1); Z2 += __shfl_xor(Z2, 2);
    if (sub == 0) {
        f32x2 zz; zz[0] = Z1; zz[1] = Z2;
        *(f32x2*)(MZ + (((size_t)(b * 16 + h) << 10) + qrow) * 2) = zz;
    }
    const float i1 = 1.f / fmaxf(Z1, 1e-20f);

    // -------- sweep 2: a1 values -> column sums -> G --------
    for (int kc = 0; kc <= qc; kc++) {
        __syncthreads();
        {
            const float* kp_ = Ykb + (((size_t)(kc * 64 + r)) << 10) + cs;
            *(f32x4*)&Ks[r][cs]      = *(const f32x4*)(kp_);
            *(f32x4*)&Ks[r][cs + 4]  = *(const f32x4*)(kp_ + 4);
            *(f32x4*)&Ks[r][cs + 8]  = *(const f32x4*)(kp_ + 8);
            *(f32x4*)&Ks[r][cs + 12] = *(const f32x4*)(kp_ + 12);
        }
        __syncthreads();
        const int kp0 = kc * 16;
#pragma unroll 4
        for (int i = 0; i < 16; i++) {
            const int ltk = (sub << 4) + i;
            const f32x4* kr = (const f32x4*)&Ks[ltk][0];
            float s1 = 0.f;
#pragma unroll
            for (int c8 = 0; c8 < 8; c8++) s1 += dot4(q[c8], kr[c8]);
            s1 *= SCALING;
            float a = 0.f;
            if ((kp0 + (ltk >> 2)) <= pq) {
                float sg = (s1 > 0.f) ? 1.f : ((s1 < 0.f) ? -1.f : 0.f);
                a = sg * __expf(fabsf(s1)) * i1;
            }
            At[r][ltk] = a;
        }
        __syncthreads();
        {
            const int kcol = t & 63, rq = t >> 6;
            float csum = 0.f;
#pragma unroll
            for (int rr = 0; rr < 16; rr++) csum += At[rq * 16 + rr][kcol];
            Pc[rq][kcol] = csum;
        }
        __syncthreads();
        if (t < 64) Gacc[kc * 64 + t] = Pc[0][t] + Pc[1][t] + Pc[2][t] + Pc[3][t];
    }
    __syncthreads();
    float* Gb = G + ((size_t)(b * 16 + h) << 10);
    const int lim = (qc + 1) * 64;
    for (int idx = t; idx < lim; idx += 256) {
        int j = ((idx & 3) << 8) + (idx >> 2);   // token -> attention index
        atomicAdd(&Gb[j], Gacc[idx]);
    }
}

// ---------------- pass B (tiled): attention + AV + RMS + store ----------------
__global__ __launch_bounds__(256) void pass_b_t(const float* __restrict__ Yq,
                                                const float* __restrict__ Yk,
                                                const float* __restrict__ Yv,
                                                const float* __restrict__ G,
                                                const float* __restrict__ MZ,
                                                const float* __restrict__ lamp,
                                                const float* __restrict__ wan,
                                                unsigned short* __restrict__ aoS) {
    const int qc = blockIdx.x, h = blockIdx.y, b = blockIdx.z;
    const int t = threadIdx.x;
    const int r = t >> 2, sub = t & 3;
    const int cs = sub << 4;
    const int tq = qc * 64 + r;
    const int pq = tq >> 2;
    const int nsq = tq & 3;
    const int qrow = (nsq << 8) + pq;

    __shared__ __align__(16) float Ks[64][68];
    __shared__ __align__(16) float Vs[64][68];
    __shared__ float At[64][65];
    __shared__ float Gs[64];

    f32x4 q[16];
    const f32x4* qp = (const f32x4*)(Yq + (((size_t)(b * 1024 + tq)) << 10) + h * 64);
#pragma unroll
    for (int i = 0; i < 16; i++) q[i] = qp[i];

    f32x2 zz = *(const f32x2*)(MZ + (((size_t)(b * 16 + h) << 10) + qrow) * 2);
    const float i1 = 1.f / fmaxf(zz[0], 1e-20f);
    const float i2 = 1.f / fmaxf(zz[1], 1e-20f);
    const float lam = *lamp;
    const float lamg = lam * (1.f / 1024.f);

    const float* Ykb = Yk + ((size_t)b << 20) + h * 64;
    const float* Yvb = Yv + ((size_t)b << 20) + h * 64;
    const float* Gb = G + ((size_t)(b * 16 + h) << 10);

    f32x4 acc0 = {0.f, 0.f, 0.f, 0.f};
    f32x4 acc1 = {0.f, 0.f, 0.f, 0.f};
    f32x4 acc2 = {0.f, 0.f, 0.f, 0.f};
    f32x4 acc3 = {0.f, 0.f, 0.f, 0.f};

    for (int kc = 0; kc <= qc; kc++) {
        __syncthreads();
        {
            const float* kp_ = Ykb + (((size_t)(kc * 64 + r)) << 10) + cs;
            *(f32x4*)&Ks[r][cs]      = *(const f32x4*)(kp_);
            *(f32x4*)&Ks[r][cs + 4]  = *(const f32x4*)(kp_ + 4);
            *(f32x4*)&Ks[r][cs + 8]  = *(const f32x4*)(kp_ + 8);
            *(f32x4*)&Ks[r][cs + 12] = *(const f32x4*)(kp_ + 12);
            // V row for attention index j is RAW index j (reference quirk)
            const int jv = ((r & 3) << 8) + kc * 16 + (r >> 2);
            const float* vp_ = Yvb + ((size_t)jv << 10) + cs;
            *(f32x4*)&Vs[r][cs]      = *(const f32x4*)(vp_);
            *(f32x4*)&Vs[r][cs + 4]  = *(const f32x4*)(vp_ + 4);
            *(f32x4*)&Vs[r][cs + 8]  = *(const f32x4*)(vp_ + 8);
            *(f32x4*)&Vs[r][cs + 12] = *(const f32x4*)(vp_ + 12);
            if (t < 64) Gs[t] = Gb[((t & 3) << 8) + kc * 16 + (t >> 2)];
        }
        __syncthreads();
        const int kp0 = kc * 16;
#pragma unroll 4
        for (int i = 0; i < 16; i++) {
            const int ltk = (sub << 4) + i;
            const f32x4* kr = (const f32x4*)&Ks[ltk][0];
            float s1 = 0.f, s2 = 0.f;
#pragma unroll
            for (int c8 = 0; c8 < 8; c8++) {
                s1 += dot4(q[c8], kr[c8]);
                s2 += dot4(q[8 + c8], kr[8 + c8]);
            }
            s1 *= SCALING; s2 *= SCALING;
            float a = 0.f;
            if ((kp0 + (ltk >> 2)) <= pq) {
                float sg1 = (s1 > 0.f) ? 1.f : ((s1 < 0.f) ? -1.f : 0.f);
                float sg2 = (s2 > 0.f) ? 1.f : ((s2 < 0.f) ? -1.f : 0.f);
                a = sg1 * __expf(fabsf(s1)) * i1
                  - lam * (sg2 * __expf(fabsf(s2)) * i2)
                  + lamg * Gs[ltk];
            }
            At[r][ltk] = a;
        }
        __syncthreads();
#pragma unroll 8
        for (int k2 = 0; k2 < 64; k2++) {
            float a = At[r][k2];
            const f32x4* vr = (const f32x4*)&Vs[k2][cs];
            acc0 += vr[0] * a;
            acc1 += vr[1] * a;
            acc2 += vr[2] * a;
            acc3 += vr[3] * a;
        }
    }

    // fused RMS over the 64-dim head + bf16 store (scrambled reshape layout)
    float ss = acc0[0]*acc0[0] + acc0[1]*acc0[1] + acc0[2]*acc0[2] + acc0[3]*acc0[3]
             + acc1[0]*acc1[0] + acc1[1]*acc1[1] + acc1[2]*acc1[2] + acc1[3]*acc1[3]
             + acc2[0]*acc2[0] + acc2[1]*acc2[1] + acc2[2]*acc2[2] + acc2[3]*acc2[3]
             + acc3[0]*acc3[0] + acc3[1]*acc3[1] + acc3[2]*acc3[2] + acc3[3]*acc3[3];
    ss += __shfl_xor(ss, 1);
    ss += __shfl_xor(ss, 2);
    const float rr_ = rsqrtf(ss * (1.f / 64.f) + EPS_ATTN);
    const f32x4* wv = (const f32x4*)(wan + cs);
    unsigned short* op = aoS + ((size_t)b << 20) + ((size_t)h << 16) + ((size_t)qrow << 6) + cs;
    {
        f32x4 w0 = wv[0], w1 = wv[1], w2 = wv[2], w3 = wv[3];
        us4 o0, o1, o2, o3;
#pragma unroll
        for (int u = 0; u < 4; u++) {
            o0[u] = f2bf(acc0[u] * rr_ * w0[u]);
            o1[u] = f2bf(acc1[u] * rr_ * w1[u]);
            o2[u] = f2bf(acc2[u] * rr_ * w2[u]);
            o3[u] = f2bf(acc3[u] * rr_ * w3[u]);
        }
        ((us4*)op)[0] = o0; ((us4*)op)[1] = o1; ((us4*)op)[2] = o2; ((us4*)op)[3] = o3;
    }
}

extern "C" void kernel_launch(void* const* d_in, const int* in_sizes, int n_in,
                              void* d_out, int out_size, void* d_ws, size_t ws_size,
                              hipStream_t stream) {
    const float* x    = (const float*)d_in[0];
    const float* fc   = (const float*)d_in[1];
    const float* w1   = (const float*)d_in[2];
    const float* w2   = (const float*)d_in[3];
    const float* Wq   = (const float*)d_in[4];
    const float* bq   = (const float*)d_in[5];
    const float* Wk   = (const float*)d_in[6];
    const float* bk   = (const float*)d_in[7];
    const float* Wv   = (const float*)d_in[8];
    const float* bv   = (const float*)d_in[9];
    const float* Wo   = (const float*)d_in[10];
    const float* bo   = (const float*)d_in[11];
    const float* lq1  = (const float*)d_in[12];
    const float* lk1  = (const float*)d_in[13];
    const float* lq2  = (const float*)d_in[14];
    const float* lk2  = (const float*)d_in[15];
    const float* wan  = (const float*)d_in[16];
    const float* Wg   = (const float*)d_in[17];
    const float* bg   = (const float*)d_in[18];
    const float* Wout = (const float*)d_in[19];
    const float* bout = (const float*)d_in[20];

    char* ws = (char*)d_ws;
    const size_t MB = 1024 * 1024;
    // Layout (peak 33 MB):
    float* G    = (float*)(ws);                     // [0, 128K)
    float* lam  = (float*)(ws + 256 * 1024);        // 4 B
    float* MZ   = (float*)(ws + 384 * 1024);        // [384K, 640K)  Z1/Z2 per row
    float* h32  = (float*)(ws + 1 * MB);            // [1,9)   fp32 2048x1024
    float* Yq   = (float*)(ws + 9 * MB);            // [9,17)
    float* Yk   = (float*)(ws + 17 * MB);           // [17,25)
    float* Yv   = (float*)(ws + 25 * MB);           // [25,33)
    unsigned short* aoS = (unsigned short*)(ws + 1 * MB);   // reuse [1,5)  (h32 dead after QKV)
    float* X1           = (float*)(ws + 9 * MB);            // reuse [9,17) (Yq dead after pass_b)
    unsigned short* h2b = (unsigned short*)(ws + 1 * MB);   // reuse [1,5)  (aoS dead after Wo gemm)
    unsigned short* mlp = (unsigned short*)(ws + 17 * MB);  // reuse [17,33) (Yk/Yv dead)

    prep<<<32, 256, 0, stream>>>(G, lam, lq1, lk1, lq2, lk2);
    rms_kernel<0><<<2048, 256, 0, stream>>>(x, w1, h32, EPS_DEF);
    dim3 gqkv(32, 16);
    gemm_v<float, 0><<<gqkv, 256, 0, stream>>>(h32, Wq, bq, nullptr, Yq, 2048, 1024, 1024);
    gemm_v<float, 0><<<gqkv, 256, 0, stream>>>(h32, Wk, bk, nullptr, Yk, 2048, 1024, 1024);
    gemm_v<float, 0><<<gqkv, 256, 0, stream>>>(h32, Wv, bv, nullptr, Yv, 2048, 1024, 1024);
    rope_inplace<<<2048, 256, 0, stream>>>(Yq, fc);
    rope_inplace<<<2048, 256, 0, stream>>>(Yk, fc);
    pass_a_t<<<dim3(16, 16, 2), 256, 0, stream>>>(Yq, Yk, G, MZ);
    pass_b_t<<<dim3(16, 16, 2), 256, 0, stream>>>(Yq, Yk, Yv, G, MZ, lam, wan, aoS);
    gemm_v<unsigned short, 1><<<gqkv, 256, 0, stream>>>(aoS, Wo, bo, x, X1, 2048, 1024, 1024);
    rms_kernel<1><<<2048, 256, 0, stream>>>(X1, w2, h2b, EPS_DEF);
    gemm_gate_v<<<dim3(32, 64), 256, 0, stream>>>(h2b, Wg, bg, mlp);
    // FINAL OUTPUT IS FP32.
    gemm_v<unsigned short, 1><<<dim3(32, 16), 256, 0, stream>>>(mlp, Wout, bout, X1, (float*)d_out, 2048, 1024, 4096);
}

// Round 3
// 1239.252 us; speedup vs baseline: 2.9854x; 1.4556x over previous
//
#include <hip/hip_runtime.h>

#define LAMBDA_INIT 0.2f
#define SCALING 0.17677669529663687f   // 1/sqrt(32)
#define EPS_DEF 1.1920928955078125e-07f
#define EPS_ATTN 1e-5f

typedef unsigned short us4 __attribute__((ext_vector_type(4)));
typedef unsigned short us8v __attribute__((ext_vector_type(8)));
typedef float f32x4 __attribute__((ext_vector_type(4)));
typedef float f32x2 __attribute__((ext_vector_type(2)));
typedef __bf16 bf16x8 __attribute__((ext_vector_type(8)));

__device__ __forceinline__ float bf2f(unsigned short u) {
    unsigned int x = ((unsigned int)u) << 16;
    return __builtin_bit_cast(float, x);
}
__device__ __forceinline__ unsigned short f2bf(float f) {
    unsigned int x = __builtin_bit_cast(unsigned int, f);
    x += 0x7fffu + ((x >> 16) & 1u);
    return (unsigned short)(x >> 16);
}
__device__ __forceinline__ float dot4(f32x4 a, f32x4 b) {
    return fmaf(a[0], b[0], fmaf(a[1], b[1], fmaf(a[2], b[2], a[3] * b[3])));
}

__device__ __forceinline__ float wave_sum(float v) {
#pragma unroll
    for (int o = 32; o > 0; o >>= 1) v += __shfl_down(v, o);
    return v;
}
__device__ __forceinline__ float block_sum(float v, float* red4) {
    int wv = threadIdx.x >> 6;
    float w = wave_sum(v);
    __syncthreads();
    if ((threadIdx.x & 63) == 0) red4[wv] = w;
    __syncthreads();
    return red4[0] + red4[1] + red4[2] + red4[3];
}

// ---------------- prep: zero G, compute lambda ----------------
__global__ __launch_bounds__(256) void prep(float* __restrict__ G, float* __restrict__ lamp,
                                            const float* lq1, const float* lk1,
                                            const float* lq2, const float* lk2) {
    int i = (blockIdx.x * 256 + threadIdx.x) * 4;
    G[i] = 0.f; G[i + 1] = 0.f; G[i + 2] = 0.f; G[i + 3] = 0.f;
    if (blockIdx.x == 0 && threadIdx.x == 0) {
        float a = 0.f, c = 0.f;
        for (int d = 0; d < 32; d++) {
            a += lq1[d] * lk1[d];
            c += lq2[d] * lk2[d];
        }
        *lamp = expf(a) - expf(c) + LAMBDA_INIT;
    }
}

// ---------------- RMSNorm: fp32 in, fp32 weight, fp32 or bf16 out ----------------
template <int OUTBF>
__global__ __launch_bounds__(256) void rms_kernel(const float* __restrict__ x,
                                                  const float* __restrict__ w,
                                                  void* __restrict__ out, float eps) {
    int row = blockIdx.x;
    int tid = threadIdx.x;
    size_t base = (size_t)row * 1024 + tid * 4;
    f32x4 v = *(const f32x4*)(x + base);
    float ss = v[0]*v[0] + v[1]*v[1] + v[2]*v[2] + v[3]*v[3];
    __shared__ float red4[4];
    float tot = block_sum(ss, red4);
    float r = rsqrtf(tot * (1.0f / 1024.f) + eps);
    f32x4 wv = *(const f32x4*)(w + tid * 4);
    if (OUTBF) {
        us4 o;
#pragma unroll
        for (int i = 0; i < 4; i++) o[i] = f2bf(v[i] * r * wv[i]);
        *(us4*)((unsigned short*)out + base) = o;
    } else {
        f32x4 o;
#pragma unroll
        for (int i = 0; i < 4; i++) o[i] = v[i] * r * wv[i];
        *(f32x4*)((float*)out + base) = o;
    }
}

// ---------------- VALU fp32 GEMM (known-good): C = A @ Bt^T + bias ----------------
// Used ONLY for QKV so the attention path keeps full fp32 precision.
__global__ __launch_bounds__(256) void gemm_v(const float* __restrict__ A,
                                              const float* __restrict__ Bt,
                                              const float* __restrict__ bias,
                                              float* __restrict__ out, int M, int N, int K) {
    __shared__ __align__(16) float As[16][68];
    __shared__ __align__(16) float Bs[16][68];
    const int tid = threadIdx.x;
    const int bm = blockIdx.x, bn = blockIdx.y;
    const int tx = tid & 15, ty = tid >> 4;
    const int r = tid >> 2, c = (tid & 3) * 4;
    const float* Ap = A + (size_t)(bm * 64 + r) * K + c;
    const float* Bp = Bt + (size_t)(bn * 64 + r) * K + c;
    float acc[4][4] = {{0.f}};
    for (int k0 = 0; k0 < K; k0 += 16) {
        f32x4 av4 = *(const f32x4*)(Ap + k0);
        f32x4 bv4 = *(const f32x4*)(Bp + k0);
        __syncthreads();
        As[c + 0][r] = av4[0]; As[c + 1][r] = av4[1]; As[c + 2][r] = av4[2]; As[c + 3][r] = av4[3];
        Bs[c + 0][r] = bv4[0]; Bs[c + 1][r] = bv4[1]; Bs[c + 2][r] = bv4[2]; Bs[c + 3][r] = bv4[3];
        __syncthreads();
#pragma unroll
        for (int kk = 0; kk < 16; kk++) {
            f32x4 av = *(const f32x4*)&As[kk][ty * 4];
            f32x4 bv = *(const f32x4*)&Bs[kk][tx * 4];
#pragma unroll
            for (int i = 0; i < 4; i++)
#pragma unroll
                for (int j = 0; j < 4; j++)
                    acc[i][j] = fmaf(av[i], bv[j], acc[i][j]);
        }
    }
#pragma unroll
    for (int i = 0; i < 4; i++) {
        int m = bm * 64 + ty * 4 + i;
#pragma unroll
        for (int j = 0; j < 4; j++) {
            int n = bn * 64 + tx * 4 + j;
            out[(size_t)m * N + n] = acc[i][j] + bias[n];
        }
    }
}

// =====================================================================
// bf16 MFMA GEMM:  out = A(bf16)[M,K] @ Bt(fp32->bf16 on the fly)[N,K]^T
//                  + bias + res.   BM=128, BN=64, BK=32, 4 waves (2x2).
// Fragment layouts (m89/m91-verified):
//   A: lane&15 = M-row, k = (lane>>4)*8 + j   (contiguous 16B in K)
//   B: lane&15 = N-col, k = (lane>>4)*8 + j
//   D: col = lane&15, row = (lane>>4)*4 + reg
// =====================================================================
__global__ __launch_bounds__(256) void gemm_mfma(const unsigned short* __restrict__ A,
                                                 const float* __restrict__ Bt,
                                                 const float* __restrict__ bias,
                                                 const float* __restrict__ res,
                                                 float* __restrict__ out,
                                                 int M, int N, int K) {
    __shared__ __align__(16) unsigned short As[128][40];
    __shared__ __align__(16) unsigned short Bs[64][40];
    const int t = threadIdx.x;
    const int bm = blockIdx.x, bn = blockIdx.y;
    const int lane = t & 63, w = t >> 6;
    const int wr = w >> 1, wc = w & 1;
    const int ar0 = t >> 2, asub = t & 3;   // staging: row, 16B chunk within row

    const unsigned short* Ag  = A + (size_t)(bm * 128 + ar0) * K + asub * 8;
    const unsigned short* Ag2 = Ag + (size_t)64 * K;
    const float* Bg = Bt + (size_t)(bn * 64 + ar0) * K + asub * 8;

    f32x4 acc[4][2] = {};

    for (int k0 = 0; k0 < K; k0 += 32) {
        us8v a0 = *(const us8v*)(Ag + k0);
        us8v a1 = *(const us8v*)(Ag2 + k0);
        f32x4 b0 = *(const f32x4*)(Bg + k0);
        f32x4 b1 = *(const f32x4*)(Bg + k0 + 4);
        us8v bw;
#pragma unroll
        for (int u = 0; u < 4; u++) { bw[u] = f2bf(b0[u]); bw[4 + u] = f2bf(b1[u]); }
        __syncthreads();
        *(us8v*)&As[ar0][asub * 8]      = a0;
        *(us8v*)&As[ar0 + 64][asub * 8] = a1;
        *(us8v*)&Bs[ar0][asub * 8]      = bw;
        __syncthreads();
        bf16x8 af[4], bf[2];
#pragma unroll
        for (int mi = 0; mi < 4; mi++)
            af[mi] = __builtin_bit_cast(bf16x8,
                *(const us8v*)&As[wr * 64 + mi * 16 + (lane & 15)][(lane >> 4) * 8]);
#pragma unroll
        for (int ni = 0; ni < 2; ni++)
            bf[ni] = __builtin_bit_cast(bf16x8,
                *(const us8v*)&Bs[wc * 32 + ni * 16 + (lane & 15)][(lane >> 4) * 8]);
#pragma unroll
        for (int mi = 0; mi < 4; mi++)
#pragma unroll
            for (int ni = 0; ni < 2; ni++)
                acc[mi][ni] = __builtin_amdgcn_mfma_f32_16x16x32_bf16(af[mi], bf[ni], acc[mi][ni], 0, 0, 0);
    }

    const int rbase = bm * 128 + wr * 64 + ((lane >> 4) << 2);
    const int cbase = bn * 64 + wc * 32 + (lane & 15);
#pragma unroll
    for (int mi = 0; mi < 4; mi++) {
#pragma unroll
        for (int ni = 0; ni < 2; ni++) {
            int col = cbase + ni * 16;
            float bb = bias[col];
#pragma unroll
            for (int r = 0; r < 4; r++) {
                int row = rbase + mi * 16 + r;
                size_t oi = (size_t)row * N + col;
                out[oi] = acc[mi][ni][r] + bb + res[oi];
            }
        }
    }
}

// ------- fused gate GEMM (MFMA): mlp = (h2@Wu^T+bu) * silu(h2@Wv^T+bv) -------
__global__ __launch_bounds__(256) void gemm_gate_mfma(const unsigned short* __restrict__ A,
                                                      const float* __restrict__ Wg,
                                                      const float* __restrict__ bg,
                                                      unsigned short* __restrict__ mlp) {
    __shared__ __align__(16) unsigned short As[128][40];
    __shared__ __align__(16) unsigned short BsU[64][40];
    __shared__ __align__(16) unsigned short BsV[64][40];
    const int t = threadIdx.x;
    const int bm = blockIdx.x, bn = blockIdx.y;
    const int lane = t & 63, w = t >> 6;
    const int wr = w >> 1, wc = w & 1;
    const int ar0 = t >> 2, asub = t & 3;

    const unsigned short* Ag  = A + (size_t)(bm * 128 + ar0) * 1024 + asub * 8;
    const unsigned short* Ag2 = Ag + (size_t)64 * 1024;
    const float* BgU = Wg + (size_t)(bn * 64 + ar0) * 1024 + asub * 8;
    const float* BgV = Wg + (size_t)(4096 + bn * 64 + ar0) * 1024 + asub * 8;

    f32x4 accU[4][2] = {};
    f32x4 accV[4][2] = {};

    for (int k0 = 0; k0 < 1024; k0 += 32) {
        us8v a0 = *(const us8v*)(Ag + k0);
        us8v a1 = *(const us8v*)(Ag2 + k0);
        f32x4 u0 = *(const f32x4*)(BgU + k0);
        f32x4 u1 = *(const f32x4*)(BgU + k0 + 4);
        f32x4 v0 = *(const f32x4*)(BgV + k0);
        f32x4 v1 = *(const f32x4*)(BgV + k0 + 4);
        us8v uw, vw;
#pragma unroll
        for (int u = 0; u < 4; u++) {
            uw[u] = f2bf(u0[u]); uw[4 + u] = f2bf(u1[u]);
            vw[u] = f2bf(v0[u]); vw[4 + u] = f2bf(v1[u]);
        }
        __syncthreads();
        *(us8v*)&As[ar0][asub * 8]      = a0;
        *(us8v*)&As[ar0 + 64][asub * 8] = a1;
        *(us8v*)&BsU[ar0][asub * 8]     = uw;
        *(us8v*)&BsV[ar0][asub * 8]     = vw;
        __syncthreads();
        bf16x8 af[4], bu[2], bv2[2];
#pragma unroll
        for (int mi = 0; mi < 4; mi++)
            af[mi] = __builtin_bit_cast(bf16x8,
                *(const us8v*)&As[wr * 64 + mi * 16 + (lane & 15)][(lane >> 4) * 8]);
#pragma unroll
        for (int ni = 0; ni < 2; ni++) {
            bu[ni] = __builtin_bit_cast(bf16x8,
                *(const us8v*)&BsU[wc * 32 + ni * 16 + (lane & 15)][(lane >> 4) * 8]);
            bv2[ni] = __builtin_bit_cast(bf16x8,
                *(const us8v*)&BsV[wc * 32 + ni * 16 + (lane & 15)][(lane >> 4) * 8]);
        }
#pragma unroll
        for (int mi = 0; mi < 4; mi++)
#pragma unroll
            for (int ni = 0; ni < 2; ni++) {
                accU[mi][ni] = __builtin_amdgcn_mfma_f32_16x16x32_bf16(af[mi], bu[ni], accU[mi][ni], 0, 0, 0);
                accV[mi][ni] = __builtin_amdgcn_mfma_f32_16x16x32_bf16(af[mi], bv2[ni], accV[mi][ni], 0, 0, 0);
            }
    }

    const int rbase = bm * 128 + wr * 64 + ((lane >> 4) << 2);
    const int cbase = bn * 64 + wc * 32 + (lane & 15);
#pragma unroll
    for (int mi = 0; mi < 4; mi++) {
#pragma unroll
        for (int ni = 0; ni < 2; ni++) {
            int col = cbase + ni * 16;
            float bu_ = bg[col], bv_ = bg[4096 + col];
#pragma unroll
            for (int r = 0; r < 4; r++) {
                int row = rbase + mi * 16 + r;
                float u = accU[mi][ni][r] + bu_;
                float v = accV[mi][ni][r] + bv_;
                float s = v / (1.f + __expf(-v));
                mlp[(size_t)row * 4096 + col] = f2bf(u * s);
            }
        }
    }
}

// ---------------- RoPE in place, token order ----------------
__global__ __launch_bounds__(256) void rope_inplace(float* __restrict__ Y,
                                                    const float* __restrict__ fc) {
    int t = blockIdx.x;
    int s = t & 1023;
    int p = s >> 2;
    if (p == 0) return;
    int c0 = threadIdx.x * 4;
    float* y = Y + (size_t)t * 1024 + c0;
    int d4 = (c0 & 31) >> 1;
    f32x4 f = *(const f32x4*)(fc + ((size_t)(p - 1) * 16 + d4) * 2);  // [cos,sin,cos,sin]
    float v0 = y[0], v1 = y[1], v2 = y[2], v3 = y[3];
    y[0] = v0 * f[0] - v1 * f[1];
    y[1] = v0 * f[1] + v1 * f[0];
    y[2] = v2 * f[2] - v3 * f[3];
    y[3] = v2 * f[3] + v3 * f[2];
}

// =====================================================================
// Tiled attention (unchanged from the passing round-1 kernel).
// =====================================================================

// ---------------- pass A (tiled): denominators Z1/Z2 + G ----------------
__global__ __launch_bounds__(256) void pass_a_t(const float* __restrict__ Yq,
                                                const float* __restrict__ Yk,
                                                float* __restrict__ G,
                                                float* __restrict__ MZ) {
    const int qc = blockIdx.x, h = blockIdx.y, b = blockIdx.z;
    const int t = threadIdx.x;
    const int r = t >> 2, sub = t & 3;
    const int cs = sub << 4;
    const int tq = qc * 64 + r;          // token index of this thread's q-row
    const int pq = tq >> 2;              // position within 256-period
    const int nsq = tq & 3;              // sequence id
    const int qrow = (nsq << 8) + pq;    // attention row index q'

    __shared__ __align__(16) float Ks[64][68];
    __shared__ float At[64][65];
    __shared__ float Pc[4][64];
    __shared__ float Gacc[1024];

    for (int i = t; i < 1024; i += 256) Gacc[i] = 0.f;

    f32x4 q[16];
    const f32x4* qp = (const f32x4*)(Yq + (((size_t)(b * 1024 + tq)) << 10) + h * 64);
#pragma unroll
    for (int i = 0; i < 16; i++) q[i] = qp[i];

    const float* Ykb = Yk + ((size_t)b << 20) + h * 64;

    float z1 = 0.f, z2 = 0.f;
    // -------- sweep 1: denominators (both halves) --------
    for (int kc = 0; kc <= qc; kc++) {
        __syncthreads();
        {
            const float* kp_ = Ykb + (((size_t)(kc * 64 + r)) << 10) + cs;
            *(f32x4*)&Ks[r][cs]      = *(const f32x4*)(kp_);
            *(f32x4*)&Ks[r][cs + 4]  = *(const f32x4*)(kp_ + 4);
            *(f32x4*)&Ks[r][cs + 8]  = *(const f32x4*)(kp_ + 8);
            *(f32x4*)&Ks[r][cs + 12] = *(const f32x4*)(kp_ + 12);
        }
        __syncthreads();
        const int kp0 = kc * 16;
#pragma unroll 4
        for (int i = 0; i < 16; i++) {
            const int ltk = (sub << 4) + i;
            const f32x4* kr = (const f32x4*)&Ks[ltk][0];
            float s1 = 0.f, s2 = 0.f;
#pragma unroll
            for (int c8 = 0; c8 < 8; c8++) {
                s1 += dot4(q[c8], kr[c8]);
                s2 += dot4(q[8 + c8], kr[8 + c8]);
            }
            if ((kp0 + (ltk >> 2)) <= pq) {
                z1 += __expf(fabsf(s1 * SCALING));
                z2 += __expf(fabsf(s2 * SCALING));
            }
        }
    }
    float Z1 = z1; Z1 += __shfl_xor(Z1, 1); Z1 += __shfl_xor(Z1, 2);
    float Z2 = z2; Z2 += __shfl_xor(Z2, 1); Z2 += __shfl_xor(Z2, 2);
    if (sub == 0) {
        f32x2 zz; zz[0] = Z1; zz[1] = Z2;
        *(f32x2*)(MZ + (((size_t)(b * 16 + h) << 10) + qrow) * 2) = zz;
    }
    const float i1 = 1.f / fmaxf(Z1, 1e-20f);

    // -------- sweep 2: a1 values -> column sums -> G --------
    for (int kc = 0; kc <= qc; kc++) {
        __syncthreads();
        {
            const float* kp_ = Ykb + (((size_t)(kc * 64 + r)) << 10) + cs;
            *(f32x4*)&Ks[r][cs]      = *(const f32x4*)(kp_);
            *(f32x4*)&Ks[r][cs + 4]  = *(const f32x4*)(kp_ + 4);
            *(f32x4*)&Ks[r][cs + 8]  = *(const f32x4*)(kp_ + 8);
            *(f32x4*)&Ks[r][cs + 12] = *(const f32x4*)(kp_ + 12);
        }
        __syncthreads();
        const int kp0 = kc * 16;
#pragma unroll 4
        for (int i = 0; i < 16; i++) {
            const int ltk = (sub << 4) + i;
            const f32x4* kr = (const f32x4*)&Ks[ltk][0];
            float s1 = 0.f;
#pragma unroll
            for (int c8 = 0; c8 < 8; c8++) s1 += dot4(q[c8], kr[c8]);
            s1 *= SCALING;
            float a = 0.f;
            if ((kp0 + (ltk >> 2)) <= pq) {
                float sg = (s1 > 0.f) ? 1.f : ((s1 < 0.f) ? -1.f : 0.f);
                a = sg * __expf(fabsf(s1)) * i1;
            }
            At[r][ltk] = a;
        }
        __syncthreads();
        {
            const int kcol = t & 63, rq = t >> 6;
            float csum = 0.f;
#pragma unroll
            for (int rr = 0; rr < 16; rr++) csum += At[rq * 16 + rr][kcol];
            Pc[rq][kcol] = csum;
        }
        __syncthreads();
        if (t < 64) Gacc[kc * 64 + t] = Pc[0][t] + Pc[1][t] + Pc[2][t] + Pc[3][t];
    }
    __syncthreads();
    float* Gb = G + ((size_t)(b * 16 + h) << 10);
    const int lim = (qc + 1) * 64;
    for (int idx = t; idx < lim; idx += 256) {
        int j = ((idx & 3) << 8) + (idx >> 2);   // token -> attention index
        atomicAdd(&Gb[j], Gacc[idx]);
    }
}

// ---------------- pass B (tiled): attention + AV + RMS + store ----------------
__global__ __launch_bounds__(256) void pass_b_t(const float* __restrict__ Yq,
                                                const float* __restrict__ Yk,
                                                const float* __restrict__ Yv,
                                                const float* __restrict__ G,
                                                const float* __restrict__ MZ,
                                                const float* __restrict__ lamp,
                                                const float* __restrict__ wan,
                                                unsigned short* __restrict__ aoS) {
    const int qc = blockIdx.x, h = blockIdx.y, b = blockIdx.z;
    const int t = threadIdx.x;
    const int r = t >> 2, sub = t & 3;
    const int cs = sub << 4;
    const int tq = qc * 64 + r;
    const int pq = tq >> 2;
    const int nsq = tq & 3;
    const int qrow = (nsq << 8) + pq;

    __shared__ __align__(16) float Ks[64][68];
    __shared__ __align__(16) float Vs[64][68];
    __shared__ float At[64][65];
    __shared__ float Gs[64];

    f32x4 q[16];
    const f32x4* qp = (const f32x4*)(Yq + (((size_t)(b * 1024 + tq)) << 10) + h * 64);
#pragma unroll
    for (int i = 0; i < 16; i++) q[i] = qp[i];

    f32x2 zz = *(const f32x2*)(MZ + (((size_t)(b * 16 + h) << 10) + qrow) * 2);
    const float i1 = 1.f / fmaxf(zz[0], 1e-20f);
    const float i2 = 1.f / fmaxf(zz[1], 1e-20f);
    const float lam = *lamp;
    const float lamg = lam * (1.f / 1024.f);

    const float* Ykb = Yk + ((size_t)b << 20) + h * 64;
    const float* Yvb = Yv + ((size_t)b << 20) + h * 64;
    const float* Gb = G + ((size_t)(b * 16 + h) << 10);

    f32x4 acc0 = {0.f, 0.f, 0.f, 0.f};
    f32x4 acc1 = {0.f, 0.f, 0.f, 0.f};
    f32x4 acc2 = {0.f, 0.f, 0.f, 0.f};
    f32x4 acc3 = {0.f, 0.f, 0.f, 0.f};

    for (int kc = 0; kc <= qc; kc++) {
        __syncthreads();
        {
            const float* kp_ = Ykb + (((size_t)(kc * 64 + r)) << 10) + cs;
            *(f32x4*)&Ks[r][cs]      = *(const f32x4*)(kp_);
            *(f32x4*)&Ks[r][cs + 4]  = *(const f32x4*)(kp_ + 4);
            *(f32x4*)&Ks[r][cs + 8]  = *(const f32x4*)(kp_ + 8);
            *(f32x4*)&Ks[r][cs + 12] = *(const f32x4*)(kp_ + 12);
            // V row for attention index j is RAW index j (reference quirk)
            const int jv = ((r & 3) << 8) + kc * 16 + (r >> 2);
            const float* vp_ = Yvb + ((size_t)jv << 10) + cs;
            *(f32x4*)&Vs[r][cs]      = *(const f32x4*)(vp_);
            *(f32x4*)&Vs[r][cs + 4]  = *(const f32x4*)(vp_ + 4);
            *(f32x4*)&Vs[r][cs + 8]  = *(const f32x4*)(vp_ + 8);
            *(f32x4*)&Vs[r][cs + 12] = *(const f32x4*)(vp_ + 12);
            if (t < 64) Gs[t] = Gb[((t & 3) << 8) + kc * 16 + (t >> 2)];
        }
        __syncthreads();
        const int kp0 = kc * 16;
#pragma unroll 4
        for (int i = 0; i < 16; i++) {
            const int ltk = (sub << 4) + i;
            const f32x4* kr = (const f32x4*)&Ks[ltk][0];
            float s1 = 0.f, s2 = 0.f;
#pragma unroll
            for (int c8 = 0; c8 < 8; c8++) {
                s1 += dot4(q[c8], kr[c8]);
                s2 += dot4(q[8 + c8], kr[8 + c8]);
            }
            s1 *= SCALING; s2 *= SCALING;
            float a = 0.f;
            if ((kp0 + (ltk >> 2)) <= pq) {
                float sg1 = (s1 > 0.f) ? 1.f : ((s1 < 0.f) ? -1.f : 0.f);
                float sg2 = (s2 > 0.f) ? 1.f : ((s2 < 0.f) ? -1.f : 0.f);
                a = sg1 * __expf(fabsf(s1)) * i1
                  - lam * (sg2 * __expf(fabsf(s2)) * i2)
                  + lamg * Gs[ltk];
            }
            At[r][ltk] = a;
        }
        __syncthreads();
#pragma unroll 8
        for (int k2 = 0; k2 < 64; k2++) {
            float a = At[r][k2];
            const f32x4* vr = (const f32x4*)&Vs[k2][cs];
            acc0 += vr[0] * a;
            acc1 += vr[1] * a;
            acc2 += vr[2] * a;
            acc3 += vr[3] * a;
        }
    }

    // fused RMS over the 64-dim head + bf16 store (scrambled reshape layout)
    float ss = acc0[0]*acc0[0] + acc0[1]*acc0[1] + acc0[2]*acc0[2] + acc0[3]*acc0[3]
             + acc1[0]*acc1[0] + acc1[1]*acc1[1] + acc1[2]*acc1[2] + acc1[3]*acc1[3]
             + acc2[0]*acc2[0] + acc2[1]*acc2[1] + acc2[2]*acc2[2] + acc2[3]*acc2[3]
             + acc3[0]*acc3[0] + acc3[1]*acc3[1] + acc3[2]*acc3[2] + acc3[3]*acc3[3];
    ss += __shfl_xor(ss, 1);
    ss += __shfl_xor(ss, 2);
    const float rr_ = rsqrtf(ss * (1.f / 64.f) + EPS_ATTN);
    const f32x4* wv = (const f32x4*)(wan + cs);
    unsigned short* op = aoS + ((size_t)b << 20) + ((size_t)h << 16) + ((size_t)qrow << 6) + cs;
    {
        f32x4 w0 = wv[0], w1 = wv[1], w2 = wv[2], w3 = wv[3];
        us4 o0, o1, o2, o3;
#pragma unroll
        for (int u = 0; u < 4; u++) {
            o0[u] = f2bf(acc0[u] * rr_ * w0[u]);
            o1[u] = f2bf(acc1[u] * rr_ * w1[u]);
            o2[u] = f2bf(acc2[u] * rr_ * w2[u]);
            o3[u] = f2bf(acc3[u] * rr_ * w3[u]);
        }
        ((us4*)op)[0] = o0; ((us4*)op)[1] = o1; ((us4*)op)[2] = o2; ((us4*)op)[3] = o3;
    }
}

extern "C" void kernel_launch(void* const* d_in, const int* in_sizes, int n_in,
                              void* d_out, int out_size, void* d_ws, size_t ws_size,
                              hipStream_t stream) {
    const float* x    = (const float*)d_in[0];
    const float* fc   = (const float*)d_in[1];
    const float* w1   = (const float*)d_in[2];
    const float* w2   = (const float*)d_in[3];
    const float* Wq   = (const float*)d_in[4];
    const float* bq   = (const float*)d_in[5];
    const float* Wk   = (const float*)d_in[6];
    const float* bk   = (const float*)d_in[7];
    const float* Wv   = (const float*)d_in[8];
    const float* bv   = (const float*)d_in[9];
    const float* Wo   = (const float*)d_in[10];
    const float* bo   = (const float*)d_in[11];
    const float* lq1  = (const float*)d_in[12];
    const float* lk1  = (const float*)d_in[13];
    const float* lq2  = (const float*)d_in[14];
    const float* lk2  = (const float*)d_in[15];
    const float* wan  = (const float*)d_in[16];
    const float* Wg   = (const float*)d_in[17];
    const float* bg   = (const float*)d_in[18];
    const float* Wout = (const float*)d_in[19];
    const float* bout = (const float*)d_in[20];

    char* ws = (char*)d_ws;
    const size_t MB = 1024 * 1024;
    // Layout (peak 33 MB, identical to the proven round-1 layout):
    float* G    = (float*)(ws);                     // [0, 128K)
    float* lam  = (float*)(ws + 256 * 1024);        // 4 B
    float* MZ   = (float*)(ws + 384 * 1024);        // [384K, 640K)
    float* h32  = (float*)(ws + 1 * MB);            // [1,9)   fp32 2048x1024
    float* Yq   = (float*)(ws + 9 * MB);            // [9,17)
    float* Yk   = (float*)(ws + 17 * MB);           // [17,25)
    float* Yv   = (float*)(ws + 25 * MB);           // [25,33)
    unsigned short* aoS = (unsigned short*)(ws + 1 * MB);   // reuse [1,5)  (h32 dead after QKV)
    float* X1           = (float*)(ws + 9 * MB);            // reuse [9,17) (Yq dead after pass_b)
    unsigned short* h2b = (unsigned short*)(ws + 1 * MB);   // reuse [1,5)  (aoS dead after Wo gemm)
    unsigned short* mlp = (unsigned short*)(ws + 17 * MB);  // reuse [17,33) (Yk/Yv dead)

    prep<<<32, 256, 0, stream>>>(G, lam, lq1, lk1, lq2, lk2);
    rms_kernel<0><<<2048, 256, 0, stream>>>(x, w1, h32, EPS_DEF);
    // QKV in full fp32 (VALU) -> attention path numerically identical to round 1.
    dim3 gqkv(32, 16);
    gemm_v<<<gqkv, 256, 0, stream>>>(h32, Wq, bq, Yq, 2048, 1024, 1024);
    gemm_v<<<gqkv, 256, 0, stream>>>(h32, Wk, bk, Yk, 2048, 1024, 1024);
    gemm_v<<<gqkv, 256, 0, stream>>>(h32, Wv, bv, Yv, 2048, 1024, 1024);
    rope_inplace<<<2048, 256, 0, stream>>>(Yq, fc);
    rope_inplace<<<2048, 256, 0, stream>>>(Yk, fc);
    pass_a_t<<<dim3(16, 16, 2), 256, 0, stream>>>(Yq, Yk, G, MZ);
    pass_b_t<<<dim3(16, 16, 2), 256, 0, stream>>>(Yq, Yk, Yv, G, MZ, lam, wan, aoS);
    // Post-attention GEMMs on the matrix cores (weights bf16-rounded on the fly).
    dim3 gmf(16, 16);
    gemm_mfma<<<gmf, 256, 0, stream>>>(aoS, Wo, bo, x, X1, 2048, 1024, 1024);
    rms_kernel<1><<<2048, 256, 0, stream>>>(X1, w2, h2b, EPS_DEF);
    gemm_gate_mfma<<<dim3(16, 64), 256, 0, stream>>>(h2b, Wg, bg, mlp);
    // FINAL OUTPUT IS FP32.
    gemm_mfma<<<gmf, 256, 0, stream>>>(mlp, Wout, bout, X1, (float*)d_out, 2048, 1024, 4096);
}

// Round 4
// 879.503 us; speedup vs baseline: 4.2066x; 1.4090x over previous
//
#include <hip/hip_runtime.h>

#define LAMBDA_INIT 0.2f
#define SCALING 0.17677669529663687f   // 1/sqrt(32)
#define EPS_DEF 1.1920928955078125e-07f
#define EPS_ATTN 1e-5f

typedef unsigned short us4 __attribute__((ext_vector_type(4)));
typedef unsigned short us8v __attribute__((ext_vector_type(8)));
typedef float f32x4 __attribute__((ext_vector_type(4)));
typedef float f32x2 __attribute__((ext_vector_type(2)));
typedef __bf16 bf16x8 __attribute__((ext_vector_type(8)));

__device__ __forceinline__ float bf2f(unsigned short u) {
    unsigned int x = ((unsigned int)u) << 16;
    return __builtin_bit_cast(float, x);
}
__device__ __forceinline__ unsigned short f2bf(float f) {
    unsigned int x = __builtin_bit_cast(unsigned int, f);
    x += 0x7fffu + ((x >> 16) & 1u);
    return (unsigned short)(x >> 16);
}
__device__ __forceinline__ float dot4(f32x4 a, f32x4 b) {
    return fmaf(a[0], b[0], fmaf(a[1], b[1], fmaf(a[2], b[2], a[3] * b[3])));
}

__device__ __forceinline__ float wave_sum(float v) {
#pragma unroll
    for (int o = 32; o > 0; o >>= 1) v += __shfl_down(v, o);
    return v;
}
__device__ __forceinline__ float block_sum(float v, float* red4) {
    int wv = threadIdx.x >> 6;
    float w = wave_sum(v);
    __syncthreads();
    if ((threadIdx.x & 63) == 0) red4[wv] = w;
    __syncthreads();
    return red4[0] + red4[1] + red4[2] + red4[3];
}

// ---------------- prep: zero G, compute lambda ----------------
__global__ __launch_bounds__(256) void prep(float* __restrict__ G, float* __restrict__ lamp,
                                            const float* lq1, const float* lk1,
                                            const float* lq2, const float* lk2) {
    int i = (blockIdx.x * 256 + threadIdx.x) * 4;
    G[i] = 0.f; G[i + 1] = 0.f; G[i + 2] = 0.f; G[i + 3] = 0.f;
    if (blockIdx.x == 0 && threadIdx.x == 0) {
        float a = 0.f, c = 0.f;
        for (int d = 0; d < 32; d++) {
            a += lq1[d] * lk1[d];
            c += lq2[d] * lk2[d];
        }
        *lamp = expf(a) - expf(c) + LAMBDA_INIT;
    }
}

// ---------------- RMSNorm: fp32 in, fp32 weight, fp32 or bf16 out ----------------
template <int OUTBF>
__global__ __launch_bounds__(256) void rms_kernel(const float* __restrict__ x,
                                                  const float* __restrict__ w,
                                                  void* __restrict__ out, float eps) {
    int row = blockIdx.x;
    int tid = threadIdx.x;
    size_t base = (size_t)row * 1024 + tid * 4;
    f32x4 v = *(const f32x4*)(x + base);
    float ss = v[0]*v[0] + v[1]*v[1] + v[2]*v[2] + v[3]*v[3];
    __shared__ float red4[4];
    float tot = block_sum(ss, red4);
    float r = rsqrtf(tot * (1.0f / 1024.f) + eps);
    f32x4 wv = *(const f32x4*)(w + tid * 4);
    if (OUTBF) {
        us4 o;
#pragma unroll
        for (int i = 0; i < 4; i++) o[i] = f2bf(v[i] * r * wv[i]);
        *(us4*)((unsigned short*)out + base) = o;
    } else {
        f32x4 o;
#pragma unroll
        for (int i = 0; i < 4; i++) o[i] = v[i] * r * wv[i];
        *(f32x4*)((float*)out + base) = o;
    }
}

// ---------------- VALU fp32 GEMM (known-good): C = A @ Bt^T + bias ----------------
// Used ONLY for QKV so the attention path keeps full fp32 precision.
__global__ __launch_bounds__(256) void gemm_v(const float* __restrict__ A,
                                              const float* __restrict__ Bt,
                                              const float* __restrict__ bias,
                                              float* __restrict__ out, int M, int N, int K) {
    __shared__ __align__(16) float As[16][68];
    __shared__ __align__(16) float Bs[16][68];
    const int tid = threadIdx.x;
    const int bm = blockIdx.x, bn = blockIdx.y;
    const int tx = tid & 15, ty = tid >> 4;
    const int r = tid >> 2, c = (tid & 3) * 4;
    const float* Ap = A + (size_t)(bm * 64 + r) * K + c;
    const float* Bp = Bt + (size_t)(bn * 64 + r) * K + c;
    float acc[4][4] = {{0.f}};
    for (int k0 = 0; k0 < K; k0 += 16) {
        f32x4 av4 = *(const f32x4*)(Ap + k0);
        f32x4 bv4 = *(const f32x4*)(Bp + k0);
        __syncthreads();
        As[c + 0][r] = av4[0]; As[c + 1][r] = av4[1]; As[c + 2][r] = av4[2]; As[c + 3][r] = av4[3];
        Bs[c + 0][r] = bv4[0]; Bs[c + 1][r] = bv4[1]; Bs[c + 2][r] = bv4[2]; Bs[c + 3][r] = bv4[3];
        __syncthreads();
#pragma unroll
        for (int kk = 0; kk < 16; kk++) {
            f32x4 av = *(const f32x4*)&As[kk][ty * 4];
            f32x4 bv = *(const f32x4*)&Bs[kk][tx * 4];
#pragma unroll
            for (int i = 0; i < 4; i++)
#pragma unroll
                for (int j = 0; j < 4; j++)
                    acc[i][j] = fmaf(av[i], bv[j], acc[i][j]);
        }
    }
#pragma unroll
    for (int i = 0; i < 4; i++) {
        int m = bm * 64 + ty * 4 + i;
#pragma unroll
        for (int j = 0; j < 4; j++) {
            int n = bn * 64 + tx * 4 + j;
            out[(size_t)m * N + n] = acc[i][j] + bias[n];
        }
    }
}

// =====================================================================
// bf16 MFMA GEMM:  out = A(bf16)[M,K] @ Bt(fp32->bf16 on the fly)[N,K]^T
//                  + bias + res.   BM=128, BN=64, BK=32, 4 waves (2x2).
// =====================================================================
__global__ __launch_bounds__(256) void gemm_mfma(const unsigned short* __restrict__ A,
                                                 const float* __restrict__ Bt,
                                                 const float* __restrict__ bias,
                                                 const float* __restrict__ res,
                                                 float* __restrict__ out,
                                                 int M, int N, int K) {
    __shared__ __align__(16) unsigned short As[128][40];
    __shared__ __align__(16) unsigned short Bs[64][40];
    const int t = threadIdx.x;
    const int bm = blockIdx.x, bn = blockIdx.y;
    const int lane = t & 63, w = t >> 6;
    const int wr = w >> 1, wc = w & 1;
    const int ar0 = t >> 2, asub = t & 3;

    const unsigned short* Ag  = A + (size_t)(bm * 128 + ar0) * K + asub * 8;
    const unsigned short* Ag2 = Ag + (size_t)64 * K;
    const float* Bg = Bt + (size_t)(bn * 64 + ar0) * K + asub * 8;

    f32x4 acc[4][2] = {};

    for (int k0 = 0; k0 < K; k0 += 32) {
        us8v a0 = *(const us8v*)(Ag + k0);
        us8v a1 = *(const us8v*)(Ag2 + k0);
        f32x4 b0 = *(const f32x4*)(Bg + k0);
        f32x4 b1 = *(const f32x4*)(Bg + k0 + 4);
        us8v bw;
#pragma unroll
        for (int u = 0; u < 4; u++) { bw[u] = f2bf(b0[u]); bw[4 + u] = f2bf(b1[u]); }
        __syncthreads();
        *(us8v*)&As[ar0][asub * 8]      = a0;
        *(us8v*)&As[ar0 + 64][asub * 8] = a1;
        *(us8v*)&Bs[ar0][asub * 8]      = bw;
        __syncthreads();
        bf16x8 af[4], bf[2];
#pragma unroll
        for (int mi = 0; mi < 4; mi++)
            af[mi] = __builtin_bit_cast(bf16x8,
                *(const us8v*)&As[wr * 64 + mi * 16 + (lane & 15)][(lane >> 4) * 8]);
#pragma unroll
        for (int ni = 0; ni < 2; ni++)
            bf[ni] = __builtin_bit_cast(bf16x8,
                *(const us8v*)&Bs[wc * 32 + ni * 16 + (lane & 15)][(lane >> 4) * 8]);
#pragma unroll
        for (int mi = 0; mi < 4; mi++)
#pragma unroll
            for (int ni = 0; ni < 2; ni++)
                acc[mi][ni] = __builtin_amdgcn_mfma_f32_16x16x32_bf16(af[mi], bf[ni], acc[mi][ni], 0, 0, 0);
    }

    const int rbase = bm * 128 + wr * 64 + ((lane >> 4) << 2);
    const int cbase = bn * 64 + wc * 32 + (lane & 15);
#pragma unroll
    for (int mi = 0; mi < 4; mi++) {
#pragma unroll
        for (int ni = 0; ni < 2; ni++) {
            int col = cbase + ni * 16;
            float bb = bias[col];
#pragma unroll
            for (int r = 0; r < 4; r++) {
                int row = rbase + mi * 16 + r;
                size_t oi = (size_t)row * N + col;
                out[oi] = acc[mi][ni][r] + bb + res[oi];
            }
        }
    }
}

// ------- fused gate GEMM (MFMA): mlp = (h2@Wu^T+bu) * silu(h2@Wv^T+bv) -------
__global__ __launch_bounds__(256) void gemm_gate_mfma(const unsigned short* __restrict__ A,
                                                      const float* __restrict__ Wg,
                                                      const float* __restrict__ bg,
                                                      unsigned short* __restrict__ mlp) {
    __shared__ __align__(16) unsigned short As[128][40];
    __shared__ __align__(16) unsigned short BsU[64][40];
    __shared__ __align__(16) unsigned short BsV[64][40];
    const int t = threadIdx.x;
    const int bm = blockIdx.x, bn = blockIdx.y;
    const int lane = t & 63, w = t >> 6;
    const int wr = w >> 1, wc = w & 1;
    const int ar0 = t >> 2, asub = t & 3;

    const unsigned short* Ag  = A + (size_t)(bm * 128 + ar0) * 1024 + asub * 8;
    const unsigned short* Ag2 = Ag + (size_t)64 * 1024;
    const float* BgU = Wg + (size_t)(bn * 64 + ar0) * 1024 + asub * 8;
    const float* BgV = Wg + (size_t)(4096 + bn * 64 + ar0) * 1024 + asub * 8;

    f32x4 accU[4][2] = {};
    f32x4 accV[4][2] = {};

    for (int k0 = 0; k0 < 1024; k0 += 32) {
        us8v a0 = *(const us8v*)(Ag + k0);
        us8v a1 = *(const us8v*)(Ag2 + k0);
        f32x4 u0 = *(const f32x4*)(BgU + k0);
        f32x4 u1 = *(const f32x4*)(BgU + k0 + 4);
        f32x4 v0 = *(const f32x4*)(BgV + k0);
        f32x4 v1 = *(const f32x4*)(BgV + k0 + 4);
        us8v uw, vw;
#pragma unroll
        for (int u = 0; u < 4; u++) {
            uw[u] = f2bf(u0[u]); uw[4 + u] = f2bf(u1[u]);
            vw[u] = f2bf(v0[u]); vw[4 + u] = f2bf(v1[u]);
        }
        __syncthreads();
        *(us8v*)&As[ar0][asub * 8]      = a0;
        *(us8v*)&As[ar0 + 64][asub * 8] = a1;
        *(us8v*)&BsU[ar0][asub * 8]     = uw;
        *(us8v*)&BsV[ar0][asub * 8]     = vw;
        __syncthreads();
        bf16x8 af[4], bu[2], bv2[2];
#pragma unroll
        for (int mi = 0; mi < 4; mi++)
            af[mi] = __builtin_bit_cast(bf16x8,
                *(const us8v*)&As[wr * 64 + mi * 16 + (lane & 15)][(lane >> 4) * 8]);
#pragma unroll
        for (int ni = 0; ni < 2; ni++) {
            bu[ni] = __builtin_bit_cast(bf16x8,
                *(const us8v*)&BsU[wc * 32 + ni * 16 + (lane & 15)][(lane >> 4) * 8]);
            bv2[ni] = __builtin_bit_cast(bf16x8,
                *(const us8v*)&BsV[wc * 32 + ni * 16 + (lane & 15)][(lane >> 4) * 8]);
        }
#pragma unroll
        for (int mi = 0; mi < 4; mi++)
#pragma unroll
            for (int ni = 0; ni < 2; ni++) {
                accU[mi][ni] = __builtin_amdgcn_mfma_f32_16x16x32_bf16(af[mi], bu[ni], accU[mi][ni], 0, 0, 0);
                accV[mi][ni] = __builtin_amdgcn_mfma_f32_16x16x32_bf16(af[mi], bv2[ni], accV[mi][ni], 0, 0, 0);
            }
    }

    const int rbase = bm * 128 + wr * 64 + ((lane >> 4) << 2);
    const int cbase = bn * 64 + wc * 32 + (lane & 15);
#pragma unroll
    for (int mi = 0; mi < 4; mi++) {
#pragma unroll
        for (int ni = 0; ni < 2; ni++) {
            int col = cbase + ni * 16;
            float bu_ = bg[col], bv_ = bg[4096 + col];
#pragma unroll
            for (int r = 0; r < 4; r++) {
                int row = rbase + mi * 16 + r;
                float u = accU[mi][ni][r] + bu_;
                float v = accV[mi][ni][r] + bv_;
                float s = v / (1.f + __expf(-v));
                mlp[(size_t)row * 4096 + col] = f2bf(u * s);
            }
        }
    }
}

// ---------------- RoPE in place, token order ----------------
__global__ __launch_bounds__(256) void rope_inplace(float* __restrict__ Y,
                                                    const float* __restrict__ fc) {
    int t = blockIdx.x;
    int s = t & 1023;
    int p = s >> 2;
    if (p == 0) return;
    int c0 = threadIdx.x * 4;
    float* y = Y + (size_t)t * 1024 + c0;
    int d4 = (c0 & 31) >> 1;
    f32x4 f = *(const f32x4*)(fc + ((size_t)(p - 1) * 16 + d4) * 2);  // [cos,sin,cos,sin]
    float v0 = y[0], v1 = y[1], v2 = y[2], v3 = y[3];
    y[0] = v0 * f[0] - v1 * f[1];
    y[1] = v0 * f[1] + v1 * f[0];
    y[2] = v2 * f[2] - v3 * f[3];
    y[3] = v2 * f[3] + v3 * f[2];
}

// =====================================================================
// Fused attention pass_1. One block = 64 consecutive TOKENS of Q for one
// (b,h). 1D grid 512, heavy-first: qc = 15 - (blk>>5) (work ~ qc+1).
// Sweep 1: Z1,Z2 denominators (per q-row, via 4-lane shfl).
// Sweep 2: w = a1 - lam*a2 weights -> At tile; a1 column sums -> Gacc via
//          shfl tree + LDS atomics; AV accumulate -> AOp (fp32, partial ao
//          WITHOUT the G-term, which pass_2 adds as a position-prefix).
// K tiles XOR-swizzled (slot ^= row>>4) -> conflict-free QK reads.
// =====================================================================
__global__ __launch_bounds__(256) void pass_1(const float* __restrict__ Yq,
                                              const float* __restrict__ Yk,
                                              const float* __restrict__ Yv,
                                              const float* __restrict__ lamp,
                                              float* __restrict__ G,
                                              float* __restrict__ AOp) {
    const int blk = blockIdx.x;
    const int qc = 15 - (blk >> 5);
    const int h  = blk & 15;
    const int b  = (blk >> 4) & 1;
    const int t = threadIdx.x;
    const int r = t >> 2, sub = t & 3;
    const int cs = sub << 4;              // dim offset AND local-token base
    const int tq = qc * 64 + r;
    const int pq = tq >> 2;
    const int nsq = tq & 3;
    const int qrow = (nsq << 8) + pq;

    __shared__ __align__(16) float Ks[64][68];
    __shared__ __align__(16) float Vs[64][68];
    __shared__ float At[64][65];
    __shared__ float Gacc[1024];

    for (int i = t; i < 1024; i += 256) Gacc[i] = 0.f;

    f32x4 q[16];
    const f32x4* qp = (const f32x4*)(Yq + (((size_t)(b * 1024 + tq)) << 10) + h * 64);
#pragma unroll
    for (int i = 0; i < 16; i++) q[i] = qp[i];

    const float* Ykb = Yk + ((size_t)b << 20) + h * 64;
    const float* Yvb = Yv + ((size_t)b << 20) + h * 64;
    const int swz = r >> 4;

    // -------- sweep 1: denominators --------
    float z1 = 0.f, z2 = 0.f;
    for (int kc = 0; kc <= qc; kc++) {
        __syncthreads();
        {
            const float* kp_ = Ykb + (((size_t)(kc * 64 + r)) << 10) + cs;
#pragma unroll
            for (int j = 0; j < 4; j++)
                *(f32x4*)&Ks[r][(((sub << 2) + j) ^ swz) << 2] = *(const f32x4*)(kp_ + (j << 2));
        }
        __syncthreads();
        const int kp0 = kc * 16;
#pragma unroll 4
        for (int i = 0; i < 16; i++) {
            const int ltk = cs + i;
            const f32x4* kr = (const f32x4*)&Ks[ltk][0];
            float s1 = 0.f, s2 = 0.f;
#pragma unroll
            for (int c8 = 0; c8 < 8; c8++) {
                s1 += dot4(q[c8], kr[c8 ^ sub]);
                s2 += dot4(q[8 + c8], kr[8 + (c8 ^ sub)]);
            }
            if ((kp0 + (ltk >> 2)) <= pq) {
                z1 += __expf(fabsf(s1 * SCALING));
                z2 += __expf(fabsf(s2 * SCALING));
            }
        }
    }
    float Z1 = z1; Z1 += __shfl_xor(Z1, 1); Z1 += __shfl_xor(Z1, 2);
    float Z2 = z2; Z2 += __shfl_xor(Z2, 1); Z2 += __shfl_xor(Z2, 2);
    const float i1 = 1.f / fmaxf(Z1, 1e-20f);
    const float i2 = 1.f / fmaxf(Z2, 1e-20f);
    const float lam = *lamp;

    // -------- sweep 2: weights + colsums + AV --------
    f32x4 acc0 = {0.f, 0.f, 0.f, 0.f};
    f32x4 acc1 = {0.f, 0.f, 0.f, 0.f};
    f32x4 acc2 = {0.f, 0.f, 0.f, 0.f};
    f32x4 acc3 = {0.f, 0.f, 0.f, 0.f};

    for (int kc = 0; kc <= qc; kc++) {
        __syncthreads();
        {
            const float* kp_ = Ykb + (((size_t)(kc * 64 + r)) << 10) + cs;
#pragma unroll
            for (int j = 0; j < 4; j++)
                *(f32x4*)&Ks[r][(((sub << 2) + j) ^ swz) << 2] = *(const f32x4*)(kp_ + (j << 2));
            // V row for attention index j is RAW index j (reference quirk)
            const int jv = ((r & 3) << 8) + kc * 16 + (r >> 2);
            const float* vp_ = Yvb + ((size_t)jv << 10) + cs;
            *(f32x4*)&Vs[r][cs]      = *(const f32x4*)(vp_);
            *(f32x4*)&Vs[r][cs + 4]  = *(const f32x4*)(vp_ + 4);
            *(f32x4*)&Vs[r][cs + 8]  = *(const f32x4*)(vp_ + 8);
            *(f32x4*)&Vs[r][cs + 12] = *(const f32x4*)(vp_ + 12);
        }
        __syncthreads();
        const int kp0 = kc * 16;
#pragma unroll 4
        for (int i = 0; i < 16; i++) {
            const int ltk = cs + i;
            const f32x4* kr = (const f32x4*)&Ks[ltk][0];
            float s1 = 0.f, s2 = 0.f;
#pragma unroll
            for (int c8 = 0; c8 < 8; c8++) {
                s1 += dot4(q[c8], kr[c8 ^ sub]);
                s2 += dot4(q[8 + c8], kr[8 + (c8 ^ sub)]);
            }
            s1 *= SCALING; s2 *= SCALING;
            float a1v = 0.f, wv_ = 0.f;
            if ((kp0 + (ltk >> 2)) <= pq) {
                float sg1 = (s1 > 0.f) ? 1.f : ((s1 < 0.f) ? -1.f : 0.f);
                float sg2 = (s2 > 0.f) ? 1.f : ((s2 < 0.f) ? -1.f : 0.f);
                a1v = sg1 * __expf(fabsf(s1)) * i1;
                wv_ = a1v - lam * (sg2 * __expf(fabsf(s2)) * i2);
            }
            At[r][ltk] = wv_;
            // a1 column sum over the wave's 16 q-rows (stride-4 lanes share sub)
            float ca = a1v;
            ca += __shfl_xor(ca, 4);
            ca += __shfl_xor(ca, 8);
            ca += __shfl_xor(ca, 16);
            ca += __shfl_xor(ca, 32);
            if ((t & 63) < 4) atomicAdd(&Gacc[kc * 64 + ltk], ca);
        }
        __syncthreads();
#pragma unroll 8
        for (int k2 = 0; k2 < 64; k2++) {
            float a = At[r][k2];
            const f32x4* vr = (const f32x4*)&Vs[k2][cs];
            acc0 += vr[0] * a;
            acc1 += vr[1] * a;
            acc2 += vr[2] * a;
            acc3 += vr[3] * a;
        }
    }

    // partial ao (no G-term) -> AOp fp32
    {
        float* aop = AOp + ((((size_t)(b * 16 + h)) << 10) + qrow) * 64 + cs;
        *(f32x4*)(aop)      = acc0;
        *(f32x4*)(aop + 4)  = acc1;
        *(f32x4*)(aop + 8)  = acc2;
        *(f32x4*)(aop + 12) = acc3;
    }

    // flush G (token -> attention index remap)
    __syncthreads();
    float* Gb = G + ((size_t)(b * 16 + h) << 10);
    const int lim = (qc + 1) << 6;
    for (int idx = t; idx < lim; idx += 256) {
        int j = ((idx & 3) << 8) + (idx >> 2);
        atomicAdd(&Gb[j], Gacc[idx]);
    }
}

// -------- pass_2a: per (b,h) masked prefix GV[p][d] = sum_{pos<=p} G.v --------
__global__ __launch_bounds__(256) void pass_2a(const float* __restrict__ G,
                                               const float* __restrict__ Yv,
                                               float* __restrict__ GVpre) {
    const int h = blockIdx.x, b = blockIdx.y;
    const int t = threadIdx.x;
    __shared__ float Gl[1024];
    __shared__ float S[256][64];
    __shared__ float segsum[4][64];
    for (int i = t; i < 1024; i += 256) Gl[i] = G[((size_t)(b * 16 + h) << 10) + i];
    __syncthreads();
    const int d = t & 63, pg = t >> 6;
    const float* Yvb = Yv + ((size_t)b << 20) + h * 64 + d;
    for (int p0 = 0; p0 < 64; p0++) {
        int pos = pg * 64 + p0;
        float s = 0.f;
#pragma unroll
        for (int sq = 0; sq < 4; sq++) {
            int j = (sq << 8) + pos;
            s += Gl[j] * Yvb[(size_t)j << 10];
        }
        S[pos][d] = s;
    }
    __syncthreads();
    // segmented prefix over pos
    float acc = 0.f;
    for (int p0 = 0; p0 < 64; p0++) {
        int pos = pg * 64 + p0;
        acc += S[pos][d];
        S[pos][d] = acc;
    }
    segsum[pg][d] = acc;
    __syncthreads();
    float off = 0.f;
    for (int g = 0; g < pg; g++) off += segsum[g][d];
    float* gv = GVpre + (((size_t)(b * 16 + h)) << 14) + d;
    for (int p0 = 0; p0 < 64; p0++) {
        int pos = pg * 64 + p0;
        gv[pos << 6] = S[pos][d] + off;
    }
}

// -------- pass_2b: ao = AOp + (lam/1024)*GV[pq]; RMS; bf16 store --------
__global__ __launch_bounds__(256) void pass_2b(const float* __restrict__ AOp,
                                               const float* __restrict__ GVpre,
                                               const float* __restrict__ lamp,
                                               const float* __restrict__ wan,
                                               unsigned short* __restrict__ aoS) {
    const int qg = blockIdx.x;   // nsq 0..3
    const int h = blockIdx.y, b = blockIdx.z;
    const int t = threadIdx.x;
    const int d = t & 63, rg = t >> 6;
    const float lamg = (*lamp) * (1.f / 1024.f);
    const float wv = wan[d];
    const float* aob = AOp + ((((size_t)(b * 16 + h)) << 10) + (qg << 8)) * 64 + d;
    const float* gvb = GVpre + (((size_t)(b * 16 + h)) << 14) + d;
    unsigned short* ob = aoS + ((size_t)b << 20) + ((size_t)h << 16) + ((size_t)(qg << 8) << 6) + d;
    for (int p0 = 0; p0 < 64; p0++) {
        int pq = p0 * 4 + rg;
        float ao = aob[(size_t)pq << 6] + lamg * gvb[(size_t)pq << 6];
        float ss = ao * ao;
#pragma unroll
        for (int o = 1; o < 64; o <<= 1) ss += __shfl_xor(ss, o);
        float rr_ = rsqrtf(ss * (1.f / 64.f) + EPS_ATTN);
        ob[(size_t)pq << 6] = f2bf(ao * rr_ * wv);
    }
}

extern "C" void kernel_launch(void* const* d_in, const int* in_sizes, int n_in,
                              void* d_out, int out_size, void* d_ws, size_t ws_size,
                              hipStream_t stream) {
    const float* x    = (const float*)d_in[0];
    const float* fc   = (const float*)d_in[1];
    const float* w1   = (const float*)d_in[2];
    const float* w2   = (const float*)d_in[3];
    const float* Wq   = (const float*)d_in[4];
    const float* bq   = (const float*)d_in[5];
    const float* Wk   = (const float*)d_in[6];
    const float* bk   = (const float*)d_in[7];
    const float* Wv   = (const float*)d_in[8];
    const float* bv   = (const float*)d_in[9];
    const float* Wo   = (const float*)d_in[10];
    const float* bo   = (const float*)d_in[11];
    const float* lq1  = (const float*)d_in[12];
    const float* lk1  = (const float*)d_in[13];
    const float* lq2  = (const float*)d_in[14];
    const float* lk2  = (const float*)d_in[15];
    const float* wan  = (const float*)d_in[16];
    const float* Wg   = (const float*)d_in[17];
    const float* bg   = (const float*)d_in[18];
    const float* Wout = (const float*)d_in[19];
    const float* bout = (const float*)d_in[20];

    char* ws = (char*)d_ws;
    const size_t MB = 1024 * 1024;
    // Layout (peak 43 MB; 55 MB was exercised fine in round 2):
    float* G    = (float*)(ws);                     // [0, 128K)
    float* lam  = (float*)(ws + 256 * 1024);        // 4 B
    float* h32  = (float*)(ws + 1 * MB);            // [1,9)   fp32 2048x1024
    float* Yq   = (float*)(ws + 9 * MB);            // [9,17)
    float* Yk   = (float*)(ws + 17 * MB);           // [17,25)
    float* Yv   = (float*)(ws + 25 * MB);           // [25,33)
    float* AOp  = (float*)(ws + 33 * MB);           // [33,41) fp32 partial ao
    float* GVpre= (float*)(ws + 41 * MB);           // [41,43)
    unsigned short* aoS = (unsigned short*)(ws + 1 * MB);   // reuse [1,5)  (h32 dead after QKV)
    float* X1           = (float*)(ws + 9 * MB);            // reuse [9,17) (Yq dead after pass_1)
    unsigned short* h2b = (unsigned short*)(ws + 1 * MB);   // reuse [1,5)  (aoS dead after Wo gemm)
    unsigned short* mlp = (unsigned short*)(ws + 17 * MB);  // reuse [17,33) (Yk/Yv dead)

    prep<<<32, 256, 0, stream>>>(G, lam, lq1, lk1, lq2, lk2);
    rms_kernel<0><<<2048, 256, 0, stream>>>(x, w1, h32, EPS_DEF);
    // QKV in full fp32 (VALU) -> attention path keeps fp32 precision.
    dim3 gqkv(32, 16);
    gemm_v<<<gqkv, 256, 0, stream>>>(h32, Wq, bq, Yq, 2048, 1024, 1024);
    gemm_v<<<gqkv, 256, 0, stream>>>(h32, Wk, bk, Yk, 2048, 1024, 1024);
    gemm_v<<<gqkv, 256, 0, stream>>>(h32, Wv, bv, Yv, 2048, 1024, 1024);
    rope_inplace<<<2048, 256, 0, stream>>>(Yq, fc);
    rope_inplace<<<2048, 256, 0, stream>>>(Yk, fc);
    pass_1<<<512, 256, 0, stream>>>(Yq, Yk, Yv, lam, G, AOp);
    pass_2a<<<dim3(16, 2), 256, 0, stream>>>(G, Yv, GVpre);
    pass_2b<<<dim3(4, 16, 2), 256, 0, stream>>>(AOp, GVpre, lam, wan, aoS);
    // Post-attention GEMMs on the matrix cores (weights bf16-rounded on the fly).
    dim3 gmf(16, 16);
    gemm_mfma<<<gmf, 256, 0, stream>>>(aoS, Wo, bo, x, X1, 2048, 1024, 1024);
    rms_kernel<1><<<2048, 256, 0, stream>>>(X1, w2, h2b, EPS_DEF);
    gemm_gate_mfma<<<dim3(16, 64), 256, 0, stream>>>(h2b, Wg, bg, mlp);
    // FINAL OUTPUT IS FP32.
    gemm_mfma<<<gmf, 256, 0, stream>>>(mlp, Wout, bout, X1, (float*)d_out, 2048, 1024, 4096);
}

// Round 5
// 731.780 us; speedup vs baseline: 5.0558x; 1.2019x over previous
//
#include <hip/hip_runtime.h>

#define LAMBDA_INIT 0.2f
#define SCALING 0.17677669529663687f   // 1/sqrt(32)
#define EPS_DEF 1.1920928955078125e-07f
#define EPS_ATTN 1e-5f

typedef unsigned short us4 __attribute__((ext_vector_type(4)));
typedef unsigned short us8v __attribute__((ext_vector_type(8)));
typedef float f32x4 __attribute__((ext_vector_type(4)));
typedef float f32x2 __attribute__((ext_vector_type(2)));
typedef __bf16 bf16x8 __attribute__((ext_vector_type(8)));

__device__ __forceinline__ float bf2f(unsigned short u) {
    unsigned int x = ((unsigned int)u) << 16;
    return __builtin_bit_cast(float, x);
}
__device__ __forceinline__ unsigned short f2bf(float f) {
    unsigned int x = __builtin_bit_cast(unsigned int, f);
    x += 0x7fffu + ((x >> 16) & 1u);
    return (unsigned short)(x >> 16);
}
__device__ __forceinline__ float dot4(f32x4 a, f32x4 b) {
    return fmaf(a[0], b[0], fmaf(a[1], b[1], fmaf(a[2], b[2], a[3] * b[3])));
}
// split a pair of f32x4 into hi/lo bf16 (x ~= hi + lo, residual ~2^-18 rel)
__device__ __forceinline__ void split8(f32x4 a, f32x4 b, us8v& hi, us8v& lo) {
#pragma unroll
    for (int u = 0; u < 4; u++) {
        unsigned short h = f2bf(a[u]);
        hi[u] = h; lo[u] = f2bf(a[u] - bf2f(h));
        unsigned short h2 = f2bf(b[u]);
        hi[4 + u] = h2; lo[4 + u] = f2bf(b[u] - bf2f(h2));
    }
}

__device__ __forceinline__ float wave_sum(float v) {
#pragma unroll
    for (int o = 32; o > 0; o >>= 1) v += __shfl_down(v, o);
    return v;
}
__device__ __forceinline__ float block_sum(float v, float* red4) {
    int wv = threadIdx.x >> 6;
    float w = wave_sum(v);
    __syncthreads();
    if ((threadIdx.x & 63) == 0) red4[wv] = w;
    __syncthreads();
    return red4[0] + red4[1] + red4[2] + red4[3];
}

// ---------------- prep: zero G, compute lambda ----------------
__global__ __launch_bounds__(256) void prep(float* __restrict__ G, float* __restrict__ lamp,
                                            const float* lq1, const float* lk1,
                                            const float* lq2, const float* lk2) {
    int i = (blockIdx.x * 256 + threadIdx.x) * 4;
    G[i] = 0.f; G[i + 1] = 0.f; G[i + 2] = 0.f; G[i + 3] = 0.f;
    if (blockIdx.x == 0 && threadIdx.x == 0) {
        float a = 0.f, c = 0.f;
        for (int d = 0; d < 32; d++) {
            a += lq1[d] * lk1[d];
            c += lq2[d] * lk2[d];
        }
        *lamp = expf(a) - expf(c) + LAMBDA_INIT;
    }
}

// ---------------- RMSNorm: fp32 in, fp32 weight, fp32 or bf16 out ----------------
template <int OUTBF>
__global__ __launch_bounds__(256) void rms_kernel(const float* __restrict__ x,
                                                  const float* __restrict__ w,
                                                  void* __restrict__ out, float eps) {
    int row = blockIdx.x;
    int tid = threadIdx.x;
    size_t base = (size_t)row * 1024 + tid * 4;
    f32x4 v = *(const f32x4*)(x + base);
    float ss = v[0]*v[0] + v[1]*v[1] + v[2]*v[2] + v[3]*v[3];
    __shared__ float red4[4];
    float tot = block_sum(ss, red4);
    float r = rsqrtf(tot * (1.0f / 1024.f) + eps);
    f32x4 wv = *(const f32x4*)(w + tid * 4);
    if (OUTBF) {
        us4 o;
#pragma unroll
        for (int i = 0; i < 4; i++) o[i] = f2bf(v[i] * r * wv[i]);
        *(us4*)((unsigned short*)out + base) = o;
    } else {
        f32x4 o;
#pragma unroll
        for (int i = 0; i < 4; i++) o[i] = v[i] * r * wv[i];
        *(f32x4*)((float*)out + base) = o;
    }
}

// =====================================================================
// QKV split-bf16 MFMA GEMM (near-fp32 precision):
//   Y = h32 @ W^T + b  computed as  al*bh + ah*bl + ah*bh  (3 MFMAs).
// Dropped lo*lo term ~2^-18 relative -> scores indistinguishable from
// fp32 (round-2's plain-bf16 failure was 2^-9). BM=128, BN=64, BK=32,
// 4 waves (2x2). blockIdx.z selects {Wq,Wk,Wv}, sharing the A panel in L2.
// =====================================================================
__global__ __launch_bounds__(256) void gemm_qkv_split(const float* __restrict__ A,
        const float* __restrict__ Wq, const float* __restrict__ Wk, const float* __restrict__ Wv,
        const float* __restrict__ bq, const float* __restrict__ bk, const float* __restrict__ bv,
        float* __restrict__ Yq, float* __restrict__ Yk, float* __restrict__ Yv) {
    const int z = blockIdx.z;
    const float* Bt  = (z == 0) ? Wq : (z == 1) ? Wk : Wv;
    const float* bias= (z == 0) ? bq : (z == 1) ? bk : bv;
    float* out       = (z == 0) ? Yq : (z == 1) ? Yk : Yv;
    const int K = 1024, N = 1024;
    __shared__ __align__(16) unsigned short Ah[128][40];
    __shared__ __align__(16) unsigned short Al[128][40];
    __shared__ __align__(16) unsigned short Bh[64][40];
    __shared__ __align__(16) unsigned short Bl[64][40];
    const int t = threadIdx.x;
    const int bm = blockIdx.x, bn = blockIdx.y;
    const int lane = t & 63, w = t >> 6;
    const int wr = w >> 1, wc = w & 1;
    const int ar0 = t >> 2, asub = t & 3;

    const float* Ag  = A + (size_t)(bm * 128 + ar0) * K + asub * 8;
    const float* Ag2 = Ag + (size_t)64 * K;
    const float* Bg  = Bt + (size_t)(bn * 64 + ar0) * K + asub * 8;

    f32x4 acc[4][2] = {};

    for (int k0 = 0; k0 < K; k0 += 32) {
        us8v a0h, a0l, a1h, a1l, b0h, b0l;
        split8(*(const f32x4*)(Ag + k0),  *(const f32x4*)(Ag + k0 + 4),  a0h, a0l);
        split8(*(const f32x4*)(Ag2 + k0), *(const f32x4*)(Ag2 + k0 + 4), a1h, a1l);
        split8(*(const f32x4*)(Bg + k0),  *(const f32x4*)(Bg + k0 + 4),  b0h, b0l);
        __syncthreads();
        *(us8v*)&Ah[ar0][asub * 8]      = a0h;
        *(us8v*)&Al[ar0][asub * 8]      = a0l;
        *(us8v*)&Ah[ar0 + 64][asub * 8] = a1h;
        *(us8v*)&Al[ar0 + 64][asub * 8] = a1l;
        *(us8v*)&Bh[ar0][asub * 8]      = b0h;
        *(us8v*)&Bl[ar0][asub * 8]      = b0l;
        __syncthreads();
        bf16x8 afh[4], afl[4], bfh[2], bfl[2];
#pragma unroll
        for (int mi = 0; mi < 4; mi++) {
            const int rr = wr * 64 + mi * 16 + (lane & 15);
            const int cc = (lane >> 4) * 8;
            afh[mi] = __builtin_bit_cast(bf16x8, *(const us8v*)&Ah[rr][cc]);
            afl[mi] = __builtin_bit_cast(bf16x8, *(const us8v*)&Al[rr][cc]);
        }
#pragma unroll
        for (int ni = 0; ni < 2; ni++) {
            const int rr = wc * 32 + ni * 16 + (lane & 15);
            const int cc = (lane >> 4) * 8;
            bfh[ni] = __builtin_bit_cast(bf16x8, *(const us8v*)&Bh[rr][cc]);
            bfl[ni] = __builtin_bit_cast(bf16x8, *(const us8v*)&Bl[rr][cc]);
        }
#pragma unroll
        for (int mi = 0; mi < 4; mi++)
#pragma unroll
            for (int ni = 0; ni < 2; ni++) {
                acc[mi][ni] = __builtin_amdgcn_mfma_f32_16x16x32_bf16(afl[mi], bfh[ni], acc[mi][ni], 0, 0, 0);
                acc[mi][ni] = __builtin_amdgcn_mfma_f32_16x16x32_bf16(afh[mi], bfl[ni], acc[mi][ni], 0, 0, 0);
                acc[mi][ni] = __builtin_amdgcn_mfma_f32_16x16x32_bf16(afh[mi], bfh[ni], acc[mi][ni], 0, 0, 0);
            }
    }

    const int rbase = bm * 128 + wr * 64 + ((lane >> 4) << 2);
    const int cbase = bn * 64 + wc * 32 + (lane & 15);
#pragma unroll
    for (int mi = 0; mi < 4; mi++) {
#pragma unroll
        for (int ni = 0; ni < 2; ni++) {
            int col = cbase + ni * 16;
            float bb = bias[col];
#pragma unroll
            for (int r = 0; r < 4; r++) {
                int row = rbase + mi * 16 + r;
                out[(size_t)row * N + col] = acc[mi][ni][r] + bb;
            }
        }
    }
}

// =====================================================================
// bf16 MFMA GEMM:  out = A(bf16)[M,K] @ Bt(fp32->bf16 on the fly)[N,K]^T
//                  + bias + res.   BM=128, BN=64, BK=32, 4 waves (2x2).
// =====================================================================
__global__ __launch_bounds__(256) void gemm_mfma(const unsigned short* __restrict__ A,
                                                 const float* __restrict__ Bt,
                                                 const float* __restrict__ bias,
                                                 const float* __restrict__ res,
                                                 float* __restrict__ out,
                                                 int M, int N, int K) {
    __shared__ __align__(16) unsigned short As[128][40];
    __shared__ __align__(16) unsigned short Bs[64][40];
    const int t = threadIdx.x;
    const int bm = blockIdx.x, bn = blockIdx.y;
    const int lane = t & 63, w = t >> 6;
    const int wr = w >> 1, wc = w & 1;
    const int ar0 = t >> 2, asub = t & 3;

    const unsigned short* Ag  = A + (size_t)(bm * 128 + ar0) * K + asub * 8;
    const unsigned short* Ag2 = Ag + (size_t)64 * K;
    const float* Bg = Bt + (size_t)(bn * 64 + ar0) * K + asub * 8;

    f32x4 acc[4][2] = {};

    for (int k0 = 0; k0 < K; k0 += 32) {
        us8v a0 = *(const us8v*)(Ag + k0);
        us8v a1 = *(const us8v*)(Ag2 + k0);
        f32x4 b0 = *(const f32x4*)(Bg + k0);
        f32x4 b1 = *(const f32x4*)(Bg + k0 + 4);
        us8v bw;
#pragma unroll
        for (int u = 0; u < 4; u++) { bw[u] = f2bf(b0[u]); bw[4 + u] = f2bf(b1[u]); }
        __syncthreads();
        *(us8v*)&As[ar0][asub * 8]      = a0;
        *(us8v*)&As[ar0 + 64][asub * 8] = a1;
        *(us8v*)&Bs[ar0][asub * 8]      = bw;
        __syncthreads();
        bf16x8 af[4], bf[2];
#pragma unroll
        for (int mi = 0; mi < 4; mi++)
            af[mi] = __builtin_bit_cast(bf16x8,
                *(const us8v*)&As[wr * 64 + mi * 16 + (lane & 15)][(lane >> 4) * 8]);
#pragma unroll
        for (int ni = 0; ni < 2; ni++)
            bf[ni] = __builtin_bit_cast(bf16x8,
                *(const us8v*)&Bs[wc * 32 + ni * 16 + (lane & 15)][(lane >> 4) * 8]);
#pragma unroll
        for (int mi = 0; mi < 4; mi++)
#pragma unroll
            for (int ni = 0; ni < 2; ni++)
                acc[mi][ni] = __builtin_amdgcn_mfma_f32_16x16x32_bf16(af[mi], bf[ni], acc[mi][ni], 0, 0, 0);
    }

    const int rbase = bm * 128 + wr * 64 + ((lane >> 4) << 2);
    const int cbase = bn * 64 + wc * 32 + (lane & 15);
#pragma unroll
    for (int mi = 0; mi < 4; mi++) {
#pragma unroll
        for (int ni = 0; ni < 2; ni++) {
            int col = cbase + ni * 16;
            float bb = bias[col];
#pragma unroll
            for (int r = 0; r < 4; r++) {
                int row = rbase + mi * 16 + r;
                size_t oi = (size_t)row * N + col;
                out[oi] = acc[mi][ni][r] + bb + res[oi];
            }
        }
    }
}

// ------- fused gate GEMM (MFMA): mlp = (h2@Wu^T+bu) * silu(h2@Wv^T+bv) -------
__global__ __launch_bounds__(256) void gemm_gate_mfma(const unsigned short* __restrict__ A,
                                                      const float* __restrict__ Wg,
                                                      const float* __restrict__ bg,
                                                      unsigned short* __restrict__ mlp) {
    __shared__ __align__(16) unsigned short As[128][40];
    __shared__ __align__(16) unsigned short BsU[64][40];
    __shared__ __align__(16) unsigned short BsV[64][40];
    const int t = threadIdx.x;
    const int bm = blockIdx.x, bn = blockIdx.y;
    const int lane = t & 63, w = t >> 6;
    const int wr = w >> 1, wc = w & 1;
    const int ar0 = t >> 2, asub = t & 3;

    const unsigned short* Ag  = A + (size_t)(bm * 128 + ar0) * 1024 + asub * 8;
    const unsigned short* Ag2 = Ag + (size_t)64 * 1024;
    const float* BgU = Wg + (size_t)(bn * 64 + ar0) * 1024 + asub * 8;
    const float* BgV = Wg + (size_t)(4096 + bn * 64 + ar0) * 1024 + asub * 8;

    f32x4 accU[4][2] = {};
    f32x4 accV[4][2] = {};

    for (int k0 = 0; k0 < 1024; k0 += 32) {
        us8v a0 = *(const us8v*)(Ag + k0);
        us8v a1 = *(const us8v*)(Ag2 + k0);
        f32x4 u0 = *(const f32x4*)(BgU + k0);
        f32x4 u1 = *(const f32x4*)(BgU + k0 + 4);
        f32x4 v0 = *(const f32x4*)(BgV + k0);
        f32x4 v1 = *(const f32x4*)(BgV + k0 + 4);
        us8v uw, vw;
#pragma unroll
        for (int u = 0; u < 4; u++) {
            uw[u] = f2bf(u0[u]); uw[4 + u] = f2bf(u1[u]);
            vw[u] = f2bf(v0[u]); vw[4 + u] = f2bf(v1[u]);
        }
        __syncthreads();
        *(us8v*)&As[ar0][asub * 8]      = a0;
        *(us8v*)&As[ar0 + 64][asub * 8] = a1;
        *(us8v*)&BsU[ar0][asub * 8]     = uw;
        *(us8v*)&BsV[ar0][asub * 8]     = vw;
        __syncthreads();
        bf16x8 af[4], bu[2], bv2[2];
#pragma unroll
        for (int mi = 0; mi < 4; mi++)
            af[mi] = __builtin_bit_cast(bf16x8,
                *(const us8v*)&As[wr * 64 + mi * 16 + (lane & 15)][(lane >> 4) * 8]);
#pragma unroll
        for (int ni = 0; ni < 2; ni++) {
            bu[ni] = __builtin_bit_cast(bf16x8,
                *(const us8v*)&BsU[wc * 32 + ni * 16 + (lane & 15)][(lane >> 4) * 8]);
            bv2[ni] = __builtin_bit_cast(bf16x8,
                *(const us8v*)&BsV[wc * 32 + ni * 16 + (lane & 15)][(lane >> 4) * 8]);
        }
#pragma unroll
        for (int mi = 0; mi < 4; mi++)
#pragma unroll
            for (int ni = 0; ni < 2; ni++) {
                accU[mi][ni] = __builtin_amdgcn_mfma_f32_16x16x32_bf16(af[mi], bu[ni], accU[mi][ni], 0, 0, 0);
                accV[mi][ni] = __builtin_amdgcn_mfma_f32_16x16x32_bf16(af[mi], bv2[ni], accV[mi][ni], 0, 0, 0);
            }
    }

    const int rbase = bm * 128 + wr * 64 + ((lane >> 4) << 2);
    const int cbase = bn * 64 + wc * 32 + (lane & 15);
#pragma unroll
    for (int mi = 0; mi < 4; mi++) {
#pragma unroll
        for (int ni = 0; ni < 2; ni++) {
            int col = cbase + ni * 16;
            float bu_ = bg[col], bv_ = bg[4096 + col];
#pragma unroll
            for (int r = 0; r < 4; r++) {
                int row = rbase + mi * 16 + r;
                float u = accU[mi][ni][r] + bu_;
                float v = accV[mi][ni][r] + bv_;
                float s = v / (1.f + __expf(-v));
                mlp[(size_t)row * 4096 + col] = f2bf(u * s);
            }
        }
    }
}

// ---------------- RoPE in place, token order ----------------
__global__ __launch_bounds__(256) void rope_inplace(float* __restrict__ Y,
                                                    const float* __restrict__ fc) {
    int t = blockIdx.x;
    int s = t & 1023;
    int p = s >> 2;
    if (p == 0) return;
    int c0 = threadIdx.x * 4;
    float* y = Y + (size_t)t * 1024 + c0;
    int d4 = (c0 & 31) >> 1;
    f32x4 f = *(const f32x4*)(fc + ((size_t)(p - 1) * 16 + d4) * 2);  // [cos,sin,cos,sin]
    float v0 = y[0], v1 = y[1], v2 = y[2], v3 = y[3];
    y[0] = v0 * f[0] - v1 * f[1];
    y[1] = v0 * f[1] + v1 * f[0];
    y[2] = v2 * f[2] - v3 * f[3];
    y[3] = v2 * f[3] + v3 * f[2];
}

// =====================================================================
// Fused attention pass_1 (unchanged from round 4).
// =====================================================================
__global__ __launch_bounds__(256) void pass_1(const float* __restrict__ Yq,
                                              const float* __restrict__ Yk,
                                              const float* __restrict__ Yv,
                                              const float* __restrict__ lamp,
                                              float* __restrict__ G,
                                              float* __restrict__ AOp) {
    const int blk = blockIdx.x;
    const int qc = 15 - (blk >> 5);
    const int h  = blk & 15;
    const int b  = (blk >> 4) & 1;
    const int t = threadIdx.x;
    const int r = t >> 2, sub = t & 3;
    const int cs = sub << 4;
    const int tq = qc * 64 + r;
    const int pq = tq >> 2;
    const int nsq = tq & 3;
    const int qrow = (nsq << 8) + pq;

    __shared__ __align__(16) float Ks[64][68];
    __shared__ __align__(16) float Vs[64][68];
    __shared__ float At[64][65];
    __shared__ float Gacc[1024];

    for (int i = t; i < 1024; i += 256) Gacc[i] = 0.f;

    f32x4 q[16];
    const f32x4* qp = (const f32x4*)(Yq + (((size_t)(b * 1024 + tq)) << 10) + h * 64);
#pragma unroll
    for (int i = 0; i < 16; i++) q[i] = qp[i];

    const float* Ykb = Yk + ((size_t)b << 20) + h * 64;
    const float* Yvb = Yv + ((size_t)b << 20) + h * 64;
    const int swz = r >> 4;

    // -------- sweep 1: denominators --------
    float z1 = 0.f, z2 = 0.f;
    for (int kc = 0; kc <= qc; kc++) {
        __syncthreads();
        {
            const float* kp_ = Ykb + (((size_t)(kc * 64 + r)) << 10) + cs;
#pragma unroll
            for (int j = 0; j < 4; j++)
                *(f32x4*)&Ks[r][(((sub << 2) + j) ^ swz) << 2] = *(const f32x4*)(kp_ + (j << 2));
        }
        __syncthreads();
        const int kp0 = kc * 16;
#pragma unroll 4
        for (int i = 0; i < 16; i++) {
            const int ltk = cs + i;
            const f32x4* kr = (const f32x4*)&Ks[ltk][0];
            float s1 = 0.f, s2 = 0.f;
#pragma unroll
            for (int c8 = 0; c8 < 8; c8++) {
                s1 += dot4(q[c8], kr[c8 ^ sub]);
                s2 += dot4(q[8 + c8], kr[8 + (c8 ^ sub)]);
            }
            if ((kp0 + (ltk >> 2)) <= pq) {
                z1 += __expf(fabsf(s1 * SCALING));
                z2 += __expf(fabsf(s2 * SCALING));
            }
        }
    }
    float Z1 = z1; Z1 += __shfl_xor(Z1, 1); Z1 += __shfl_xor(Z1, 2);
    float Z2 = z2; Z2 += __shfl_xor(Z2, 1); Z2 += __shfl_xor(Z2, 2);
    const float i1 = 1.f / fmaxf(Z1, 1e-20f);
    const float i2 = 1.f / fmaxf(Z2, 1e-20f);
    const float lam = *lamp;

    // -------- sweep 2: weights + colsums + AV --------
    f32x4 acc0 = {0.f, 0.f, 0.f, 0.f};
    f32x4 acc1 = {0.f, 0.f, 0.f, 0.f};
    f32x4 acc2 = {0.f, 0.f, 0.f, 0.f};
    f32x4 acc3 = {0.f, 0.f, 0.f, 0.f};

    for (int kc = 0; kc <= qc; kc++) {
        __syncthreads();
        {
            const float* kp_ = Ykb + (((size_t)(kc * 64 + r)) << 10) + cs;
#pragma unroll
            for (int j = 0; j < 4; j++)
                *(f32x4*)&Ks[r][(((sub << 2) + j) ^ swz) << 2] = *(const f32x4*)(kp_ + (j << 2));
            const int jv = ((r & 3) << 8) + kc * 16 + (r >> 2);
            const float* vp_ = Yvb + ((size_t)jv << 10) + cs;
            *(f32x4*)&Vs[r][cs]      = *(const f32x4*)(vp_);
            *(f32x4*)&Vs[r][cs + 4]  = *(const f32x4*)(vp_ + 4);
            *(f32x4*)&Vs[r][cs + 8]  = *(const f32x4*)(vp_ + 8);
            *(f32x4*)&Vs[r][cs + 12] = *(const f32x4*)(vp_ + 12);
        }
        __syncthreads();
        const int kp0 = kc * 16;
#pragma unroll 4
        for (int i = 0; i < 16; i++) {
            const int ltk = cs + i;
            const f32x4* kr = (const f32x4*)&Ks[ltk][0];
            float s1 = 0.f, s2 = 0.f;
#pragma unroll
            for (int c8 = 0; c8 < 8; c8++) {
                s1 += dot4(q[c8], kr[c8 ^ sub]);
                s2 += dot4(q[8 + c8], kr[8 + (c8 ^ sub)]);
            }
            s1 *= SCALING; s2 *= SCALING;
            float a1v = 0.f, wv_ = 0.f;
            if ((kp0 + (ltk >> 2)) <= pq) {
                float sg1 = (s1 > 0.f) ? 1.f : ((s1 < 0.f) ? -1.f : 0.f);
                float sg2 = (s2 > 0.f) ? 1.f : ((s2 < 0.f) ? -1.f : 0.f);
                a1v = sg1 * __expf(fabsf(s1)) * i1;
                wv_ = a1v - lam * (sg2 * __expf(fabsf(s2)) * i2);
            }
            At[r][ltk] = wv_;
            float ca = a1v;
            ca += __shfl_xor(ca, 4);
            ca += __shfl_xor(ca, 8);
            ca += __shfl_xor(ca, 16);
            ca += __shfl_xor(ca, 32);
            if ((t & 63) < 4) atomicAdd(&Gacc[kc * 64 + ltk], ca);
        }
        __syncthreads();
#pragma unroll 8
        for (int k2 = 0; k2 < 64; k2++) {
            float a = At[r][k2];
            const f32x4* vr = (const f32x4*)&Vs[k2][cs];
            acc0 += vr[0] * a;
            acc1 += vr[1] * a;
            acc2 += vr[2] * a;
            acc3 += vr[3] * a;
        }
    }

    {
        float* aop = AOp + ((((size_t)(b * 16 + h)) << 10) + qrow) * 64 + cs;
        *(f32x4*)(aop)      = acc0;
        *(f32x4*)(aop + 4)  = acc1;
        *(f32x4*)(aop + 8)  = acc2;
        *(f32x4*)(aop + 12) = acc3;
    }

    __syncthreads();
    float* Gb = G + ((size_t)(b * 16 + h) << 10);
    const int lim = (qc + 1) << 6;
    for (int idx = t; idx < lim; idx += 256) {
        int j = ((idx & 3) << 8) + (idx >> 2);
        atomicAdd(&Gb[j], Gacc[idx]);
    }
}

// -------- pass_2a: per (b,h) masked prefix GV[p][d] = sum_{pos<=p} G.v --------
__global__ __launch_bounds__(256) void pass_2a(const float* __restrict__ G,
                                               const float* __restrict__ Yv,
                                               float* __restrict__ GVpre) {
    const int h = blockIdx.x, b = blockIdx.y;
    const int t = threadIdx.x;
    __shared__ float Gl[1024];
    __shared__ float S[256][64];
    __shared__ float segsum[4][64];
    for (int i = t; i < 1024; i += 256) Gl[i] = G[((size_t)(b * 16 + h) << 10) + i];
    __syncthreads();
    const int d = t & 63, pg = t >> 6;
    const float* Yvb = Yv + ((size_t)b << 20) + h * 64 + d;
    for (int p0 = 0; p0 < 64; p0++) {
        int pos = pg * 64 + p0;
        float s = 0.f;
#pragma unroll
        for (int sq = 0; sq < 4; sq++) {
            int j = (sq << 8) + pos;
            s += Gl[j] * Yvb[(size_t)j << 10];
        }
        S[pos][d] = s;
    }
    __syncthreads();
    float acc = 0.f;
    for (int p0 = 0; p0 < 64; p0++) {
        int pos = pg * 64 + p0;
        acc += S[pos][d];
        S[pos][d] = acc;
    }
    segsum[pg][d] = acc;
    __syncthreads();
    float off = 0.f;
    for (int g = 0; g < pg; g++) off += segsum[g][d];
    float* gv = GVpre + (((size_t)(b * 16 + h)) << 14) + d;
    for (int p0 = 0; p0 < 64; p0++) {
        int pos = pg * 64 + p0;
        gv[pos << 6] = S[pos][d] + off;
    }
}

// -------- pass_2b: ao = AOp + (lam/1024)*GV[pq]; RMS; bf16 store --------
__global__ __launch_bounds__(256) void pass_2b(const float* __restrict__ AOp,
                                               const float* __restrict__ GVpre,
                                               const float* __restrict__ lamp,
                                               const float* __restrict__ wan,
                                               unsigned short* __restrict__ aoS) {
    const int qg = blockIdx.x;
    const int h = blockIdx.y, b = blockIdx.z;
    const int t = threadIdx.x;
    const int d = t & 63, rg = t >> 6;
    const float lamg = (*lamp) * (1.f / 1024.f);
    const float wv = wan[d];
    const float* aob = AOp + ((((size_t)(b * 16 + h)) << 10) + (qg << 8)) * 64 + d;
    const float* gvb = GVpre + (((size_t)(b * 16 + h)) << 14) + d;
    unsigned short* ob = aoS + ((size_t)b << 20) + ((size_t)h << 16) + ((size_t)(qg << 8) << 6) + d;
    for (int p0 = 0; p0 < 64; p0++) {
        int pq = p0 * 4 + rg;
        float ao = aob[(size_t)pq << 6] + lamg * gvb[(size_t)pq << 6];
        float ss = ao * ao;
#pragma unroll
        for (int o = 1; o < 64; o <<= 1) ss += __shfl_xor(ss, o);
        float rr_ = rsqrtf(ss * (1.f / 64.f) + EPS_ATTN);
        ob[(size_t)pq << 6] = f2bf(ao * rr_ * wv);
    }
}

extern "C" void kernel_launch(void* const* d_in, const int* in_sizes, int n_in,
                              void* d_out, int out_size, void* d_ws, size_t ws_size,
                              hipStream_t stream) {
    const float* x    = (const float*)d_in[0];
    const float* fc   = (const float*)d_in[1];
    const float* w1   = (const float*)d_in[2];
    const float* w2   = (const float*)d_in[3];
    const float* Wq   = (const float*)d_in[4];
    const float* bq   = (const float*)d_in[5];
    const float* Wk   = (const float*)d_in[6];
    const float* bk   = (const float*)d_in[7];
    const float* Wv   = (const float*)d_in[8];
    const float* bv   = (const float*)d_in[9];
    const float* Wo   = (const float*)d_in[10];
    const float* bo   = (const float*)d_in[11];
    const float* lq1  = (const float*)d_in[12];
    const float* lk1  = (const float*)d_in[13];
    const float* lq2  = (const float*)d_in[14];
    const float* lk2  = (const float*)d_in[15];
    const float* wan  = (const float*)d_in[16];
    const float* Wg   = (const float*)d_in[17];
    const float* bg   = (const float*)d_in[18];
    const float* Wout = (const float*)d_in[19];
    const float* bout = (const float*)d_in[20];

    char* ws = (char*)d_ws;
    const size_t MB = 1024 * 1024;
    // Layout (peak 43 MB):
    float* G    = (float*)(ws);                     // [0, 128K)
    float* lam  = (float*)(ws + 256 * 1024);        // 4 B
    float* h32  = (float*)(ws + 1 * MB);            // [1,9)   fp32 2048x1024
    float* Yq   = (float*)(ws + 9 * MB);            // [9,17)
    float* Yk   = (float*)(ws + 17 * MB);           // [17,25)
    float* Yv   = (float*)(ws + 25 * MB);           // [25,33)
    float* AOp  = (float*)(ws + 33 * MB);           // [33,41) fp32 partial ao
    float* GVpre= (float*)(ws + 41 * MB);           // [41,43)
    unsigned short* aoS = (unsigned short*)(ws + 1 * MB);   // reuse [1,5)  (h32 dead after QKV)
    float* X1           = (float*)(ws + 9 * MB);            // reuse [9,17) (Yq dead after pass_1)
    unsigned short* h2b = (unsigned short*)(ws + 1 * MB);   // reuse [1,5)  (aoS dead after Wo gemm)
    unsigned short* mlp = (unsigned short*)(ws + 17 * MB);  // reuse [17,33) (Yk/Yv dead)

    prep<<<32, 256, 0, stream>>>(G, lam, lq1, lk1, lq2, lk2);
    rms_kernel<0><<<2048, 256, 0, stream>>>(x, w1, h32, EPS_DEF);
    // QKV via split-bf16 3-MFMA (near-fp32 precision), fused z-launch.
    gemm_qkv_split<<<dim3(16, 16, 3), 256, 0, stream>>>(h32, Wq, Wk, Wv, bq, bk, bv, Yq, Yk, Yv);
    rope_inplace<<<2048, 256, 0, stream>>>(Yq, fc);
    rope_inplace<<<2048, 256, 0, stream>>>(Yk, fc);
    pass_1<<<512, 256, 0, stream>>>(Yq, Yk, Yv, lam, G, AOp);
    pass_2a<<<dim3(16, 2), 256, 0, stream>>>(G, Yv, GVpre);
    pass_2b<<<dim3(4, 16, 2), 256, 0, stream>>>(AOp, GVpre, lam, wan, aoS);
    // Post-attention GEMMs on the matrix cores (weights bf16-rounded on the fly).
    dim3 gmf(16, 16);
    gemm_mfma<<<gmf, 256, 0, stream>>>(aoS, Wo, bo, x, X1, 2048, 1024, 1024);
    rms_kernel<1><<<2048, 256, 0, stream>>>(X1, w2, h2b, EPS_DEF);
    gemm_gate_mfma<<<dim3(16, 64), 256, 0, stream>>>(h2b, Wg, bg, mlp);
    // FINAL OUTPUT IS FP32.
    gemm_mfma<<<gmf, 256, 0, stream>>>(mlp, Wout, bout, X1, (float*)d_out, 2048, 1024, 4096);
}

// Round 6
// 543.078 us; speedup vs baseline: 6.8125x; 1.3475x over previous
//
#include <hip/hip_runtime.h>

#define LAMBDA_INIT 0.2f
#define SCALING 0.17677669529663687f   // 1/sqrt(32)
#define EPS_DEF 1.1920928955078125e-07f
#define EPS_ATTN 1e-5f

typedef unsigned short us4 __attribute__((ext_vector_type(4)));
typedef unsigned short us8v __attribute__((ext_vector_type(8)));
typedef float f32x4 __attribute__((ext_vector_type(4)));
typedef float f32x2 __attribute__((ext_vector_type(2)));
typedef __bf16 bf16x8 __attribute__((ext_vector_type(8)));

#define MFMA16(a, b, c) __builtin_amdgcn_mfma_f32_16x16x32_bf16((a), (b), (c), 0, 0, 0)

__device__ __forceinline__ float bf2f(unsigned short u) {
    unsigned int x = ((unsigned int)u) << 16;
    return __builtin_bit_cast(float, x);
}
__device__ __forceinline__ unsigned short f2bf(float f) {
    unsigned int x = __builtin_bit_cast(unsigned int, f);
    x += 0x7fffu + ((x >> 16) & 1u);
    return (unsigned short)(x >> 16);
}
__device__ __forceinline__ float dot4(f32x4 a, f32x4 b) {
    return fmaf(a[0], b[0], fmaf(a[1], b[1], fmaf(a[2], b[2], a[3] * b[3])));
}
// split a pair of f32x4 into hi/lo bf16 (x ~= hi + lo, residual ~2^-18 rel)
__device__ __forceinline__ void split8(f32x4 a, f32x4 b, us8v& hi, us8v& lo) {
#pragma unroll
    for (int u = 0; u < 4; u++) {
        unsigned short h = f2bf(a[u]);
        hi[u] = h; lo[u] = f2bf(a[u] - bf2f(h));
        unsigned short h2 = f2bf(b[u]);
        hi[4 + u] = h2; lo[4 + u] = f2bf(b[u] - bf2f(h2));
    }
}
__device__ __forceinline__ bf16x8 ldb(const unsigned short* p) {
    return __builtin_bit_cast(bf16x8, *(const us8v*)p);
}

__device__ __forceinline__ float wave_sum(float v) {
#pragma unroll
    for (int o = 32; o > 0; o >>= 1) v += __shfl_down(v, o);
    return v;
}
__device__ __forceinline__ float block_sum(float v, float* red4) {
    int wv = threadIdx.x >> 6;
    float w = wave_sum(v);
    __syncthreads();
    if ((threadIdx.x & 63) == 0) red4[wv] = w;
    __syncthreads();
    return red4[0] + red4[1] + red4[2] + red4[3];
}

// ---------------- prep: zero G, compute lambda ----------------
__global__ __launch_bounds__(256) void prep(float* __restrict__ G, float* __restrict__ lamp,
                                            const float* lq1, const float* lk1,
                                            const float* lq2, const float* lk2) {
    int i = (blockIdx.x * 256 + threadIdx.x) * 4;
    G[i] = 0.f; G[i + 1] = 0.f; G[i + 2] = 0.f; G[i + 3] = 0.f;
    if (blockIdx.x == 0 && threadIdx.x == 0) {
        float a = 0.f, c = 0.f;
        for (int d = 0; d < 32; d++) {
            a += lq1[d] * lk1[d];
            c += lq2[d] * lk2[d];
        }
        *lamp = expf(a) - expf(c) + LAMBDA_INIT;
    }
}

// ---------------- RMSNorm: fp32 in, fp32 weight, fp32 or bf16 out ----------------
template <int OUTBF>
__global__ __launch_bounds__(256) void rms_kernel(const float* __restrict__ x,
                                                  const float* __restrict__ w,
                                                  void* __restrict__ out, float eps) {
    int row = blockIdx.x;
    int tid = threadIdx.x;
    size_t base = (size_t)row * 1024 + tid * 4;
    f32x4 v = *(const f32x4*)(x + base);
    float ss = v[0]*v[0] + v[1]*v[1] + v[2]*v[2] + v[3]*v[3];
    __shared__ float red4[4];
    float tot = block_sum(ss, red4);
    float r = rsqrtf(tot * (1.0f / 1024.f) + eps);
    f32x4 wv = *(const f32x4*)(w + tid * 4);
    if (OUTBF) {
        us4 o;
#pragma unroll
        for (int i = 0; i < 4; i++) o[i] = f2bf(v[i] * r * wv[i]);
        *(us4*)((unsigned short*)out + base) = o;
    } else {
        f32x4 o;
#pragma unroll
        for (int i = 0; i < 4; i++) o[i] = v[i] * r * wv[i];
        *(f32x4*)((float*)out + base) = o;
    }
}

// =====================================================================
// QKV split-bf16 MFMA GEMM (near-fp32 precision):
//   Y = h32 @ W^T + b  computed as  al*bh + ah*bl + ah*bh  (3 MFMAs).
// =====================================================================
__global__ __launch_bounds__(256) void gemm_qkv_split(const float* __restrict__ A,
        const float* __restrict__ Wq, const float* __restrict__ Wk, const float* __restrict__ Wv,
        const float* __restrict__ bq, const float* __restrict__ bk, const float* __restrict__ bv,
        float* __restrict__ Yq, float* __restrict__ Yk, float* __restrict__ Yv) {
    const int z = blockIdx.z;
    const float* Bt  = (z == 0) ? Wq : (z == 1) ? Wk : Wv;
    const float* bias= (z == 0) ? bq : (z == 1) ? bk : bv;
    float* out       = (z == 0) ? Yq : (z == 1) ? Yk : Yv;
    const int K = 1024, N = 1024;
    __shared__ __align__(16) unsigned short Ah[128][40];
    __shared__ __align__(16) unsigned short Al[128][40];
    __shared__ __align__(16) unsigned short Bh[64][40];
    __shared__ __align__(16) unsigned short Bl[64][40];
    const int t = threadIdx.x;
    const int bm = blockIdx.x, bn = blockIdx.y;
    const int lane = t & 63, w = t >> 6;
    const int wr = w >> 1, wc = w & 1;
    const int ar0 = t >> 2, asub = t & 3;

    const float* Ag  = A + (size_t)(bm * 128 + ar0) * K + asub * 8;
    const float* Ag2 = Ag + (size_t)64 * K;
    const float* Bg  = Bt + (size_t)(bn * 64 + ar0) * K + asub * 8;

    f32x4 acc[4][2] = {};

    for (int k0 = 0; k0 < K; k0 += 32) {
        us8v a0h, a0l, a1h, a1l, b0h, b0l;
        split8(*(const f32x4*)(Ag + k0),  *(const f32x4*)(Ag + k0 + 4),  a0h, a0l);
        split8(*(const f32x4*)(Ag2 + k0), *(const f32x4*)(Ag2 + k0 + 4), a1h, a1l);
        split8(*(const f32x4*)(Bg + k0),  *(const f32x4*)(Bg + k0 + 4),  b0h, b0l);
        __syncthreads();
        *(us8v*)&Ah[ar0][asub * 8]      = a0h;
        *(us8v*)&Al[ar0][asub * 8]      = a0l;
        *(us8v*)&Ah[ar0 + 64][asub * 8] = a1h;
        *(us8v*)&Al[ar0 + 64][asub * 8] = a1l;
        *(us8v*)&Bh[ar0][asub * 8]      = b0h;
        *(us8v*)&Bl[ar0][asub * 8]      = b0l;
        __syncthreads();
        bf16x8 afh[4], afl[4], bfh[2], bfl[2];
#pragma unroll
        for (int mi = 0; mi < 4; mi++) {
            const int rr = wr * 64 + mi * 16 + (lane & 15);
            const int cc = (lane >> 4) * 8;
            afh[mi] = ldb(&Ah[rr][cc]);
            afl[mi] = ldb(&Al[rr][cc]);
        }
#pragma unroll
        for (int ni = 0; ni < 2; ni++) {
            const int rr = wc * 32 + ni * 16 + (lane & 15);
            const int cc = (lane >> 4) * 8;
            bfh[ni] = ldb(&Bh[rr][cc]);
            bfl[ni] = ldb(&Bl[rr][cc]);
        }
#pragma unroll
        for (int mi = 0; mi < 4; mi++)
#pragma unroll
            for (int ni = 0; ni < 2; ni++) {
                acc[mi][ni] = MFMA16(afl[mi], bfh[ni], acc[mi][ni]);
                acc[mi][ni] = MFMA16(afh[mi], bfl[ni], acc[mi][ni]);
                acc[mi][ni] = MFMA16(afh[mi], bfh[ni], acc[mi][ni]);
            }
    }

    const int rbase = bm * 128 + wr * 64 + ((lane >> 4) << 2);
    const int cbase = bn * 64 + wc * 32 + (lane & 15);
#pragma unroll
    for (int mi = 0; mi < 4; mi++) {
#pragma unroll
        for (int ni = 0; ni < 2; ni++) {
            int col = cbase + ni * 16;
            float bb = bias[col];
#pragma unroll
            for (int r = 0; r < 4; r++) {
                int row = rbase + mi * 16 + r;
                out[(size_t)row * N + col] = acc[mi][ni][r] + bb;
            }
        }
    }
}

// =====================================================================
// bf16 MFMA GEMM:  out = A(bf16)[M,K] @ Bt(fp32->bf16 on the fly)[N,K]^T
// =====================================================================
__global__ __launch_bounds__(256) void gemm_mfma(const unsigned short* __restrict__ A,
                                                 const float* __restrict__ Bt,
                                                 const float* __restrict__ bias,
                                                 const float* __restrict__ res,
                                                 float* __restrict__ out,
                                                 int M, int N, int K) {
    __shared__ __align__(16) unsigned short As[128][40];
    __shared__ __align__(16) unsigned short Bs[64][40];
    const int t = threadIdx.x;
    const int bm = blockIdx.x, bn = blockIdx.y;
    const int lane = t & 63, w = t >> 6;
    const int wr = w >> 1, wc = w & 1;
    const int ar0 = t >> 2, asub = t & 3;

    const unsigned short* Ag  = A + (size_t)(bm * 128 + ar0) * K + asub * 8;
    const unsigned short* Ag2 = Ag + (size_t)64 * K;
    const float* Bg = Bt + (size_t)(bn * 64 + ar0) * K + asub * 8;

    f32x4 acc[4][2] = {};

    for (int k0 = 0; k0 < K; k0 += 32) {
        us8v a0 = *(const us8v*)(Ag + k0);
        us8v a1 = *(const us8v*)(Ag2 + k0);
        f32x4 b0 = *(const f32x4*)(Bg + k0);
        f32x4 b1 = *(const f32x4*)(Bg + k0 + 4);
        us8v bw;
#pragma unroll
        for (int u = 0; u < 4; u++) { bw[u] = f2bf(b0[u]); bw[4 + u] = f2bf(b1[u]); }
        __syncthreads();
        *(us8v*)&As[ar0][asub * 8]      = a0;
        *(us8v*)&As[ar0 + 64][asub * 8] = a1;
        *(us8v*)&Bs[ar0][asub * 8]      = bw;
        __syncthreads();
        bf16x8 af[4], bf[2];
#pragma unroll
        for (int mi = 0; mi < 4; mi++)
            af[mi] = ldb(&As[wr * 64 + mi * 16 + (lane & 15)][(lane >> 4) * 8]);
#pragma unroll
        for (int ni = 0; ni < 2; ni++)
            bf[ni] = ldb(&Bs[wc * 32 + ni * 16 + (lane & 15)][(lane >> 4) * 8]);
#pragma unroll
        for (int mi = 0; mi < 4; mi++)
#pragma unroll
            for (int ni = 0; ni < 2; ni++)
                acc[mi][ni] = MFMA16(af[mi], bf[ni], acc[mi][ni]);
    }

    const int rbase = bm * 128 + wr * 64 + ((lane >> 4) << 2);
    const int cbase = bn * 64 + wc * 32 + (lane & 15);
#pragma unroll
    for (int mi = 0; mi < 4; mi++) {
#pragma unroll
        for (int ni = 0; ni < 2; ni++) {
            int col = cbase + ni * 16;
            float bb = bias[col];
#pragma unroll
            for (int r = 0; r < 4; r++) {
                int row = rbase + mi * 16 + r;
                size_t oi = (size_t)row * N + col;
                out[oi] = acc[mi][ni][r] + bb + res[oi];
            }
        }
    }
}

// ------- fused gate GEMM (MFMA): mlp = (h2@Wu^T+bu) * silu(h2@Wv^T+bv) -------
__global__ __launch_bounds__(256) void gemm_gate_mfma(const unsigned short* __restrict__ A,
                                                      const float* __restrict__ Wg,
                                                      const float* __restrict__ bg,
                                                      unsigned short* __restrict__ mlp) {
    __shared__ __align__(16) unsigned short As[128][40];
    __shared__ __align__(16) unsigned short BsU[64][40];
    __shared__ __align__(16) unsigned short BsV[64][40];
    const int t = threadIdx.x;
    const int bm = blockIdx.x, bn = blockIdx.y;
    const int lane = t & 63, w = t >> 6;
    const int wr = w >> 1, wc = w & 1;
    const int ar0 = t >> 2, asub = t & 3;

    const unsigned short* Ag  = A + (size_t)(bm * 128 + ar0) * 1024 + asub * 8;
    const unsigned short* Ag2 = Ag + (size_t)64 * 1024;
    const float* BgU = Wg + (size_t)(bn * 64 + ar0) * 1024 + asub * 8;
    const float* BgV = Wg + (size_t)(4096 + bn * 64 + ar0) * 1024 + asub * 8;

    f32x4 accU[4][2] = {};
    f32x4 accV[4][2] = {};

    for (int k0 = 0; k0 < 1024; k0 += 32) {
        us8v a0 = *(const us8v*)(Ag + k0);
        us8v a1 = *(const us8v*)(Ag2 + k0);
        f32x4 u0 = *(const f32x4*)(BgU + k0);
        f32x4 u1 = *(const f32x4*)(BgU + k0 + 4);
        f32x4 v0 = *(const f32x4*)(BgV + k0);
        f32x4 v1 = *(const f32x4*)(BgV + k0 + 4);
        us8v uw, vw;
#pragma unroll
        for (int u = 0; u < 4; u++) {
            uw[u] = f2bf(u0[u]); uw[4 + u] = f2bf(u1[u]);
            vw[u] = f2bf(v0[u]); vw[4 + u] = f2bf(v1[u]);
        }
        __syncthreads();
        *(us8v*)&As[ar0][asub * 8]      = a0;
        *(us8v*)&As[ar0 + 64][asub * 8] = a1;
        *(us8v*)&BsU[ar0][asub * 8]     = uw;
        *(us8v*)&BsV[ar0][asub * 8]     = vw;
        __syncthreads();
        bf16x8 af[4], bu[2], bv2[2];
#pragma unroll
        for (int mi = 0; mi < 4; mi++)
            af[mi] = ldb(&As[wr * 64 + mi * 16 + (lane & 15)][(lane >> 4) * 8]);
#pragma unroll
        for (int ni = 0; ni < 2; ni++) {
            bu[ni] = ldb(&BsU[wc * 32 + ni * 16 + (lane & 15)][(lane >> 4) * 8]);
            bv2[ni] = ldb(&BsV[wc * 32 + ni * 16 + (lane & 15)][(lane >> 4) * 8]);
        }
#pragma unroll
        for (int mi = 0; mi < 4; mi++)
#pragma unroll
            for (int ni = 0; ni < 2; ni++) {
                accU[mi][ni] = MFMA16(af[mi], bu[ni], accU[mi][ni]);
                accV[mi][ni] = MFMA16(af[mi], bv2[ni], accV[mi][ni]);
            }
    }

    const int rbase = bm * 128 + wr * 64 + ((lane >> 4) << 2);
    const int cbase = bn * 64 + wc * 32 + (lane & 15);
#pragma unroll
    for (int mi = 0; mi < 4; mi++) {
#pragma unroll
        for (int ni = 0; ni < 2; ni++) {
            int col = cbase + ni * 16;
            float bu_ = bg[col], bv_ = bg[4096 + col];
#pragma unroll
            for (int r = 0; r < 4; r++) {
                int row = rbase + mi * 16 + r;
                float u = accU[mi][ni][r] + bu_;
                float v = accV[mi][ni][r] + bv_;
                float s = v / (1.f + __expf(-v));
                mlp[(size_t)row * 4096 + col] = f2bf(u * s);
            }
        }
    }
}

// ---------------- RoPE in place, token order ----------------
__global__ __launch_bounds__(256) void rope_inplace(float* __restrict__ Y,
                                                    const float* __restrict__ fc) {
    int t = blockIdx.x;
    int s = t & 1023;
    int p = s >> 2;
    if (p == 0) return;
    int c0 = threadIdx.x * 4;
    float* y = Y + (size_t)t * 1024 + c0;
    int d4 = (c0 & 31) >> 1;
    f32x4 f = *(const f32x4*)(fc + ((size_t)(p - 1) * 16 + d4) * 2);  // [cos,sin,cos,sin]
    float v0 = y[0], v1 = y[1], v2 = y[2], v3 = y[3];
    y[0] = v0 * f[0] - v1 * f[1];
    y[1] = v0 * f[1] + v1 * f[0];
    y[2] = v2 * f[2] - v3 * f[3];
    y[3] = v2 * f[3] + v3 * f[2];
}

// =====================================================================
// MFMA attention pass_1. Block = (b,h,qc): 64 consecutive Q-tokens.
// 4 waves; wave w owns q-strip [w*16, w*16+16). All matmuls are split-bf16
// (hi+lo, 3 MFMAs, error ~2^-18 -> numerically equivalent to fp32):
//   sweep1: S = Q.K^T per 16x16 fragment -> Z1,Z2 (shfl-tree over k-cols)
//   sweep2: recompute S -> weights w = a1 - lam*a2 (hi/lo to LDS), G colsums
//           (shfl 16/32 + LDS atomic), AV via MFMA with V staged TRANSPOSED.
// Fragment layouts identical to gemm_mfma (session-verified):
//   A: lane&15 = M-row, k=(lane>>4)*8+j ; B: lane&15 = N-col, same k
//   D: col=lane&15, row=(lane>>4)*4+reg
// =====================================================================
__global__ __launch_bounds__(256) void pass_1(const float* __restrict__ Yq,
                                              const float* __restrict__ Yk,
                                              const float* __restrict__ Yv,
                                              const float* __restrict__ lamp,
                                              float* __restrict__ G,
                                              float* __restrict__ AOp) {
    const int blk = blockIdx.x;
    const int qc = 15 - (blk >> 5);
    const int h  = blk & 15;
    const int b  = (blk >> 4) & 1;
    const int t = threadIdx.x;
    const int lane = t & 63, w = t >> 6;
    const int l15 = lane & 15, lg = lane >> 4;

    __shared__ __align__(16) unsigned short Kh[64][72];
    __shared__ __align__(16) unsigned short Kl[64][72];
    __shared__ __align__(16) unsigned short Vth[64][72];
    __shared__ __align__(16) unsigned short Vtl[64][72];
    __shared__ __align__(16) unsigned short Wh[64][72];
    __shared__ __align__(16) unsigned short Wl[64][72];
    __shared__ float Gacc[1024];

    for (int i = t; i < 1024; i += 256) Gacc[i] = 0.f;

    // ---- Q A-fragments (once; rows fixed per wave) ----
    us8v qh[2], ql[2];
    {
        const float* qp = Yq + ((size_t)(b * 1024 + qc * 64 + w * 16 + l15) << 10)
                          + h * 64 + lg * 8;
#pragma unroll
        for (int H = 0; H < 2; H++)
            split8(*(const f32x4*)(qp + H * 32), *(const f32x4*)(qp + H * 32 + 4), qh[H], ql[H]);
    }
    const int dq0 = w * 16 + (lg << 2);   // block-local q for D-frag reg r=0

    const float* Ykb = Yk + ((size_t)b << 20) + h * 64;
    const float* Yvb = Yv + ((size_t)b << 20) + h * 64;
    const int srow = t >> 2, ssub = t & 3;

    float z1r[4] = {0.f, 0.f, 0.f, 0.f};
    float z2r[4] = {0.f, 0.f, 0.f, 0.f};

    // -------- sweep 1: denominators --------
    for (int kc = 0; kc <= qc; kc++) {
        __syncthreads();
        {
            const float* kp = Ykb + ((size_t)(kc * 64 + srow) << 10) + ssub * 16;
            us8v h0, l0, h1, l1;
            split8(*(const f32x4*)kp,       *(const f32x4*)(kp + 4),  h0, l0);
            split8(*(const f32x4*)(kp + 8), *(const f32x4*)(kp + 12), h1, l1);
            *(us8v*)&Kh[srow][ssub * 16]     = h0;
            *(us8v*)&Kh[srow][ssub * 16 + 8] = h1;
            *(us8v*)&Kl[srow][ssub * 16]     = l0;
            *(us8v*)&Kl[srow][ssub * 16 + 8] = l1;
        }
        __syncthreads();
#pragma unroll
        for (int kf = 0; kf < 4; kf++) {
            const int krow = kf * 16 + l15;
            const int kcol = lg * 8;
            bf16x8 b1h = ldb(&Kh[krow][kcol]),      b1l = ldb(&Kl[krow][kcol]);
            bf16x8 b2h = ldb(&Kh[krow][32 + kcol]), b2l = ldb(&Kl[krow][32 + kcol]);
            f32x4 s1 = {}, s2 = {};
            s1 = MFMA16(__builtin_bit_cast(bf16x8, ql[0]), b1h, s1);
            s1 = MFMA16(__builtin_bit_cast(bf16x8, qh[0]), b1l, s1);
            s1 = MFMA16(__builtin_bit_cast(bf16x8, qh[0]), b1h, s1);
            s2 = MFMA16(__builtin_bit_cast(bf16x8, ql[1]), b2h, s2);
            s2 = MFMA16(__builtin_bit_cast(bf16x8, qh[1]), b2l, s2);
            s2 = MFMA16(__builtin_bit_cast(bf16x8, qh[1]), b2h, s2);
            const int kpos = (kc * 64 + kf * 16 + l15) >> 2;
#pragma unroll
            for (int r = 0; r < 4; r++) {
                int pq = (qc * 64 + dq0 + r) >> 2;
                if (kpos <= pq) {
                    z1r[r] += __expf(fabsf(s1[r] * SCALING));
                    z2r[r] += __expf(fabsf(s2[r] * SCALING));
                }
            }
        }
    }
    // reduce over the 16 k-columns (D-frag lane&15 bits)
#pragma unroll
    for (int r = 0; r < 4; r++) {
        float a = z1r[r];
        a += __shfl_xor(a, 1); a += __shfl_xor(a, 2);
        a += __shfl_xor(a, 4); a += __shfl_xor(a, 8);
        z1r[r] = 1.f / fmaxf(a, 1e-20f);
        float c = z2r[r];
        c += __shfl_xor(c, 1); c += __shfl_xor(c, 2);
        c += __shfl_xor(c, 4); c += __shfl_xor(c, 8);
        z2r[r] = 1.f / fmaxf(c, 1e-20f);
    }
    const float lam = *lamp;

    f32x4 ao[4] = {};   // per d-fragment, accumulated over all chunks

    // -------- sweep 2: weights + G colsums + AV --------
    for (int kc = 0; kc <= qc; kc++) {
        __syncthreads();
        {
            const float* kp = Ykb + ((size_t)(kc * 64 + srow) << 10) + ssub * 16;
            us8v h0, l0, h1, l1;
            split8(*(const f32x4*)kp,       *(const f32x4*)(kp + 4),  h0, l0);
            split8(*(const f32x4*)(kp + 8), *(const f32x4*)(kp + 12), h1, l1);
            *(us8v*)&Kh[srow][ssub * 16]     = h0;
            *(us8v*)&Kh[srow][ssub * 16 + 8] = h1;
            *(us8v*)&Kl[srow][ssub * 16]     = l0;
            *(us8v*)&Kl[srow][ssub * 16 + 8] = l1;
            // V row for local token srow is RAW index jv (reference quirk),
            // staged TRANSPOSED: Vt[d][k] so AV B-frags are contiguous.
            const int jv = ((srow & 3) << 8) + kc * 16 + (srow >> 2);
            const float* vp = Yvb + ((size_t)jv << 10) + ssub * 16;
            f32x4 vv[4];
            vv[0] = *(const f32x4*)vp;       vv[1] = *(const f32x4*)(vp + 4);
            vv[2] = *(const f32x4*)(vp + 8); vv[3] = *(const f32x4*)(vp + 12);
#pragma unroll
            for (int j = 0; j < 16; j++) {
                float val = vv[j >> 2][j & 3];
                unsigned short hh = f2bf(val);
                Vth[ssub * 16 + j][srow] = hh;
                Vtl[ssub * 16 + j][srow] = f2bf(val - bf2f(hh));
            }
        }
        __syncthreads();
#pragma unroll
        for (int kf = 0; kf < 4; kf++) {
            const int krow = kf * 16 + l15;
            const int kcol = lg * 8;
            bf16x8 b1h = ldb(&Kh[krow][kcol]),      b1l = ldb(&Kl[krow][kcol]);
            bf16x8 b2h = ldb(&Kh[krow][32 + kcol]), b2l = ldb(&Kl[krow][32 + kcol]);
            f32x4 s1 = {}, s2 = {};
            s1 = MFMA16(__builtin_bit_cast(bf16x8, ql[0]), b1h, s1);
            s1 = MFMA16(__builtin_bit_cast(bf16x8, qh[0]), b1l, s1);
            s1 = MFMA16(__builtin_bit_cast(bf16x8, qh[0]), b1h, s1);
            s2 = MFMA16(__builtin_bit_cast(bf16x8, ql[1]), b2h, s2);
            s2 = MFMA16(__builtin_bit_cast(bf16x8, qh[1]), b2l, s2);
            s2 = MFMA16(__builtin_bit_cast(bf16x8, qh[1]), b2h, s2);
            const int kli = kf * 16 + l15;
            const int kpos = (kc * 64 + kli) >> 2;
            float colsum = 0.f;
#pragma unroll
            for (int r = 0; r < 4; r++) {
                int pq = (qc * 64 + dq0 + r) >> 2;
                float wv = 0.f, a1 = 0.f;
                if (kpos <= pq) {
                    float t1 = s1[r] * SCALING, t2 = s2[r] * SCALING;
                    float sg1 = (t1 > 0.f) ? 1.f : ((t1 < 0.f) ? -1.f : 0.f);
                    float sg2 = (t2 > 0.f) ? 1.f : ((t2 < 0.f) ? -1.f : 0.f);
                    a1 = sg1 * __expf(fabsf(t1)) * z1r[r];
                    wv = a1 - lam * (sg2 * __expf(fabsf(t2)) * z2r[r]);
                }
                colsum += a1;
                unsigned short hh = f2bf(wv);
                Wh[dq0 + r][kli] = hh;
                Wl[dq0 + r][kli] = f2bf(wv - bf2f(hh));
            }
            colsum += __shfl_xor(colsum, 16);
            colsum += __shfl_xor(colsum, 32);
            if (lane < 16) atomicAdd(&Gacc[kc * 64 + kf * 16 + lane], colsum);
        }
        __syncthreads();
        // AV: ao[q][d] += W[q][k] * Vt[d][k]^T  (split 3-MFMA)
#pragma unroll
        for (int kh2 = 0; kh2 < 2; kh2++) {
            bf16x8 wah = ldb(&Wh[w * 16 + l15][kh2 * 32 + lg * 8]);
            bf16x8 wal = ldb(&Wl[w * 16 + l15][kh2 * 32 + lg * 8]);
#pragma unroll
            for (int df = 0; df < 4; df++) {
                bf16x8 vbh = ldb(&Vth[df * 16 + l15][kh2 * 32 + lg * 8]);
                bf16x8 vbl = ldb(&Vtl[df * 16 + l15][kh2 * 32 + lg * 8]);
                ao[df] = MFMA16(wah, vbl, ao[df]);
                ao[df] = MFMA16(wal, vbh, ao[df]);
                ao[df] = MFMA16(wah, vbh, ao[df]);
            }
        }
    }

    // store partial ao (no G-term) -> AOp fp32
#pragma unroll
    for (int df = 0; df < 4; df++) {
#pragma unroll
        for (int r = 0; r < 4; r++) {
            int tq = qc * 64 + dq0 + r;
            int qrow = ((tq & 3) << 8) + (tq >> 2);
            AOp[((((size_t)(b * 16 + h)) << 10) + qrow) * 64 + df * 16 + l15] = ao[df][r];
        }
    }

    // flush G (token -> attention index remap)
    __syncthreads();
    float* Gb = G + ((size_t)(b * 16 + h) << 10);
    const int lim = (qc + 1) << 6;
    for (int idx = t; idx < lim; idx += 256) {
        int j = ((idx & 3) << 8) + (idx >> 2);
        atomicAdd(&Gb[j], Gacc[idx]);
    }
}

// -------- pass_2a: per (b,h) masked prefix GV[p][d] = sum_{pos<=p} G.v --------
__global__ __launch_bounds__(256) void pass_2a(const float* __restrict__ G,
                                               const float* __restrict__ Yv,
                                               float* __restrict__ GVpre) {
    const int h = blockIdx.x, b = blockIdx.y;
    const int t = threadIdx.x;
    __shared__ float Gl[1024];
    __shared__ float S[256][64];
    __shared__ float segsum[4][64];
    for (int i = t; i < 1024; i += 256) Gl[i] = G[((size_t)(b * 16 + h) << 10) + i];
    __syncthreads();
    const int d = t & 63, pg = t >> 6;
    const float* Yvb = Yv + ((size_t)b << 20) + h * 64 + d;
    for (int p0 = 0; p0 < 64; p0++) {
        int pos = pg * 64 + p0;
        float s = 0.f;
#pragma unroll
        for (int sq = 0; sq < 4; sq++) {
            int j = (sq << 8) + pos;
            s += Gl[j] * Yvb[(size_t)j << 10];
        }
        S[pos][d] = s;
    }
    __syncthreads();
    float acc = 0.f;
    for (int p0 = 0; p0 < 64; p0++) {
        int pos = pg * 64 + p0;
        acc += S[pos][d];
        S[pos][d] = acc;
    }
    segsum[pg][d] = acc;
    __syncthreads();
    float off = 0.f;
    for (int g = 0; g < pg; g++) off += segsum[g][d];
    float* gv = GVpre + (((size_t)(b * 16 + h)) << 14) + d;
    for (int p0 = 0; p0 < 64; p0++) {
        int pos = pg * 64 + p0;
        gv[pos << 6] = S[pos][d] + off;
    }
}

// -------- pass_2b: ao = AOp + (lam/1024)*GV[pq]; RMS; bf16 store --------
__global__ __launch_bounds__(256) void pass_2b(const float* __restrict__ AOp,
                                               const float* __restrict__ GVpre,
                                               const float* __restrict__ lamp,
                                               const float* __restrict__ wan,
                                               unsigned short* __restrict__ aoS) {
    const int qg = blockIdx.x;
    const int h = blockIdx.y, b = blockIdx.z;
    const int t = threadIdx.x;
    const int d = t & 63, rg = t >> 6;
    const float lamg = (*lamp) * (1.f / 1024.f);
    const float wv = wan[d];
    const float* aob = AOp + ((((size_t)(b * 16 + h)) << 10) + (qg << 8)) * 64 + d;
    const float* gvb = GVpre + (((size_t)(b * 16 + h)) << 14) + d;
    unsigned short* ob = aoS + ((size_t)b << 20) + ((size_t)h << 16) + ((size_t)(qg << 8) << 6) + d;
    for (int p0 = 0; p0 < 64; p0++) {
        int pq = p0 * 4 + rg;
        float ao = aob[(size_t)pq << 6] + lamg * gvb[(size_t)pq << 6];
        float ss = ao * ao;
#pragma unroll
        for (int o = 1; o < 64; o <<= 1) ss += __shfl_xor(ss, o);
        float rr_ = rsqrtf(ss * (1.f / 64.f) + EPS_ATTN);
        ob[(size_t)pq << 6] = f2bf(ao * rr_ * wv);
    }
}

extern "C" void kernel_launch(void* const* d_in, const int* in_sizes, int n_in,
                              void* d_out, int out_size, void* d_ws, size_t ws_size,
                              hipStream_t stream) {
    const float* x    = (const float*)d_in[0];
    const float* fc   = (const float*)d_in[1];
    const float* w1   = (const float*)d_in[2];
    const float* w2   = (const float*)d_in[3];
    const float* Wq   = (const float*)d_in[4];
    const float* bq   = (const float*)d_in[5];
    const float* Wk   = (const float*)d_in[6];
    const float* bk   = (const float*)d_in[7];
    const float* Wv   = (const float*)d_in[8];
    const float* bv   = (const float*)d_in[9];
    const float* Wo   = (const float*)d_in[10];
    const float* bo   = (const float*)d_in[11];
    const float* lq1  = (const float*)d_in[12];
    const float* lk1  = (const float*)d_in[13];
    const float* lq2  = (const float*)d_in[14];
    const float* lk2  = (const float*)d_in[15];
    const float* wan  = (const float*)d_in[16];
    const float* Wg   = (const float*)d_in[17];
    const float* bg   = (const float*)d_in[18];
    const float* Wout = (const float*)d_in[19];
    const float* bout = (const float*)d_in[20];

    char* ws = (char*)d_ws;
    const size_t MB = 1024 * 1024;
    // Layout (peak 43 MB):
    float* G    = (float*)(ws);                     // [0, 128K)
    float* lam  = (float*)(ws + 256 * 1024);        // 4 B
    float* h32  = (float*)(ws + 1 * MB);            // [1,9)   fp32 2048x1024
    float* Yq   = (float*)(ws + 9 * MB);            // [9,17)
    float* Yk   = (float*)(ws + 17 * MB);           // [17,25)
    float* Yv   = (float*)(ws + 25 * MB);           // [25,33)
    float* AOp  = (float*)(ws + 33 * MB);           // [33,41) fp32 partial ao
    float* GVpre= (float*)(ws + 41 * MB);           // [41,43)
    unsigned short* aoS = (unsigned short*)(ws + 1 * MB);   // reuse [1,5)  (h32 dead after QKV)
    float* X1           = (float*)(ws + 9 * MB);            // reuse [9,17) (Yq dead after pass_1)
    unsigned short* h2b = (unsigned short*)(ws + 1 * MB);   // reuse [1,5)  (aoS dead after Wo gemm)
    unsigned short* mlp = (unsigned short*)(ws + 17 * MB);  // reuse [17,33) (Yk/Yv dead)

    prep<<<32, 256, 0, stream>>>(G, lam, lq1, lk1, lq2, lk2);
    rms_kernel<0><<<2048, 256, 0, stream>>>(x, w1, h32, EPS_DEF);
    // QKV via split-bf16 3-MFMA (near-fp32 precision), fused z-launch.
    gemm_qkv_split<<<dim3(16, 16, 3), 256, 0, stream>>>(h32, Wq, Wk, Wv, bq, bk, bv, Yq, Yk, Yv);
    rope_inplace<<<2048, 256, 0, stream>>>(Yq, fc);
    rope_inplace<<<2048, 256, 0, stream>>>(Yk, fc);
    pass_1<<<512, 256, 0, stream>>>(Yq, Yk, Yv, lam, G, AOp);
    pass_2a<<<dim3(16, 2), 256, 0, stream>>>(G, Yv, GVpre);
    pass_2b<<<dim3(4, 16, 2), 256, 0, stream>>>(AOp, GVpre, lam, wan, aoS);
    // Post-attention GEMMs on the matrix cores (weights bf16-rounded on the fly).
    dim3 gmf(16, 16);
    gemm_mfma<<<gmf, 256, 0, stream>>>(aoS, Wo, bo, x, X1, 2048, 1024, 1024);
    rms_kernel<1><<<2048, 256, 0, stream>>>(X1, w2, h2b, EPS_DEF);
    gemm_gate_mfma<<<dim3(16, 64), 256, 0, stream>>>(h2b, Wg, bg, mlp);
    // FINAL OUTPUT IS FP32.
    gemm_mfma<<<gmf, 256, 0, stream>>>(mlp, Wout, bout, X1, (float*)d_out, 2048, 1024, 4096);
}

// Round 7
// 503.373 us; speedup vs baseline: 7.3498x; 1.0789x over previous
//
#include <hip/hip_runtime.h>

#define LAMBDA_INIT 0.2f
#define SCALING 0.17677669529663687f   // 1/sqrt(32)
#define EPS_DEF 1.1920928955078125e-07f
#define EPS_ATTN 1e-5f

typedef unsigned short us4 __attribute__((ext_vector_type(4)));
typedef unsigned short us8v __attribute__((ext_vector_type(8)));
typedef float f32x4 __attribute__((ext_vector_type(4)));
typedef float f32x2 __attribute__((ext_vector_type(2)));
typedef __bf16 bf16x8 __attribute__((ext_vector_type(8)));

#define MFMA16(a, b, c) __builtin_amdgcn_mfma_f32_16x16x32_bf16((a), (b), (c), 0, 0, 0)

__device__ __forceinline__ float bf2f(unsigned short u) {
    unsigned int x = ((unsigned int)u) << 16;
    return __builtin_bit_cast(float, x);
}
__device__ __forceinline__ unsigned short f2bf(float f) {
    unsigned int x = __builtin_bit_cast(unsigned int, f);
    x += 0x7fffu + ((x >> 16) & 1u);
    return (unsigned short)(x >> 16);
}
// split a pair of f32x4 into hi/lo bf16 (x ~= hi + lo, residual ~2^-18 rel)
__device__ __forceinline__ void split8(f32x4 a, f32x4 b, us8v& hi, us8v& lo) {
#pragma unroll
    for (int u = 0; u < 4; u++) {
        unsigned short h = f2bf(a[u]);
        hi[u] = h; lo[u] = f2bf(a[u] - bf2f(h));
        unsigned short h2 = f2bf(b[u]);
        hi[4 + u] = h2; lo[4 + u] = f2bf(b[u] - bf2f(h2));
    }
}
__device__ __forceinline__ bf16x8 ldb(const unsigned short* p) {
    return __builtin_bit_cast(bf16x8, *(const us8v*)p);
}

__device__ __forceinline__ float wave_sum(float v) {
#pragma unroll
    for (int o = 32; o > 0; o >>= 1) v += __shfl_down(v, o);
    return v;
}
__device__ __forceinline__ float block_sum(float v, float* red4) {
    int wv = threadIdx.x >> 6;
    float w = wave_sum(v);
    __syncthreads();
    if ((threadIdx.x & 63) == 0) red4[wv] = w;
    __syncthreads();
    return red4[0] + red4[1] + red4[2] + red4[3];
}

// ---------------- prep: zero G, compute lambda ----------------
__global__ __launch_bounds__(256) void prep(float* __restrict__ G, float* __restrict__ lamp,
                                            const float* lq1, const float* lk1,
                                            const float* lq2, const float* lk2) {
    int i = (blockIdx.x * 256 + threadIdx.x) * 4;
    G[i] = 0.f; G[i + 1] = 0.f; G[i + 2] = 0.f; G[i + 3] = 0.f;
    if (blockIdx.x == 0 && threadIdx.x == 0) {
        float a = 0.f, c = 0.f;
        for (int d = 0; d < 32; d++) {
            a += lq1[d] * lk1[d];
            c += lq2[d] * lk2[d];
        }
        *lamp = expf(a) - expf(c) + LAMBDA_INIT;
    }
}

// ---------------- RMSNorm: fp32 in, fp32 weight, fp32 or bf16 out ----------------
template <int OUTBF>
__global__ __launch_bounds__(256) void rms_kernel(const float* __restrict__ x,
                                                  const float* __restrict__ w,
                                                  void* __restrict__ out, float eps) {
    int row = blockIdx.x;
    int tid = threadIdx.x;
    size_t base = (size_t)row * 1024 + tid * 4;
    f32x4 v = *(const f32x4*)(x + base);
    float ss = v[0]*v[0] + v[1]*v[1] + v[2]*v[2] + v[3]*v[3];
    __shared__ float red4[4];
    float tot = block_sum(ss, red4);
    float r = rsqrtf(tot * (1.0f / 1024.f) + eps);
    f32x4 wv = *(const f32x4*)(w + tid * 4);
    if (OUTBF) {
        us4 o;
#pragma unroll
        for (int i = 0; i < 4; i++) o[i] = f2bf(v[i] * r * wv[i]);
        *(us4*)((unsigned short*)out + base) = o;
    } else {
        f32x4 o;
#pragma unroll
        for (int i = 0; i < 4; i++) o[i] = v[i] * r * wv[i];
        *(f32x4*)((float*)out + base) = o;
    }
}

// =====================================================================
// QKV split-bf16 MFMA GEMM. BM=64, BN=64, BK=32, 4 waves (2x2), each
// wave a 32x32 sub-tile (2x2 frags). Grid (32,16,3) = 1536 blocks (6/CU).
//   Y = h32 @ W^T + b  via  al*bh + ah*bl + ah*bh  (3 MFMAs, err ~2^-18).
// =====================================================================
__global__ __launch_bounds__(256) void gemm_qkv_split(const float* __restrict__ A,
        const float* __restrict__ Wq, const float* __restrict__ Wk, const float* __restrict__ Wv,
        const float* __restrict__ bq, const float* __restrict__ bk, const float* __restrict__ bv,
        float* __restrict__ Yq, float* __restrict__ Yk, float* __restrict__ Yv) {
    const int z = blockIdx.z;
    const float* Bt  = (z == 0) ? Wq : (z == 1) ? Wk : Wv;
    const float* bias= (z == 0) ? bq : (z == 1) ? bk : bv;
    float* out       = (z == 0) ? Yq : (z == 1) ? Yk : Yv;
    const int K = 1024, N = 1024;
    __shared__ __align__(16) unsigned short Ah[64][40];
    __shared__ __align__(16) unsigned short Al[64][40];
    __shared__ __align__(16) unsigned short Bh[64][40];
    __shared__ __align__(16) unsigned short Bl[64][40];
    const int t = threadIdx.x;
    const int bm = blockIdx.x, bn = blockIdx.y;
    const int lane = t & 63, w = t >> 6;
    const int wr = w >> 1, wc = w & 1;
    const int l15 = lane & 15, lg = lane >> 4;
    const int sr = t >> 2, sc = (t & 3) * 8;

    const float* Ag = A + (size_t)(bm * 64 + sr) * K + sc;
    const float* Bg = Bt + (size_t)(bn * 64 + sr) * K + sc;

    f32x4 acc[2][2] = {};

    for (int k0 = 0; k0 < K; k0 += 32) {
        us8v ah, al, bh, bl;
        split8(*(const f32x4*)(Ag + k0), *(const f32x4*)(Ag + k0 + 4), ah, al);
        split8(*(const f32x4*)(Bg + k0), *(const f32x4*)(Bg + k0 + 4), bh, bl);
        __syncthreads();
        *(us8v*)&Ah[sr][sc] = ah;
        *(us8v*)&Al[sr][sc] = al;
        *(us8v*)&Bh[sr][sc] = bh;
        *(us8v*)&Bl[sr][sc] = bl;
        __syncthreads();
        bf16x8 afh[2], afl[2], bfh[2], bfl[2];
#pragma unroll
        for (int mi = 0; mi < 2; mi++) {
            afh[mi] = ldb(&Ah[wr * 32 + mi * 16 + l15][lg * 8]);
            afl[mi] = ldb(&Al[wr * 32 + mi * 16 + l15][lg * 8]);
        }
#pragma unroll
        for (int ni = 0; ni < 2; ni++) {
            bfh[ni] = ldb(&Bh[wc * 32 + ni * 16 + l15][lg * 8]);
            bfl[ni] = ldb(&Bl[wc * 32 + ni * 16 + l15][lg * 8]);
        }
#pragma unroll
        for (int mi = 0; mi < 2; mi++)
#pragma unroll
            for (int ni = 0; ni < 2; ni++) {
                acc[mi][ni] = MFMA16(afl[mi], bfh[ni], acc[mi][ni]);
                acc[mi][ni] = MFMA16(afh[mi], bfl[ni], acc[mi][ni]);
                acc[mi][ni] = MFMA16(afh[mi], bfh[ni], acc[mi][ni]);
            }
    }

    const int rbase = bm * 64 + wr * 32 + (lg << 2);
    const int cbase = bn * 64 + wc * 32 + l15;
#pragma unroll
    for (int mi = 0; mi < 2; mi++) {
#pragma unroll
        for (int ni = 0; ni < 2; ni++) {
            int col = cbase + ni * 16;
            float bb = bias[col];
#pragma unroll
            for (int r = 0; r < 4; r++) {
                int row = rbase + mi * 16 + r;
                out[(size_t)row * N + col] = acc[mi][ni][r] + bb;
            }
        }
    }
}

// =====================================================================
// bf16 MFMA GEMM: out = A(bf16) @ Bt(fp32->bf16 otf)^T + bias + res.
// BM=64, BN=64, BK=64, 4 waves (2x2), wave = 32x32 (2x2 frags).
// Grid (M/64, N/64) -> 512 blocks for M=2048,N=1024 (2 blocks/CU).
// =====================================================================
__global__ __launch_bounds__(256) void gemm_mfma(const unsigned short* __restrict__ A,
                                                 const float* __restrict__ Bt,
                                                 const float* __restrict__ bias,
                                                 const float* __restrict__ res,
                                                 float* __restrict__ out,
                                                 int M, int N, int K) {
    __shared__ __align__(16) unsigned short As[64][72];
    __shared__ __align__(16) unsigned short Bs[64][72];
    const int t = threadIdx.x;
    const int bm = blockIdx.x, bn = blockIdx.y;
    const int lane = t & 63, w = t >> 6;
    const int wr = w >> 1, wc = w & 1;
    const int l15 = lane & 15, lg = lane >> 4;
    const int sr = t >> 2, sc = (t & 3) * 16;

    const unsigned short* Ag = A + (size_t)(bm * 64 + sr) * K + sc;
    const float* Bg = Bt + (size_t)(bn * 64 + sr) * K + sc;

    f32x4 acc[2][2] = {};

    for (int k0 = 0; k0 < K; k0 += 64) {
        us8v a0 = *(const us8v*)(Ag + k0);
        us8v a1 = *(const us8v*)(Ag + k0 + 8);
        f32x4 b0 = *(const f32x4*)(Bg + k0);
        f32x4 b1 = *(const f32x4*)(Bg + k0 + 4);
        f32x4 b2 = *(const f32x4*)(Bg + k0 + 8);
        f32x4 b3 = *(const f32x4*)(Bg + k0 + 12);
        us8v bw0, bw1;
#pragma unroll
        for (int u = 0; u < 4; u++) {
            bw0[u] = f2bf(b0[u]); bw0[4 + u] = f2bf(b1[u]);
            bw1[u] = f2bf(b2[u]); bw1[4 + u] = f2bf(b3[u]);
        }
        __syncthreads();
        *(us8v*)&As[sr][sc]     = a0;
        *(us8v*)&As[sr][sc + 8] = a1;
        *(us8v*)&Bs[sr][sc]     = bw0;
        *(us8v*)&Bs[sr][sc + 8] = bw1;
        __syncthreads();
#pragma unroll
        for (int kk = 0; kk < 2; kk++) {
            bf16x8 af[2], bf[2];
#pragma unroll
            for (int mi = 0; mi < 2; mi++)
                af[mi] = ldb(&As[wr * 32 + mi * 16 + l15][kk * 32 + lg * 8]);
#pragma unroll
            for (int ni = 0; ni < 2; ni++)
                bf[ni] = ldb(&Bs[wc * 32 + ni * 16 + l15][kk * 32 + lg * 8]);
#pragma unroll
            for (int mi = 0; mi < 2; mi++)
#pragma unroll
                for (int ni = 0; ni < 2; ni++)
                    acc[mi][ni] = MFMA16(af[mi], bf[ni], acc[mi][ni]);
        }
    }

    const int rbase = bm * 64 + wr * 32 + (lg << 2);
    const int cbase = bn * 64 + wc * 32 + l15;
#pragma unroll
    for (int mi = 0; mi < 2; mi++) {
#pragma unroll
        for (int ni = 0; ni < 2; ni++) {
            int col = cbase + ni * 16;
            float bb = bias[col];
#pragma unroll
            for (int r = 0; r < 4; r++) {
                int row = rbase + mi * 16 + r;
                size_t oi = (size_t)row * N + col;
                out[oi] = acc[mi][ni][r] + bb + res[oi];
            }
        }
    }
}

// ------- fused gate GEMM (MFMA): mlp = (h2@Wu^T+bu) * silu(h2@Wv^T+bv) -------
// BM=128, BN=64, BK=64 (halved barrier count), grid (16,64) = 1024 blocks.
__global__ __launch_bounds__(256) void gemm_gate_mfma(const unsigned short* __restrict__ A,
                                                      const float* __restrict__ Wg,
                                                      const float* __restrict__ bg,
                                                      unsigned short* __restrict__ mlp) {
    __shared__ __align__(16) unsigned short As[128][72];
    __shared__ __align__(16) unsigned short BsU[64][72];
    __shared__ __align__(16) unsigned short BsV[64][72];
    const int t = threadIdx.x;
    const int bm = blockIdx.x, bn = blockIdx.y;
    const int lane = t & 63, w = t >> 6;
    const int wr = w >> 1, wc = w & 1;
    const int l15 = lane & 15, lg = lane >> 4;
    const int sr = t >> 2, sc = (t & 3) * 16;

    const unsigned short* Ag  = A + (size_t)(bm * 128 + sr) * 1024 + sc;
    const unsigned short* Ag2 = Ag + (size_t)64 * 1024;
    const float* BgU = Wg + (size_t)(bn * 64 + sr) * 1024 + sc;
    const float* BgV = Wg + (size_t)(4096 + bn * 64 + sr) * 1024 + sc;

    f32x4 accU[4][2] = {};
    f32x4 accV[4][2] = {};

    for (int k0 = 0; k0 < 1024; k0 += 64) {
        us8v a0 = *(const us8v*)(Ag + k0);
        us8v a1 = *(const us8v*)(Ag + k0 + 8);
        us8v a2 = *(const us8v*)(Ag2 + k0);
        us8v a3 = *(const us8v*)(Ag2 + k0 + 8);
        f32x4 u0 = *(const f32x4*)(BgU + k0);
        f32x4 u1 = *(const f32x4*)(BgU + k0 + 4);
        f32x4 u2 = *(const f32x4*)(BgU + k0 + 8);
        f32x4 u3 = *(const f32x4*)(BgU + k0 + 12);
        f32x4 v0 = *(const f32x4*)(BgV + k0);
        f32x4 v1 = *(const f32x4*)(BgV + k0 + 4);
        f32x4 v2 = *(const f32x4*)(BgV + k0 + 8);
        f32x4 v3 = *(const f32x4*)(BgV + k0 + 12);
        us8v uw0, uw1, vw0, vw1;
#pragma unroll
        for (int u = 0; u < 4; u++) {
            uw0[u] = f2bf(u0[u]); uw0[4 + u] = f2bf(u1[u]);
            uw1[u] = f2bf(u2[u]); uw1[4 + u] = f2bf(u3[u]);
            vw0[u] = f2bf(v0[u]); vw0[4 + u] = f2bf(v1[u]);
            vw1[u] = f2bf(v2[u]); vw1[4 + u] = f2bf(v3[u]);
        }
        __syncthreads();
        *(us8v*)&As[sr][sc]          = a0;
        *(us8v*)&As[sr][sc + 8]      = a1;
        *(us8v*)&As[sr + 64][sc]     = a2;
        *(us8v*)&As[sr + 64][sc + 8] = a3;
        *(us8v*)&BsU[sr][sc]         = uw0;
        *(us8v*)&BsU[sr][sc + 8]     = uw1;
        *(us8v*)&BsV[sr][sc]         = vw0;
        *(us8v*)&BsV[sr][sc + 8]     = vw1;
        __syncthreads();
#pragma unroll
        for (int kk = 0; kk < 2; kk++) {
            bf16x8 af[4], bu[2], bv2[2];
#pragma unroll
            for (int mi = 0; mi < 4; mi++)
                af[mi] = ldb(&As[wr * 64 + mi * 16 + l15][kk * 32 + lg * 8]);
#pragma unroll
            for (int ni = 0; ni < 2; ni++) {
                bu[ni]  = ldb(&BsU[wc * 32 + ni * 16 + l15][kk * 32 + lg * 8]);
                bv2[ni] = ldb(&BsV[wc * 32 + ni * 16 + l15][kk * 32 + lg * 8]);
            }
#pragma unroll
            for (int mi = 0; mi < 4; mi++)
#pragma unroll
                for (int ni = 0; ni < 2; ni++) {
                    accU[mi][ni] = MFMA16(af[mi], bu[ni], accU[mi][ni]);
                    accV[mi][ni] = MFMA16(af[mi], bv2[ni], accV[mi][ni]);
                }
        }
    }

    const int rbase = bm * 128 + wr * 64 + (lg << 2);
    const int cbase = bn * 64 + wc * 32 + l15;
#pragma unroll
    for (int mi = 0; mi < 4; mi++) {
#pragma unroll
        for (int ni = 0; ni < 2; ni++) {
            int col = cbase + ni * 16;
            float bu_ = bg[col], bv_ = bg[4096 + col];
#pragma unroll
            for (int r = 0; r < 4; r++) {
                int row = rbase + mi * 16 + r;
                float u = accU[mi][ni][r] + bu_;
                float v = accV[mi][ni][r] + bv_;
                float s = v / (1.f + __expf(-v));
                mlp[(size_t)row * 4096 + col] = f2bf(u * s);
            }
        }
    }
}

// ---------------- RoPE in place, token order ----------------
__global__ __launch_bounds__(256) void rope_inplace(float* __restrict__ Y,
                                                    const float* __restrict__ fc) {
    int t = blockIdx.x;
    int s = t & 1023;
    int p = s >> 2;
    if (p == 0) return;
    int c0 = threadIdx.x * 4;
    float* y = Y + (size_t)t * 1024 + c0;
    int d4 = (c0 & 31) >> 1;
    f32x4 f = *(const f32x4*)(fc + ((size_t)(p - 1) * 16 + d4) * 2);  // [cos,sin,cos,sin]
    float v0 = y[0], v1 = y[1], v2 = y[2], v3 = y[3];
    y[0] = v0 * f[0] - v1 * f[1];
    y[1] = v0 * f[1] + v1 * f[0];
    y[2] = v2 * f[2] - v3 * f[3];
    y[3] = v2 * f[3] + v3 * f[2];
}

// =====================================================================
// MFMA attention pass_1 (unchanged from passing round 6).
// =====================================================================
__global__ __launch_bounds__(256) void pass_1(const float* __restrict__ Yq,
                                              const float* __restrict__ Yk,
                                              const float* __restrict__ Yv,
                                              const float* __restrict__ lamp,
                                              float* __restrict__ G,
                                              float* __restrict__ AOp) {
    const int blk = blockIdx.x;
    const int qc = 15 - (blk >> 5);
    const int h  = blk & 15;
    const int b  = (blk >> 4) & 1;
    const int t = threadIdx.x;
    const int lane = t & 63, w = t >> 6;
    const int l15 = lane & 15, lg = lane >> 4;

    __shared__ __align__(16) unsigned short Kh[64][72];
    __shared__ __align__(16) unsigned short Kl[64][72];
    __shared__ __align__(16) unsigned short Vth[64][72];
    __shared__ __align__(16) unsigned short Vtl[64][72];
    __shared__ __align__(16) unsigned short Wh[64][72];
    __shared__ __align__(16) unsigned short Wl[64][72];
    __shared__ float Gacc[1024];

    for (int i = t; i < 1024; i += 256) Gacc[i] = 0.f;

    us8v qh[2], ql[2];
    {
        const float* qp = Yq + ((size_t)(b * 1024 + qc * 64 + w * 16 + l15) << 10)
                          + h * 64 + lg * 8;
#pragma unroll
        for (int H = 0; H < 2; H++)
            split8(*(const f32x4*)(qp + H * 32), *(const f32x4*)(qp + H * 32 + 4), qh[H], ql[H]);
    }
    const int dq0 = w * 16 + (lg << 2);

    const float* Ykb = Yk + ((size_t)b << 20) + h * 64;
    const float* Yvb = Yv + ((size_t)b << 20) + h * 64;
    const int srow = t >> 2, ssub = t & 3;

    float z1r[4] = {0.f, 0.f, 0.f, 0.f};
    float z2r[4] = {0.f, 0.f, 0.f, 0.f};

    // -------- sweep 1: denominators --------
    for (int kc = 0; kc <= qc; kc++) {
        __syncthreads();
        {
            const float* kp = Ykb + ((size_t)(kc * 64 + srow) << 10) + ssub * 16;
            us8v h0, l0, h1, l1;
            split8(*(const f32x4*)kp,       *(const f32x4*)(kp + 4),  h0, l0);
            split8(*(const f32x4*)(kp + 8), *(const f32x4*)(kp + 12), h1, l1);
            *(us8v*)&Kh[srow][ssub * 16]     = h0;
            *(us8v*)&Kh[srow][ssub * 16 + 8] = h1;
            *(us8v*)&Kl[srow][ssub * 16]     = l0;
            *(us8v*)&Kl[srow][ssub * 16 + 8] = l1;
        }
        __syncthreads();
#pragma unroll
        for (int kf = 0; kf < 4; kf++) {
            const int krow = kf * 16 + l15;
            const int kcol = lg * 8;
            bf16x8 b1h = ldb(&Kh[krow][kcol]),      b1l = ldb(&Kl[krow][kcol]);
            bf16x8 b2h = ldb(&Kh[krow][32 + kcol]), b2l = ldb(&Kl[krow][32 + kcol]);
            f32x4 s1 = {}, s2 = {};
            s1 = MFMA16(__builtin_bit_cast(bf16x8, ql[0]), b1h, s1);
            s1 = MFMA16(__builtin_bit_cast(bf16x8, qh[0]), b1l, s1);
            s1 = MFMA16(__builtin_bit_cast(bf16x8, qh[0]), b1h, s1);
            s2 = MFMA16(__builtin_bit_cast(bf16x8, ql[1]), b2h, s2);
            s2 = MFMA16(__builtin_bit_cast(bf16x8, qh[1]), b2l, s2);
            s2 = MFMA16(__builtin_bit_cast(bf16x8, qh[1]), b2h, s2);
            const int kpos = (kc * 64 + kf * 16 + l15) >> 2;
#pragma unroll
            for (int r = 0; r < 4; r++) {
                int pq = (qc * 64 + dq0 + r) >> 2;
                if (kpos <= pq) {
                    z1r[r] += __expf(fabsf(s1[r] * SCALING));
                    z2r[r] += __expf(fabsf(s2[r] * SCALING));
                }
            }
        }
    }
#pragma unroll
    for (int r = 0; r < 4; r++) {
        float a = z1r[r];
        a += __shfl_xor(a, 1); a += __shfl_xor(a, 2);
        a += __shfl_xor(a, 4); a += __shfl_xor(a, 8);
        z1r[r] = 1.f / fmaxf(a, 1e-20f);
        float c = z2r[r];
        c += __shfl_xor(c, 1); c += __shfl_xor(c, 2);
        c += __shfl_xor(c, 4); c += __shfl_xor(c, 8);
        z2r[r] = 1.f / fmaxf(c, 1e-20f);
    }
    const float lam = *lamp;

    f32x4 ao[4] = {};

    // -------- sweep 2: weights + G colsums + AV --------
    for (int kc = 0; kc <= qc; kc++) {
        __syncthreads();
        {
            const float* kp = Ykb + ((size_t)(kc * 64 + srow) << 10) + ssub * 16;
            us8v h0, l0, h1, l1;
            split8(*(const f32x4*)kp,       *(const f32x4*)(kp + 4),  h0, l0);
            split8(*(const f32x4*)(kp + 8), *(const f32x4*)(kp + 12), h1, l1);
            *(us8v*)&Kh[srow][ssub * 16]     = h0;
            *(us8v*)&Kh[srow][ssub * 16 + 8] = h1;
            *(us8v*)&Kl[srow][ssub * 16]     = l0;
            *(us8v*)&Kl[srow][ssub * 16 + 8] = l1;
            const int jv = ((srow & 3) << 8) + kc * 16 + (srow >> 2);
            const float* vp = Yvb + ((size_t)jv << 10) + ssub * 16;
            f32x4 vv[4];
            vv[0] = *(const f32x4*)vp;       vv[1] = *(const f32x4*)(vp + 4);
            vv[2] = *(const f32x4*)(vp + 8); vv[3] = *(const f32x4*)(vp + 12);
#pragma unroll
            for (int j = 0; j < 16; j++) {
                float val = vv[j >> 2][j & 3];
                unsigned short hh = f2bf(val);
                Vth[ssub * 16 + j][srow] = hh;
                Vtl[ssub * 16 + j][srow] = f2bf(val - bf2f(hh));
            }
        }
        __syncthreads();
#pragma unroll
        for (int kf = 0; kf < 4; kf++) {
            const int krow = kf * 16 + l15;
            const int kcol = lg * 8;
            bf16x8 b1h = ldb(&Kh[krow][kcol]),      b1l = ldb(&Kl[krow][kcol]);
            bf16x8 b2h = ldb(&Kh[krow][32 + kcol]), b2l = ldb(&Kl[krow][32 + kcol]);
            f32x4 s1 = {}, s2 = {};
            s1 = MFMA16(__builtin_bit_cast(bf16x8, ql[0]), b1h, s1);
            s1 = MFMA16(__builtin_bit_cast(bf16x8, qh[0]), b1l, s1);
            s1 = MFMA16(__builtin_bit_cast(bf16x8, qh[0]), b1h, s1);
            s2 = MFMA16(__builtin_bit_cast(bf16x8, ql[1]), b2h, s2);
            s2 = MFMA16(__builtin_bit_cast(bf16x8, qh[1]), b2l, s2);
            s2 = MFMA16(__builtin_bit_cast(bf16x8, qh[1]), b2h, s2);
            const int kli = kf * 16 + l15;
            const int kpos = (kc * 64 + kli) >> 2;
            float colsum = 0.f;
#pragma unroll
            for (int r = 0; r < 4; r++) {
                int pq = (qc * 64 + dq0 + r) >> 2;
                float wv = 0.f, a1 = 0.f;
                if (kpos <= pq) {
                    float t1 = s1[r] * SCALING, t2 = s2[r] * SCALING;
                    float sg1 = (t1 > 0.f) ? 1.f : ((t1 < 0.f) ? -1.f : 0.f);
                    float sg2 = (t2 > 0.f) ? 1.f : ((t2 < 0.f) ? -1.f : 0.f);
                    a1 = sg1 * __expf(fabsf(t1)) * z1r[r];
                    wv = a1 - lam * (sg2 * __expf(fabsf(t2)) * z2r[r]);
                }
                colsum += a1;
                unsigned short hh = f2bf(wv);
                Wh[dq0 + r][kli] = hh;
                Wl[dq0 + r][kli] = f2bf(wv - bf2f(hh));
            }
            colsum += __shfl_xor(colsum, 16);
            colsum += __shfl_xor(colsum, 32);
            if (lane < 16) atomicAdd(&Gacc[kc * 64 + kf * 16 + lane], colsum);
        }
        __syncthreads();
#pragma unroll
        for (int kh2 = 0; kh2 < 2; kh2++) {
            bf16x8 wah = ldb(&Wh[w * 16 + l15][kh2 * 32 + lg * 8]);
            bf16x8 wal = ldb(&Wl[w * 16 + l15][kh2 * 32 + lg * 8]);
#pragma unroll
            for (int df = 0; df < 4; df++) {
                bf16x8 vbh = ldb(&Vth[df * 16 + l15][kh2 * 32 + lg * 8]);
                bf16x8 vbl = ldb(&Vtl[df * 16 + l15][kh2 * 32 + lg * 8]);
                ao[df] = MFMA16(wah, vbl, ao[df]);
                ao[df] = MFMA16(wal, vbh, ao[df]);
                ao[df] = MFMA16(wah, vbh, ao[df]);
            }
        }
    }

#pragma unroll
    for (int df = 0; df < 4; df++) {
#pragma unroll
        for (int r = 0; r < 4; r++) {
            int tq = qc * 64 + dq0 + r;
            int qrow = ((tq & 3) << 8) + (tq >> 2);
            AOp[((((size_t)(b * 16 + h)) << 10) + qrow) * 64 + df * 16 + l15] = ao[df][r];
        }
    }

    __syncthreads();
    float* Gb = G + ((size_t)(b * 16 + h) << 10);
    const int lim = (qc + 1) << 6;
    for (int idx = t; idx < lim; idx += 256) {
        int j = ((idx & 3) << 8) + (idx >> 2);
        atomicAdd(&Gb[j], Gacc[idx]);
    }
}

// -------- pass_2a: per (b,h) masked prefix GV[p][d] = sum_{pos<=p} G.v --------
__global__ __launch_bounds__(256) void pass_2a(const float* __restrict__ G,
                                               const float* __restrict__ Yv,
                                               float* __restrict__ GVpre) {
    const int h = blockIdx.x, b = blockIdx.y;
    const int t = threadIdx.x;
    __shared__ float Gl[1024];
    __shared__ float S[256][64];
    __shared__ float segsum[4][64];
    for (int i = t; i < 1024; i += 256) Gl[i] = G[((size_t)(b * 16 + h) << 10) + i];
    __syncthreads();
    const int d = t & 63, pg = t >> 6;
    const float* Yvb = Yv + ((size_t)b << 20) + h * 64 + d;
    for (int p0 = 0; p0 < 64; p0++) {
        int pos = pg * 64 + p0;
        float s = 0.f;
#pragma unroll
        for (int sq = 0; sq < 4; sq++) {
            int j = (sq << 8) + pos;
            s += Gl[j] * Yvb[(size_t)j << 10];
        }
        S[pos][d] = s;
    }
    __syncthreads();
    float acc = 0.f;
    for (int p0 = 0; p0 < 64; p0++) {
        int pos = pg * 64 + p0;
        acc += S[pos][d];
        S[pos][d] = acc;
    }
    segsum[pg][d] = acc;
    __syncthreads();
    float off = 0.f;
    for (int g = 0; g < pg; g++) off += segsum[g][d];
    float* gv = GVpre + (((size_t)(b * 16 + h)) << 14) + d;
    for (int p0 = 0; p0 < 64; p0++) {
        int pos = pg * 64 + p0;
        gv[pos << 6] = S[pos][d] + off;
    }
}

// -------- pass_2b: ao = AOp + (lam/1024)*GV[pq]; RMS; bf16 store --------
__global__ __launch_bounds__(256) void pass_2b(const float* __restrict__ AOp,
                                               const float* __restrict__ GVpre,
                                               const float* __restrict__ lamp,
                                               const float* __restrict__ wan,
                                               unsigned short* __restrict__ aoS) {
    const int qg = blockIdx.x;
    const int h = blockIdx.y, b = blockIdx.z;
    const int t = threadIdx.x;
    const int d = t & 63, rg = t >> 6;
    const float lamg = (*lamp) * (1.f / 1024.f);
    const float wv = wan[d];
    const float* aob = AOp + ((((size_t)(b * 16 + h)) << 10) + (qg << 8)) * 64 + d;
    const float* gvb = GVpre + (((size_t)(b * 16 + h)) << 14) + d;
    unsigned short* ob = aoS + ((size_t)b << 20) + ((size_t)h << 16) + ((size_t)(qg << 8) << 6) + d;
    for (int p0 = 0; p0 < 64; p0++) {
        int pq = p0 * 4 + rg;
        float ao = aob[(size_t)pq << 6] + lamg * gvb[(size_t)pq << 6];
        float ss = ao * ao;
#pragma unroll
        for (int o = 1; o < 64; o <<= 1) ss += __shfl_xor(ss, o);
        float rr_ = rsqrtf(ss * (1.f / 64.f) + EPS_ATTN);
        ob[(size_t)pq << 6] = f2bf(ao * rr_ * wv);
    }
}

extern "C" void kernel_launch(void* const* d_in, const int* in_sizes, int n_in,
                              void* d_out, int out_size, void* d_ws, size_t ws_size,
                              hipStream_t stream) {
    const float* x    = (const float*)d_in[0];
    const float* fc   = (const float*)d_in[1];
    const float* w1   = (const float*)d_in[2];
    const float* w2   = (const float*)d_in[3];
    const float* Wq   = (const float*)d_in[4];
    const float* bq   = (const float*)d_in[5];
    const float* Wk   = (const float*)d_in[6];
    const float* bk   = (const float*)d_in[7];
    const float* Wv   = (const float*)d_in[8];
    const float* bv   = (const float*)d_in[9];
    const float* Wo   = (const float*)d_in[10];
    const float* bo   = (const float*)d_in[11];
    const float* lq1  = (const float*)d_in[12];
    const float* lk1  = (const float*)d_in[13];
    const float* lq2  = (const float*)d_in[14];
    const float* lk2  = (const float*)d_in[15];
    const float* wan  = (const float*)d_in[16];
    const float* Wg   = (const float*)d_in[17];
    const float* bg   = (const float*)d_in[18];
    const float* Wout = (const float*)d_in[19];
    const float* bout = (const float*)d_in[20];

    char* ws = (char*)d_ws;
    const size_t MB = 1024 * 1024;
    // Layout (peak 43 MB):
    float* G    = (float*)(ws);                     // [0, 128K)
    float* lam  = (float*)(ws + 256 * 1024);        // 4 B
    float* h32  = (float*)(ws + 1 * MB);            // [1,9)   fp32 2048x1024
    float* Yq   = (float*)(ws + 9 * MB);            // [9,17)
    float* Yk   = (float*)(ws + 17 * MB);           // [17,25)
    float* Yv   = (float*)(ws + 25 * MB);           // [25,33)
    float* AOp  = (float*)(ws + 33 * MB);           // [33,41) fp32 partial ao
    float* GVpre= (float*)(ws + 41 * MB);           // [41,43)
    unsigned short* aoS = (unsigned short*)(ws + 1 * MB);   // reuse [1,5)  (h32 dead after QKV)
    float* X1           = (float*)(ws + 9 * MB);            // reuse [9,17) (Yq dead after pass_1)
    unsigned short* h2b = (unsigned short*)(ws + 1 * MB);   // reuse [1,5)  (aoS dead after Wo gemm)
    unsigned short* mlp = (unsigned short*)(ws + 17 * MB);  // reuse [17,33) (Yk/Yv dead)

    prep<<<32, 256, 0, stream>>>(G, lam, lq1, lk1, lq2, lk2);
    rms_kernel<0><<<2048, 256, 0, stream>>>(x, w1, h32, EPS_DEF);
    // QKV via split-bf16 3-MFMA (near-fp32 precision), 64x64 tiles (6 blocks/CU).
    gemm_qkv_split<<<dim3(32, 16, 3), 256, 0, stream>>>(h32, Wq, Wk, Wv, bq, bk, bv, Yq, Yk, Yv);
    rope_inplace<<<2048, 256, 0, stream>>>(Yq, fc);
    rope_inplace<<<2048, 256, 0, stream>>>(Yk, fc);
    pass_1<<<512, 256, 0, stream>>>(Yq, Yk, Yv, lam, G, AOp);
    pass_2a<<<dim3(16, 2), 256, 0, stream>>>(G, Yv, GVpre);
    pass_2b<<<dim3(4, 16, 2), 256, 0, stream>>>(AOp, GVpre, lam, wan, aoS);
    // Post-attention GEMMs: 64x64x64 tiles, 512 blocks (2/CU).
    dim3 gmf(32, 16);
    gemm_mfma<<<gmf, 256, 0, stream>>>(aoS, Wo, bo, x, X1, 2048, 1024, 1024);
    rms_kernel<1><<<2048, 256, 0, stream>>>(X1, w2, h2b, EPS_DEF);
    gemm_gate_mfma<<<dim3(16, 64), 256, 0, stream>>>(h2b, Wg, bg, mlp);
    // FINAL OUTPUT IS FP32.
    gemm_mfma<<<gmf, 256, 0, stream>>>(mlp, Wout, bout, X1, (float*)d_out, 2048, 1024, 4096);
}

// Round 9
// 476.206 us; speedup vs baseline: 7.7691x; 1.0570x over previous
//
#include <hip/hip_runtime.h>

#define LAMBDA_INIT 0.2f
#define SCALING 0.17677669529663687f   // 1/sqrt(32)
#define EPS_DEF 1.1920928955078125e-07f
#define EPS_ATTN 1e-5f

typedef unsigned short us4 __attribute__((ext_vector_type(4)));
typedef unsigned short us8v __attribute__((ext_vector_type(8)));
typedef float f32x4 __attribute__((ext_vector_type(4)));
typedef float f32x2 __attribute__((ext_vector_type(2)));
typedef __bf16 bf16x8 __attribute__((ext_vector_type(8)));

#define MFMA16(a, b, c) __builtin_amdgcn_mfma_f32_16x16x32_bf16((a), (b), (c), 0, 0, 0)

__device__ __forceinline__ float bf2f(unsigned short u) {
    unsigned int x = ((unsigned int)u) << 16;
    return __builtin_bit_cast(float, x);
}
__device__ __forceinline__ unsigned short f2bf(float f) {
    unsigned int x = __builtin_bit_cast(unsigned int, f);
    x += 0x7fffu + ((x >> 16) & 1u);
    return (unsigned short)(x >> 16);
}
// split a pair of f32x4 into hi/lo bf16 (x ~= hi + lo, residual ~2^-18 rel)
__device__ __forceinline__ void split8(f32x4 a, f32x4 b, us8v& hi, us8v& lo) {
#pragma unroll
    for (int u = 0; u < 4; u++) {
        unsigned short h = f2bf(a[u]);
        hi[u] = h; lo[u] = f2bf(a[u] - bf2f(h));
        unsigned short h2 = f2bf(b[u]);
        hi[4 + u] = h2; lo[4 + u] = f2bf(b[u] - bf2f(h2));
    }
}
__device__ __forceinline__ bf16x8 ldb(const unsigned short* p) {
    return __builtin_bit_cast(bf16x8, *(const us8v*)p);
}

__device__ __forceinline__ float wave_sum(float v) {
#pragma unroll
    for (int o = 32; o > 0; o >>= 1) v += __shfl_down(v, o);
    return v;
}
__device__ __forceinline__ float block_sum(float v, float* red4) {
    int wv = threadIdx.x >> 6;
    float w = wave_sum(v);
    __syncthreads();
    if ((threadIdx.x & 63) == 0) red4[wv] = w;
    __syncthreads();
    return red4[0] + red4[1] + red4[2] + red4[3];
}

// ---------------- prep: zero G, compute lambda ----------------
__global__ __launch_bounds__(256) void prep(float* __restrict__ G, float* __restrict__ lamp,
                                            const float* lq1, const float* lk1,
                                            const float* lq2, const float* lk2) {
    int i = (blockIdx.x * 256 + threadIdx.x) * 4;
    G[i] = 0.f; G[i + 1] = 0.f; G[i + 2] = 0.f; G[i + 3] = 0.f;
    if (blockIdx.x == 0 && threadIdx.x == 0) {
        float a = 0.f, c = 0.f;
        for (int d = 0; d < 32; d++) {
            a += lq1[d] * lk1[d];
            c += lq2[d] * lk2[d];
        }
        *lamp = expf(a) - expf(c) + LAMBDA_INIT;
    }
}

// ---------------- fp32 -> bf16 weight conversion ----------------
__global__ __launch_bounds__(256) void cvt_bf16(const float* __restrict__ s,
                                                unsigned short* __restrict__ d, int n4) {
    int i = blockIdx.x * 256 + threadIdx.x;
    if (i >= n4) return;
    f32x4 v = ((const f32x4*)s)[i];
    us4 o;
#pragma unroll
    for (int u = 0; u < 4; u++) o[u] = f2bf(v[u]);
    ((us4*)d)[i] = o;
}

// ---------------- RMSNorm: fp32 in, fp32 weight, fp32 or bf16 out ----------------
template <int OUTBF>
__global__ __launch_bounds__(256) void rms_kernel(const float* __restrict__ x,
                                                  const float* __restrict__ w,
                                                  void* __restrict__ out, float eps) {
    int row = blockIdx.x;
    int tid = threadIdx.x;
    size_t base = (size_t)row * 1024 + tid * 4;
    f32x4 v = *(const f32x4*)(x + base);
    float ss = v[0]*v[0] + v[1]*v[1] + v[2]*v[2] + v[3]*v[3];
    __shared__ float red4[4];
    float tot = block_sum(ss, red4);
    float r = rsqrtf(tot * (1.0f / 1024.f) + eps);
    f32x4 wv = *(const f32x4*)(w + tid * 4);
    if (OUTBF) {
        us4 o;
#pragma unroll
        for (int i = 0; i < 4; i++) o[i] = f2bf(v[i] * r * wv[i]);
        *(us4*)((unsigned short*)out + base) = o;
    } else {
        f32x4 o;
#pragma unroll
        for (int i = 0; i < 4; i++) o[i] = v[i] * r * wv[i];
        *(f32x4*)((float*)out + base) = o;
    }
}

// =====================================================================
// QKV split-bf16 MFMA GEMM. BM=64, BN=64, BK=32, 4 waves (2x2).
// =====================================================================
__global__ __launch_bounds__(256) void gemm_qkv_split(const float* __restrict__ A,
        const float* __restrict__ Wq, const float* __restrict__ Wk, const float* __restrict__ Wv,
        const float* __restrict__ bq, const float* __restrict__ bk, const float* __restrict__ bv,
        float* __restrict__ Yq, float* __restrict__ Yk, float* __restrict__ Yv) {
    const int z = blockIdx.z;
    const float* Bt  = (z == 0) ? Wq : (z == 1) ? Wk : Wv;
    const float* bias= (z == 0) ? bq : (z == 1) ? bk : bv;
    float* out       = (z == 0) ? Yq : (z == 1) ? Yk : Yv;
    const int K = 1024, N = 1024;
    __shared__ __align__(16) unsigned short Ah[64][40];
    __shared__ __align__(16) unsigned short Al[64][40];
    __shared__ __align__(16) unsigned short Bh[64][40];
    __shared__ __align__(16) unsigned short Bl[64][40];
    const int t = threadIdx.x;
    const int bm = blockIdx.x, bn = blockIdx.y;
    const int lane = t & 63, w = t >> 6;
    const int wr = w >> 1, wc = w & 1;
    const int l15 = lane & 15, lg = lane >> 4;
    const int sr = t >> 2, sc = (t & 3) * 8;

    const float* Ag = A + (size_t)(bm * 64 + sr) * K + sc;
    const float* Bg = Bt + (size_t)(bn * 64 + sr) * K + sc;

    f32x4 acc[2][2] = {};

    for (int k0 = 0; k0 < K; k0 += 32) {
        us8v ah, al, bh, bl;
        split8(*(const f32x4*)(Ag + k0), *(const f32x4*)(Ag + k0 + 4), ah, al);
        split8(*(const f32x4*)(Bg + k0), *(const f32x4*)(Bg + k0 + 4), bh, bl);
        __syncthreads();
        *(us8v*)&Ah[sr][sc] = ah;
        *(us8v*)&Al[sr][sc] = al;
        *(us8v*)&Bh[sr][sc] = bh;
        *(us8v*)&Bl[sr][sc] = bl;
        __syncthreads();
        bf16x8 afh[2], afl[2], bfh[2], bfl[2];
#pragma unroll
        for (int mi = 0; mi < 2; mi++) {
            afh[mi] = ldb(&Ah[wr * 32 + mi * 16 + l15][lg * 8]);
            afl[mi] = ldb(&Al[wr * 32 + mi * 16 + l15][lg * 8]);
        }
#pragma unroll
        for (int ni = 0; ni < 2; ni++) {
            bfh[ni] = ldb(&Bh[wc * 32 + ni * 16 + l15][lg * 8]);
            bfl[ni] = ldb(&Bl[wc * 32 + ni * 16 + l15][lg * 8]);
        }
#pragma unroll
        for (int mi = 0; mi < 2; mi++)
#pragma unroll
            for (int ni = 0; ni < 2; ni++) {
                acc[mi][ni] = MFMA16(afl[mi], bfh[ni], acc[mi][ni]);
                acc[mi][ni] = MFMA16(afh[mi], bfl[ni], acc[mi][ni]);
                acc[mi][ni] = MFMA16(afh[mi], bfh[ni], acc[mi][ni]);
            }
    }

    const int rbase = bm * 64 + wr * 32 + (lg << 2);
    const int cbase = bn * 64 + wc * 32 + l15;
#pragma unroll
    for (int mi = 0; mi < 2; mi++) {
#pragma unroll
        for (int ni = 0; ni < 2; ni++) {
            int col = cbase + ni * 16;
            float bb = bias[col];
#pragma unroll
            for (int r = 0; r < 4; r++) {
                int row = rbase + mi * 16 + r;
                out[(size_t)row * N + col] = acc[mi][ni][r] + bb;
            }
        }
    }
}

// =====================================================================
// bf16 MFMA GEMM, pre-converted bf16 B: out = A @ Bt^T + bias + res.
// BM=64, BN=64, BK=64, 4 waves (2x2).
// =====================================================================
__global__ __launch_bounds__(256) void gemm_mfma_wb(const unsigned short* __restrict__ A,
                                                    const unsigned short* __restrict__ Bt,
                                                    const float* __restrict__ bias,
                                                    const float* __restrict__ res,
                                                    float* __restrict__ out,
                                                    int M, int N, int K) {
    __shared__ __align__(16) unsigned short As[64][72];
    __shared__ __align__(16) unsigned short Bs[64][72];
    const int t = threadIdx.x;
    const int bm = blockIdx.x, bn = blockIdx.y;
    const int lane = t & 63, w = t >> 6;
    const int wr = w >> 1, wc = w & 1;
    const int l15 = lane & 15, lg = lane >> 4;
    const int sr = t >> 2, sc = (t & 3) * 16;

    const unsigned short* Ag = A + (size_t)(bm * 64 + sr) * K + sc;
    const unsigned short* Bg = Bt + (size_t)(bn * 64 + sr) * K + sc;

    f32x4 acc[2][2] = {};

    for (int k0 = 0; k0 < K; k0 += 64) {
        us8v a0 = *(const us8v*)(Ag + k0);
        us8v a1 = *(const us8v*)(Ag + k0 + 8);
        us8v b0 = *(const us8v*)(Bg + k0);
        us8v b1 = *(const us8v*)(Bg + k0 + 8);
        __syncthreads();
        *(us8v*)&As[sr][sc]     = a0;
        *(us8v*)&As[sr][sc + 8] = a1;
        *(us8v*)&Bs[sr][sc]     = b0;
        *(us8v*)&Bs[sr][sc + 8] = b1;
        __syncthreads();
#pragma unroll
        for (int kk = 0; kk < 2; kk++) {
            bf16x8 af[2], bf[2];
#pragma unroll
            for (int mi = 0; mi < 2; mi++)
                af[mi] = ldb(&As[wr * 32 + mi * 16 + l15][kk * 32 + lg * 8]);
#pragma unroll
            for (int ni = 0; ni < 2; ni++)
                bf[ni] = ldb(&Bs[wc * 32 + ni * 16 + l15][kk * 32 + lg * 8]);
#pragma unroll
            for (int mi = 0; mi < 2; mi++)
#pragma unroll
                for (int ni = 0; ni < 2; ni++)
                    acc[mi][ni] = MFMA16(af[mi], bf[ni], acc[mi][ni]);
        }
    }

    const int rbase = bm * 64 + wr * 32 + (lg << 2);
    const int cbase = bn * 64 + wc * 32 + l15;
#pragma unroll
    for (int mi = 0; mi < 2; mi++) {
#pragma unroll
        for (int ni = 0; ni < 2; ni++) {
            int col = cbase + ni * 16;
            float bb = bias[col];
#pragma unroll
            for (int r = 0; r < 4; r++) {
                int row = rbase + mi * 16 + r;
                size_t oi = (size_t)row * N + col;
                out[oi] = acc[mi][ni][r] + bb + res[oi];
            }
        }
    }
}

// ------- fused gate GEMM (MFMA): mlp = (h2@Wu^T+bu) * silu(h2@Wv^T+bv) -------
__global__ __launch_bounds__(256) void gemm_gate_mfma(const unsigned short* __restrict__ A,
                                                      const float* __restrict__ Wg,
                                                      const float* __restrict__ bg,
                                                      unsigned short* __restrict__ mlp) {
    __shared__ __align__(16) unsigned short As[128][72];
    __shared__ __align__(16) unsigned short BsU[64][72];
    __shared__ __align__(16) unsigned short BsV[64][72];
    const int t = threadIdx.x;
    const int bm = blockIdx.x, bn = blockIdx.y;
    const int lane = t & 63, w = t >> 6;
    const int wr = w >> 1, wc = w & 1;
    const int l15 = lane & 15, lg = lane >> 4;
    const int sr = t >> 2, sc = (t & 3) * 16;

    const unsigned short* Ag  = A + (size_t)(bm * 128 + sr) * 1024 + sc;
    const unsigned short* Ag2 = Ag + (size_t)64 * 1024;
    const float* BgU = Wg + (size_t)(bn * 64 + sr) * 1024 + sc;
    const float* BgV = Wg + (size_t)(4096 + bn * 64 + sr) * 1024 + sc;

    f32x4 accU[4][2] = {};
    f32x4 accV[4][2] = {};

    for (int k0 = 0; k0 < 1024; k0 += 64) {
        us8v a0 = *(const us8v*)(Ag + k0);
        us8v a1 = *(const us8v*)(Ag + k0 + 8);
        us8v a2 = *(const us8v*)(Ag2 + k0);
        us8v a3 = *(const us8v*)(Ag2 + k0 + 8);
        f32x4 u0 = *(const f32x4*)(BgU + k0);
        f32x4 u1 = *(const f32x4*)(BgU + k0 + 4);
        f32x4 u2 = *(const f32x4*)(BgU + k0 + 8);
        f32x4 u3 = *(const f32x4*)(BgU + k0 + 12);
        f32x4 v0 = *(const f32x4*)(BgV + k0);
        f32x4 v1 = *(const f32x4*)(BgV + k0 + 4);
        f32x4 v2 = *(const f32x4*)(BgV + k0 + 8);
        f32x4 v3 = *(const f32x4*)(BgV + k0 + 12);
        us8v uw0, uw1, vw0, vw1;
#pragma unroll
        for (int u = 0; u < 4; u++) {
            uw0[u] = f2bf(u0[u]); uw0[4 + u] = f2bf(u1[u]);
            uw1[u] = f2bf(u2[u]); uw1[4 + u] = f2bf(u3[u]);
            vw0[u] = f2bf(v0[u]); vw0[4 + u] = f2bf(v1[u]);
            vw1[u] = f2bf(v2[u]); vw1[4 + u] = f2bf(v3[u]);
        }
        __syncthreads();
        *(us8v*)&As[sr][sc]          = a0;
        *(us8v*)&As[sr][sc + 8]      = a1;
        *(us8v*)&As[sr + 64][sc]     = a2;
        *(us8v*)&As[sr + 64][sc + 8] = a3;
        *(us8v*)&BsU[sr][sc]         = uw0;
        *(us8v*)&BsU[sr][sc + 8]     = uw1;
        *(us8v*)&BsV[sr][sc]         = vw0;
        *(us8v*)&BsV[sr][sc + 8]     = vw1;
        __syncthreads();
#pragma unroll
        for (int kk = 0; kk < 2; kk++) {
            bf16x8 af[4], bu[2], bv2[2];
#pragma unroll
            for (int mi = 0; mi < 4; mi++)
                af[mi] = ldb(&As[wr * 64 + mi * 16 + l15][kk * 32 + lg * 8]);
#pragma unroll
            for (int ni = 0; ni < 2; ni++) {
                bu[ni]  = ldb(&BsU[wc * 32 + ni * 16 + l15][kk * 32 + lg * 8]);
                bv2[ni] = ldb(&BsV[wc * 32 + ni * 16 + l15][kk * 32 + lg * 8]);
            }
#pragma unroll
            for (int mi = 0; mi < 4; mi++)
#pragma unroll
                for (int ni = 0; ni < 2; ni++) {
                    accU[mi][ni] = MFMA16(af[mi], bu[ni], accU[mi][ni]);
                    accV[mi][ni] = MFMA16(af[mi], bv2[ni], accV[mi][ni]);
                }
        }
    }

    const int rbase = bm * 128 + wr * 64 + (lg << 2);
    const int cbase = bn * 64 + wc * 32 + l15;
#pragma unroll
    for (int mi = 0; mi < 4; mi++) {
#pragma unroll
        for (int ni = 0; ni < 2; ni++) {
            int col = cbase + ni * 16;
            float bu_ = bg[col], bv_ = bg[4096 + col];
#pragma unroll
            for (int r = 0; r < 4; r++) {
                int row = rbase + mi * 16 + r;
                float u = accU[mi][ni][r] + bu_;
                float v = accV[mi][ni][r] + bv_;
                float s = v / (1.f + __expf(-v));
                mlp[(size_t)row * 4096 + col] = f2bf(u * s);
            }
        }
    }
}

// ---------------- RoPE in place (Q), token order ----------------
__global__ __launch_bounds__(256) void rope_inplace(float* __restrict__ Y,
                                                    const float* __restrict__ fc) {
    int t = blockIdx.x;
    int s = t & 1023;
    int p = s >> 2;
    if (p == 0) return;
    int c0 = threadIdx.x * 4;
    float* y = Y + (size_t)t * 1024 + c0;
    int d4 = (c0 & 31) >> 1;
    f32x4 f = *(const f32x4*)(fc + ((size_t)(p - 1) * 16 + d4) * 2);  // [cos,sin,cos,sin]
    float v0 = y[0], v1 = y[1], v2 = y[2], v3 = y[3];
    y[0] = v0 * f[0] - v1 * f[1];
    y[1] = v0 * f[1] + v1 * f[0];
    y[2] = v2 * f[2] - v3 * f[3];
    y[3] = v2 * f[3] + v3 * f[2];
}

// ------- RoPE(K) + hi/lo bf16 split, token-order output -------
__global__ __launch_bounds__(256) void rope_split_k(const float* __restrict__ Yk,
                                                    const float* __restrict__ fc,
                                                    unsigned short* __restrict__ KhG,
                                                    unsigned short* __restrict__ KlG) {
    int t = blockIdx.x;           // b*1024 + s
    int s = t & 1023;
    int p = s >> 2;
    int c0 = threadIdx.x * 4;
    const float* y = Yk + (size_t)t * 1024 + c0;
    float v0 = y[0], v1 = y[1], v2 = y[2], v3 = y[3];
    if (p > 0) {
        int d4 = (c0 & 31) >> 1;
        f32x4 f = *(const f32x4*)(fc + ((size_t)(p - 1) * 16 + d4) * 2);
        float w0 = v0 * f[0] - v1 * f[1];
        float w1 = v0 * f[1] + v1 * f[0];
        float w2 = v2 * f[2] - v3 * f[3];
        float w3 = v2 * f[3] + v3 * f[2];
        v0 = w0; v1 = w1; v2 = w2; v3 = w3;
    }
    us4 hi, lo;
    hi[0] = f2bf(v0); lo[0] = f2bf(v0 - bf2f(hi[0]));
    hi[1] = f2bf(v1); lo[1] = f2bf(v1 - bf2f(hi[1]));
    hi[2] = f2bf(v2); lo[2] = f2bf(v2 - bf2f(hi[2]));
    hi[3] = f2bf(v3); lo[3] = f2bf(v3 - bf2f(hi[3]));
    *(us4*)(KhG + (size_t)t * 1024 + c0) = hi;
    *(us4*)(KlG + (size_t)t * 1024 + c0) = lo;
}

// ------- V transpose + hi/lo split: Vt[(b,h)][d (64)][j (1024)] -------
// V row for attention index j is RAW Yv row j (reference quirk).
__global__ __launch_bounds__(256) void v_split_t(const float* __restrict__ Yv,
                                                 unsigned short* __restrict__ VtH,
                                                 unsigned short* __restrict__ VtL) {
    const int jc = blockIdx.x, h = blockIdx.y, b = blockIdx.z;   // (16,16,2)
    __shared__ float tile[64][65];
    const int t = threadIdx.x;
    {
        const int jr = t >> 2, dc = (t & 3) * 16;
        const float* src = Yv + ((size_t)(b * 1024 + jc * 64 + jr) << 10) + h * 64 + dc;
        *(f32x4*)&tile[jr][dc]      = *(const f32x4*)src;
        *(f32x4*)&tile[jr][dc + 4]  = *(const f32x4*)(src + 4);
        *(f32x4*)&tile[jr][dc + 8]  = *(const f32x4*)(src + 8);
        *(f32x4*)&tile[jr][dc + 12] = *(const f32x4*)(src + 12);
    }
    __syncthreads();
    const int d = t >> 2, js = (t & 3) * 16;
    us8v h0, h1, l0, l1;
#pragma unroll
    for (int n = 0; n < 16; n++) {
        float val = tile[js + n][d];
        unsigned short hh = f2bf(val);
        unsigned short ll = f2bf(val - bf2f(hh));
        if (n < 8) { h0[n] = hh; l0[n] = ll; }
        else       { h1[n - 8] = hh; l1[n - 8] = ll; }
    }
    size_t ob = (((size_t)(b * 16 + h) * 64 + d) << 10) + jc * 64 + js;
    *(us8v*)(VtH + ob) = h0; *(us8v*)(VtH + ob + 8) = h1;
    *(us8v*)(VtL + ob) = l0; *(us8v*)(VtL + ob + 8) = l1;
}

// =====================================================================
// MFMA attention pass_1 (pre-split K, pre-transposed+split V).
// Column permutation: local column r <-> token kc*64 + 4*(r&15) + (r>>4),
// so column r's attention index j = (r>>4)*256 + kc*16 + (r&15) and the
// causal position is kc*16 + (r&15)  (kf-uniform mask). Gacc is kept in
// attention-index order (no remap at flush). All math identical to R7.
// =====================================================================
__global__ __launch_bounds__(256) void pass_1(const float* __restrict__ Yq,
                                              const unsigned short* __restrict__ KhG,
                                              const unsigned short* __restrict__ KlG,
                                              const unsigned short* __restrict__ VtH,
                                              const unsigned short* __restrict__ VtL,
                                              const float* __restrict__ lamp,
                                              float* __restrict__ G,
                                              float* __restrict__ AOp) {
    const int blk = blockIdx.x;
    const int qc = 15 - (blk >> 5);
    const int h  = blk & 15;
    const int b  = (blk >> 4) & 1;
    const int t = threadIdx.x;
    const int lane = t & 63, w = t >> 6;
    const int l15 = lane & 15, lg = lane >> 4;

    __shared__ __align__(16) unsigned short Kh[64][72];
    __shared__ __align__(16) unsigned short Kl[64][72];
    __shared__ __align__(16) unsigned short Vth[64][72];
    __shared__ __align__(16) unsigned short Vtl[64][72];
    __shared__ __align__(16) unsigned short Wh[64][72];
    __shared__ __align__(16) unsigned short Wl[64][72];
    __shared__ float Gacc[1024];

    for (int i = t; i < 1024; i += 256) Gacc[i] = 0.f;

    us8v qh[2], ql[2];
    {
        const float* qp = Yq + ((size_t)(b * 1024 + qc * 64 + w * 16 + l15) << 10)
                          + h * 64 + lg * 8;
#pragma unroll
        for (int H = 0; H < 2; H++)
            split8(*(const f32x4*)(qp + H * 32), *(const f32x4*)(qp + H * 32 + 4), qh[H], ql[H]);
    }
    const int dq0 = w * 16 + (lg << 2);

    const int srow = t >> 2, ssub = t & 3;
    const int ptk = 4 * (srow & 15) + (srow >> 4);   // permuted in-chunk token for row srow
    const unsigned short* KhB = KhG + ((size_t)(b * 1024) << 10) + h * 64;
    const unsigned short* KlB = KlG + ((size_t)(b * 1024) << 10) + h * 64;
    const unsigned short* VhB = VtH + (((size_t)(b * 16 + h) * 64 + srow) << 10) + ssub * 256;
    const unsigned short* VlB = VtL + (((size_t)(b * 16 + h) * 64 + srow) << 10) + ssub * 256;

    float z1r[4] = {0.f, 0.f, 0.f, 0.f};
    float z2r[4] = {0.f, 0.f, 0.f, 0.f};

    // -------- sweep 1: denominators --------
    for (int kc = 0; kc <= qc; kc++) {
        __syncthreads();
        {
            const unsigned short* kh = KhB + ((size_t)(kc * 64 + ptk) << 10) + ssub * 16;
            const unsigned short* kl = KlB + ((size_t)(kc * 64 + ptk) << 10) + ssub * 16;
            *(us8v*)&Kh[srow][ssub * 16]     = *(const us8v*)kh;
            *(us8v*)&Kh[srow][ssub * 16 + 8] = *(const us8v*)(kh + 8);
            *(us8v*)&Kl[srow][ssub * 16]     = *(const us8v*)kl;
            *(us8v*)&Kl[srow][ssub * 16 + 8] = *(const us8v*)(kl + 8);
        }
        __syncthreads();
        const int kpos = kc * 16 + l15;
#pragma unroll
        for (int kf = 0; kf < 4; kf++) {
            const int krow = kf * 16 + l15;
            const int kcol = lg * 8;
            bf16x8 b1h = ldb(&Kh[krow][kcol]),      b1l = ldb(&Kl[krow][kcol]);
            bf16x8 b2h = ldb(&Kh[krow][32 + kcol]), b2l = ldb(&Kl[krow][32 + kcol]);
            f32x4 s1 = {}, s2 = {};
            s1 = MFMA16(__builtin_bit_cast(bf16x8, ql[0]), b1h, s1);
            s1 = MFMA16(__builtin_bit_cast(bf16x8, qh[0]), b1l, s1);
            s1 = MFMA16(__builtin_bit_cast(bf16x8, qh[0]), b1h, s1);
            s2 = MFMA16(__builtin_bit_cast(bf16x8, ql[1]), b2h, s2);
            s2 = MFMA16(__builtin_bit_cast(bf16x8, qh[1]), b2l, s2);
            s2 = MFMA16(__builtin_bit_cast(bf16x8, qh[1]), b2h, s2);
#pragma unroll
            for (int r = 0; r < 4; r++) {
                int pq = (qc * 64 + dq0 + r) >> 2;
                if (kpos <= pq) {
                    z1r[r] += __expf(fabsf(s1[r] * SCALING));
                    z2r[r] += __expf(fabsf(s2[r] * SCALING));
                }
            }
        }
    }
#pragma unroll
    for (int r = 0; r < 4; r++) {
        float a = z1r[r];
        a += __shfl_xor(a, 1); a += __shfl_xor(a, 2);
        a += __shfl_xor(a, 4); a += __shfl_xor(a, 8);
        z1r[r] = 1.f / fmaxf(a, 1e-20f);
        float c = z2r[r];
        c += __shfl_xor(c, 1); c += __shfl_xor(c, 2);
        c += __shfl_xor(c, 4); c += __shfl_xor(c, 8);
        z2r[r] = 1.f / fmaxf(c, 1e-20f);
    }
    const float lam = *lamp;

    f32x4 ao[4] = {};

    // -------- sweep 2: weights + G colsums + AV --------
    for (int kc = 0; kc <= qc; kc++) {
        __syncthreads();
        {
            const unsigned short* kh = KhB + ((size_t)(kc * 64 + ptk) << 10) + ssub * 16;
            const unsigned short* kl = KlB + ((size_t)(kc * 64 + ptk) << 10) + ssub * 16;
            *(us8v*)&Kh[srow][ssub * 16]     = *(const us8v*)kh;
            *(us8v*)&Kh[srow][ssub * 16 + 8] = *(const us8v*)(kh + 8);
            *(us8v*)&Kl[srow][ssub * 16]     = *(const us8v*)kl;
            *(us8v*)&Kl[srow][ssub * 16 + 8] = *(const us8v*)(kl + 8);
            // V: row srow = d, segment ssub = m; 16 contiguous j tokens.
            const unsigned short* vh = VhB + kc * 16;
            const unsigned short* vl = VlB + kc * 16;
            *(us8v*)&Vth[srow][ssub * 16]     = *(const us8v*)vh;
            *(us8v*)&Vth[srow][ssub * 16 + 8] = *(const us8v*)(vh + 8);
            *(us8v*)&Vtl[srow][ssub * 16]     = *(const us8v*)vl;
            *(us8v*)&Vtl[srow][ssub * 16 + 8] = *(const us8v*)(vl + 8);
        }
        __syncthreads();
        const int kpos = kc * 16 + l15;
#pragma unroll
        for (int kf = 0; kf < 4; kf++) {
            const int krow = kf * 16 + l15;
            const int kcol = lg * 8;
            bf16x8 b1h = ldb(&Kh[krow][kcol]),      b1l = ldb(&Kl[krow][kcol]);
            bf16x8 b2h = ldb(&Kh[krow][32 + kcol]), b2l = ldb(&Kl[krow][32 + kcol]);
            f32x4 s1 = {}, s2 = {};
            s1 = MFMA16(__builtin_bit_cast(bf16x8, ql[0]), b1h, s1);
            s1 = MFMA16(__builtin_bit_cast(bf16x8, qh[0]), b1l, s1);
            s1 = MFMA16(__builtin_bit_cast(bf16x8, qh[0]), b1h, s1);
            s2 = MFMA16(__builtin_bit_cast(bf16x8, ql[1]), b2h, s2);
            s2 = MFMA16(__builtin_bit_cast(bf16x8, qh[1]), b2l, s2);
            s2 = MFMA16(__builtin_bit_cast(bf16x8, qh[1]), b2h, s2);
            const int kli = kf * 16 + l15;
            float colsum = 0.f;
#pragma unroll
            for (int r = 0; r < 4; r++) {
                int pq = (qc * 64 + dq0 + r) >> 2;
                float wv = 0.f, a1 = 0.f;
                if (kpos <= pq) {
                    float t1 = s1[r] * SCALING, t2 = s2[r] * SCALING;
                    float sg1 = (t1 > 0.f) ? 1.f : ((t1 < 0.f) ? -1.f : 0.f);
                    float sg2 = (t2 > 0.f) ? 1.f : ((t2 < 0.f) ? -1.f : 0.f);
                    a1 = sg1 * __expf(fabsf(t1)) * z1r[r];
                    wv = a1 - lam * (sg2 * __expf(fabsf(t2)) * z2r[r]);
                }
                colsum += a1;
                unsigned short hh = f2bf(wv);
                Wh[dq0 + r][kli] = hh;
                Wl[dq0 + r][kli] = f2bf(wv - bf2f(hh));
            }
            colsum += __shfl_xor(colsum, 16);
            colsum += __shfl_xor(colsum, 32);
            // column r=kf*16+lane -> attention index j = kf*256 + kc*16 + lane
            if (lane < 16) atomicAdd(&Gacc[kf * 256 + kc * 16 + lane], colsum);
        }
        __syncthreads();
#pragma unroll
        for (int kh2 = 0; kh2 < 2; kh2++) {
            bf16x8 wah = ldb(&Wh[w * 16 + l15][kh2 * 32 + lg * 8]);
            bf16x8 wal = ldb(&Wl[w * 16 + l15][kh2 * 32 + lg * 8]);
#pragma unroll
            for (int df = 0; df < 4; df++) {
                bf16x8 vbh = ldb(&Vth[df * 16 + l15][kh2 * 32 + lg * 8]);
                bf16x8 vbl = ldb(&Vtl[df * 16 + l15][kh2 * 32 + lg * 8]);
                ao[df] = MFMA16(wah, vbl, ao[df]);
                ao[df] = MFMA16(wal, vbh, ao[df]);
                ao[df] = MFMA16(wah, vbh, ao[df]);
            }
        }
    }

#pragma unroll
    for (int df = 0; df < 4; df++) {
#pragma unroll
        for (int r = 0; r < 4; r++) {
            int tq = qc * 64 + dq0 + r;
            int qrow = ((tq & 3) << 8) + (tq >> 2);
            AOp[((((size_t)(b * 16 + h)) << 10) + qrow) * 64 + df * 16 + l15] = ao[df][r];
        }
    }

    __syncthreads();
    float* Gb = G + ((size_t)(b * 16 + h) << 10);
    const int limp = (qc + 1) << 4;
    for (int idx = t; idx < 1024; idx += 256) {
        if ((idx & 255) < limp) atomicAdd(&Gb[idx], Gacc[idx]);
    }
}

// -------- pass_2a: per (b,h) masked prefix GV[p][d] = sum_{pos<=p} G.v --------
__global__ __launch_bounds__(256) void pass_2a(const float* __restrict__ G,
                                               const float* __restrict__ Yv,
                                               float* __restrict__ GVpre) {
    const int h = blockIdx.x, b = blockIdx.y;
    const int t = threadIdx.x;
    __shared__ float Gl[1024];
    __shared__ float S[256][64];
    __shared__ float segsum[4][64];
    for (int i = t; i < 1024; i += 256) Gl[i] = G[((size_t)(b * 16 + h) << 10) + i];
    __syncthreads();
    const int d = t & 63, pg = t >> 6;
    const float* Yvb = Yv + ((size_t)b << 20) + h * 64 + d;
    for (int p0 = 0; p0 < 64; p0++) {
        int pos = pg * 64 + p0;
        float s = 0.f;
#pragma unroll
        for (int sq = 0; sq < 4; sq++) {
            int j = (sq << 8) + pos;
            s += Gl[j] * Yvb[(size_t)j << 10];
        }
        S[pos][d] = s;
    }
    __syncthreads();
    float acc = 0.f;
    for (int p0 = 0; p0 < 64; p0++) {
        int pos = pg * 64 + p0;
        acc += S[pos][d];
        S[pos][d] = acc;
    }
    segsum[pg][d] = acc;
    __syncthreads();
    float off = 0.f;
    for (int g = 0; g < pg; g++) off += segsum[g][d];
    float* gv = GVpre + (((size_t)(b * 16 + h)) << 14) + d;
    for (int p0 = 0; p0 < 64; p0++) {
        int pos = pg * 64 + p0;
        gv[pos << 6] = S[pos][d] + off;
    }
}

// -------- pass_2b: ao = AOp + (lam/1024)*GV[pq]; RMS; bf16 store --------
__global__ __launch_bounds__(256) void pass_2b(const float* __restrict__ AOp,
                                               const float* __restrict__ GVpre,
                                               const float* __restrict__ lamp,
                                               const float* __restrict__ wan,
                                               unsigned short* __restrict__ aoS) {
    const int qg = blockIdx.x;
    const int h = blockIdx.y, b = blockIdx.z;
    const int t = threadIdx.x;
    const int d = t & 63, rg = t >> 6;
    const float lamg = (*lamp) * (1.f / 1024.f);
    const float wv = wan[d];
    const float* aob = AOp + ((((size_t)(b * 16 + h)) << 10) + (qg << 8)) * 64 + d;
    const float* gvb = GVpre + (((size_t)(b * 16 + h)) << 14) + d;
    unsigned short* ob = aoS + ((size_t)b << 20) + ((size_t)h << 16) + ((size_t)(qg << 8) << 6) + d;
    for (int p0 = 0; p0 < 64; p0++) {
        int pq = p0 * 4 + rg;
        float ao = aob[(size_t)pq << 6] + lamg * gvb[(size_t)pq << 6];
        float ss = ao * ao;
#pragma unroll
        for (int o = 1; o < 64; o <<= 1) ss += __shfl_xor(ss, o);
        float rr_ = rsqrtf(ss * (1.f / 64.f) + EPS_ATTN);
        ob[(size_t)pq << 6] = f2bf(ao * rr_ * wv);
    }
}

extern "C" void kernel_launch(void* const* d_in, const int* in_sizes, int n_in,
                              void* d_out, int out_size, void* d_ws, size_t ws_size,
                              hipStream_t stream) {
    const float* x    = (const float*)d_in[0];
    const float* fc   = (const float*)d_in[1];
    const float* w1   = (const float*)d_in[2];
    const float* w2   = (const float*)d_in[3];
    const float* Wq   = (const float*)d_in[4];
    const float* bq   = (const float*)d_in[5];
    const float* Wk   = (const float*)d_in[6];
    const float* bk   = (const float*)d_in[7];
    const float* Wv   = (const float*)d_in[8];
    const float* bv   = (const float*)d_in[9];
    const float* Wo   = (const float*)d_in[10];
    const float* bo   = (const float*)d_in[11];
    const float* lq1  = (const float*)d_in[12];
    const float* lk1  = (const float*)d_in[13];
    const float* lq2  = (const float*)d_in[14];
    const float* lk2  = (const float*)d_in[15];
    const float* wan  = (const float*)d_in[16];
    const float* Wg   = (const float*)d_in[17];
    const float* bg   = (const float*)d_in[18];
    const float* Wout = (const float*)d_in[19];
    const float* bout = (const float*)d_in[20];

    char* ws = (char*)d_ws;
    const size_t MB = 1024 * 1024;
    // Layout (peak 53 MB; 55 MB proven in round 2):
    float* G    = (float*)(ws);                     // [0, 128K)
    float* lam  = (float*)(ws + 256 * 1024);        // 4 B
    float* h32  = (float*)(ws + 1 * MB);            // [1,9)  fp32 2048x1024 (dead after QKV)
    float* Yq   = (float*)(ws + 9 * MB);            // [9,17)
    float* Yk   = (float*)(ws + 17 * MB);           // [17,25) (dead after rope_split_k)
    float* Yv   = (float*)(ws + 25 * MB);           // [25,33) (dead after pass_2a)
    float* AOp  = (float*)(ws + 33 * MB);           // [33,41)
    float* GVpre= (float*)(ws + 41 * MB);           // [41,43)
    unsigned short* WoB   = (unsigned short*)(ws + 43 * MB);  // [43,45)
    unsigned short* WoutB = (unsigned short*)(ws + 45 * MB);  // [45,53)
    unsigned short* KhG = (unsigned short*)(ws + 1 * MB);     // reuse [1,5)  (h32 dead)
    unsigned short* KlG = (unsigned short*)(ws + 5 * MB);     // reuse [5,9)
    unsigned short* VtH = (unsigned short*)(ws + 17 * MB);    // reuse [17,21) (Yk dead)
    unsigned short* VtL = (unsigned short*)(ws + 21 * MB);    // reuse [21,25)
    unsigned short* aoS = (unsigned short*)(ws + 1 * MB);     // reuse [1,5)  (KhG dead after pass_1)
    float* X1           = (float*)(ws + 9 * MB);              // reuse [9,17) (Yq dead after pass_1)
    unsigned short* h2b = (unsigned short*)(ws + 5 * MB);     // reuse [5,9)  (KlG dead)
    unsigned short* mlp = (unsigned short*)(ws + 17 * MB);    // reuse [17,33) (VtH/L, Yv dead)

    prep<<<32, 256, 0, stream>>>(G, lam, lq1, lk1, lq2, lk2);
    cvt_bf16<<<1024, 256, 0, stream>>>(Wo, WoB, 262144);
    cvt_bf16<<<4096, 256, 0, stream>>>(Wout, WoutB, 1048576);
    rms_kernel<0><<<2048, 256, 0, stream>>>(x, w1, h32, EPS_DEF);
    gemm_qkv_split<<<dim3(32, 16, 3), 256, 0, stream>>>(h32, Wq, Wk, Wv, bq, bk, bv, Yq, Yk, Yv);
    rope_inplace<<<2048, 256, 0, stream>>>(Yq, fc);
    rope_split_k<<<2048, 256, 0, stream>>>(Yk, fc, KhG, KlG);
    v_split_t<<<dim3(16, 16, 2), 256, 0, stream>>>(Yv, VtH, VtL);
    pass_1<<<512, 256, 0, stream>>>(Yq, KhG, KlG, VtH, VtL, lam, G, AOp);
    pass_2a<<<dim3(16, 2), 256, 0, stream>>>(G, Yv, GVpre);
    pass_2b<<<dim3(4, 16, 2), 256, 0, stream>>>(AOp, GVpre, lam, wan, aoS);
    dim3 gmf(32, 16);
    gemm_mfma_wb<<<gmf, 256, 0, stream>>>(aoS, WoB, bo, x, X1, 2048, 1024, 1024);
    rms_kernel<1><<<2048, 256, 0, stream>>>(X1, w2, h2b, EPS_DEF);
    gemm_gate_mfma<<<dim3(16, 64), 256, 0, stream>>>(h2b, Wg, bg, mlp);
    // FINAL OUTPUT IS FP32.
    gemm_mfma_wb<<<gmf, 256, 0, stream>>>(mlp, WoutB, bout, X1, (float*)d_out, 2048, 1024, 4096);
}

// Round 10
// 464.376 us; speedup vs baseline: 7.9671x; 1.0255x over previous
//
#include <hip/hip_runtime.h>

#define LAMBDA_INIT 0.2f
#define SCALING 0.17677669529663687f   // 1/sqrt(32)
#define EPS_DEF 1.1920928955078125e-07f
#define EPS_ATTN 1e-5f

typedef unsigned short us4 __attribute__((ext_vector_type(4)));
typedef unsigned short us8v __attribute__((ext_vector_type(8)));
typedef float f32x4 __attribute__((ext_vector_type(4)));
typedef float f32x2 __attribute__((ext_vector_type(2)));
typedef __bf16 bf16x8 __attribute__((ext_vector_type(8)));

#define MFMA16(a, b, c) __builtin_amdgcn_mfma_f32_16x16x32_bf16((a), (b), (c), 0, 0, 0)

__device__ __forceinline__ float bf2f(unsigned short u) {
    unsigned int x = ((unsigned int)u) << 16;
    return __builtin_bit_cast(float, x);
}
__device__ __forceinline__ unsigned short f2bf(float f) {
    unsigned int x = __builtin_bit_cast(unsigned int, f);
    x += 0x7fffu + ((x >> 16) & 1u);
    return (unsigned short)(x >> 16);
}
// split a pair of f32x4 into hi/lo bf16 (x ~= hi + lo, residual ~2^-18 rel)
__device__ __forceinline__ void split8(f32x4 a, f32x4 b, us8v& hi, us8v& lo) {
#pragma unroll
    for (int u = 0; u < 4; u++) {
        unsigned short h = f2bf(a[u]);
        hi[u] = h; lo[u] = f2bf(a[u] - bf2f(h));
        unsigned short h2 = f2bf(b[u]);
        hi[4 + u] = h2; lo[4 + u] = f2bf(b[u] - bf2f(h2));
    }
}
__device__ __forceinline__ bf16x8 ldb(const unsigned short* p) {
    return __builtin_bit_cast(bf16x8, *(const us8v*)p);
}

__device__ __forceinline__ float wave_sum(float v) {
#pragma unroll
    for (int o = 32; o > 0; o >>= 1) v += __shfl_down(v, o);
    return v;
}
__device__ __forceinline__ float block_sum(float v, float* red4) {
    int wv = threadIdx.x >> 6;
    float w = wave_sum(v);
    __syncthreads();
    if ((threadIdx.x & 63) == 0) red4[wv] = w;
    __syncthreads();
    return red4[0] + red4[1] + red4[2] + red4[3];
}

// ---------------- prep: zero G, compute lambda ----------------
__global__ __launch_bounds__(256) void prep(float* __restrict__ G, float* __restrict__ lamp,
                                            const float* lq1, const float* lk1,
                                            const float* lq2, const float* lk2) {
    int i = (blockIdx.x * 256 + threadIdx.x) * 4;
    G[i] = 0.f; G[i + 1] = 0.f; G[i + 2] = 0.f; G[i + 3] = 0.f;
    if (blockIdx.x == 0 && threadIdx.x == 0) {
        float a = 0.f, c = 0.f;
        for (int d = 0; d < 32; d++) {
            a += lq1[d] * lk1[d];
            c += lq2[d] * lk2[d];
        }
        *lamp = expf(a) - expf(c) + LAMBDA_INIT;
    }
}

// ---------------- fp32 -> bf16 weight conversion ----------------
__global__ __launch_bounds__(256) void cvt_bf16(const float* __restrict__ s,
                                                unsigned short* __restrict__ d, int n4) {
    int i = blockIdx.x * 256 + threadIdx.x;
    if (i >= n4) return;
    f32x4 v = ((const f32x4*)s)[i];
    us4 o;
#pragma unroll
    for (int u = 0; u < 4; u++) o[u] = f2bf(v[u]);
    ((us4*)d)[i] = o;
}

// ---------------- fp32 -> hi/lo bf16 split conversion ----------------
__global__ __launch_bounds__(256) void cvt_split(const float* __restrict__ s,
                                                 unsigned short* __restrict__ hi,
                                                 unsigned short* __restrict__ lo, int n4) {
    int i = blockIdx.x * 256 + threadIdx.x;
    if (i >= n4) return;
    f32x4 v = ((const f32x4*)s)[i];
    us4 h, l;
#pragma unroll
    for (int u = 0; u < 4; u++) {
        h[u] = f2bf(v[u]);
        l[u] = f2bf(v[u] - bf2f(h[u]));
    }
    ((us4*)hi)[i] = h;
    ((us4*)lo)[i] = l;
}

// ---------------- RMSNorm: fp32 in, fp32 weight, bf16 out ----------------
template <int OUTBF>
__global__ __launch_bounds__(256) void rms_kernel(const float* __restrict__ x,
                                                  const float* __restrict__ w,
                                                  void* __restrict__ out, float eps) {
    int row = blockIdx.x;
    int tid = threadIdx.x;
    size_t base = (size_t)row * 1024 + tid * 4;
    f32x4 v = *(const f32x4*)(x + base);
    float ss = v[0]*v[0] + v[1]*v[1] + v[2]*v[2] + v[3]*v[3];
    __shared__ float red4[4];
    float tot = block_sum(ss, red4);
    float r = rsqrtf(tot * (1.0f / 1024.f) + eps);
    f32x4 wv = *(const f32x4*)(w + tid * 4);
    if (OUTBF) {
        us4 o;
#pragma unroll
        for (int i = 0; i < 4; i++) o[i] = f2bf(v[i] * r * wv[i]);
        *(us4*)((unsigned short*)out + base) = o;
    } else {
        f32x4 o;
#pragma unroll
        for (int i = 0; i < 4; i++) o[i] = v[i] * r * wv[i];
        *(f32x4*)((float*)out + base) = o;
    }
}

// ---------------- RMSNorm with hi/lo split output ----------------
__global__ __launch_bounds__(256) void rms_split(const float* __restrict__ x,
                                                 const float* __restrict__ w,
                                                 unsigned short* __restrict__ hh,
                                                 unsigned short* __restrict__ hl, float eps) {
    int row = blockIdx.x;
    int tid = threadIdx.x;
    size_t base = (size_t)row * 1024 + tid * 4;
    f32x4 v = *(const f32x4*)(x + base);
    float ss = v[0]*v[0] + v[1]*v[1] + v[2]*v[2] + v[3]*v[3];
    __shared__ float red4[4];
    float tot = block_sum(ss, red4);
    float r = rsqrtf(tot * (1.0f / 1024.f) + eps);
    f32x4 wv = *(const f32x4*)(w + tid * 4);
    us4 oh, ol;
#pragma unroll
    for (int i = 0; i < 4; i++) {
        float val = v[i] * r * wv[i];
        oh[i] = f2bf(val);
        ol[i] = f2bf(val - bf2f(oh[i]));
    }
    *(us4*)(hh + base) = oh;
    *(us4*)(hl + base) = ol;
}

// =====================================================================
// QKV split-bf16 MFMA GEMM, PRE-SPLIT operands (no VALU split in loop).
// BM=64, BN=64, BK=64, 4 waves (2x2). Grid (32,16,3).
//   Y = h @ W^T + b  via  al*bh + ah*bl + ah*bh  (3 MFMAs, err ~2^-18).
// =====================================================================
__global__ __launch_bounds__(256) void gemm_qkv_ps(
        const unsigned short* __restrict__ AH, const unsigned short* __restrict__ AL,
        const unsigned short* __restrict__ WqH, const unsigned short* __restrict__ WqL,
        const unsigned short* __restrict__ WkH, const unsigned short* __restrict__ WkL,
        const unsigned short* __restrict__ WvH, const unsigned short* __restrict__ WvL,
        const float* __restrict__ bq, const float* __restrict__ bk, const float* __restrict__ bv,
        float* __restrict__ Yq, float* __restrict__ Yk, float* __restrict__ Yv) {
    const int z = blockIdx.z;
    const unsigned short* BH = (z == 0) ? WqH : (z == 1) ? WkH : WvH;
    const unsigned short* BL = (z == 0) ? WqL : (z == 1) ? WkL : WvL;
    const float* bias = (z == 0) ? bq : (z == 1) ? bk : bv;
    float* out        = (z == 0) ? Yq : (z == 1) ? Yk : Yv;
    const int K = 1024, N = 1024;
    __shared__ __align__(16) unsigned short Ah[64][72];
    __shared__ __align__(16) unsigned short Al[64][72];
    __shared__ __align__(16) unsigned short Bh[64][72];
    __shared__ __align__(16) unsigned short Bl[64][72];
    const int t = threadIdx.x;
    const int bm = blockIdx.x, bn = blockIdx.y;
    const int lane = t & 63, w = t >> 6;
    const int wr = w >> 1, wc = w & 1;
    const int l15 = lane & 15, lg = lane >> 4;
    const int sr = t >> 2, sc = (t & 3) * 16;

    const unsigned short* AgH = AH + (size_t)(bm * 64 + sr) * K + sc;
    const unsigned short* AgL = AL + (size_t)(bm * 64 + sr) * K + sc;
    const unsigned short* BgH = BH + (size_t)(bn * 64 + sr) * K + sc;
    const unsigned short* BgL = BL + (size_t)(bn * 64 + sr) * K + sc;

    f32x4 acc[2][2] = {};

    for (int k0 = 0; k0 < K; k0 += 64) {
        us8v ah0 = *(const us8v*)(AgH + k0), ah1 = *(const us8v*)(AgH + k0 + 8);
        us8v al0 = *(const us8v*)(AgL + k0), al1 = *(const us8v*)(AgL + k0 + 8);
        us8v bh0 = *(const us8v*)(BgH + k0), bh1 = *(const us8v*)(BgH + k0 + 8);
        us8v bl0 = *(const us8v*)(BgL + k0), bl1 = *(const us8v*)(BgL + k0 + 8);
        __syncthreads();
        *(us8v*)&Ah[sr][sc] = ah0; *(us8v*)&Ah[sr][sc + 8] = ah1;
        *(us8v*)&Al[sr][sc] = al0; *(us8v*)&Al[sr][sc + 8] = al1;
        *(us8v*)&Bh[sr][sc] = bh0; *(us8v*)&Bh[sr][sc + 8] = bh1;
        *(us8v*)&Bl[sr][sc] = bl0; *(us8v*)&Bl[sr][sc + 8] = bl1;
        __syncthreads();
#pragma unroll
        for (int kk = 0; kk < 2; kk++) {
            bf16x8 afh[2], afl[2], bfh[2], bfl[2];
#pragma unroll
            for (int mi = 0; mi < 2; mi++) {
                afh[mi] = ldb(&Ah[wr * 32 + mi * 16 + l15][kk * 32 + lg * 8]);
                afl[mi] = ldb(&Al[wr * 32 + mi * 16 + l15][kk * 32 + lg * 8]);
            }
#pragma unroll
            for (int ni = 0; ni < 2; ni++) {
                bfh[ni] = ldb(&Bh[wc * 32 + ni * 16 + l15][kk * 32 + lg * 8]);
                bfl[ni] = ldb(&Bl[wc * 32 + ni * 16 + l15][kk * 32 + lg * 8]);
            }
#pragma unroll
            for (int mi = 0; mi < 2; mi++)
#pragma unroll
                for (int ni = 0; ni < 2; ni++) {
                    acc[mi][ni] = MFMA16(afl[mi], bfh[ni], acc[mi][ni]);
                    acc[mi][ni] = MFMA16(afh[mi], bfl[ni], acc[mi][ni]);
                    acc[mi][ni] = MFMA16(afh[mi], bfh[ni], acc[mi][ni]);
                }
        }
    }

    const int rbase = bm * 64 + wr * 32 + (lg << 2);
    const int cbase = bn * 64 + wc * 32 + l15;
#pragma unroll
    for (int mi = 0; mi < 2; mi++) {
#pragma unroll
        for (int ni = 0; ni < 2; ni++) {
            int col = cbase + ni * 16;
            float bb = bias[col];
#pragma unroll
            for (int r = 0; r < 4; r++) {
                int row = rbase + mi * 16 + r;
                out[(size_t)row * N + col] = acc[mi][ni][r] + bb;
            }
        }
    }
}

// =====================================================================
// bf16 MFMA GEMM, pre-converted bf16 B: out = A @ Bt^T + bias + res.
// BM=64, BN=64, BK=64, 4 waves (2x2).
// =====================================================================
__global__ __launch_bounds__(256) void gemm_mfma_wb(const unsigned short* __restrict__ A,
                                                    const unsigned short* __restrict__ Bt,
                                                    const float* __restrict__ bias,
                                                    const float* __restrict__ res,
                                                    float* __restrict__ out,
                                                    int M, int N, int K) {
    __shared__ __align__(16) unsigned short As[64][72];
    __shared__ __align__(16) unsigned short Bs[64][72];
    const int t = threadIdx.x;
    const int bm = blockIdx.x, bn = blockIdx.y;
    const int lane = t & 63, w = t >> 6;
    const int wr = w >> 1, wc = w & 1;
    const int l15 = lane & 15, lg = lane >> 4;
    const int sr = t >> 2, sc = (t & 3) * 16;

    const unsigned short* Ag = A + (size_t)(bm * 64 + sr) * K + sc;
    const unsigned short* Bg = Bt + (size_t)(bn * 64 + sr) * K + sc;

    f32x4 acc[2][2] = {};

    for (int k0 = 0; k0 < K; k0 += 64) {
        us8v a0 = *(const us8v*)(Ag + k0);
        us8v a1 = *(const us8v*)(Ag + k0 + 8);
        us8v b0 = *(const us8v*)(Bg + k0);
        us8v b1 = *(const us8v*)(Bg + k0 + 8);
        __syncthreads();
        *(us8v*)&As[sr][sc]     = a0;
        *(us8v*)&As[sr][sc + 8] = a1;
        *(us8v*)&Bs[sr][sc]     = b0;
        *(us8v*)&Bs[sr][sc + 8] = b1;
        __syncthreads();
#pragma unroll
        for (int kk = 0; kk < 2; kk++) {
            bf16x8 af[2], bf[2];
#pragma unroll
            for (int mi = 0; mi < 2; mi++)
                af[mi] = ldb(&As[wr * 32 + mi * 16 + l15][kk * 32 + lg * 8]);
#pragma unroll
            for (int ni = 0; ni < 2; ni++)
                bf[ni] = ldb(&Bs[wc * 32 + ni * 16 + l15][kk * 32 + lg * 8]);
#pragma unroll
            for (int mi = 0; mi < 2; mi++)
#pragma unroll
                for (int ni = 0; ni < 2; ni++)
                    acc[mi][ni] = MFMA16(af[mi], bf[ni], acc[mi][ni]);
        }
    }

    const int rbase = bm * 64 + wr * 32 + (lg << 2);
    const int cbase = bn * 64 + wc * 32 + l15;
#pragma unroll
    for (int mi = 0; mi < 2; mi++) {
#pragma unroll
        for (int ni = 0; ni < 2; ni++) {
            int col = cbase + ni * 16;
            float bb = bias[col];
#pragma unroll
            for (int r = 0; r < 4; r++) {
                int row = rbase + mi * 16 + r;
                size_t oi = (size_t)row * N + col;
                out[oi] = acc[mi][ni][r] + bb + res[oi];
            }
        }
    }
}

// ------- fused gate GEMM (MFMA): mlp = (h2@Wu^T+bu) * silu(h2@Wv^T+bv) -------
__global__ __launch_bounds__(256) void gemm_gate_mfma(const unsigned short* __restrict__ A,
                                                      const float* __restrict__ Wg,
                                                      const float* __restrict__ bg,
                                                      unsigned short* __restrict__ mlp) {
    __shared__ __align__(16) unsigned short As[128][72];
    __shared__ __align__(16) unsigned short BsU[64][72];
    __shared__ __align__(16) unsigned short BsV[64][72];
    const int t = threadIdx.x;
    const int bm = blockIdx.x, bn = blockIdx.y;
    const int lane = t & 63, w = t >> 6;
    const int wr = w >> 1, wc = w & 1;
    const int l15 = lane & 15, lg = lane >> 4;
    const int sr = t >> 2, sc = (t & 3) * 16;

    const unsigned short* Ag  = A + (size_t)(bm * 128 + sr) * 1024 + sc;
    const unsigned short* Ag2 = Ag + (size_t)64 * 1024;
    const float* BgU = Wg + (size_t)(bn * 64 + sr) * 1024 + sc;
    const float* BgV = Wg + (size_t)(4096 + bn * 64 + sr) * 1024 + sc;

    f32x4 accU[4][2] = {};
    f32x4 accV[4][2] = {};

    for (int k0 = 0; k0 < 1024; k0 += 64) {
        us8v a0 = *(const us8v*)(Ag + k0);
        us8v a1 = *(const us8v*)(Ag + k0 + 8);
        us8v a2 = *(const us8v*)(Ag2 + k0);
        us8v a3 = *(const us8v*)(Ag2 + k0 + 8);
        f32x4 u0 = *(const f32x4*)(BgU + k0);
        f32x4 u1 = *(const f32x4*)(BgU + k0 + 4);
        f32x4 u2 = *(const f32x4*)(BgU + k0 + 8);
        f32x4 u3 = *(const f32x4*)(BgU + k0 + 12);
        f32x4 v0 = *(const f32x4*)(BgV + k0);
        f32x4 v1 = *(const f32x4*)(BgV + k0 + 4);
        f32x4 v2 = *(const f32x4*)(BgV + k0 + 8);
        f32x4 v3 = *(const f32x4*)(BgV + k0 + 12);
        us8v uw0, uw1, vw0, vw1;
#pragma unroll
        for (int u = 0; u < 4; u++) {
            uw0[u] = f2bf(u0[u]); uw0[4 + u] = f2bf(u1[u]);
            uw1[u] = f2bf(u2[u]); uw1[4 + u] = f2bf(u3[u]);
            vw0[u] = f2bf(v0[u]); vw0[4 + u] = f2bf(v1[u]);
            vw1[u] = f2bf(v2[u]); vw1[4 + u] = f2bf(v3[u]);
        }
        __syncthreads();
        *(us8v*)&As[sr][sc]          = a0;
        *(us8v*)&As[sr][sc + 8]      = a1;
        *(us8v*)&As[sr + 64][sc]     = a2;
        *(us8v*)&As[sr + 64][sc + 8] = a3;
        *(us8v*)&BsU[sr][sc]         = uw0;
        *(us8v*)&BsU[sr][sc + 8]     = uw1;
        *(us8v*)&BsV[sr][sc]         = vw0;
        *(us8v*)&BsV[sr][sc + 8]     = vw1;
        __syncthreads();
#pragma unroll
        for (int kk = 0; kk < 2; kk++) {
            bf16x8 af[4], bu[2], bv2[2];
#pragma unroll
            for (int mi = 0; mi < 4; mi++)
                af[mi] = ldb(&As[wr * 64 + mi * 16 + l15][kk * 32 + lg * 8]);
#pragma unroll
            for (int ni = 0; ni < 2; ni++) {
                bu[ni]  = ldb(&BsU[wc * 32 + ni * 16 + l15][kk * 32 + lg * 8]);
                bv2[ni] = ldb(&BsV[wc * 32 + ni * 16 + l15][kk * 32 + lg * 8]);
            }
#pragma unroll
            for (int mi = 0; mi < 4; mi++)
#pragma unroll
                for (int ni = 0; ni < 2; ni++) {
                    accU[mi][ni] = MFMA16(af[mi], bu[ni], accU[mi][ni]);
                    accV[mi][ni] = MFMA16(af[mi], bv2[ni], accV[mi][ni]);
                }
        }
    }

    const int rbase = bm * 128 + wr * 64 + (lg << 2);
    const int cbase = bn * 64 + wc * 32 + l15;
#pragma unroll
    for (int mi = 0; mi < 4; mi++) {
#pragma unroll
        for (int ni = 0; ni < 2; ni++) {
            int col = cbase + ni * 16;
            float bu_ = bg[col], bv_ = bg[4096 + col];
#pragma unroll
            for (int r = 0; r < 4; r++) {
                int row = rbase + mi * 16 + r;
                float u = accU[mi][ni][r] + bu_;
                float v = accV[mi][ni][r] + bv_;
                float s = v / (1.f + __expf(-v));
                mlp[(size_t)row * 4096 + col] = f2bf(u * s);
            }
        }
    }
}

// ---------------- RoPE in place (Q), token order ----------------
__global__ __launch_bounds__(256) void rope_inplace(float* __restrict__ Y,
                                                    const float* __restrict__ fc) {
    int t = blockIdx.x;
    int s = t & 1023;
    int p = s >> 2;
    if (p == 0) return;
    int c0 = threadIdx.x * 4;
    float* y = Y + (size_t)t * 1024 + c0;
    int d4 = (c0 & 31) >> 1;
    f32x4 f = *(const f32x4*)(fc + ((size_t)(p - 1) * 16 + d4) * 2);  // [cos,sin,cos,sin]
    float v0 = y[0], v1 = y[1], v2 = y[2], v3 = y[3];
    y[0] = v0 * f[0] - v1 * f[1];
    y[1] = v0 * f[1] + v1 * f[0];
    y[2] = v2 * f[2] - v3 * f[3];
    y[3] = v2 * f[3] + v3 * f[2];
}

// ------- RoPE(K) + hi/lo bf16 split, token-order output -------
__global__ __launch_bounds__(256) void rope_split_k(const float* __restrict__ Yk,
                                                    const float* __restrict__ fc,
                                                    unsigned short* __restrict__ KhG,
                                                    unsigned short* __restrict__ KlG) {
    int t = blockIdx.x;           // b*1024 + s
    int s = t & 1023;
    int p = s >> 2;
    int c0 = threadIdx.x * 4;
    const float* y = Yk + (size_t)t * 1024 + c0;
    float v0 = y[0], v1 = y[1], v2 = y[2], v3 = y[3];
    if (p > 0) {
        int d4 = (c0 & 31) >> 1;
        f32x4 f = *(const f32x4*)(fc + ((size_t)(p - 1) * 16 + d4) * 2);
        float w0 = v0 * f[0] - v1 * f[1];
        float w1 = v0 * f[1] + v1 * f[0];
        float w2 = v2 * f[2] - v3 * f[3];
        float w3 = v2 * f[3] + v3 * f[2];
        v0 = w0; v1 = w1; v2 = w2; v3 = w3;
    }
    us4 hi, lo;
    hi[0] = f2bf(v0); lo[0] = f2bf(v0 - bf2f(hi[0]));
    hi[1] = f2bf(v1); lo[1] = f2bf(v1 - bf2f(hi[1]));
    hi[2] = f2bf(v2); lo[2] = f2bf(v2 - bf2f(hi[2]));
    hi[3] = f2bf(v3); lo[3] = f2bf(v3 - bf2f(hi[3]));
    *(us4*)(KhG + (size_t)t * 1024 + c0) = hi;
    *(us4*)(KlG + (size_t)t * 1024 + c0) = lo;
}

// ------- V transpose + hi/lo split: Vt[(b,h)][d (64)][j (1024)] -------
// V row for attention index j is RAW Yv row j (reference quirk).
__global__ __launch_bounds__(256) void v_split_t(const float* __restrict__ Yv,
                                                 unsigned short* __restrict__ VtH,
                                                 unsigned short* __restrict__ VtL) {
    const int jc = blockIdx.x, h = blockIdx.y, b = blockIdx.z;   // (16,16,2)
    __shared__ float tile[64][65];
    const int t = threadIdx.x;
    {
        const int jr = t >> 2, dc = (t & 3) * 16;
        const float* src = Yv + ((size_t)(b * 1024 + jc * 64 + jr) << 10) + h * 64 + dc;
        *(f32x4*)&tile[jr][dc]      = *(const f32x4*)src;
        *(f32x4*)&tile[jr][dc + 4]  = *(const f32x4*)(src + 4);
        *(f32x4*)&tile[jr][dc + 8]  = *(const f32x4*)(src + 8);
        *(f32x4*)&tile[jr][dc + 12] = *(const f32x4*)(src + 12);
    }
    __syncthreads();
    const int d = t >> 2, js = (t & 3) * 16;
    us8v h0, h1, l0, l1;
#pragma unroll
    for (int n = 0; n < 16; n++) {
        float val = tile[js + n][d];
        unsigned short hh = f2bf(val);
        unsigned short ll = f2bf(val - bf2f(hh));
        if (n < 8) { h0[n] = hh; l0[n] = ll; }
        else       { h1[n - 8] = hh; l1[n - 8] = ll; }
    }
    size_t ob = (((size_t)(b * 16 + h) * 64 + d) << 10) + jc * 64 + js;
    *(us8v*)(VtH + ob) = h0; *(us8v*)(VtH + ob + 8) = h1;
    *(us8v*)(VtL + ob) = l0; *(us8v*)(VtL + ob + 8) = l1;
}

// =====================================================================
// MFMA attention pass_1, PAIRED chunks for load balance:
// block (b,h,p) runs qc = 15-p then qc = p -> uniform 17 chunk-units.
// Grid 256. Per-qc math identical to the round-9 kernel; Gacc is
// accumulated across both qc (same (b,h)) and flushed once.
// =====================================================================
__global__ __launch_bounds__(256) void pass_1(const float* __restrict__ Yq,
                                              const unsigned short* __restrict__ KhG,
                                              const unsigned short* __restrict__ KlG,
                                              const unsigned short* __restrict__ VtH,
                                              const unsigned short* __restrict__ VtL,
                                              const float* __restrict__ lamp,
                                              float* __restrict__ G,
                                              float* __restrict__ AOp) {
    const int blk = blockIdx.x;
    const int p  = blk >> 5;          // 0..7
    const int h  = blk & 15;
    const int b  = (blk >> 4) & 1;
    const int t = threadIdx.x;
    const int lane = t & 63, w = t >> 6;
    const int l15 = lane & 15, lg = lane >> 4;

    __shared__ __align__(16) unsigned short Kh[64][72];
    __shared__ __align__(16) unsigned short Kl[64][72];
    __shared__ __align__(16) unsigned short Vth[64][72];
    __shared__ __align__(16) unsigned short Vtl[64][72];
    __shared__ __align__(16) unsigned short Wh[64][72];
    __shared__ __align__(16) unsigned short Wl[64][72];
    __shared__ float Gacc[1024];

    for (int i = t; i < 1024; i += 256) Gacc[i] = 0.f;

    const int srow = t >> 2, ssub = t & 3;
    const int ptk = 4 * (srow & 15) + (srow >> 4);   // permuted in-chunk token for row srow
    const unsigned short* KhB = KhG + ((size_t)(b * 1024) << 10) + h * 64;
    const unsigned short* KlB = KlG + ((size_t)(b * 1024) << 10) + h * 64;
    const unsigned short* VhB = VtH + (((size_t)(b * 16 + h) * 64 + srow) << 10) + ssub * 256;
    const unsigned short* VlB = VtL + (((size_t)(b * 16 + h) * 64 + srow) << 10) + ssub * 256;
    const float lam = *lamp;
    const int dq0 = w * 16 + (lg << 2);

    for (int qq = 0; qq < 2; qq++) {
        const int qc = qq ? p : (15 - p);

        // ---- Q A-fragments for this qc ----
        us8v qh[2], ql[2];
        {
            const float* qp = Yq + ((size_t)(b * 1024 + qc * 64 + w * 16 + l15) << 10)
                              + h * 64 + lg * 8;
#pragma unroll
            for (int H = 0; H < 2; H++)
                split8(*(const f32x4*)(qp + H * 32), *(const f32x4*)(qp + H * 32 + 4), qh[H], ql[H]);
        }

        float z1r[4] = {0.f, 0.f, 0.f, 0.f};
        float z2r[4] = {0.f, 0.f, 0.f, 0.f};

        // -------- sweep 1: denominators --------
        for (int kc = 0; kc <= qc; kc++) {
            __syncthreads();
            {
                const unsigned short* kh = KhB + ((size_t)(kc * 64 + ptk) << 10) + ssub * 16;
                const unsigned short* kl = KlB + ((size_t)(kc * 64 + ptk) << 10) + ssub * 16;
                *(us8v*)&Kh[srow][ssub * 16]     = *(const us8v*)kh;
                *(us8v*)&Kh[srow][ssub * 16 + 8] = *(const us8v*)(kh + 8);
                *(us8v*)&Kl[srow][ssub * 16]     = *(const us8v*)kl;
                *(us8v*)&Kl[srow][ssub * 16 + 8] = *(const us8v*)(kl + 8);
            }
            __syncthreads();
            const int kpos = kc * 16 + l15;
#pragma unroll
            for (int kf = 0; kf < 4; kf++) {
                const int krow = kf * 16 + l15;
                const int kcol = lg * 8;
                bf16x8 b1h = ldb(&Kh[krow][kcol]),      b1l = ldb(&Kl[krow][kcol]);
                bf16x8 b2h = ldb(&Kh[krow][32 + kcol]), b2l = ldb(&Kl[krow][32 + kcol]);
                f32x4 s1 = {}, s2 = {};
                s1 = MFMA16(__builtin_bit_cast(bf16x8, ql[0]), b1h, s1);
                s1 = MFMA16(__builtin_bit_cast(bf16x8, qh[0]), b1l, s1);
                s1 = MFMA16(__builtin_bit_cast(bf16x8, qh[0]), b1h, s1);
                s2 = MFMA16(__builtin_bit_cast(bf16x8, ql[1]), b2h, s2);
                s2 = MFMA16(__builtin_bit_cast(bf16x8, qh[1]), b2l, s2);
                s2 = MFMA16(__builtin_bit_cast(bf16x8, qh[1]), b2h, s2);
#pragma unroll
                for (int r = 0; r < 4; r++) {
                    int pq = (qc * 64 + dq0 + r) >> 2;
                    if (kpos <= pq) {
                        z1r[r] += __expf(fabsf(s1[r] * SCALING));
                        z2r[r] += __expf(fabsf(s2[r] * SCALING));
                    }
                }
            }
        }
#pragma unroll
        for (int r = 0; r < 4; r++) {
            float a = z1r[r];
            a += __shfl_xor(a, 1); a += __shfl_xor(a, 2);
            a += __shfl_xor(a, 4); a += __shfl_xor(a, 8);
            z1r[r] = 1.f / fmaxf(a, 1e-20f);
            float c = z2r[r];
            c += __shfl_xor(c, 1); c += __shfl_xor(c, 2);
            c += __shfl_xor(c, 4); c += __shfl_xor(c, 8);
            z2r[r] = 1.f / fmaxf(c, 1e-20f);
        }

        f32x4 ao[4] = {};

        // -------- sweep 2: weights + G colsums + AV --------
        for (int kc = 0; kc <= qc; kc++) {
            __syncthreads();
            {
                const unsigned short* kh = KhB + ((size_t)(kc * 64 + ptk) << 10) + ssub * 16;
                const unsigned short* kl = KlB + ((size_t)(kc * 64 + ptk) << 10) + ssub * 16;
                *(us8v*)&Kh[srow][ssub * 16]     = *(const us8v*)kh;
                *(us8v*)&Kh[srow][ssub * 16 + 8] = *(const us8v*)(kh + 8);
                *(us8v*)&Kl[srow][ssub * 16]     = *(const us8v*)kl;
                *(us8v*)&Kl[srow][ssub * 16 + 8] = *(const us8v*)(kl + 8);
                const unsigned short* vh = VhB + kc * 16;
                const unsigned short* vl = VlB + kc * 16;
                *(us8v*)&Vth[srow][ssub * 16]     = *(const us8v*)vh;
                *(us8v*)&Vth[srow][ssub * 16 + 8] = *(const us8v*)(vh + 8);
                *(us8v*)&Vtl[srow][ssub * 16]     = *(const us8v*)vl;
                *(us8v*)&Vtl[srow][ssub * 16 + 8] = *(const us8v*)(vl + 8);
            }
            __syncthreads();
            const int kpos = kc * 16 + l15;
#pragma unroll
            for (int kf = 0; kf < 4; kf++) {
                const int krow = kf * 16 + l15;
                const int kcol = lg * 8;
                bf16x8 b1h = ldb(&Kh[krow][kcol]),      b1l = ldb(&Kl[krow][kcol]);
                bf16x8 b2h = ldb(&Kh[krow][32 + kcol]), b2l = ldb(&Kl[krow][32 + kcol]);
                f32x4 s1 = {}, s2 = {};
                s1 = MFMA16(__builtin_bit_cast(bf16x8, ql[0]), b1h, s1);
                s1 = MFMA16(__builtin_bit_cast(bf16x8, qh[0]), b1l, s1);
                s1 = MFMA16(__builtin_bit_cast(bf16x8, qh[0]), b1h, s1);
                s2 = MFMA16(__builtin_bit_cast(bf16x8, ql[1]), b2h, s2);
                s2 = MFMA16(__builtin_bit_cast(bf16x8, qh[1]), b2l, s2);
                s2 = MFMA16(__builtin_bit_cast(bf16x8, qh[1]), b2h, s2);
                const int kli = kf * 16 + l15;
                float colsum = 0.f;
#pragma unroll
                for (int r = 0; r < 4; r++) {
                    int pq = (qc * 64 + dq0 + r) >> 2;
                    float wv = 0.f, a1 = 0.f;
                    if (kpos <= pq) {
                        float t1 = s1[r] * SCALING, t2 = s2[r] * SCALING;
                        float sg1 = (t1 > 0.f) ? 1.f : ((t1 < 0.f) ? -1.f : 0.f);
                        float sg2 = (t2 > 0.f) ? 1.f : ((t2 < 0.f) ? -1.f : 0.f);
                        a1 = sg1 * __expf(fabsf(t1)) * z1r[r];
                        wv = a1 - lam * (sg2 * __expf(fabsf(t2)) * z2r[r]);
                    }
                    colsum += a1;
                    unsigned short hh = f2bf(wv);
                    Wh[dq0 + r][kli] = hh;
                    Wl[dq0 + r][kli] = f2bf(wv - bf2f(hh));
                }
                colsum += __shfl_xor(colsum, 16);
                colsum += __shfl_xor(colsum, 32);
                // column r=kf*16+lane -> attention index j = kf*256 + kc*16 + lane
                if (lane < 16) atomicAdd(&Gacc[kf * 256 + kc * 16 + lane], colsum);
            }
            __syncthreads();
#pragma unroll
            for (int kh2 = 0; kh2 < 2; kh2++) {
                bf16x8 wah = ldb(&Wh[w * 16 + l15][kh2 * 32 + lg * 8]);
                bf16x8 wal = ldb(&Wl[w * 16 + l15][kh2 * 32 + lg * 8]);
#pragma unroll
                for (int df = 0; df < 4; df++) {
                    bf16x8 vbh = ldb(&Vth[df * 16 + l15][kh2 * 32 + lg * 8]);
                    bf16x8 vbl = ldb(&Vtl[df * 16 + l15][kh2 * 32 + lg * 8]);
                    ao[df] = MFMA16(wah, vbl, ao[df]);
                    ao[df] = MFMA16(wal, vbh, ao[df]);
                    ao[df] = MFMA16(wah, vbh, ao[df]);
                }
            }
        }

#pragma unroll
        for (int df = 0; df < 4; df++) {
#pragma unroll
            for (int r = 0; r < 4; r++) {
                int tq = qc * 64 + dq0 + r;
                int qrow = ((tq & 3) << 8) + (tq >> 2);
                AOp[((((size_t)(b * 16 + h)) << 10) + qrow) * 64 + df * 16 + l15] = ao[df][r];
            }
        }
    }

    // flush G once (attention-index order); columns touched: pos < (16-p)*16
    __syncthreads();
    float* Gb = G + ((size_t)(b * 16 + h) << 10);
    const int limp = (16 - p) << 4;
    for (int idx = t; idx < 1024; idx += 256) {
        if ((idx & 255) < limp) atomicAdd(&Gb[idx], Gacc[idx]);
    }
}

// -------- pass_2a: per (b,h) masked prefix GV[p][d] = sum_{pos<=p} G.v --------
__global__ __launch_bounds__(256) void pass_2a(const float* __restrict__ G,
                                               const float* __restrict__ Yv,
                                               float* __restrict__ GVpre) {
    const int h = blockIdx.x, b = blockIdx.y;
    const int t = threadIdx.x;
    __shared__ float Gl[1024];
    __shared__ float S[256][64];
    __shared__ float segsum[4][64];
    for (int i = t; i < 1024; i += 256) Gl[i] = G[((size_t)(b * 16 + h) << 10) + i];
    __syncthreads();
    const int d = t & 63, pg = t >> 6;
    const float* Yvb = Yv + ((size_t)b << 20) + h * 64 + d;
    for (int p0 = 0; p0 < 64; p0++) {
        int pos = pg * 64 + p0;
        float s = 0.f;
#pragma unroll
        for (int sq = 0; sq < 4; sq++) {
            int j = (sq << 8) + pos;
            s += Gl[j] * Yvb[(size_t)j << 10];
        }
        S[pos][d] = s;
    }
    __syncthreads();
    float acc = 0.f;
    for (int p0 = 0; p0 < 64; p0++) {
        int pos = pg * 64 + p0;
        acc += S[pos][d];
        S[pos][d] = acc;
    }
    segsum[pg][d] = acc;
    __syncthreads();
    float off = 0.f;
    for (int g = 0; g < pg; g++) off += segsum[g][d];
    float* gv = GVpre + (((size_t)(b * 16 + h)) << 14) + d;
    for (int p0 = 0; p0 < 64; p0++) {
        int pos = pg * 64 + p0;
        gv[pos << 6] = S[pos][d] + off;
    }
}

// -------- pass_2b: ao = AOp + (lam/1024)*GV[pq]; RMS; bf16 store --------
__global__ __launch_bounds__(256) void pass_2b(const float* __restrict__ AOp,
                                               const float* __restrict__ GVpre,
                                               const float* __restrict__ lamp,
                                               const float* __restrict__ wan,
                                               unsigned short* __restrict__ aoS) {
    const int qg = blockIdx.x;
    const int h = blockIdx.y, b = blockIdx.z;
    const int t = threadIdx.x;
    const int d = t & 63, rg = t >> 6;
    const float lamg = (*lamp) * (1.f / 1024.f);
    const float wv = wan[d];
    const float* aob = AOp + ((((size_t)(b * 16 + h)) << 10) + (qg << 8)) * 64 + d;
    const float* gvb = GVpre + (((size_t)(b * 16 + h)) << 14) + d;
    unsigned short* ob = aoS + ((size_t)b << 20) + ((size_t)h << 16) + ((size_t)(qg << 8) << 6) + d;
    for (int p0 = 0; p0 < 64; p0++) {
        int pq = p0 * 4 + rg;
        float ao = aob[(size_t)pq << 6] + lamg * gvb[(size_t)pq << 6];
        float ss = ao * ao;
#pragma unroll
        for (int o = 1; o < 64; o <<= 1) ss += __shfl_xor(ss, o);
        float rr_ = rsqrtf(ss * (1.f / 64.f) + EPS_ATTN);
        ob[(size_t)pq << 6] = f2bf(ao * rr_ * wv);
    }
}

extern "C" void kernel_launch(void* const* d_in, const int* in_sizes, int n_in,
                              void* d_out, int out_size, void* d_ws, size_t ws_size,
                              hipStream_t stream) {
    const float* x    = (const float*)d_in[0];
    const float* fc   = (const float*)d_in[1];
    const float* w1   = (const float*)d_in[2];
    const float* w2   = (const float*)d_in[3];
    const float* Wq   = (const float*)d_in[4];
    const float* bq   = (const float*)d_in[5];
    const float* Wk   = (const float*)d_in[6];
    const float* bk   = (const float*)d_in[7];
    const float* Wv   = (const float*)d_in[8];
    const float* bv   = (const float*)d_in[9];
    const float* Wo   = (const float*)d_in[10];
    const float* bo   = (const float*)d_in[11];
    const float* lq1  = (const float*)d_in[12];
    const float* lk1  = (const float*)d_in[13];
    const float* lq2  = (const float*)d_in[14];
    const float* lk2  = (const float*)d_in[15];
    const float* wan  = (const float*)d_in[16];
    const float* Wg   = (const float*)d_in[17];
    const float* bg   = (const float*)d_in[18];
    const float* Wout = (const float*)d_in[19];
    const float* bout = (const float*)d_in[20];

    char* ws = (char*)d_ws;
    const size_t MB = 1024 * 1024;
    // Layout (peak 53 MB, same as the passing round 9):
    float* G    = (float*)(ws);                     // [0, 128K)
    float* lam  = (float*)(ws + 256 * 1024);        // 4 B
    unsigned short* hH = (unsigned short*)(ws + 1 * MB);   // [1,5)  (dead after QKV)
    unsigned short* hL = (unsigned short*)(ws + 5 * MB);   // [5,9)
    float* Yq   = (float*)(ws + 9 * MB);            // [9,17)
    float* Yk   = (float*)(ws + 17 * MB);           // [17,25) (dead after rope_split_k)
    float* Yv   = (float*)(ws + 25 * MB);           // [25,33) (dead after pass_2a)
    unsigned short* WqH = (unsigned short*)(ws + 33 * MB); // [33,35) (dead after QKV)
    unsigned short* WqL = (unsigned short*)(ws + 35 * MB); // [35,37)
    unsigned short* WkH = (unsigned short*)(ws + 37 * MB); // [37,39)
    unsigned short* WkL = (unsigned short*)(ws + 39 * MB); // [39,41)
    unsigned short* WvH = (unsigned short*)(ws + 41 * MB); // [41,43)
    unsigned short* WvL = (unsigned short*)(ws + 43 * MB); // [43,45)
    unsigned short* WoutB = (unsigned short*)(ws + 45 * MB); // [45,53)
    float* AOp  = (float*)(ws + 33 * MB);           // reuse [33,41) after QKV
    float* GVpre= (float*)(ws + 41 * MB);           // reuse [41,43) after QKV
    unsigned short* WoB = (unsigned short*)(ws + 43 * MB); // reuse [43,45) after QKV
    unsigned short* KhG = (unsigned short*)(ws + 1 * MB);  // reuse [1,5)  (hH dead)
    unsigned short* KlG = (unsigned short*)(ws + 5 * MB);  // reuse [5,9)  (hL dead)
    unsigned short* VtH = (unsigned short*)(ws + 17 * MB); // reuse [17,21) (Yk dead)
    unsigned short* VtL = (unsigned short*)(ws + 21 * MB); // reuse [21,25)
    unsigned short* aoS = (unsigned short*)(ws + 1 * MB);  // reuse [1,5)  (KhG dead after pass_1)
    float* X1           = (float*)(ws + 9 * MB);           // reuse [9,17) (Yq dead after pass_1)
    unsigned short* h2b = (unsigned short*)(ws + 5 * MB);  // reuse [5,9)  (KlG dead)
    unsigned short* mlp = (unsigned short*)(ws + 17 * MB); // reuse [17,33) (VtH/L, Yv dead)

    prep<<<32, 256, 0, stream>>>(G, lam, lq1, lk1, lq2, lk2);
    cvt_bf16<<<4096, 256, 0, stream>>>(Wout, WoutB, 1048576);
    rms_split<<<2048, 256, 0, stream>>>(x, w1, hH, hL, EPS_DEF);
    cvt_split<<<1024, 256, 0, stream>>>(Wq, WqH, WqL, 262144);
    cvt_split<<<1024, 256, 0, stream>>>(Wk, WkH, WkL, 262144);
    cvt_split<<<1024, 256, 0, stream>>>(Wv, WvH, WvL, 262144);
    gemm_qkv_ps<<<dim3(32, 16, 3), 256, 0, stream>>>(hH, hL, WqH, WqL, WkH, WkL, WvH, WvL,
                                                     bq, bk, bv, Yq, Yk, Yv);
    cvt_bf16<<<1024, 256, 0, stream>>>(Wo, WoB, 262144);   // after QKV (region overlaps WvL)
    rope_inplace<<<2048, 256, 0, stream>>>(Yq, fc);
    rope_split_k<<<2048, 256, 0, stream>>>(Yk, fc, KhG, KlG);   // after QKV (overlaps hH/hL)
    v_split_t<<<dim3(16, 16, 2), 256, 0, stream>>>(Yv, VtH, VtL);
    pass_1<<<256, 256, 0, stream>>>(Yq, KhG, KlG, VtH, VtL, lam, G, AOp);
    pass_2a<<<dim3(16, 2), 256, 0, stream>>>(G, Yv, GVpre);
    pass_2b<<<dim3(4, 16, 2), 256, 0, stream>>>(AOp, GVpre, lam, wan, aoS);
    dim3 gmf(32, 16);
    gemm_mfma_wb<<<gmf, 256, 0, stream>>>(aoS, WoB, bo, x, X1, 2048, 1024, 1024);
    rms_kernel<1><<<2048, 256, 0, stream>>>(X1, w2, h2b, EPS_DEF);
    gemm_gate_mfma<<<dim3(16, 64), 256, 0, stream>>>(h2b, Wg, bg, mlp);
    // FINAL OUTPUT IS FP32.
    gemm_mfma_wb<<<gmf, 256, 0, stream>>>(mlp, WoutB, bout, X1, (float*)d_out, 2048, 1024, 4096);
}

// Round 11
// 439.187 us; speedup vs baseline: 8.4240x; 1.0574x over previous
//
#include <hip/hip_runtime.h>

#define LAMBDA_INIT 0.2f
#define SCALING 0.17677669529663687f   // 1/sqrt(32)
#define EPS_DEF 1.1920928955078125e-07f
#define EPS_ATTN 1e-5f

typedef unsigned short us4 __attribute__((ext_vector_type(4)));
typedef unsigned short us8v __attribute__((ext_vector_type(8)));
typedef float f32x4 __attribute__((ext_vector_type(4)));
typedef float f32x2 __attribute__((ext_vector_type(2)));
typedef __bf16 bf16x8 __attribute__((ext_vector_type(8)));

#define MFMA16(a, b, c) __builtin_amdgcn_mfma_f32_16x16x32_bf16((a), (b), (c), 0, 0, 0)

__device__ __forceinline__ float bf2f(unsigned short u) {
    unsigned int x = ((unsigned int)u) << 16;
    return __builtin_bit_cast(float, x);
}
__device__ __forceinline__ unsigned short f2bf(float f) {
    unsigned int x = __builtin_bit_cast(unsigned int, f);
    x += 0x7fffu + ((x >> 16) & 1u);
    return (unsigned short)(x >> 16);
}
// split a pair of f32x4 into hi/lo bf16 (x ~= hi + lo, residual ~2^-18 rel)
__device__ __forceinline__ void split8(f32x4 a, f32x4 b, us8v& hi, us8v& lo) {
#pragma unroll
    for (int u = 0; u < 4; u++) {
        unsigned short h = f2bf(a[u]);
        hi[u] = h; lo[u] = f2bf(a[u] - bf2f(h));
        unsigned short h2 = f2bf(b[u]);
        hi[4 + u] = h2; lo[4 + u] = f2bf(b[u] - bf2f(h2));
    }
}
__device__ __forceinline__ bf16x8 ldb(const unsigned short* p) {
    return __builtin_bit_cast(bf16x8, *(const us8v*)p);
}

__device__ __forceinline__ float wave_sum(float v) {
#pragma unroll
    for (int o = 32; o > 0; o >>= 1) v += __shfl_down(v, o);
    return v;
}
__device__ __forceinline__ float block_sum(float v, float* red4) {
    int wv = threadIdx.x >> 6;
    float w = wave_sum(v);
    __syncthreads();
    if ((threadIdx.x & 63) == 0) red4[wv] = w;
    __syncthreads();
    return red4[0] + red4[1] + red4[2] + red4[3];
}

// ---------------- prep: zero G, compute lambda ----------------
__global__ __launch_bounds__(256) void prep(float* __restrict__ G, float* __restrict__ lamp,
                                            const float* lq1, const float* lk1,
                                            const float* lq2, const float* lk2) {
    int i = (blockIdx.x * 256 + threadIdx.x) * 4;
    G[i] = 0.f; G[i + 1] = 0.f; G[i + 2] = 0.f; G[i + 3] = 0.f;
    if (blockIdx.x == 0 && threadIdx.x == 0) {
        float a = 0.f, c = 0.f;
        for (int d = 0; d < 32; d++) {
            a += lq1[d] * lk1[d];
            c += lq2[d] * lk2[d];
        }
        *lamp = expf(a) - expf(c) + LAMBDA_INIT;
    }
}

// ---------------- fp32 -> bf16 weight conversion ----------------
__global__ __launch_bounds__(256) void cvt_bf16(const float* __restrict__ s,
                                                unsigned short* __restrict__ d, int n4) {
    int i = blockIdx.x * 256 + threadIdx.x;
    if (i >= n4) return;
    f32x4 v = ((const f32x4*)s)[i];
    us4 o;
#pragma unroll
    for (int u = 0; u < 4; u++) o[u] = f2bf(v[u]);
    ((us4*)d)[i] = o;
}

// ---------------- fp32 -> hi/lo bf16 split conversion ----------------
__global__ __launch_bounds__(256) void cvt_split(const float* __restrict__ s,
                                                 unsigned short* __restrict__ hi,
                                                 unsigned short* __restrict__ lo, int n4) {
    int i = blockIdx.x * 256 + threadIdx.x;
    if (i >= n4) return;
    f32x4 v = ((const f32x4*)s)[i];
    us4 h, l;
#pragma unroll
    for (int u = 0; u < 4; u++) {
        h[u] = f2bf(v[u]);
        l[u] = f2bf(v[u] - bf2f(h[u]));
    }
    ((us4*)hi)[i] = h;
    ((us4*)lo)[i] = l;
}

// ---------------- RMSNorm: fp32 in, fp32 weight, bf16/fp32 out ----------------
template <int OUTBF>
__global__ __launch_bounds__(256) void rms_kernel(const float* __restrict__ x,
                                                  const float* __restrict__ w,
                                                  void* __restrict__ out, float eps) {
    int row = blockIdx.x;
    int tid = threadIdx.x;
    size_t base = (size_t)row * 1024 + tid * 4;
    f32x4 v = *(const f32x4*)(x + base);
    float ss = v[0]*v[0] + v[1]*v[1] + v[2]*v[2] + v[3]*v[3];
    __shared__ float red4[4];
    float tot = block_sum(ss, red4);
    float r = rsqrtf(tot * (1.0f / 1024.f) + eps);
    f32x4 wv = *(const f32x4*)(w + tid * 4);
    if (OUTBF) {
        us4 o;
#pragma unroll
        for (int i = 0; i < 4; i++) o[i] = f2bf(v[i] * r * wv[i]);
        *(us4*)((unsigned short*)out + base) = o;
    } else {
        f32x4 o;
#pragma unroll
        for (int i = 0; i < 4; i++) o[i] = v[i] * r * wv[i];
        *(f32x4*)((float*)out + base) = o;
    }
}

// ---------------- RMSNorm with hi/lo split output ----------------
__global__ __launch_bounds__(256) void rms_split(const float* __restrict__ x,
                                                 const float* __restrict__ w,
                                                 unsigned short* __restrict__ hh,
                                                 unsigned short* __restrict__ hl, float eps) {
    int row = blockIdx.x;
    int tid = threadIdx.x;
    size_t base = (size_t)row * 1024 + tid * 4;
    f32x4 v = *(const f32x4*)(x + base);
    float ss = v[0]*v[0] + v[1]*v[1] + v[2]*v[2] + v[3]*v[3];
    __shared__ float red4[4];
    float tot = block_sum(ss, red4);
    float r = rsqrtf(tot * (1.0f / 1024.f) + eps);
    f32x4 wv = *(const f32x4*)(w + tid * 4);
    us4 oh, ol;
#pragma unroll
    for (int i = 0; i < 4; i++) {
        float val = v[i] * r * wv[i];
        oh[i] = f2bf(val);
        ol[i] = f2bf(val - bf2f(oh[i]));
    }
    *(us4*)(hh + base) = oh;
    *(us4*)(hl + base) = ol;
}

// =====================================================================
// QKV split-bf16 MFMA GEMM, PRE-SPLIT operands, SOFTWARE-PIPELINED.
// BM=64, BN=64, BK=64, 4 waves (2x2). Grid (32,16,3).
// =====================================================================
__global__ __launch_bounds__(256) void gemm_qkv_ps(
        const unsigned short* __restrict__ AH, const unsigned short* __restrict__ AL,
        const unsigned short* __restrict__ WqH, const unsigned short* __restrict__ WqL,
        const unsigned short* __restrict__ WkH, const unsigned short* __restrict__ WkL,
        const unsigned short* __restrict__ WvH, const unsigned short* __restrict__ WvL,
        const float* __restrict__ bq, const float* __restrict__ bk, const float* __restrict__ bv,
        float* __restrict__ Yq, float* __restrict__ Yk, float* __restrict__ Yv) {
    const int z = blockIdx.z;
    const unsigned short* BH = (z == 0) ? WqH : (z == 1) ? WkH : WvH;
    const unsigned short* BL = (z == 0) ? WqL : (z == 1) ? WkL : WvL;
    const float* bias = (z == 0) ? bq : (z == 1) ? bk : bv;
    float* out        = (z == 0) ? Yq : (z == 1) ? Yk : Yv;
    const int K = 1024, N = 1024;
    __shared__ __align__(16) unsigned short Ah[64][72];
    __shared__ __align__(16) unsigned short Al[64][72];
    __shared__ __align__(16) unsigned short Bh[64][72];
    __shared__ __align__(16) unsigned short Bl[64][72];
    const int t = threadIdx.x;
    const int bm = blockIdx.x, bn = blockIdx.y;
    const int lane = t & 63, w = t >> 6;
    const int wr = w >> 1, wc = w & 1;
    const int l15 = lane & 15, lg = lane >> 4;
    const int sr = t >> 2, sc = (t & 3) * 16;

    const unsigned short* AgH = AH + (size_t)(bm * 64 + sr) * K + sc;
    const unsigned short* AgL = AL + (size_t)(bm * 64 + sr) * K + sc;
    const unsigned short* BgH = BH + (size_t)(bn * 64 + sr) * K + sc;
    const unsigned short* BgL = BL + (size_t)(bn * 64 + sr) * K + sc;

    f32x4 acc[2][2] = {};

    // prologue: load k0 = 0
    us8v ah0 = *(const us8v*)AgH, ah1 = *(const us8v*)(AgH + 8);
    us8v al0 = *(const us8v*)AgL, al1 = *(const us8v*)(AgL + 8);
    us8v bh0 = *(const us8v*)BgH, bh1 = *(const us8v*)(BgH + 8);
    us8v bl0 = *(const us8v*)BgL, bl1 = *(const us8v*)(BgL + 8);

    for (int k0 = 0; k0 < K; k0 += 64) {
        __syncthreads();
        *(us8v*)&Ah[sr][sc] = ah0; *(us8v*)&Ah[sr][sc + 8] = ah1;
        *(us8v*)&Al[sr][sc] = al0; *(us8v*)&Al[sr][sc + 8] = al1;
        *(us8v*)&Bh[sr][sc] = bh0; *(us8v*)&Bh[sr][sc + 8] = bh1;
        *(us8v*)&Bl[sr][sc] = bl0; *(us8v*)&Bl[sr][sc + 8] = bl1;
        __syncthreads();
        if (k0 + 64 < K) {
            const int kn = k0 + 64;
            ah0 = *(const us8v*)(AgH + kn); ah1 = *(const us8v*)(AgH + kn + 8);
            al0 = *(const us8v*)(AgL + kn); al1 = *(const us8v*)(AgL + kn + 8);
            bh0 = *(const us8v*)(BgH + kn); bh1 = *(const us8v*)(BgH + kn + 8);
            bl0 = *(const us8v*)(BgL + kn); bl1 = *(const us8v*)(BgL + kn + 8);
        }
#pragma unroll
        for (int kk = 0; kk < 2; kk++) {
            bf16x8 afh[2], afl[2], bfh[2], bfl[2];
#pragma unroll
            for (int mi = 0; mi < 2; mi++) {
                afh[mi] = ldb(&Ah[wr * 32 + mi * 16 + l15][kk * 32 + lg * 8]);
                afl[mi] = ldb(&Al[wr * 32 + mi * 16 + l15][kk * 32 + lg * 8]);
            }
#pragma unroll
            for (int ni = 0; ni < 2; ni++) {
                bfh[ni] = ldb(&Bh[wc * 32 + ni * 16 + l15][kk * 32 + lg * 8]);
                bfl[ni] = ldb(&Bl[wc * 32 + ni * 16 + l15][kk * 32 + lg * 8]);
            }
#pragma unroll
            for (int mi = 0; mi < 2; mi++)
#pragma unroll
                for (int ni = 0; ni < 2; ni++) {
                    acc[mi][ni] = MFMA16(afl[mi], bfh[ni], acc[mi][ni]);
                    acc[mi][ni] = MFMA16(afh[mi], bfl[ni], acc[mi][ni]);
                    acc[mi][ni] = MFMA16(afh[mi], bfh[ni], acc[mi][ni]);
                }
        }
    }

    const int rbase = bm * 64 + wr * 32 + (lg << 2);
    const int cbase = bn * 64 + wc * 32 + l15;
#pragma unroll
    for (int mi = 0; mi < 2; mi++) {
#pragma unroll
        for (int ni = 0; ni < 2; ni++) {
            int col = cbase + ni * 16;
            float bb = bias[col];
#pragma unroll
            for (int r = 0; r < 4; r++) {
                int row = rbase + mi * 16 + r;
                out[(size_t)row * N + col] = acc[mi][ni][r] + bb;
            }
        }
    }
}

// =====================================================================
// bf16 MFMA GEMM, pre-converted bf16 B, SOFTWARE-PIPELINED.
// BM=64, BN=64, BK=64, 4 waves (2x2).
// =====================================================================
__global__ __launch_bounds__(256) void gemm_mfma_wb(const unsigned short* __restrict__ A,
                                                    const unsigned short* __restrict__ Bt,
                                                    const float* __restrict__ bias,
                                                    const float* __restrict__ res,
                                                    float* __restrict__ out,
                                                    int M, int N, int K) {
    __shared__ __align__(16) unsigned short As[64][72];
    __shared__ __align__(16) unsigned short Bs[64][72];
    const int t = threadIdx.x;
    const int bm = blockIdx.x, bn = blockIdx.y;
    const int lane = t & 63, w = t >> 6;
    const int wr = w >> 1, wc = w & 1;
    const int l15 = lane & 15, lg = lane >> 4;
    const int sr = t >> 2, sc = (t & 3) * 16;

    const unsigned short* Ag = A + (size_t)(bm * 64 + sr) * K + sc;
    const unsigned short* Bg = Bt + (size_t)(bn * 64 + sr) * K + sc;

    f32x4 acc[2][2] = {};

    us8v a0 = *(const us8v*)Ag, a1 = *(const us8v*)(Ag + 8);
    us8v b0 = *(const us8v*)Bg, b1 = *(const us8v*)(Bg + 8);

    for (int k0 = 0; k0 < K; k0 += 64) {
        __syncthreads();
        *(us8v*)&As[sr][sc]     = a0;
        *(us8v*)&As[sr][sc + 8] = a1;
        *(us8v*)&Bs[sr][sc]     = b0;
        *(us8v*)&Bs[sr][sc + 8] = b1;
        __syncthreads();
        if (k0 + 64 < K) {
            const int kn = k0 + 64;
            a0 = *(const us8v*)(Ag + kn); a1 = *(const us8v*)(Ag + kn + 8);
            b0 = *(const us8v*)(Bg + kn); b1 = *(const us8v*)(Bg + kn + 8);
        }
#pragma unroll
        for (int kk = 0; kk < 2; kk++) {
            bf16x8 af[2], bf[2];
#pragma unroll
            for (int mi = 0; mi < 2; mi++)
                af[mi] = ldb(&As[wr * 32 + mi * 16 + l15][kk * 32 + lg * 8]);
#pragma unroll
            for (int ni = 0; ni < 2; ni++)
                bf[ni] = ldb(&Bs[wc * 32 + ni * 16 + l15][kk * 32 + lg * 8]);
#pragma unroll
            for (int mi = 0; mi < 2; mi++)
#pragma unroll
                for (int ni = 0; ni < 2; ni++)
                    acc[mi][ni] = MFMA16(af[mi], bf[ni], acc[mi][ni]);
        }
    }

    const int rbase = bm * 64 + wr * 32 + (lg << 2);
    const int cbase = bn * 64 + wc * 32 + l15;
#pragma unroll
    for (int mi = 0; mi < 2; mi++) {
#pragma unroll
        for (int ni = 0; ni < 2; ni++) {
            int col = cbase + ni * 16;
            float bb = bias[col];
#pragma unroll
            for (int r = 0; r < 4; r++) {
                int row = rbase + mi * 16 + r;
                size_t oi = (size_t)row * N + col;
                out[oi] = acc[mi][ni][r] + bb + res[oi];
            }
        }
    }
}

// ------- fused gate GEMM (MFMA): mlp = (h2@Wu^T+bu) * silu(h2@Wv^T+bv) -------
__global__ __launch_bounds__(256) void gemm_gate_mfma(const unsigned short* __restrict__ A,
                                                      const float* __restrict__ Wg,
                                                      const float* __restrict__ bg,
                                                      unsigned short* __restrict__ mlp) {
    __shared__ __align__(16) unsigned short As[128][72];
    __shared__ __align__(16) unsigned short BsU[64][72];
    __shared__ __align__(16) unsigned short BsV[64][72];
    const int t = threadIdx.x;
    const int bm = blockIdx.x, bn = blockIdx.y;
    const int lane = t & 63, w = t >> 6;
    const int wr = w >> 1, wc = w & 1;
    const int l15 = lane & 15, lg = lane >> 4;
    const int sr = t >> 2, sc = (t & 3) * 16;

    const unsigned short* Ag  = A + (size_t)(bm * 128 + sr) * 1024 + sc;
    const unsigned short* Ag2 = Ag + (size_t)64 * 1024;
    const float* BgU = Wg + (size_t)(bn * 64 + sr) * 1024 + sc;
    const float* BgV = Wg + (size_t)(4096 + bn * 64 + sr) * 1024 + sc;

    f32x4 accU[4][2] = {};
    f32x4 accV[4][2] = {};

    for (int k0 = 0; k0 < 1024; k0 += 64) {
        us8v a0 = *(const us8v*)(Ag + k0);
        us8v a1 = *(const us8v*)(Ag + k0 + 8);
        us8v a2 = *(const us8v*)(Ag2 + k0);
        us8v a3 = *(const us8v*)(Ag2 + k0 + 8);
        f32x4 u0 = *(const f32x4*)(BgU + k0);
        f32x4 u1 = *(const f32x4*)(BgU + k0 + 4);
        f32x4 u2 = *(const f32x4*)(BgU + k0 + 8);
        f32x4 u3 = *(const f32x4*)(BgU + k0 + 12);
        f32x4 v0 = *(const f32x4*)(BgV + k0);
        f32x4 v1 = *(const f32x4*)(BgV + k0 + 4);
        f32x4 v2 = *(const f32x4*)(BgV + k0 + 8);
        f32x4 v3 = *(const f32x4*)(BgV + k0 + 12);
        us8v uw0, uw1, vw0, vw1;
#pragma unroll
        for (int u = 0; u < 4; u++) {
            uw0[u] = f2bf(u0[u]); uw0[4 + u] = f2bf(u1[u]);
            uw1[u] = f2bf(u2[u]); uw1[4 + u] = f2bf(u3[u]);
            vw0[u] = f2bf(v0[u]); vw0[4 + u] = f2bf(v1[u]);
            vw1[u] = f2bf(v2[u]); vw1[4 + u] = f2bf(v3[u]);
        }
        __syncthreads();
        *(us8v*)&As[sr][sc]          = a0;
        *(us8v*)&As[sr][sc + 8]      = a1;
        *(us8v*)&As[sr + 64][sc]     = a2;
        *(us8v*)&As[sr + 64][sc + 8] = a3;
        *(us8v*)&BsU[sr][sc]         = uw0;
        *(us8v*)&BsU[sr][sc + 8]     = uw1;
        *(us8v*)&BsV[sr][sc]         = vw0;
        *(us8v*)&BsV[sr][sc + 8]     = vw1;
        __syncthreads();
#pragma unroll
        for (int kk = 0; kk < 2; kk++) {
            bf16x8 af[4], bu[2], bv2[2];
#pragma unroll
            for (int mi = 0; mi < 4; mi++)
                af[mi] = ldb(&As[wr * 64 + mi * 16 + l15][kk * 32 + lg * 8]);
#pragma unroll
            for (int ni = 0; ni < 2; ni++) {
                bu[ni]  = ldb(&BsU[wc * 32 + ni * 16 + l15][kk * 32 + lg * 8]);
                bv2[ni] = ldb(&BsV[wc * 32 + ni * 16 + l15][kk * 32 + lg * 8]);
            }
#pragma unroll
            for (int mi = 0; mi < 4; mi++)
#pragma unroll
                for (int ni = 0; ni < 2; ni++) {
                    accU[mi][ni] = MFMA16(af[mi], bu[ni], accU[mi][ni]);
                    accV[mi][ni] = MFMA16(af[mi], bv2[ni], accV[mi][ni]);
                }
        }
    }

    const int rbase = bm * 128 + wr * 64 + (lg << 2);
    const int cbase = bn * 64 + wc * 32 + l15;
#pragma unroll
    for (int mi = 0; mi < 4; mi++) {
#pragma unroll
        for (int ni = 0; ni < 2; ni++) {
            int col = cbase + ni * 16;
            float bu_ = bg[col], bv_ = bg[4096 + col];
#pragma unroll
            for (int r = 0; r < 4; r++) {
                int row = rbase + mi * 16 + r;
                float u = accU[mi][ni][r] + bu_;
                float v = accV[mi][ni][r] + bv_;
                float s = v / (1.f + __expf(-v));
                mlp[(size_t)row * 4096 + col] = f2bf(u * s);
            }
        }
    }
}

// ---------------- RoPE in place (Q), token order ----------------
__global__ __launch_bounds__(256) void rope_inplace(float* __restrict__ Y,
                                                    const float* __restrict__ fc) {
    int t = blockIdx.x;
    int s = t & 1023;
    int p = s >> 2;
    if (p == 0) return;
    int c0 = threadIdx.x * 4;
    float* y = Y + (size_t)t * 1024 + c0;
    int d4 = (c0 & 31) >> 1;
    f32x4 f = *(const f32x4*)(fc + ((size_t)(p - 1) * 16 + d4) * 2);  // [cos,sin,cos,sin]
    float v0 = y[0], v1 = y[1], v2 = y[2], v3 = y[3];
    y[0] = v0 * f[0] - v1 * f[1];
    y[1] = v0 * f[1] + v1 * f[0];
    y[2] = v2 * f[2] - v3 * f[3];
    y[3] = v2 * f[3] + v3 * f[2];
}

// ------- RoPE(K) + hi/lo bf16 split, token-order output -------
__global__ __launch_bounds__(256) void rope_split_k(const float* __restrict__ Yk,
                                                    const float* __restrict__ fc,
                                                    unsigned short* __restrict__ KhG,
                                                    unsigned short* __restrict__ KlG) {
    int t = blockIdx.x;           // b*1024 + s
    int s = t & 1023;
    int p = s >> 2;
    int c0 = threadIdx.x * 4;
    const float* y = Yk + (size_t)t * 1024 + c0;
    float v0 = y[0], v1 = y[1], v2 = y[2], v3 = y[3];
    if (p > 0) {
        int d4 = (c0 & 31) >> 1;
        f32x4 f = *(const f32x4*)(fc + ((size_t)(p - 1) * 16 + d4) * 2);
        float w0 = v0 * f[0] - v1 * f[1];
        float w1 = v0 * f[1] + v1 * f[0];
        float w2 = v2 * f[2] - v3 * f[3];
        float w3 = v2 * f[3] + v3 * f[2];
        v0 = w0; v1 = w1; v2 = w2; v3 = w3;
    }
    us4 hi, lo;
    hi[0] = f2bf(v0); lo[0] = f2bf(v0 - bf2f(hi[0]));
    hi[1] = f2bf(v1); lo[1] = f2bf(v1 - bf2f(hi[1]));
    hi[2] = f2bf(v2); lo[2] = f2bf(v2 - bf2f(hi[2]));
    hi[3] = f2bf(v3); lo[3] = f2bf(v3 - bf2f(hi[3]));
    *(us4*)(KhG + (size_t)t * 1024 + c0) = hi;
    *(us4*)(KlG + (size_t)t * 1024 + c0) = lo;
}

// ------- V transpose + hi/lo split: Vt[(b,h)][d (64)][j (1024)] -------
// V row for attention index j is RAW Yv row j (reference quirk).
__global__ __launch_bounds__(256) void v_split_t(const float* __restrict__ Yv,
                                                 unsigned short* __restrict__ VtH,
                                                 unsigned short* __restrict__ VtL) {
    const int jc = blockIdx.x, h = blockIdx.y, b = blockIdx.z;   // (16,16,2)
    __shared__ float tile[64][65];
    const int t = threadIdx.x;
    {
        const int jr = t >> 2, dc = (t & 3) * 16;
        const float* src = Yv + ((size_t)(b * 1024 + jc * 64 + jr) << 10) + h * 64 + dc;
        *(f32x4*)&tile[jr][dc]      = *(const f32x4*)src;
        *(f32x4*)&tile[jr][dc + 4]  = *(const f32x4*)(src + 4);
        *(f32x4*)&tile[jr][dc + 8]  = *(const f32x4*)(src + 8);
        *(f32x4*)&tile[jr][dc + 12] = *(const f32x4*)(src + 12);
    }
    __syncthreads();
    const int d = t >> 2, js = (t & 3) * 16;
    us8v h0, h1, l0, l1;
#pragma unroll
    for (int n = 0; n < 16; n++) {
        float val = tile[js + n][d];
        unsigned short hh = f2bf(val);
        unsigned short ll = f2bf(val - bf2f(hh));
        if (n < 8) { h0[n] = hh; l0[n] = ll; }
        else       { h1[n - 8] = hh; l1[n - 8] = ll; }
    }
    size_t ob = (((size_t)(b * 16 + h) * 64 + d) << 10) + jc * 64 + js;
    *(us8v*)(VtH + ob) = h0; *(us8v*)(VtH + ob + 8) = h1;
    *(us8v*)(VtL + ob) = l0; *(us8v*)(VtL + ob + 8) = l1;
}

// =====================================================================
// MFMA attention pass_1: 512 blocks heavy-first (2 blocks/CU),
// SOFTWARE-PIPELINED staging (loads for chunk kc+1 issue before the
// compute of chunk kc). Math identical to rounds 9/10.
// =====================================================================
__global__ __launch_bounds__(256) void pass_1(const float* __restrict__ Yq,
                                              const unsigned short* __restrict__ KhG,
                                              const unsigned short* __restrict__ KlG,
                                              const unsigned short* __restrict__ VtH,
                                              const unsigned short* __restrict__ VtL,
                                              const float* __restrict__ lamp,
                                              float* __restrict__ G,
                                              float* __restrict__ AOp) {
    const int blk = blockIdx.x;
    const int qc = 15 - (blk >> 5);
    const int h  = blk & 15;
    const int b  = (blk >> 4) & 1;
    const int t = threadIdx.x;
    const int lane = t & 63, w = t >> 6;
    const int l15 = lane & 15, lg = lane >> 4;

    __shared__ __align__(16) unsigned short Kh[64][72];
    __shared__ __align__(16) unsigned short Kl[64][72];
    __shared__ __align__(16) unsigned short Vth[64][72];
    __shared__ __align__(16) unsigned short Vtl[64][72];
    __shared__ __align__(16) unsigned short Wh[64][72];
    __shared__ __align__(16) unsigned short Wl[64][72];
    __shared__ float Gacc[1024];

    for (int i = t; i < 1024; i += 256) Gacc[i] = 0.f;

    us8v qh[2], ql[2];
    {
        const float* qp = Yq + ((size_t)(b * 1024 + qc * 64 + w * 16 + l15) << 10)
                          + h * 64 + lg * 8;
#pragma unroll
        for (int H = 0; H < 2; H++)
            split8(*(const f32x4*)(qp + H * 32), *(const f32x4*)(qp + H * 32 + 4), qh[H], ql[H]);
    }
    const int dq0 = w * 16 + (lg << 2);

    const int srow = t >> 2, ssub = t & 3;
    const int ptk = 4 * (srow & 15) + (srow >> 4);   // permuted in-chunk token for row srow
    const unsigned short* KhB = KhG + ((size_t)(b * 1024) << 10) + h * 64;
    const unsigned short* KlB = KlG + ((size_t)(b * 1024) << 10) + h * 64;
    const unsigned short* VhB = VtH + (((size_t)(b * 16 + h) * 64 + srow) << 10) + ssub * 256;
    const unsigned short* VlB = VtL + (((size_t)(b * 16 + h) * 64 + srow) << 10) + ssub * 256;
    const float lam = *lamp;

    float z1r[4] = {0.f, 0.f, 0.f, 0.f};
    float z2r[4] = {0.f, 0.f, 0.f, 0.f};

    // -------- sweep 1: denominators (pipelined K staging) --------
    us8v rkh0, rkh1, rkl0, rkl1;
    {
        const unsigned short* kh = KhB + ((size_t)ptk << 10) + ssub * 16;
        const unsigned short* kl = KlB + ((size_t)ptk << 10) + ssub * 16;
        rkh0 = *(const us8v*)kh; rkh1 = *(const us8v*)(kh + 8);
        rkl0 = *(const us8v*)kl; rkl1 = *(const us8v*)(kl + 8);
    }
    for (int kc = 0; kc <= qc; kc++) {
        __syncthreads();
        *(us8v*)&Kh[srow][ssub * 16]     = rkh0;
        *(us8v*)&Kh[srow][ssub * 16 + 8] = rkh1;
        *(us8v*)&Kl[srow][ssub * 16]     = rkl0;
        *(us8v*)&Kl[srow][ssub * 16 + 8] = rkl1;
        __syncthreads();
        if (kc < qc) {
            const unsigned short* kh = KhB + ((size_t)((kc + 1) * 64 + ptk) << 10) + ssub * 16;
            const unsigned short* kl = KlB + ((size_t)((kc + 1) * 64 + ptk) << 10) + ssub * 16;
            rkh0 = *(const us8v*)kh; rkh1 = *(const us8v*)(kh + 8);
            rkl0 = *(const us8v*)kl; rkl1 = *(const us8v*)(kl + 8);
        }
        const int kpos = kc * 16 + l15;
#pragma unroll
        for (int kf = 0; kf < 4; kf++) {
            const int krow = kf * 16 + l15;
            const int kcol = lg * 8;
            bf16x8 b1h = ldb(&Kh[krow][kcol]),      b1l = ldb(&Kl[krow][kcol]);
            bf16x8 b2h = ldb(&Kh[krow][32 + kcol]), b2l = ldb(&Kl[krow][32 + kcol]);
            f32x4 s1 = {}, s2 = {};
            s1 = MFMA16(__builtin_bit_cast(bf16x8, ql[0]), b1h, s1);
            s1 = MFMA16(__builtin_bit_cast(bf16x8, qh[0]), b1l, s1);
            s1 = MFMA16(__builtin_bit_cast(bf16x8, qh[0]), b1h, s1);
            s2 = MFMA16(__builtin_bit_cast(bf16x8, ql[1]), b2h, s2);
            s2 = MFMA16(__builtin_bit_cast(bf16x8, qh[1]), b2l, s2);
            s2 = MFMA16(__builtin_bit_cast(bf16x8, qh[1]), b2h, s2);
#pragma unroll
            for (int r = 0; r < 4; r++) {
                int pq = (qc * 64 + dq0 + r) >> 2;
                if (kpos <= pq) {
                    z1r[r] += __expf(fabsf(s1[r] * SCALING));
                    z2r[r] += __expf(fabsf(s2[r] * SCALING));
                }
            }
        }
    }
#pragma unroll
    for (int r = 0; r < 4; r++) {
        float a = z1r[r];
        a += __shfl_xor(a, 1); a += __shfl_xor(a, 2);
        a += __shfl_xor(a, 4); a += __shfl_xor(a, 8);
        z1r[r] = 1.f / fmaxf(a, 1e-20f);
        float c = z2r[r];
        c += __shfl_xor(c, 1); c += __shfl_xor(c, 2);
        c += __shfl_xor(c, 4); c += __shfl_xor(c, 8);
        z2r[r] = 1.f / fmaxf(c, 1e-20f);
    }

    f32x4 ao[4] = {};

    // -------- sweep 2: weights + G colsums + AV (pipelined K+V) --------
    us8v rvh0, rvh1, rvl0, rvl1;
    {
        const unsigned short* kh = KhB + ((size_t)ptk << 10) + ssub * 16;
        const unsigned short* kl = KlB + ((size_t)ptk << 10) + ssub * 16;
        rkh0 = *(const us8v*)kh; rkh1 = *(const us8v*)(kh + 8);
        rkl0 = *(const us8v*)kl; rkl1 = *(const us8v*)(kl + 8);
        rvh0 = *(const us8v*)VhB; rvh1 = *(const us8v*)(VhB + 8);
        rvl0 = *(const us8v*)VlB; rvl1 = *(const us8v*)(VlB + 8);
    }
    for (int kc = 0; kc <= qc; kc++) {
        __syncthreads();
        *(us8v*)&Kh[srow][ssub * 16]      = rkh0;
        *(us8v*)&Kh[srow][ssub * 16 + 8]  = rkh1;
        *(us8v*)&Kl[srow][ssub * 16]      = rkl0;
        *(us8v*)&Kl[srow][ssub * 16 + 8]  = rkl1;
        *(us8v*)&Vth[srow][ssub * 16]     = rvh0;
        *(us8v*)&Vth[srow][ssub * 16 + 8] = rvh1;
        *(us8v*)&Vtl[srow][ssub * 16]     = rvl0;
        *(us8v*)&Vtl[srow][ssub * 16 + 8] = rvl1;
        __syncthreads();
        if (kc < qc) {
            const unsigned short* kh = KhB + ((size_t)((kc + 1) * 64 + ptk) << 10) + ssub * 16;
            const unsigned short* kl = KlB + ((size_t)((kc + 1) * 64 + ptk) << 10) + ssub * 16;
            rkh0 = *(const us8v*)kh; rkh1 = *(const us8v*)(kh + 8);
            rkl0 = *(const us8v*)kl; rkl1 = *(const us8v*)(kl + 8);
            const unsigned short* vh = VhB + (kc + 1) * 16;
            const unsigned short* vl = VlB + (kc + 1) * 16;
            rvh0 = *(const us8v*)vh; rvh1 = *(const us8v*)(vh + 8);
            rvl0 = *(const us8v*)vl; rvl1 = *(const us8v*)(vl + 8);
        }
        const int kpos = kc * 16 + l15;
#pragma unroll
        for (int kf = 0; kf < 4; kf++) {
            const int krow = kf * 16 + l15;
            const int kcol = lg * 8;
            bf16x8 b1h = ldb(&Kh[krow][kcol]),      b1l = ldb(&Kl[krow][kcol]);
            bf16x8 b2h = ldb(&Kh[krow][32 + kcol]), b2l = ldb(&Kl[krow][32 + kcol]);
            f32x4 s1 = {}, s2 = {};
            s1 = MFMA16(__builtin_bit_cast(bf16x8, ql[0]), b1h, s1);
            s1 = MFMA16(__builtin_bit_cast(bf16x8, qh[0]), b1l, s1);
            s1 = MFMA16(__builtin_bit_cast(bf16x8, qh[0]), b1h, s1);
            s2 = MFMA16(__builtin_bit_cast(bf16x8, ql[1]), b2h, s2);
            s2 = MFMA16(__builtin_bit_cast(bf16x8, qh[1]), b2l, s2);
            s2 = MFMA16(__builtin_bit_cast(bf16x8, qh[1]), b2h, s2);
            const int kli = kf * 16 + l15;
            float colsum = 0.f;
#pragma unroll
            for (int r = 0; r < 4; r++) {
                int pq = (qc * 64 + dq0 + r) >> 2;
                float wv = 0.f, a1 = 0.f;
                if (kpos <= pq) {
                    float t1 = s1[r] * SCALING, t2 = s2[r] * SCALING;
                    float sg1 = (t1 > 0.f) ? 1.f : ((t1 < 0.f) ? -1.f : 0.f);
                    float sg2 = (t2 > 0.f) ? 1.f : ((t2 < 0.f) ? -1.f : 0.f);
                    a1 = sg1 * __expf(fabsf(t1)) * z1r[r];
                    wv = a1 - lam * (sg2 * __expf(fabsf(t2)) * z2r[r]);
                }
                colsum += a1;
                unsigned short hh = f2bf(wv);
                Wh[dq0 + r][kli] = hh;
                Wl[dq0 + r][kli] = f2bf(wv - bf2f(hh));
            }
            colsum += __shfl_xor(colsum, 16);
            colsum += __shfl_xor(colsum, 32);
            // column r=kf*16+lane -> attention index j = kf*256 + kc*16 + lane
            if (lane < 16) atomicAdd(&Gacc[kf * 256 + kc * 16 + lane], colsum);
        }
        __syncthreads();
#pragma unroll
        for (int kh2 = 0; kh2 < 2; kh2++) {
            bf16x8 wah = ldb(&Wh[w * 16 + l15][kh2 * 32 + lg * 8]);
            bf16x8 wal = ldb(&Wl[w * 16 + l15][kh2 * 32 + lg * 8]);
#pragma unroll
            for (int df = 0; df < 4; df++) {
                bf16x8 vbh = ldb(&Vth[df * 16 + l15][kh2 * 32 + lg * 8]);
                bf16x8 vbl = ldb(&Vtl[df * 16 + l15][kh2 * 32 + lg * 8]);
                ao[df] = MFMA16(wah, vbl, ao[df]);
                ao[df] = MFMA16(wal, vbh, ao[df]);
                ao[df] = MFMA16(wah, vbh, ao[df]);
            }
        }
    }

#pragma unroll
    for (int df = 0; df < 4; df++) {
#pragma unroll
        for (int r = 0; r < 4; r++) {
            int tq = qc * 64 + dq0 + r;
            int qrow = ((tq & 3) << 8) + (tq >> 2);
            AOp[((((size_t)(b * 16 + h)) << 10) + qrow) * 64 + df * 16 + l15] = ao[df][r];
        }
    }

    // flush G (attention-index order); columns touched: pos < (qc+1)*16
    __syncthreads();
    float* Gb = G + ((size_t)(b * 16 + h) << 10);
    const int limp = (qc + 1) << 4;
    for (int idx = t; idx < 1024; idx += 256) {
        if ((idx & 255) < limp) atomicAdd(&Gb[idx], Gacc[idx]);
    }
}

// -------- pass_2a: per (b,h) masked prefix GV[p][d] = sum_{pos<=p} G.v --------
__global__ __launch_bounds__(256) void pass_2a(const float* __restrict__ G,
                                               const float* __restrict__ Yv,
                                               float* __restrict__ GVpre) {
    const int h = blockIdx.x, b = blockIdx.y;
    const int t = threadIdx.x;
    __shared__ float Gl[1024];
    __shared__ float S[256][64];
    __shared__ float segsum[4][64];
    for (int i = t; i < 1024; i += 256) Gl[i] = G[((size_t)(b * 16 + h) << 10) + i];
    __syncthreads();
    const int d = t & 63, pg = t >> 6;
    const float* Yvb = Yv + ((size_t)b << 20) + h * 64 + d;
    for (int p0 = 0; p0 < 64; p0++) {
        int pos = pg * 64 + p0;
        float s = 0.f;
#pragma unroll
        for (int sq = 0; sq < 4; sq++) {
            int j = (sq << 8) + pos;
            s += Gl[j] * Yvb[(size_t)j << 10];
        }
        S[pos][d] = s;
    }
    __syncthreads();
    float acc = 0.f;
    for (int p0 = 0; p0 < 64; p0++) {
        int pos = pg * 64 + p0;
        acc += S[pos][d];
        S[pos][d] = acc;
    }
    segsum[pg][d] = acc;
    __syncthreads();
    float off = 0.f;
    for (int g = 0; g < pg; g++) off += segsum[g][d];
    float* gv = GVpre + (((size_t)(b * 16 + h)) << 14) + d;
    for (int p0 = 0; p0 < 64; p0++) {
        int pos = pg * 64 + p0;
        gv[pos << 6] = S[pos][d] + off;
    }
}

// -------- pass_2b: ao = AOp + (lam/1024)*GV[pq]; RMS; bf16 store --------
__global__ __launch_bounds__(256) void pass_2b(const float* __restrict__ AOp,
                                               const float* __restrict__ GVpre,
                                               const float* __restrict__ lamp,
                                               const float* __restrict__ wan,
                                               unsigned short* __restrict__ aoS) {
    const int qg = blockIdx.x;
    const int h = blockIdx.y, b = blockIdx.z;
    const int t = threadIdx.x;
    const int d = t & 63, rg = t >> 6;
    const float lamg = (*lamp) * (1.f / 1024.f);
    const float wv = wan[d];
    const float* aob = AOp + ((((size_t)(b * 16 + h)) << 10) + (qg << 8)) * 64 + d;
    const float* gvb = GVpre + (((size_t)(b * 16 + h)) << 14) + d;
    unsigned short* ob = aoS + ((size_t)b << 20) + ((size_t)h << 16) + ((size_t)(qg << 8) << 6) + d;
    for (int p0 = 0; p0 < 64; p0++) {
        int pq = p0 * 4 + rg;
        float ao = aob[(size_t)pq << 6] + lamg * gvb[(size_t)pq << 6];
        float ss = ao * ao;
#pragma unroll
        for (int o = 1; o < 64; o <<= 1) ss += __shfl_xor(ss, o);
        float rr_ = rsqrtf(ss * (1.f / 64.f) + EPS_ATTN);
        ob[(size_t)pq << 6] = f2bf(ao * rr_ * wv);
    }
}

extern "C" void kernel_launch(void* const* d_in, const int* in_sizes, int n_in,
                              void* d_out, int out_size, void* d_ws, size_t ws_size,
                              hipStream_t stream) {
    const float* x    = (const float*)d_in[0];
    const float* fc   = (const float*)d_in[1];
    const float* w1   = (const float*)d_in[2];
    const float* w2   = (const float*)d_in[3];
    const float* Wq   = (const float*)d_in[4];
    const float* bq   = (const float*)d_in[5];
    const float* Wk   = (const float*)d_in[6];
    const float* bk   = (const float*)d_in[7];
    const float* Wv   = (const float*)d_in[8];
    const float* bv   = (const float*)d_in[9];
    const float* Wo   = (const float*)d_in[10];
    const float* bo   = (const float*)d_in[11];
    const float* lq1  = (const float*)d_in[12];
    const float* lk1  = (const float*)d_in[13];
    const float* lq2  = (const float*)d_in[14];
    const float* lk2  = (const float*)d_in[15];
    const float* wan  = (const float*)d_in[16];
    const float* Wg   = (const float*)d_in[17];
    const float* bg   = (const float*)d_in[18];
    const float* Wout = (const float*)d_in[19];
    const float* bout = (const float*)d_in[20];

    char* ws = (char*)d_ws;
    const size_t MB = 1024 * 1024;
    // Layout (peak 53 MB, same as the passing rounds 9/10):
    float* G    = (float*)(ws);                     // [0, 128K)
    float* lam  = (float*)(ws + 256 * 1024);        // 4 B
    unsigned short* hH = (unsigned short*)(ws + 1 * MB);   // [1,5)  (dead after QKV)
    unsigned short* hL = (unsigned short*)(ws + 5 * MB);   // [5,9)
    float* Yq   = (float*)(ws + 9 * MB);            // [9,17)
    float* Yk   = (float*)(ws + 17 * MB);           // [17,25) (dead after rope_split_k)
    float* Yv   = (float*)(ws + 25 * MB);           // [25,33) (dead after pass_2a)
    unsigned short* WqH = (unsigned short*)(ws + 33 * MB); // [33,35) (dead after QKV)
    unsigned short* WqL = (unsigned short*)(ws + 35 * MB); // [35,37)
    unsigned short* WkH = (unsigned short*)(ws + 37 * MB); // [37,39)
    unsigned short* WkL = (unsigned short*)(ws + 39 * MB); // [39,41)
    unsigned short* WvH = (unsigned short*)(ws + 41 * MB); // [41,43)
    unsigned short* WvL = (unsigned short*)(ws + 43 * MB); // [43,45)
    unsigned short* WoutB = (unsigned short*)(ws + 45 * MB); // [45,53)
    float* AOp  = (float*)(ws + 33 * MB);           // reuse [33,41) after QKV
    float* GVpre= (float*)(ws + 41 * MB);           // reuse [41,43) after QKV
    unsigned short* WoB = (unsigned short*)(ws + 43 * MB); // reuse [43,45) after QKV
    unsigned short* KhG = (unsigned short*)(ws + 1 * MB);  // reuse [1,5)  (hH dead)
    unsigned short* KlG = (unsigned short*)(ws + 5 * MB);  // reuse [5,9)  (hL dead)
    unsigned short* VtH = (unsigned short*)(ws + 17 * MB); // reuse [17,21) (Yk dead)
    unsigned short* VtL = (unsigned short*)(ws + 21 * MB); // reuse [21,25)
    unsigned short* aoS = (unsigned short*)(ws + 1 * MB);  // reuse [1,5)  (KhG dead after pass_1)
    float* X1           = (float*)(ws + 9 * MB);           // reuse [9,17) (Yq dead after pass_1)
    unsigned short* h2b = (unsigned short*)(ws + 5 * MB);  // reuse [5,9)  (KlG dead)
    unsigned short* mlp = (unsigned short*)(ws + 17 * MB); // reuse [17,33) (VtH/L, Yv dead)

    prep<<<32, 256, 0, stream>>>(G, lam, lq1, lk1, lq2, lk2);
    cvt_bf16<<<4096, 256, 0, stream>>>(Wout, WoutB, 1048576);
    rms_split<<<2048, 256, 0, stream>>>(x, w1, hH, hL, EPS_DEF);
    cvt_split<<<1024, 256, 0, stream>>>(Wq, WqH, WqL, 262144);
    cvt_split<<<1024, 256, 0, stream>>>(Wk, WkH, WkL, 262144);
    cvt_split<<<1024, 256, 0, stream>>>(Wv, WvH, WvL, 262144);
    gemm_qkv_ps<<<dim3(32, 16, 3), 256, 0, stream>>>(hH, hL, WqH, WqL, WkH, WkL, WvH, WvL,
                                                     bq, bk, bv, Yq, Yk, Yv);
    cvt_bf16<<<1024, 256, 0, stream>>>(Wo, WoB, 262144);   // after QKV (region overlaps WvL)
    rope_inplace<<<2048, 256, 0, stream>>>(Yq, fc);
    rope_split_k<<<2048, 256, 0, stream>>>(Yk, fc, KhG, KlG);   // after QKV (overlaps hH/hL)
    v_split_t<<<dim3(16, 16, 2), 256, 0, stream>>>(Yv, VtH, VtL);
    pass_1<<<512, 256, 0, stream>>>(Yq, KhG, KlG, VtH, VtL, lam, G, AOp);
    pass_2a<<<dim3(16, 2), 256, 0, stream>>>(G, Yv, GVpre);
    pass_2b<<<dim3(4, 16, 2), 256, 0, stream>>>(AOp, GVpre, lam, wan, aoS);
    dim3 gmf(32, 16);
    gemm_mfma_wb<<<gmf, 256, 0, stream>>>(aoS, WoB, bo, x, X1, 2048, 1024, 1024);
    rms_kernel<1><<<2048, 256, 0, stream>>>(X1, w2, h2b, EPS_DEF);
    gemm_gate_mfma<<<dim3(16, 64), 256, 0, stream>>>(h2b, Wg, bg, mlp);
    // FINAL OUTPUT IS FP32.
    gemm_mfma_wb<<<gmf, 256, 0, stream>>>(mlp, WoutB, bout, X1, (float*)d_out, 2048, 1024, 4096);
}

// Round 12
// 422.213 us; speedup vs baseline: 8.7627x; 1.0402x over previous
//
#include <hip/hip_runtime.h>

#define LAMBDA_INIT 0.2f
#define SCALING 0.17677669529663687f   // 1/sqrt(32)
#define EPS_DEF 1.1920928955078125e-07f
#define EPS_ATTN 1e-5f

typedef unsigned short us4 __attribute__((ext_vector_type(4)));
typedef unsigned short us8v __attribute__((ext_vector_type(8)));
typedef float f32x4 __attribute__((ext_vector_type(4)));
typedef float f32x2 __attribute__((ext_vector_type(2)));
typedef __bf16 bf16x8 __attribute__((ext_vector_type(8)));

#define MFMA16(a, b, c) __builtin_amdgcn_mfma_f32_16x16x32_bf16((a), (b), (c), 0, 0, 0)

__device__ __forceinline__ float bf2f(unsigned short u) {
    unsigned int x = ((unsigned int)u) << 16;
    return __builtin_bit_cast(float, x);
}
__device__ __forceinline__ unsigned short f2bf(float f) {
    unsigned int x = __builtin_bit_cast(unsigned int, f);
    x += 0x7fffu + ((x >> 16) & 1u);
    return (unsigned short)(x >> 16);
}
// split a pair of f32x4 into hi/lo bf16 (x ~= hi + lo, residual ~2^-18 rel)
__device__ __forceinline__ void split8(f32x4 a, f32x4 b, us8v& hi, us8v& lo) {
#pragma unroll
    for (int u = 0; u < 4; u++) {
        unsigned short h = f2bf(a[u]);
        hi[u] = h; lo[u] = f2bf(a[u] - bf2f(h));
        unsigned short h2 = f2bf(b[u]);
        hi[4 + u] = h2; lo[4 + u] = f2bf(b[u] - bf2f(h2));
    }
}
__device__ __forceinline__ bf16x8 ldb(const unsigned short* p) {
    return __builtin_bit_cast(bf16x8, *(const us8v*)p);
}

__device__ __forceinline__ float wave_sum(float v) {
#pragma unroll
    for (int o = 32; o > 0; o >>= 1) v += __shfl_down(v, o);
    return v;
}
__device__ __forceinline__ float block_sum(float v, float* red4) {
    int wv = threadIdx.x >> 6;
    float w = wave_sum(v);
    __syncthreads();
    if ((threadIdx.x & 63) == 0) red4[wv] = w;
    __syncthreads();
    return red4[0] + red4[1] + red4[2] + red4[3];
}

// ---------------- prep: zero G, compute lambda ----------------
__global__ __launch_bounds__(256) void prep(float* __restrict__ G, float* __restrict__ lamp,
                                            const float* lq1, const float* lk1,
                                            const float* lq2, const float* lk2) {
    int i = (blockIdx.x * 256 + threadIdx.x) * 4;
    G[i] = 0.f; G[i + 1] = 0.f; G[i + 2] = 0.f; G[i + 3] = 0.f;
    if (blockIdx.x == 0 && threadIdx.x == 0) {
        float a = 0.f, c = 0.f;
        for (int d = 0; d < 32; d++) {
            a += lq1[d] * lk1[d];
            c += lq2[d] * lk2[d];
        }
        *lamp = expf(a) - expf(c) + LAMBDA_INIT;
    }
}

// ---------------- fp32 -> bf16 weight conversion ----------------
__global__ __launch_bounds__(256) void cvt_bf16(const float* __restrict__ s,
                                                unsigned short* __restrict__ d, int n4) {
    int i = blockIdx.x * 256 + threadIdx.x;
    if (i >= n4) return;
    f32x4 v = ((const f32x4*)s)[i];
    us4 o;
#pragma unroll
    for (int u = 0; u < 4; u++) o[u] = f2bf(v[u]);
    ((us4*)d)[i] = o;
}

// ---------------- fp32 -> hi/lo split conversion, 3 weights fused ----------------
__global__ __launch_bounds__(256) void cvt_split3(
        const float* __restrict__ s0, const float* __restrict__ s1, const float* __restrict__ s2,
        unsigned short* __restrict__ h0, unsigned short* __restrict__ l0,
        unsigned short* __restrict__ h1p, unsigned short* __restrict__ l1p,
        unsigned short* __restrict__ h2p, unsigned short* __restrict__ l2p, int n4) {
    const int z = blockIdx.y;
    const float* s = (z == 0) ? s0 : (z == 1) ? s1 : s2;
    unsigned short* hi = (z == 0) ? h0 : (z == 1) ? h1p : h2p;
    unsigned short* lo = (z == 0) ? l0 : (z == 1) ? l1p : l2p;
    int i = blockIdx.x * 256 + threadIdx.x;
    if (i >= n4) return;
    f32x4 v = ((const f32x4*)s)[i];
    us4 h, l;
#pragma unroll
    for (int u = 0; u < 4; u++) {
        h[u] = f2bf(v[u]);
        l[u] = f2bf(v[u] - bf2f(h[u]));
    }
    ((us4*)hi)[i] = h;
    ((us4*)lo)[i] = l;
}

// ---------------- RMSNorm: fp32 in, fp32 weight, bf16/fp32 out ----------------
template <int OUTBF>
__global__ __launch_bounds__(256) void rms_kernel(const float* __restrict__ x,
                                                  const float* __restrict__ w,
                                                  void* __restrict__ out, float eps) {
    int row = blockIdx.x;
    int tid = threadIdx.x;
    size_t base = (size_t)row * 1024 + tid * 4;
    f32x4 v = *(const f32x4*)(x + base);
    float ss = v[0]*v[0] + v[1]*v[1] + v[2]*v[2] + v[3]*v[3];
    __shared__ float red4[4];
    float tot = block_sum(ss, red4);
    float r = rsqrtf(tot * (1.0f / 1024.f) + eps);
    f32x4 wv = *(const f32x4*)(w + tid * 4);
    if (OUTBF) {
        us4 o;
#pragma unroll
        for (int i = 0; i < 4; i++) o[i] = f2bf(v[i] * r * wv[i]);
        *(us4*)((unsigned short*)out + base) = o;
    } else {
        f32x4 o;
#pragma unroll
        for (int i = 0; i < 4; i++) o[i] = v[i] * r * wv[i];
        *(f32x4*)((float*)out + base) = o;
    }
}

// ---------------- RMSNorm with hi/lo split output ----------------
__global__ __launch_bounds__(256) void rms_split(const float* __restrict__ x,
                                                 const float* __restrict__ w,
                                                 unsigned short* __restrict__ hh,
                                                 unsigned short* __restrict__ hl, float eps) {
    int row = blockIdx.x;
    int tid = threadIdx.x;
    size_t base = (size_t)row * 1024 + tid * 4;
    f32x4 v = *(const f32x4*)(x + base);
    float ss = v[0]*v[0] + v[1]*v[1] + v[2]*v[2] + v[3]*v[3];
    __shared__ float red4[4];
    float tot = block_sum(ss, red4);
    float r = rsqrtf(tot * (1.0f / 1024.f) + eps);
    f32x4 wv = *(const f32x4*)(w + tid * 4);
    us4 oh, ol;
#pragma unroll
    for (int i = 0; i < 4; i++) {
        float val = v[i] * r * wv[i];
        oh[i] = f2bf(val);
        ol[i] = f2bf(val - bf2f(oh[i]));
    }
    *(us4*)(hh + base) = oh;
    *(us4*)(hl + base) = ol;
}

// =====================================================================
// QKV split-bf16 MFMA GEMM, PRE-SPLIT operands, SOFTWARE-PIPELINED.
// BM=64, BN=64, BK=64, 4 waves (2x2). Grid (32,16,3).
// =====================================================================
__global__ __launch_bounds__(256) void gemm_qkv_ps(
        const unsigned short* __restrict__ AH, const unsigned short* __restrict__ AL,
        const unsigned short* __restrict__ WqH, const unsigned short* __restrict__ WqL,
        const unsigned short* __restrict__ WkH, const unsigned short* __restrict__ WkL,
        const unsigned short* __restrict__ WvH, const unsigned short* __restrict__ WvL,
        const float* __restrict__ bq, const float* __restrict__ bk, const float* __restrict__ bv,
        float* __restrict__ Yq, float* __restrict__ Yk, float* __restrict__ Yv) {
    const int z = blockIdx.z;
    const unsigned short* BH = (z == 0) ? WqH : (z == 1) ? WkH : WvH;
    const unsigned short* BL = (z == 0) ? WqL : (z == 1) ? WkL : WvL;
    const float* bias = (z == 0) ? bq : (z == 1) ? bk : bv;
    float* out        = (z == 0) ? Yq : (z == 1) ? Yk : Yv;
    const int K = 1024, N = 1024;
    __shared__ __align__(16) unsigned short Ah[64][72];
    __shared__ __align__(16) unsigned short Al[64][72];
    __shared__ __align__(16) unsigned short Bh[64][72];
    __shared__ __align__(16) unsigned short Bl[64][72];
    const int t = threadIdx.x;
    const int bm = blockIdx.x, bn = blockIdx.y;
    const int lane = t & 63, w = t >> 6;
    const int wr = w >> 1, wc = w & 1;
    const int l15 = lane & 15, lg = lane >> 4;
    const int sr = t >> 2, sc = (t & 3) * 16;

    const unsigned short* AgH = AH + (size_t)(bm * 64 + sr) * K + sc;
    const unsigned short* AgL = AL + (size_t)(bm * 64 + sr) * K + sc;
    const unsigned short* BgH = BH + (size_t)(bn * 64 + sr) * K + sc;
    const unsigned short* BgL = BL + (size_t)(bn * 64 + sr) * K + sc;

    f32x4 acc[2][2] = {};

    us8v ah0 = *(const us8v*)AgH, ah1 = *(const us8v*)(AgH + 8);
    us8v al0 = *(const us8v*)AgL, al1 = *(const us8v*)(AgL + 8);
    us8v bh0 = *(const us8v*)BgH, bh1 = *(const us8v*)(BgH + 8);
    us8v bl0 = *(const us8v*)BgL, bl1 = *(const us8v*)(BgL + 8);

    for (int k0 = 0; k0 < K; k0 += 64) {
        __syncthreads();
        *(us8v*)&Ah[sr][sc] = ah0; *(us8v*)&Ah[sr][sc + 8] = ah1;
        *(us8v*)&Al[sr][sc] = al0; *(us8v*)&Al[sr][sc + 8] = al1;
        *(us8v*)&Bh[sr][sc] = bh0; *(us8v*)&Bh[sr][sc + 8] = bh1;
        *(us8v*)&Bl[sr][sc] = bl0; *(us8v*)&Bl[sr][sc + 8] = bl1;
        __syncthreads();
        if (k0 + 64 < K) {
            const int kn = k0 + 64;
            ah0 = *(const us8v*)(AgH + kn); ah1 = *(const us8v*)(AgH + kn + 8);
            al0 = *(const us8v*)(AgL + kn); al1 = *(const us8v*)(AgL + kn + 8);
            bh0 = *(const us8v*)(BgH + kn); bh1 = *(const us8v*)(BgH + kn + 8);
            bl0 = *(const us8v*)(BgL + kn); bl1 = *(const us8v*)(BgL + kn + 8);
        }
#pragma unroll
        for (int kk = 0; kk < 2; kk++) {
            bf16x8 afh[2], afl[2], bfh[2], bfl[2];
#pragma unroll
            for (int mi = 0; mi < 2; mi++) {
                afh[mi] = ldb(&Ah[wr * 32 + mi * 16 + l15][kk * 32 + lg * 8]);
                afl[mi] = ldb(&Al[wr * 32 + mi * 16 + l15][kk * 32 + lg * 8]);
            }
#pragma unroll
            for (int ni = 0; ni < 2; ni++) {
                bfh[ni] = ldb(&Bh[wc * 32 + ni * 16 + l15][kk * 32 + lg * 8]);
                bfl[ni] = ldb(&Bl[wc * 32 + ni * 16 + l15][kk * 32 + lg * 8]);
            }
#pragma unroll
            for (int mi = 0; mi < 2; mi++)
#pragma unroll
                for (int ni = 0; ni < 2; ni++) {
                    acc[mi][ni] = MFMA16(afl[mi], bfh[ni], acc[mi][ni]);
                    acc[mi][ni] = MFMA16(afh[mi], bfl[ni], acc[mi][ni]);
                    acc[mi][ni] = MFMA16(afh[mi], bfh[ni], acc[mi][ni]);
                }
        }
    }

    const int rbase = bm * 64 + wr * 32 + (lg << 2);
    const int cbase = bn * 64 + wc * 32 + l15;
#pragma unroll
    for (int mi = 0; mi < 2; mi++) {
#pragma unroll
        for (int ni = 0; ni < 2; ni++) {
            int col = cbase + ni * 16;
            float bb = bias[col];
#pragma unroll
            for (int r = 0; r < 4; r++) {
                int row = rbase + mi * 16 + r;
                out[(size_t)row * N + col] = acc[mi][ni][r] + bb;
            }
        }
    }
}

// =====================================================================
// bf16 MFMA GEMM, pre-converted bf16 B, SOFTWARE-PIPELINED.
// BM=64, BN=64, BK=64, 4 waves (2x2).
// =====================================================================
__global__ __launch_bounds__(256) void gemm_mfma_wb(const unsigned short* __restrict__ A,
                                                    const unsigned short* __restrict__ Bt,
                                                    const float* __restrict__ bias,
                                                    const float* __restrict__ res,
                                                    float* __restrict__ out,
                                                    int M, int N, int K) {
    __shared__ __align__(16) unsigned short As[64][72];
    __shared__ __align__(16) unsigned short Bs[64][72];
    const int t = threadIdx.x;
    const int bm = blockIdx.x, bn = blockIdx.y;
    const int lane = t & 63, w = t >> 6;
    const int wr = w >> 1, wc = w & 1;
    const int l15 = lane & 15, lg = lane >> 4;
    const int sr = t >> 2, sc = (t & 3) * 16;

    const unsigned short* Ag = A + (size_t)(bm * 64 + sr) * K + sc;
    const unsigned short* Bg = Bt + (size_t)(bn * 64 + sr) * K + sc;

    f32x4 acc[2][2] = {};

    us8v a0 = *(const us8v*)Ag, a1 = *(const us8v*)(Ag + 8);
    us8v b0 = *(const us8v*)Bg, b1 = *(const us8v*)(Bg + 8);

    for (int k0 = 0; k0 < K; k0 += 64) {
        __syncthreads();
        *(us8v*)&As[sr][sc]     = a0;
        *(us8v*)&As[sr][sc + 8] = a1;
        *(us8v*)&Bs[sr][sc]     = b0;
        *(us8v*)&Bs[sr][sc + 8] = b1;
        __syncthreads();
        if (k0 + 64 < K) {
            const int kn = k0 + 64;
            a0 = *(const us8v*)(Ag + kn); a1 = *(const us8v*)(Ag + kn + 8);
            b0 = *(const us8v*)(Bg + kn); b1 = *(const us8v*)(Bg + kn + 8);
        }
#pragma unroll
        for (int kk = 0; kk < 2; kk++) {
            bf16x8 af[2], bf[2];
#pragma unroll
            for (int mi = 0; mi < 2; mi++)
                af[mi] = ldb(&As[wr * 32 + mi * 16 + l15][kk * 32 + lg * 8]);
#pragma unroll
            for (int ni = 0; ni < 2; ni++)
                bf[ni] = ldb(&Bs[wc * 32 + ni * 16 + l15][kk * 32 + lg * 8]);
#pragma unroll
            for (int mi = 0; mi < 2; mi++)
#pragma unroll
                for (int ni = 0; ni < 2; ni++)
                    acc[mi][ni] = MFMA16(af[mi], bf[ni], acc[mi][ni]);
        }
    }

    const int rbase = bm * 64 + wr * 32 + (lg << 2);
    const int cbase = bn * 64 + wc * 32 + l15;
#pragma unroll
    for (int mi = 0; mi < 2; mi++) {
#pragma unroll
        for (int ni = 0; ni < 2; ni++) {
            int col = cbase + ni * 16;
            float bb = bias[col];
#pragma unroll
            for (int r = 0; r < 4; r++) {
                int row = rbase + mi * 16 + r;
                size_t oi = (size_t)row * N + col;
                out[oi] = acc[mi][ni][r] + bb + res[oi];
            }
        }
    }
}

// ------- fused gate GEMM, PRE-CONVERTED bf16 weights, PIPELINED -------
// mlp = (h2@Wu^T+bu) * silu(h2@Wv^T+bv). BM=128, BN=64, BK=64, grid (16,64).
__global__ __launch_bounds__(256) void gemm_gate_wb(const unsigned short* __restrict__ A,
                                                    const unsigned short* __restrict__ WuB,
                                                    const unsigned short* __restrict__ WvB,
                                                    const float* __restrict__ bg,
                                                    unsigned short* __restrict__ mlp) {
    __shared__ __align__(16) unsigned short As[128][72];
    __shared__ __align__(16) unsigned short BsU[64][72];
    __shared__ __align__(16) unsigned short BsV[64][72];
    const int t = threadIdx.x;
    const int bm = blockIdx.x, bn = blockIdx.y;
    const int lane = t & 63, w = t >> 6;
    const int wr = w >> 1, wc = w & 1;
    const int l15 = lane & 15, lg = lane >> 4;
    const int sr = t >> 2, sc = (t & 3) * 16;

    const unsigned short* Ag  = A + (size_t)(bm * 128 + sr) * 1024 + sc;
    const unsigned short* Ag2 = Ag + (size_t)64 * 1024;
    const unsigned short* BgU = WuB + (size_t)(bn * 64 + sr) * 1024 + sc;
    const unsigned short* BgV = WvB + (size_t)(bn * 64 + sr) * 1024 + sc;

    f32x4 accU[4][2] = {};
    f32x4 accV[4][2] = {};

    us8v a0 = *(const us8v*)Ag,  a1 = *(const us8v*)(Ag + 8);
    us8v a2 = *(const us8v*)Ag2, a3 = *(const us8v*)(Ag2 + 8);
    us8v u0 = *(const us8v*)BgU, u1 = *(const us8v*)(BgU + 8);
    us8v v0 = *(const us8v*)BgV, v1 = *(const us8v*)(BgV + 8);

    for (int k0 = 0; k0 < 1024; k0 += 64) {
        __syncthreads();
        *(us8v*)&As[sr][sc]          = a0;
        *(us8v*)&As[sr][sc + 8]      = a1;
        *(us8v*)&As[sr + 64][sc]     = a2;
        *(us8v*)&As[sr + 64][sc + 8] = a3;
        *(us8v*)&BsU[sr][sc]         = u0;
        *(us8v*)&BsU[sr][sc + 8]     = u1;
        *(us8v*)&BsV[sr][sc]         = v0;
        *(us8v*)&BsV[sr][sc + 8]     = v1;
        __syncthreads();
        if (k0 + 64 < 1024) {
            const int kn = k0 + 64;
            a0 = *(const us8v*)(Ag + kn);  a1 = *(const us8v*)(Ag + kn + 8);
            a2 = *(const us8v*)(Ag2 + kn); a3 = *(const us8v*)(Ag2 + kn + 8);
            u0 = *(const us8v*)(BgU + kn); u1 = *(const us8v*)(BgU + kn + 8);
            v0 = *(const us8v*)(BgV + kn); v1 = *(const us8v*)(BgV + kn + 8);
        }
#pragma unroll
        for (int kk = 0; kk < 2; kk++) {
            bf16x8 af[4], bu[2], bv2[2];
#pragma unroll
            for (int mi = 0; mi < 4; mi++)
                af[mi] = ldb(&As[wr * 64 + mi * 16 + l15][kk * 32 + lg * 8]);
#pragma unroll
            for (int ni = 0; ni < 2; ni++) {
                bu[ni]  = ldb(&BsU[wc * 32 + ni * 16 + l15][kk * 32 + lg * 8]);
                bv2[ni] = ldb(&BsV[wc * 32 + ni * 16 + l15][kk * 32 + lg * 8]);
            }
#pragma unroll
            for (int mi = 0; mi < 4; mi++)
#pragma unroll
                for (int ni = 0; ni < 2; ni++) {
                    accU[mi][ni] = MFMA16(af[mi], bu[ni], accU[mi][ni]);
                    accV[mi][ni] = MFMA16(af[mi], bv2[ni], accV[mi][ni]);
                }
        }
    }

    const int rbase = bm * 128 + wr * 64 + (lg << 2);
    const int cbase = bn * 64 + wc * 32 + l15;
#pragma unroll
    for (int mi = 0; mi < 4; mi++) {
#pragma unroll
        for (int ni = 0; ni < 2; ni++) {
            int col = cbase + ni * 16;
            float bu_ = bg[col], bv_ = bg[4096 + col];
#pragma unroll
            for (int r = 0; r < 4; r++) {
                int row = rbase + mi * 16 + r;
                float u = accU[mi][ni][r] + bu_;
                float v = accV[mi][ni][r] + bv_;
                float s = v / (1.f + __expf(-v));
                mlp[(size_t)row * 4096 + col] = f2bf(u * s);
            }
        }
    }
}

// ---------------- RoPE in place (Q), token order ----------------
__global__ __launch_bounds__(256) void rope_inplace(float* __restrict__ Y,
                                                    const float* __restrict__ fc) {
    int t = blockIdx.x;
    int s = t & 1023;
    int p = s >> 2;
    if (p == 0) return;
    int c0 = threadIdx.x * 4;
    float* y = Y + (size_t)t * 1024 + c0;
    int d4 = (c0 & 31) >> 1;
    f32x4 f = *(const f32x4*)(fc + ((size_t)(p - 1) * 16 + d4) * 2);  // [cos,sin,cos,sin]
    float v0 = y[0], v1 = y[1], v2 = y[2], v3 = y[3];
    y[0] = v0 * f[0] - v1 * f[1];
    y[1] = v0 * f[1] + v1 * f[0];
    y[2] = v2 * f[2] - v3 * f[3];
    y[3] = v2 * f[3] + v3 * f[2];
}

// ------- RoPE(K) + hi/lo bf16 split, token-order output -------
__global__ __launch_bounds__(256) void rope_split_k(const float* __restrict__ Yk,
                                                    const float* __restrict__ fc,
                                                    unsigned short* __restrict__ KhG,
                                                    unsigned short* __restrict__ KlG) {
    int t = blockIdx.x;           // b*1024 + s
    int s = t & 1023;
    int p = s >> 2;
    int c0 = threadIdx.x * 4;
    const float* y = Yk + (size_t)t * 1024 + c0;
    float v0 = y[0], v1 = y[1], v2 = y[2], v3 = y[3];
    if (p > 0) {
        int d4 = (c0 & 31) >> 1;
        f32x4 f = *(const f32x4*)(fc + ((size_t)(p - 1) * 16 + d4) * 2);
        float w0 = v0 * f[0] - v1 * f[1];
        float w1 = v0 * f[1] + v1 * f[0];
        float w2 = v2 * f[2] - v3 * f[3];
        float w3 = v2 * f[3] + v3 * f[2];
        v0 = w0; v1 = w1; v2 = w2; v3 = w3;
    }
    us4 hi, lo;
    hi[0] = f2bf(v0); lo[0] = f2bf(v0 - bf2f(hi[0]));
    hi[1] = f2bf(v1); lo[1] = f2bf(v1 - bf2f(hi[1]));
    hi[2] = f2bf(v2); lo[2] = f2bf(v2 - bf2f(hi[2]));
    hi[3] = f2bf(v3); lo[3] = f2bf(v3 - bf2f(hi[3]));
    *(us4*)(KhG + (size_t)t * 1024 + c0) = hi;
    *(us4*)(KlG + (size_t)t * 1024 + c0) = lo;
}

// ------- V transpose + hi/lo split: Vt[(b,h)][d (64)][j (1024)] -------
__global__ __launch_bounds__(256) void v_split_t(const float* __restrict__ Yv,
                                                 unsigned short* __restrict__ VtH,
                                                 unsigned short* __restrict__ VtL) {
    const int jc = blockIdx.x, h = blockIdx.y, b = blockIdx.z;   // (16,16,2)
    __shared__ float tile[64][65];
    const int t = threadIdx.x;
    {
        const int jr = t >> 2, dc = (t & 3) * 16;
        const float* src = Yv + ((size_t)(b * 1024 + jc * 64 + jr) << 10) + h * 64 + dc;
        *(f32x4*)&tile[jr][dc]      = *(const f32x4*)src;
        *(f32x4*)&tile[jr][dc + 4]  = *(const f32x4*)(src + 4);
        *(f32x4*)&tile[jr][dc + 8]  = *(const f32x4*)(src + 8);
        *(f32x4*)&tile[jr][dc + 12] = *(const f32x4*)(src + 12);
    }
    __syncthreads();
    const int d = t >> 2, js = (t & 3) * 16;
    us8v h0, h1, l0, l1;
#pragma unroll
    for (int n = 0; n < 16; n++) {
        float val = tile[js + n][d];
        unsigned short hh = f2bf(val);
        unsigned short ll = f2bf(val - bf2f(hh));
        if (n < 8) { h0[n] = hh; l0[n] = ll; }
        else       { h1[n - 8] = hh; l1[n - 8] = ll; }
    }
    size_t ob = (((size_t)(b * 16 + h) * 64 + d) << 10) + jc * 64 + js;
    *(us8v*)(VtH + ob) = h0; *(us8v*)(VtH + ob + 8) = h1;
    *(us8v*)(VtL + ob) = l0; *(us8v*)(VtL + ob + 8) = l1;
}

// =====================================================================
// MFMA attention pass_1: 512 blocks heavy-first, pipelined staging.
// This round: (a) removed the barrier between weight-write and AV
// (Wh/Wl rows [w*16,w*16+16) are wave-private: written by wave w's
// dq0=w*16+lg*4 rows, read by the same wave's l15 rows); (b) replaced
// contended LDS atomicAdd on Gacc with per-wave slices + merge at flush.
// LDS 70 KB -> still 2 blocks/CU. Math identical to round 11.
// =====================================================================
__global__ __launch_bounds__(256) void pass_1(const float* __restrict__ Yq,
                                              const unsigned short* __restrict__ KhG,
                                              const unsigned short* __restrict__ KlG,
                                              const unsigned short* __restrict__ VtH,
                                              const unsigned short* __restrict__ VtL,
                                              const float* __restrict__ lamp,
                                              float* __restrict__ G,
                                              float* __restrict__ AOp) {
    const int blk = blockIdx.x;
    const int qc = 15 - (blk >> 5);
    const int h  = blk & 15;
    const int b  = (blk >> 4) & 1;
    const int t = threadIdx.x;
    const int lane = t & 63, w = t >> 6;
    const int l15 = lane & 15, lg = lane >> 4;

    __shared__ __align__(16) unsigned short Kh[64][72];
    __shared__ __align__(16) unsigned short Kl[64][72];
    __shared__ __align__(16) unsigned short Vth[64][72];
    __shared__ __align__(16) unsigned short Vtl[64][72];
    __shared__ __align__(16) unsigned short Wh[64][72];
    __shared__ __align__(16) unsigned short Wl[64][72];
    __shared__ float Gacc[4][1024];

    for (int i = t; i < 4096; i += 256) ((float*)Gacc)[i] = 0.f;

    us8v qh[2], ql[2];
    {
        const float* qp = Yq + ((size_t)(b * 1024 + qc * 64 + w * 16 + l15) << 10)
                          + h * 64 + lg * 8;
#pragma unroll
        for (int H = 0; H < 2; H++)
            split8(*(const f32x4*)(qp + H * 32), *(const f32x4*)(qp + H * 32 + 4), qh[H], ql[H]);
    }
    const int dq0 = w * 16 + (lg << 2);

    const int srow = t >> 2, ssub = t & 3;
    const int ptk = 4 * (srow & 15) + (srow >> 4);   // permuted in-chunk token for row srow
    const unsigned short* KhB = KhG + ((size_t)(b * 1024) << 10) + h * 64;
    const unsigned short* KlB = KlG + ((size_t)(b * 1024) << 10) + h * 64;
    const unsigned short* VhB = VtH + (((size_t)(b * 16 + h) * 64 + srow) << 10) + ssub * 256;
    const unsigned short* VlB = VtL + (((size_t)(b * 16 + h) * 64 + srow) << 10) + ssub * 256;
    const float lam = *lamp;

    float z1r[4] = {0.f, 0.f, 0.f, 0.f};
    float z2r[4] = {0.f, 0.f, 0.f, 0.f};

    // -------- sweep 1: denominators (pipelined K staging) --------
    us8v rkh0, rkh1, rkl0, rkl1;
    {
        const unsigned short* kh = KhB + ((size_t)ptk << 10) + ssub * 16;
        const unsigned short* kl = KlB + ((size_t)ptk << 10) + ssub * 16;
        rkh0 = *(const us8v*)kh; rkh1 = *(const us8v*)(kh + 8);
        rkl0 = *(const us8v*)kl; rkl1 = *(const us8v*)(kl + 8);
    }
    for (int kc = 0; kc <= qc; kc++) {
        __syncthreads();
        *(us8v*)&Kh[srow][ssub * 16]     = rkh0;
        *(us8v*)&Kh[srow][ssub * 16 + 8] = rkh1;
        *(us8v*)&Kl[srow][ssub * 16]     = rkl0;
        *(us8v*)&Kl[srow][ssub * 16 + 8] = rkl1;
        __syncthreads();
        if (kc < qc) {
            const unsigned short* kh = KhB + ((size_t)((kc + 1) * 64 + ptk) << 10) + ssub * 16;
            const unsigned short* kl = KlB + ((size_t)((kc + 1) * 64 + ptk) << 10) + ssub * 16;
            rkh0 = *(const us8v*)kh; rkh1 = *(const us8v*)(kh + 8);
            rkl0 = *(const us8v*)kl; rkl1 = *(const us8v*)(kl + 8);
        }
        const int kpos = kc * 16 + l15;
#pragma unroll
        for (int kf = 0; kf < 4; kf++) {
            const int krow = kf * 16 + l15;
            const int kcol = lg * 8;
            bf16x8 b1h = ldb(&Kh[krow][kcol]),      b1l = ldb(&Kl[krow][kcol]);
            bf16x8 b2h = ldb(&Kh[krow][32 + kcol]), b2l = ldb(&Kl[krow][32 + kcol]);
            f32x4 s1 = {}, s2 = {};
            s1 = MFMA16(__builtin_bit_cast(bf16x8, ql[0]), b1h, s1);
            s1 = MFMA16(__builtin_bit_cast(bf16x8, qh[0]), b1l, s1);
            s1 = MFMA16(__builtin_bit_cast(bf16x8, qh[0]), b1h, s1);
            s2 = MFMA16(__builtin_bit_cast(bf16x8, ql[1]), b2h, s2);
            s2 = MFMA16(__builtin_bit_cast(bf16x8, qh[1]), b2l, s2);
            s2 = MFMA16(__builtin_bit_cast(bf16x8, qh[1]), b2h, s2);
#pragma unroll
            for (int r = 0; r < 4; r++) {
                int pq = (qc * 64 + dq0 + r) >> 2;
                if (kpos <= pq) {
                    z1r[r] += __expf(fabsf(s1[r] * SCALING));
                    z2r[r] += __expf(fabsf(s2[r] * SCALING));
                }
            }
        }
    }
#pragma unroll
    for (int r = 0; r < 4; r++) {
        float a = z1r[r];
        a += __shfl_xor(a, 1); a += __shfl_xor(a, 2);
        a += __shfl_xor(a, 4); a += __shfl_xor(a, 8);
        z1r[r] = 1.f / fmaxf(a, 1e-20f);
        float c = z2r[r];
        c += __shfl_xor(c, 1); c += __shfl_xor(c, 2);
        c += __shfl_xor(c, 4); c += __shfl_xor(c, 8);
        z2r[r] = 1.f / fmaxf(c, 1e-20f);
    }

    f32x4 ao[4] = {};

    // -------- sweep 2: weights + G colsums + AV (pipelined K+V) --------
    us8v rvh0, rvh1, rvl0, rvl1;
    {
        const unsigned short* kh = KhB + ((size_t)ptk << 10) + ssub * 16;
        const unsigned short* kl = KlB + ((size_t)ptk << 10) + ssub * 16;
        rkh0 = *(const us8v*)kh; rkh1 = *(const us8v*)(kh + 8);
        rkl0 = *(const us8v*)kl; rkl1 = *(const us8v*)(kl + 8);
        rvh0 = *(const us8v*)VhB; rvh1 = *(const us8v*)(VhB + 8);
        rvl0 = *(const us8v*)VlB; rvl1 = *(const us8v*)(VlB + 8);
    }
    for (int kc = 0; kc <= qc; kc++) {
        __syncthreads();
        *(us8v*)&Kh[srow][ssub * 16]      = rkh0;
        *(us8v*)&Kh[srow][ssub * 16 + 8]  = rkh1;
        *(us8v*)&Kl[srow][ssub * 16]      = rkl0;
        *(us8v*)&Kl[srow][ssub * 16 + 8]  = rkl1;
        *(us8v*)&Vth[srow][ssub * 16]     = rvh0;
        *(us8v*)&Vth[srow][ssub * 16 + 8] = rvh1;
        *(us8v*)&Vtl[srow][ssub * 16]     = rvl0;
        *(us8v*)&Vtl[srow][ssub * 16 + 8] = rvl1;
        __syncthreads();
        if (kc < qc) {
            const unsigned short* kh = KhB + ((size_t)((kc + 1) * 64 + ptk) << 10) + ssub * 16;
            const unsigned short* kl = KlB + ((size_t)((kc + 1) * 64 + ptk) << 10) + ssub * 16;
            rkh0 = *(const us8v*)kh; rkh1 = *(const us8v*)(kh + 8);
            rkl0 = *(const us8v*)kl; rkl1 = *(const us8v*)(kl + 8);
            const unsigned short* vh = VhB + (kc + 1) * 16;
            const unsigned short* vl = VlB + (kc + 1) * 16;
            rvh0 = *(const us8v*)vh; rvh1 = *(const us8v*)(vh + 8);
            rvl0 = *(const us8v*)vl; rvl1 = *(const us8v*)(vl + 8);
        }
        const int kpos = kc * 16 + l15;
#pragma unroll
        for (int kf = 0; kf < 4; kf++) {
            const int krow = kf * 16 + l15;
            const int kcol = lg * 8;
            bf16x8 b1h = ldb(&Kh[krow][kcol]),      b1l = ldb(&Kl[krow][kcol]);
            bf16x8 b2h = ldb(&Kh[krow][32 + kcol]), b2l = ldb(&Kl[krow][32 + kcol]);
            f32x4 s1 = {}, s2 = {};
            s1 = MFMA16(__builtin_bit_cast(bf16x8, ql[0]), b1h, s1);
            s1 = MFMA16(__builtin_bit_cast(bf16x8, qh[0]), b1l, s1);
            s1 = MFMA16(__builtin_bit_cast(bf16x8, qh[0]), b1h, s1);
            s2 = MFMA16(__builtin_bit_cast(bf16x8, ql[1]), b2h, s2);
            s2 = MFMA16(__builtin_bit_cast(bf16x8, qh[1]), b2l, s2);
            s2 = MFMA16(__builtin_bit_cast(bf16x8, qh[1]), b2h, s2);
            const int kli = kf * 16 + l15;
            float colsum = 0.f;
#pragma unroll
            for (int r = 0; r < 4; r++) {
                int pq = (qc * 64 + dq0 + r) >> 2;
                float wv = 0.f, a1 = 0.f;
                if (kpos <= pq) {
                    float t1 = s1[r] * SCALING, t2 = s2[r] * SCALING;
                    float sg1 = (t1 > 0.f) ? 1.f : ((t1 < 0.f) ? -1.f : 0.f);
                    float sg2 = (t2 > 0.f) ? 1.f : ((t2 < 0.f) ? -1.f : 0.f);
                    a1 = sg1 * __expf(fabsf(t1)) * z1r[r];
                    wv = a1 - lam * (sg2 * __expf(fabsf(t2)) * z2r[r]);
                }
                colsum += a1;
                unsigned short hh = f2bf(wv);
                Wh[dq0 + r][kli] = hh;
                Wl[dq0 + r][kli] = f2bf(wv - bf2f(hh));
            }
            colsum += __shfl_xor(colsum, 16);
            colsum += __shfl_xor(colsum, 32);
            // per-wave slice, plain store (each (w,kf,kc,lane) written once)
            if (lane < 16) Gacc[w][kf * 256 + kc * 16 + lane] = colsum;
        }
        // NO barrier here: Wh/Wl rows [w*16, w*16+16) are wave-private,
        // Vth/Vtl were staged before the chunk's second barrier.
#pragma unroll
        for (int kh2 = 0; kh2 < 2; kh2++) {
            bf16x8 wah = ldb(&Wh[w * 16 + l15][kh2 * 32 + lg * 8]);
            bf16x8 wal = ldb(&Wl[w * 16 + l15][kh2 * 32 + lg * 8]);
#pragma unroll
            for (int df = 0; df < 4; df++) {
                bf16x8 vbh = ldb(&Vth[df * 16 + l15][kh2 * 32 + lg * 8]);
                bf16x8 vbl = ldb(&Vtl[df * 16 + l15][kh2 * 32 + lg * 8]);
                ao[df] = MFMA16(wah, vbl, ao[df]);
                ao[df] = MFMA16(wal, vbh, ao[df]);
                ao[df] = MFMA16(wah, vbh, ao[df]);
            }
        }
    }

#pragma unroll
    for (int df = 0; df < 4; df++) {
#pragma unroll
        for (int r = 0; r < 4; r++) {
            int tq = qc * 64 + dq0 + r;
            int qrow = ((tq & 3) << 8) + (tq >> 2);
            AOp[((((size_t)(b * 16 + h)) << 10) + qrow) * 64 + df * 16 + l15] = ao[df][r];
        }
    }

    // merge per-wave G slices and flush (attention-index order)
    __syncthreads();
    float* Gb = G + ((size_t)(b * 16 + h) << 10);
    const int limp = (qc + 1) << 4;
    for (int idx = t; idx < 1024; idx += 256) {
        if ((idx & 255) < limp) {
            float s = Gacc[0][idx] + Gacc[1][idx] + Gacc[2][idx] + Gacc[3][idx];
            atomicAdd(&Gb[idx], s);
        }
    }
}

// -------- pass_2a: per (b,h) masked prefix GV[p][d] = sum_{pos<=p} G.v --------
__global__ __launch_bounds__(256) void pass_2a(const float* __restrict__ G,
                                               const float* __restrict__ Yv,
                                               float* __restrict__ GVpre) {
    const int h = blockIdx.x, b = blockIdx.y;
    const int t = threadIdx.x;
    __shared__ float Gl[1024];
    __shared__ float S[256][64];
    __shared__ float segsum[4][64];
    for (int i = t; i < 1024; i += 256) Gl[i] = G[((size_t)(b * 16 + h) << 10) + i];
    __syncthreads();
    const int d = t & 63, pg = t >> 6;
    const float* Yvb = Yv + ((size_t)b << 20) + h * 64 + d;
    for (int p0 = 0; p0 < 64; p0++) {
        int pos = pg * 64 + p0;
        float s = 0.f;
#pragma unroll
        for (int sq = 0; sq < 4; sq++) {
            int j = (sq << 8) + pos;
            s += Gl[j] * Yvb[(size_t)j << 10];
        }
        S[pos][d] = s;
    }
    __syncthreads();
    float acc = 0.f;
    for (int p0 = 0; p0 < 64; p0++) {
        int pos = pg * 64 + p0;
        acc += S[pos][d];
        S[pos][d] = acc;
    }
    segsum[pg][d] = acc;
    __syncthreads();
    float off = 0.f;
    for (int g = 0; g < pg; g++) off += segsum[g][d];
    float* gv = GVpre + (((size_t)(b * 16 + h)) << 14) + d;
    for (int p0 = 0; p0 < 64; p0++) {
        int pos = pg * 64 + p0;
        gv[pos << 6] = S[pos][d] + off;
    }
}

// -------- pass_2b: ao = AOp + (lam/1024)*GV[pq]; RMS; bf16 store --------
__global__ __launch_bounds__(256) void pass_2b(const float* __restrict__ AOp,
                                               const float* __restrict__ GVpre,
                                               const float* __restrict__ lamp,
                                               const float* __restrict__ wan,
                                               unsigned short* __restrict__ aoS) {
    const int qg = blockIdx.x;
    const int h = blockIdx.y, b = blockIdx.z;
    const int t = threadIdx.x;
    const int d = t & 63, rg = t >> 6;
    const float lamg = (*lamp) * (1.f / 1024.f);
    const float wv = wan[d];
    const float* aob = AOp + ((((size_t)(b * 16 + h)) << 10) + (qg << 8)) * 64 + d;
    const float* gvb = GVpre + (((size_t)(b * 16 + h)) << 14) + d;
    unsigned short* ob = aoS + ((size_t)b << 20) + ((size_t)h << 16) + ((size_t)(qg << 8) << 6) + d;
    for (int p0 = 0; p0 < 64; p0++) {
        int pq = p0 * 4 + rg;
        float ao = aob[(size_t)pq << 6] + lamg * gvb[(size_t)pq << 6];
        float ss = ao * ao;
#pragma unroll
        for (int o = 1; o < 64; o <<= 1) ss += __shfl_xor(ss, o);
        float rr_ = rsqrtf(ss * (1.f / 64.f) + EPS_ATTN);
        ob[(size_t)pq << 6] = f2bf(ao * rr_ * wv);
    }
}

extern "C" void kernel_launch(void* const* d_in, const int* in_sizes, int n_in,
                              void* d_out, int out_size, void* d_ws, size_t ws_size,
                              hipStream_t stream) {
    const float* x    = (const float*)d_in[0];
    const float* fc   = (const float*)d_in[1];
    const float* w1   = (const float*)d_in[2];
    const float* w2   = (const float*)d_in[3];
    const float* Wq   = (const float*)d_in[4];
    const float* bq   = (const float*)d_in[5];
    const float* Wk   = (const float*)d_in[6];
    const float* bk   = (const float*)d_in[7];
    const float* Wv   = (const float*)d_in[8];
    const float* bv   = (const float*)d_in[9];
    const float* Wo   = (const float*)d_in[10];
    const float* bo   = (const float*)d_in[11];
    const float* lq1  = (const float*)d_in[12];
    const float* lk1  = (const float*)d_in[13];
    const float* lq2  = (const float*)d_in[14];
    const float* lk2  = (const float*)d_in[15];
    const float* wan  = (const float*)d_in[16];
    const float* Wg   = (const float*)d_in[17];
    const float* bg   = (const float*)d_in[18];
    const float* Wout = (const float*)d_in[19];
    const float* bout = (const float*)d_in[20];

    char* ws = (char*)d_ws;
    const size_t MB = 1024 * 1024;
    // Layout (peak 49 MB):
    float* G    = (float*)(ws);                     // [0, 128K)
    float* lam  = (float*)(ws + 256 * 1024);        // 4 B
    unsigned short* hH = (unsigned short*)(ws + 1 * MB);   // [1,5)  (dead after QKV)
    unsigned short* hL = (unsigned short*)(ws + 5 * MB);   // [5,9)
    float* Yq   = (float*)(ws + 9 * MB);            // [9,17)
    float* Yk   = (float*)(ws + 17 * MB);           // [17,25) (dead after rope_split_k)
    float* Yv   = (float*)(ws + 25 * MB);           // [25,33) (dead after pass_2a)
    unsigned short* WqH = (unsigned short*)(ws + 33 * MB); // [33,35) (dead after QKV)
    unsigned short* WqL = (unsigned short*)(ws + 35 * MB); // [35,37)
    unsigned short* WkH = (unsigned short*)(ws + 37 * MB); // [37,39)
    unsigned short* WkL = (unsigned short*)(ws + 39 * MB); // [39,41)
    unsigned short* WvH = (unsigned short*)(ws + 41 * MB); // [41,43)
    unsigned short* WvL = (unsigned short*)(ws + 43 * MB); // [43,45)
    float* AOp  = (float*)(ws + 33 * MB);           // reuse [33,41) after QKV
    float* GVpre= (float*)(ws + 41 * MB);           // reuse [41,43) after QKV
    unsigned short* WoB = (unsigned short*)(ws + 43 * MB); // reuse [43,45) after QKV
    unsigned short* KhG = (unsigned short*)(ws + 1 * MB);  // reuse [1,5)  (hH dead)
    unsigned short* KlG = (unsigned short*)(ws + 5 * MB);  // reuse [5,9)  (hL dead)
    unsigned short* VtH = (unsigned short*)(ws + 17 * MB); // reuse [17,21) (Yk dead)
    unsigned short* VtL = (unsigned short*)(ws + 21 * MB); // reuse [21,25)
    unsigned short* aoS = (unsigned short*)(ws + 1 * MB);  // reuse [1,5)  (KhG dead after pass_1)
    float* X1           = (float*)(ws + 9 * MB);           // reuse [9,17) (Yq dead after pass_1)
    unsigned short* h2b = (unsigned short*)(ws + 5 * MB);  // reuse [5,9)  (KlG dead)
    unsigned short* mlp = (unsigned short*)(ws + 17 * MB); // reuse [17,33) (VtH/L, Yv dead)
    unsigned short* WuB = (unsigned short*)(ws + 33 * MB); // reuse [33,41) after pass_2b (AOp dead)
    unsigned short* WvB2= (unsigned short*)(ws + 41 * MB); // reuse [41,49) after Wo gemm (GVpre/WoB dead)
    unsigned short* WoutB=(unsigned short*)(ws + 33 * MB); // reuse [33,41) after gate (WuB dead)

    prep<<<32, 256, 0, stream>>>(G, lam, lq1, lk1, lq2, lk2);
    rms_split<<<2048, 256, 0, stream>>>(x, w1, hH, hL, EPS_DEF);
    cvt_split3<<<dim3(1024, 3), 256, 0, stream>>>(Wq, Wk, Wv, WqH, WqL, WkH, WkL, WvH, WvL, 262144);
    gemm_qkv_ps<<<dim3(32, 16, 3), 256, 0, stream>>>(hH, hL, WqH, WqL, WkH, WkL, WvH, WvL,
                                                     bq, bk, bv, Yq, Yk, Yv);
    cvt_bf16<<<1024, 256, 0, stream>>>(Wo, WoB, 262144);   // [43,45): WvL dead after QKV
    rope_inplace<<<2048, 256, 0, stream>>>(Yq, fc);
    rope_split_k<<<2048, 256, 0, stream>>>(Yk, fc, KhG, KlG);
    v_split_t<<<dim3(16, 16, 2), 256, 0, stream>>>(Yv, VtH, VtL);
    pass_1<<<512, 256, 0, stream>>>(Yq, KhG, KlG, VtH, VtL, lam, G, AOp);
    pass_2a<<<dim3(16, 2), 256, 0, stream>>>(G, Yv, GVpre);
    pass_2b<<<dim3(4, 16, 2), 256, 0, stream>>>(AOp, GVpre, lam, wan, aoS);
    dim3 gmf(32, 16);
    gemm_mfma_wb<<<gmf, 256, 0, stream>>>(aoS, WoB, bo, x, X1, 2048, 1024, 1024);
    // Pre-convert gate weights (AOp/GVpre/WoB regions now dead).
    cvt_bf16<<<4096, 256, 0, stream>>>(Wg, WuB, 1048576);
    cvt_bf16<<<4096, 256, 0, stream>>>(Wg + 4194304, WvB2, 1048576);
    rms_kernel<1><<<2048, 256, 0, stream>>>(X1, w2, h2b, EPS_DEF);
    gemm_gate_wb<<<dim3(16, 64), 256, 0, stream>>>(h2b, WuB, WvB2, bg, mlp);
    // Pre-convert Wout into [33,41) (WuB dead after gate).
    cvt_bf16<<<4096, 256, 0, stream>>>(Wout, WoutB, 1048576);
    // FINAL OUTPUT IS FP32.
    gemm_mfma_wb<<<gmf, 256, 0, stream>>>(mlp, WoutB, bout, X1, (float*)d_out, 2048, 1024, 4096);
}

// Round 13
// 422.027 us; speedup vs baseline: 8.7665x; 1.0004x over previous
//
#include <hip/hip_runtime.h>

#define LAMBDA_INIT 0.2f
#define SCALING 0.17677669529663687f   // 1/sqrt(32)
#define EPS_DEF 1.1920928955078125e-07f
#define EPS_ATTN 1e-5f

typedef unsigned short us4 __attribute__((ext_vector_type(4)));
typedef unsigned short us8v __attribute__((ext_vector_type(8)));
typedef float f32x4 __attribute__((ext_vector_type(4)));
typedef float f32x2 __attribute__((ext_vector_type(2)));
typedef __bf16 bf16x8 __attribute__((ext_vector_type(8)));

#define MFMA16(a, b, c) __builtin_amdgcn_mfma_f32_16x16x32_bf16((a), (b), (c), 0, 0, 0)

__device__ __forceinline__ float bf2f(unsigned short u) {
    unsigned int x = ((unsigned int)u) << 16;
    return __builtin_bit_cast(float, x);
}
__device__ __forceinline__ unsigned short f2bf(float f) {
    unsigned int x = __builtin_bit_cast(unsigned int, f);
    x += 0x7fffu + ((x >> 16) & 1u);
    return (unsigned short)(x >> 16);
}
// split a pair of f32x4 into hi/lo bf16 (x ~= hi + lo, residual ~2^-18 rel)
__device__ __forceinline__ void split8(f32x4 a, f32x4 b, us8v& hi, us8v& lo) {
#pragma unroll
    for (int u = 0; u < 4; u++) {
        unsigned short h = f2bf(a[u]);
        hi[u] = h; lo[u] = f2bf(a[u] - bf2f(h));
        unsigned short h2 = f2bf(b[u]);
        hi[4 + u] = h2; lo[4 + u] = f2bf(b[u] - bf2f(h2));
    }
}
__device__ __forceinline__ bf16x8 ldb(const unsigned short* p) {
    return __builtin_bit_cast(bf16x8, *(const us8v*)p);
}
// RoPE on 4 consecutive dims starting at dd (within head); identical fp32
// expression to the retired rope_inplace kernel.
__device__ __forceinline__ f32x4 rope4(f32x4 v, const float* __restrict__ fc, int p, int dd) {
    if (p == 0) return v;
    int d4 = (dd & 31) >> 1;
    f32x4 f = *(const f32x4*)(fc + ((size_t)(p - 1) * 16 + d4) * 2);
    f32x4 o;
    o[0] = v[0] * f[0] - v[1] * f[1];
    o[1] = v[0] * f[1] + v[1] * f[0];
    o[2] = v[2] * f[2] - v[3] * f[3];
    o[3] = v[2] * f[3] + v[3] * f[2];
    return o;
}

__device__ __forceinline__ float wave_sum(float v) {
#pragma unroll
    for (int o = 32; o > 0; o >>= 1) v += __shfl_down(v, o);
    return v;
}
__device__ __forceinline__ float block_sum(float v, float* red4) {
    int wv = threadIdx.x >> 6;
    float w = wave_sum(v);
    __syncthreads();
    if ((threadIdx.x & 63) == 0) red4[wv] = w;
    __syncthreads();
    return red4[0] + red4[1] + red4[2] + red4[3];
}

// ---------------- prep: zero G, compute lambda ----------------
__global__ __launch_bounds__(256) void prep(float* __restrict__ G, float* __restrict__ lamp,
                                            const float* lq1, const float* lk1,
                                            const float* lq2, const float* lk2) {
    int i = (blockIdx.x * 256 + threadIdx.x) * 4;
    G[i] = 0.f; G[i + 1] = 0.f; G[i + 2] = 0.f; G[i + 3] = 0.f;
    if (blockIdx.x == 0 && threadIdx.x == 0) {
        float a = 0.f, c = 0.f;
        for (int d = 0; d < 32; d++) {
            a += lq1[d] * lk1[d];
            c += lq2[d] * lk2[d];
        }
        *lamp = expf(a) - expf(c) + LAMBDA_INIT;
    }
}

// ---------------- fp32 -> bf16 weight conversion ----------------
__global__ __launch_bounds__(256) void cvt_bf16(const float* __restrict__ s,
                                                unsigned short* __restrict__ d, int n4) {
    int i = blockIdx.x * 256 + threadIdx.x;
    if (i >= n4) return;
    f32x4 v = ((const f32x4*)s)[i];
    us4 o;
#pragma unroll
    for (int u = 0; u < 4; u++) o[u] = f2bf(v[u]);
    ((us4*)d)[i] = o;
}

// ---------------- fp32 -> hi/lo split conversion, 3 weights fused ----------------
__global__ __launch_bounds__(256) void cvt_split3(
        const float* __restrict__ s0, const float* __restrict__ s1, const float* __restrict__ s2,
        unsigned short* __restrict__ h0, unsigned short* __restrict__ l0,
        unsigned short* __restrict__ h1p, unsigned short* __restrict__ l1p,
        unsigned short* __restrict__ h2p, unsigned short* __restrict__ l2p, int n4) {
    const int z = blockIdx.y;
    const float* s = (z == 0) ? s0 : (z == 1) ? s1 : s2;
    unsigned short* hi = (z == 0) ? h0 : (z == 1) ? h1p : h2p;
    unsigned short* lo = (z == 0) ? l0 : (z == 1) ? l1p : l2p;
    int i = blockIdx.x * 256 + threadIdx.x;
    if (i >= n4) return;
    f32x4 v = ((const f32x4*)s)[i];
    us4 h, l;
#pragma unroll
    for (int u = 0; u < 4; u++) {
        h[u] = f2bf(v[u]);
        l[u] = f2bf(v[u] - bf2f(h[u]));
    }
    ((us4*)hi)[i] = h;
    ((us4*)lo)[i] = l;
}

// ---------------- RMSNorm: fp32 in, fp32 weight, bf16/fp32 out ----------------
template <int OUTBF>
__global__ __launch_bounds__(256) void rms_kernel(const float* __restrict__ x,
                                                  const float* __restrict__ w,
                                                  void* __restrict__ out, float eps) {
    int row = blockIdx.x;
    int tid = threadIdx.x;
    size_t base = (size_t)row * 1024 + tid * 4;
    f32x4 v = *(const f32x4*)(x + base);
    float ss = v[0]*v[0] + v[1]*v[1] + v[2]*v[2] + v[3]*v[3];
    __shared__ float red4[4];
    float tot = block_sum(ss, red4);
    float r = rsqrtf(tot * (1.0f / 1024.f) + eps);
    f32x4 wv = *(const f32x4*)(w + tid * 4);
    if (OUTBF) {
        us4 o;
#pragma unroll
        for (int i = 0; i < 4; i++) o[i] = f2bf(v[i] * r * wv[i]);
        *(us4*)((unsigned short*)out + base) = o;
    } else {
        f32x4 o;
#pragma unroll
        for (int i = 0; i < 4; i++) o[i] = v[i] * r * wv[i];
        *(f32x4*)((float*)out + base) = o;
    }
}

// ---------------- RMSNorm with hi/lo split output ----------------
__global__ __launch_bounds__(256) void rms_split(const float* __restrict__ x,
                                                 const float* __restrict__ w,
                                                 unsigned short* __restrict__ hh,
                                                 unsigned short* __restrict__ hl, float eps) {
    int row = blockIdx.x;
    int tid = threadIdx.x;
    size_t base = (size_t)row * 1024 + tid * 4;
    f32x4 v = *(const f32x4*)(x + base);
    float ss = v[0]*v[0] + v[1]*v[1] + v[2]*v[2] + v[3]*v[3];
    __shared__ float red4[4];
    float tot = block_sum(ss, red4);
    float r = rsqrtf(tot * (1.0f / 1024.f) + eps);
    f32x4 wv = *(const f32x4*)(w + tid * 4);
    us4 oh, ol;
#pragma unroll
    for (int i = 0; i < 4; i++) {
        float val = v[i] * r * wv[i];
        oh[i] = f2bf(val);
        ol[i] = f2bf(val - bf2f(oh[i]));
    }
    *(us4*)(hh + base) = oh;
    *(us4*)(hl + base) = ol;
}

// =====================================================================
// QKV split-bf16 MFMA GEMM, PRE-SPLIT operands, SOFTWARE-PIPELINED.
// BM=64, BN=64, BK=64, 4 waves (2x2). Grid (32,16,3).
// =====================================================================
__global__ __launch_bounds__(256) void gemm_qkv_ps(
        const unsigned short* __restrict__ AH, const unsigned short* __restrict__ AL,
        const unsigned short* __restrict__ WqH, const unsigned short* __restrict__ WqL,
        const unsigned short* __restrict__ WkH, const unsigned short* __restrict__ WkL,
        const unsigned short* __restrict__ WvH, const unsigned short* __restrict__ WvL,
        const float* __restrict__ bq, const float* __restrict__ bk, const float* __restrict__ bv,
        float* __restrict__ Yq, float* __restrict__ Yk, float* __restrict__ Yv) {
    const int z = blockIdx.z;
    const unsigned short* BH = (z == 0) ? WqH : (z == 1) ? WkH : WvH;
    const unsigned short* BL = (z == 0) ? WqL : (z == 1) ? WkL : WvL;
    const float* bias = (z == 0) ? bq : (z == 1) ? bk : bv;
    float* out        = (z == 0) ? Yq : (z == 1) ? Yk : Yv;
    const int K = 1024, N = 1024;
    __shared__ __align__(16) unsigned short Ah[64][72];
    __shared__ __align__(16) unsigned short Al[64][72];
    __shared__ __align__(16) unsigned short Bh[64][72];
    __shared__ __align__(16) unsigned short Bl[64][72];
    const int t = threadIdx.x;
    const int bm = blockIdx.x, bn = blockIdx.y;
    const int lane = t & 63, w = t >> 6;
    const int wr = w >> 1, wc = w & 1;
    const int l15 = lane & 15, lg = lane >> 4;
    const int sr = t >> 2, sc = (t & 3) * 16;

    const unsigned short* AgH = AH + (size_t)(bm * 64 + sr) * K + sc;
    const unsigned short* AgL = AL + (size_t)(bm * 64 + sr) * K + sc;
    const unsigned short* BgH = BH + (size_t)(bn * 64 + sr) * K + sc;
    const unsigned short* BgL = BL + (size_t)(bn * 64 + sr) * K + sc;

    f32x4 acc[2][2] = {};

    us8v ah0 = *(const us8v*)AgH, ah1 = *(const us8v*)(AgH + 8);
    us8v al0 = *(const us8v*)AgL, al1 = *(const us8v*)(AgL + 8);
    us8v bh0 = *(const us8v*)BgH, bh1 = *(const us8v*)(BgH + 8);
    us8v bl0 = *(const us8v*)BgL, bl1 = *(const us8v*)(BgL + 8);

    for (int k0 = 0; k0 < K; k0 += 64) {
        __syncthreads();
        *(us8v*)&Ah[sr][sc] = ah0; *(us8v*)&Ah[sr][sc + 8] = ah1;
        *(us8v*)&Al[sr][sc] = al0; *(us8v*)&Al[sr][sc + 8] = al1;
        *(us8v*)&Bh[sr][sc] = bh0; *(us8v*)&Bh[sr][sc + 8] = bh1;
        *(us8v*)&Bl[sr][sc] = bl0; *(us8v*)&Bl[sr][sc + 8] = bl1;
        __syncthreads();
        if (k0 + 64 < K) {
            const int kn = k0 + 64;
            ah0 = *(const us8v*)(AgH + kn); ah1 = *(const us8v*)(AgH + kn + 8);
            al0 = *(const us8v*)(AgL + kn); al1 = *(const us8v*)(AgL + kn + 8);
            bh0 = *(const us8v*)(BgH + kn); bh1 = *(const us8v*)(BgH + kn + 8);
            bl0 = *(const us8v*)(BgL + kn); bl1 = *(const us8v*)(BgL + kn + 8);
        }
#pragma unroll
        for (int kk = 0; kk < 2; kk++) {
            bf16x8 afh[2], afl[2], bfh[2], bfl[2];
#pragma unroll
            for (int mi = 0; mi < 2; mi++) {
                afh[mi] = ldb(&Ah[wr * 32 + mi * 16 + l15][kk * 32 + lg * 8]);
                afl[mi] = ldb(&Al[wr * 32 + mi * 16 + l15][kk * 32 + lg * 8]);
            }
#pragma unroll
            for (int ni = 0; ni < 2; ni++) {
                bfh[ni] = ldb(&Bh[wc * 32 + ni * 16 + l15][kk * 32 + lg * 8]);
                bfl[ni] = ldb(&Bl[wc * 32 + ni * 16 + l15][kk * 32 + lg * 8]);
            }
#pragma unroll
            for (int mi = 0; mi < 2; mi++)
#pragma unroll
                for (int ni = 0; ni < 2; ni++) {
                    acc[mi][ni] = MFMA16(afl[mi], bfh[ni], acc[mi][ni]);
                    acc[mi][ni] = MFMA16(afh[mi], bfl[ni], acc[mi][ni]);
                    acc[mi][ni] = MFMA16(afh[mi], bfh[ni], acc[mi][ni]);
                }
        }
    }

    const int rbase = bm * 64 + wr * 32 + (lg << 2);
    const int cbase = bn * 64 + wc * 32 + l15;
#pragma unroll
    for (int mi = 0; mi < 2; mi++) {
#pragma unroll
        for (int ni = 0; ni < 2; ni++) {
            int col = cbase + ni * 16;
            float bb = bias[col];
#pragma unroll
            for (int r = 0; r < 4; r++) {
                int row = rbase + mi * 16 + r;
                out[(size_t)row * N + col] = acc[mi][ni][r] + bb;
            }
        }
    }
}

// =====================================================================
// bf16 MFMA GEMM, pre-converted bf16 B, SOFTWARE-PIPELINED.
// BM=64, BN=64, BK=64, 4 waves (2x2).
// =====================================================================
__global__ __launch_bounds__(256) void gemm_mfma_wb(const unsigned short* __restrict__ A,
                                                    const unsigned short* __restrict__ Bt,
                                                    const float* __restrict__ bias,
                                                    const float* __restrict__ res,
                                                    float* __restrict__ out,
                                                    int M, int N, int K) {
    __shared__ __align__(16) unsigned short As[64][72];
    __shared__ __align__(16) unsigned short Bs[64][72];
    const int t = threadIdx.x;
    const int bm = blockIdx.x, bn = blockIdx.y;
    const int lane = t & 63, w = t >> 6;
    const int wr = w >> 1, wc = w & 1;
    const int l15 = lane & 15, lg = lane >> 4;
    const int sr = t >> 2, sc = (t & 3) * 16;

    const unsigned short* Ag = A + (size_t)(bm * 64 + sr) * K + sc;
    const unsigned short* Bg = Bt + (size_t)(bn * 64 + sr) * K + sc;

    f32x4 acc[2][2] = {};

    us8v a0 = *(const us8v*)Ag, a1 = *(const us8v*)(Ag + 8);
    us8v b0 = *(const us8v*)Bg, b1 = *(const us8v*)(Bg + 8);

    for (int k0 = 0; k0 < K; k0 += 64) {
        __syncthreads();
        *(us8v*)&As[sr][sc]     = a0;
        *(us8v*)&As[sr][sc + 8] = a1;
        *(us8v*)&Bs[sr][sc]     = b0;
        *(us8v*)&Bs[sr][sc + 8] = b1;
        __syncthreads();
        if (k0 + 64 < K) {
            const int kn = k0 + 64;
            a0 = *(const us8v*)(Ag + kn); a1 = *(const us8v*)(Ag + kn + 8);
            b0 = *(const us8v*)(Bg + kn); b1 = *(const us8v*)(Bg + kn + 8);
        }
#pragma unroll
        for (int kk = 0; kk < 2; kk++) {
            bf16x8 af[2], bf[2];
#pragma unroll
            for (int mi = 0; mi < 2; mi++)
                af[mi] = ldb(&As[wr * 32 + mi * 16 + l15][kk * 32 + lg * 8]);
#pragma unroll
            for (int ni = 0; ni < 2; ni++)
                bf[ni] = ldb(&Bs[wc * 32 + ni * 16 + l15][kk * 32 + lg * 8]);
#pragma unroll
            for (int mi = 0; mi < 2; mi++)
#pragma unroll
                for (int ni = 0; ni < 2; ni++)
                    acc[mi][ni] = MFMA16(af[mi], bf[ni], acc[mi][ni]);
        }
    }

    const int rbase = bm * 64 + wr * 32 + (lg << 2);
    const int cbase = bn * 64 + wc * 32 + l15;
#pragma unroll
    for (int mi = 0; mi < 2; mi++) {
#pragma unroll
        for (int ni = 0; ni < 2; ni++) {
            int col = cbase + ni * 16;
            float bb = bias[col];
#pragma unroll
            for (int r = 0; r < 4; r++) {
                int row = rbase + mi * 16 + r;
                size_t oi = (size_t)row * N + col;
                out[oi] = acc[mi][ni][r] + bb + res[oi];
            }
        }
    }
}

// ------- fused gate GEMM, PRE-CONVERTED bf16 weights, PIPELINED -------
__global__ __launch_bounds__(256) void gemm_gate_wb(const unsigned short* __restrict__ A,
                                                    const unsigned short* __restrict__ WuB,
                                                    const unsigned short* __restrict__ WvB,
                                                    const float* __restrict__ bg,
                                                    unsigned short* __restrict__ mlp) {
    __shared__ __align__(16) unsigned short As[128][72];
    __shared__ __align__(16) unsigned short BsU[64][72];
    __shared__ __align__(16) unsigned short BsV[64][72];
    const int t = threadIdx.x;
    const int bm = blockIdx.x, bn = blockIdx.y;
    const int lane = t & 63, w = t >> 6;
    const int wr = w >> 1, wc = w & 1;
    const int l15 = lane & 15, lg = lane >> 4;
    const int sr = t >> 2, sc = (t & 3) * 16;

    const unsigned short* Ag  = A + (size_t)(bm * 128 + sr) * 1024 + sc;
    const unsigned short* Ag2 = Ag + (size_t)64 * 1024;
    const unsigned short* BgU = WuB + (size_t)(bn * 64 + sr) * 1024 + sc;
    const unsigned short* BgV = WvB + (size_t)(bn * 64 + sr) * 1024 + sc;

    f32x4 accU[4][2] = {};
    f32x4 accV[4][2] = {};

    us8v a0 = *(const us8v*)Ag,  a1 = *(const us8v*)(Ag + 8);
    us8v a2 = *(const us8v*)Ag2, a3 = *(const us8v*)(Ag2 + 8);
    us8v u0 = *(const us8v*)BgU, u1 = *(const us8v*)(BgU + 8);
    us8v v0 = *(const us8v*)BgV, v1 = *(const us8v*)(BgV + 8);

    for (int k0 = 0; k0 < 1024; k0 += 64) {
        __syncthreads();
        *(us8v*)&As[sr][sc]          = a0;
        *(us8v*)&As[sr][sc + 8]      = a1;
        *(us8v*)&As[sr + 64][sc]     = a2;
        *(us8v*)&As[sr + 64][sc + 8] = a3;
        *(us8v*)&BsU[sr][sc]         = u0;
        *(us8v*)&BsU[sr][sc + 8]     = u1;
        *(us8v*)&BsV[sr][sc]         = v0;
        *(us8v*)&BsV[sr][sc + 8]     = v1;
        __syncthreads();
        if (k0 + 64 < 1024) {
            const int kn = k0 + 64;
            a0 = *(const us8v*)(Ag + kn);  a1 = *(const us8v*)(Ag + kn + 8);
            a2 = *(const us8v*)(Ag2 + kn); a3 = *(const us8v*)(Ag2 + kn + 8);
            u0 = *(const us8v*)(BgU + kn); u1 = *(const us8v*)(BgU + kn + 8);
            v0 = *(const us8v*)(BgV + kn); v1 = *(const us8v*)(BgV + kn + 8);
        }
#pragma unroll
        for (int kk = 0; kk < 2; kk++) {
            bf16x8 af[4], bu[2], bv2[2];
#pragma unroll
            for (int mi = 0; mi < 4; mi++)
                af[mi] = ldb(&As[wr * 64 + mi * 16 + l15][kk * 32 + lg * 8]);
#pragma unroll
            for (int ni = 0; ni < 2; ni++) {
                bu[ni]  = ldb(&BsU[wc * 32 + ni * 16 + l15][kk * 32 + lg * 8]);
                bv2[ni] = ldb(&BsV[wc * 32 + ni * 16 + l15][kk * 32 + lg * 8]);
            }
#pragma unroll
            for (int mi = 0; mi < 4; mi++)
#pragma unroll
                for (int ni = 0; ni < 2; ni++) {
                    accU[mi][ni] = MFMA16(af[mi], bu[ni], accU[mi][ni]);
                    accV[mi][ni] = MFMA16(af[mi], bv2[ni], accV[mi][ni]);
                }
        }
    }

    const int rbase = bm * 128 + wr * 64 + (lg << 2);
    const int cbase = bn * 64 + wc * 32 + l15;
#pragma unroll
    for (int mi = 0; mi < 4; mi++) {
#pragma unroll
        for (int ni = 0; ni < 2; ni++) {
            int col = cbase + ni * 16;
            float bu_ = bg[col], bv_ = bg[4096 + col];
#pragma unroll
            for (int r = 0; r < 4; r++) {
                int row = rbase + mi * 16 + r;
                float u = accU[mi][ni][r] + bu_;
                float v = accV[mi][ni][r] + bv_;
                float s = v / (1.f + __expf(-v));
                mlp[(size_t)row * 4096 + col] = f2bf(u * s);
            }
        }
    }
}

// ------- RoPE(K) + hi/lo bf16 split, token-order output -------
__global__ __launch_bounds__(256) void rope_split_k(const float* __restrict__ Yk,
                                                    const float* __restrict__ fc,
                                                    unsigned short* __restrict__ KhG,
                                                    unsigned short* __restrict__ KlG) {
    int t = blockIdx.x;           // b*1024 + s
    int s = t & 1023;
    int p = s >> 2;
    int c0 = threadIdx.x * 4;
    const float* y = Yk + (size_t)t * 1024 + c0;
    float v0 = y[0], v1 = y[1], v2 = y[2], v3 = y[3];
    if (p > 0) {
        int d4 = (c0 & 31) >> 1;
        f32x4 f = *(const f32x4*)(fc + ((size_t)(p - 1) * 16 + d4) * 2);
        float w0 = v0 * f[0] - v1 * f[1];
        float w1 = v0 * f[1] + v1 * f[0];
        float w2 = v2 * f[2] - v3 * f[3];
        float w3 = v2 * f[3] + v3 * f[2];
        v0 = w0; v1 = w1; v2 = w2; v3 = w3;
    }
    us4 hi, lo;
    hi[0] = f2bf(v0); lo[0] = f2bf(v0 - bf2f(hi[0]));
    hi[1] = f2bf(v1); lo[1] = f2bf(v1 - bf2f(hi[1]));
    hi[2] = f2bf(v2); lo[2] = f2bf(v2 - bf2f(hi[2]));
    hi[3] = f2bf(v3); lo[3] = f2bf(v3 - bf2f(hi[3]));
    *(us4*)(KhG + (size_t)t * 1024 + c0) = hi;
    *(us4*)(KlG + (size_t)t * 1024 + c0) = lo;
}

// ------- V transpose + hi/lo split: Vt[(b,h)][d (64)][j (1024)] -------
__global__ __launch_bounds__(256) void v_split_t(const float* __restrict__ Yv,
                                                 unsigned short* __restrict__ VtH,
                                                 unsigned short* __restrict__ VtL) {
    const int jc = blockIdx.x, h = blockIdx.y, b = blockIdx.z;   // (16,16,2)
    __shared__ float tile[64][65];
    const int t = threadIdx.x;
    {
        const int jr = t >> 2, dc = (t & 3) * 16;
        const float* src = Yv + ((size_t)(b * 1024 + jc * 64 + jr) << 10) + h * 64 + dc;
        *(f32x4*)&tile[jr][dc]      = *(const f32x4*)src;
        *(f32x4*)&tile[jr][dc + 4]  = *(const f32x4*)(src + 4);
        *(f32x4*)&tile[jr][dc + 8]  = *(const f32x4*)(src + 8);
        *(f32x4*)&tile[jr][dc + 12] = *(const f32x4*)(src + 12);
    }
    __syncthreads();
    const int d = t >> 2, js = (t & 3) * 16;
    us8v h0, h1, l0, l1;
#pragma unroll
    for (int n = 0; n < 16; n++) {
        float val = tile[js + n][d];
        unsigned short hh = f2bf(val);
        unsigned short ll = f2bf(val - bf2f(hh));
        if (n < 8) { h0[n] = hh; l0[n] = ll; }
        else       { h1[n - 8] = hh; l1[n - 8] = ll; }
    }
    size_t ob = (((size_t)(b * 16 + h) * 64 + d) << 10) + jc * 64 + js;
    *(us8v*)(VtH + ob) = h0; *(us8v*)(VtH + ob + 8) = h1;
    *(us8v*)(VtL + ob) = l0; *(us8v*)(VtL + ob + 8) = l1;
}

// =====================================================================
// pass_0: Z1/Z2 denominators only. LDS = K tiles (18 KB) -> high
// occupancy. RoPE(Q) fused into the fragment load. Same MFMA/exp
// sequence as the former sweep 1; stores RAW Z sums to MZ.
// =====================================================================
__global__ __launch_bounds__(256) void pass_0(const float* __restrict__ Yq,
                                              const float* __restrict__ fc,
                                              const unsigned short* __restrict__ KhG,
                                              const unsigned short* __restrict__ KlG,
                                              float* __restrict__ MZ) {
    const int blk = blockIdx.x;
    const int qc = 15 - (blk >> 5);
    const int h  = blk & 15;
    const int b  = (blk >> 4) & 1;
    const int t = threadIdx.x;
    const int lane = t & 63, w = t >> 6;
    const int l15 = lane & 15, lg = lane >> 4;

    __shared__ __align__(16) unsigned short Kh[64][72];
    __shared__ __align__(16) unsigned short Kl[64][72];

    us8v qh[2], ql[2];
    {
        const int srq = qc * 64 + w * 16 + l15;
        const int p = srq >> 2;
        const float* qp = Yq + ((size_t)(b * 1024 + srq) << 10) + h * 64 + lg * 8;
#pragma unroll
        for (int H = 0; H < 2; H++) {
            int dd = lg * 8 + H * 32;
            f32x4 a = rope4(*(const f32x4*)(qp + H * 32), fc, p, dd);
            f32x4 c = rope4(*(const f32x4*)(qp + H * 32 + 4), fc, p, dd + 4);
            split8(a, c, qh[H], ql[H]);
        }
    }
    const int dq0 = w * 16 + (lg << 2);

    const int srow = t >> 2, ssub = t & 3;
    const int ptk = 4 * (srow & 15) + (srow >> 4);
    const unsigned short* KhB = KhG + ((size_t)(b * 1024) << 10) + h * 64;
    const unsigned short* KlB = KlG + ((size_t)(b * 1024) << 10) + h * 64;

    float z1r[4] = {0.f, 0.f, 0.f, 0.f};
    float z2r[4] = {0.f, 0.f, 0.f, 0.f};

    us8v rkh0, rkh1, rkl0, rkl1;
    {
        const unsigned short* kh = KhB + ((size_t)ptk << 10) + ssub * 16;
        const unsigned short* kl = KlB + ((size_t)ptk << 10) + ssub * 16;
        rkh0 = *(const us8v*)kh; rkh1 = *(const us8v*)(kh + 8);
        rkl0 = *(const us8v*)kl; rkl1 = *(const us8v*)(kl + 8);
    }
    for (int kc = 0; kc <= qc; kc++) {
        __syncthreads();
        *(us8v*)&Kh[srow][ssub * 16]     = rkh0;
        *(us8v*)&Kh[srow][ssub * 16 + 8] = rkh1;
        *(us8v*)&Kl[srow][ssub * 16]     = rkl0;
        *(us8v*)&Kl[srow][ssub * 16 + 8] = rkl1;
        __syncthreads();
        if (kc < qc) {
            const unsigned short* kh = KhB + ((size_t)((kc + 1) * 64 + ptk) << 10) + ssub * 16;
            const unsigned short* kl = KlB + ((size_t)((kc + 1) * 64 + ptk) << 10) + ssub * 16;
            rkh0 = *(const us8v*)kh; rkh1 = *(const us8v*)(kh + 8);
            rkl0 = *(const us8v*)kl; rkl1 = *(const us8v*)(kl + 8);
        }
        const int kpos = kc * 16 + l15;
#pragma unroll
        for (int kf = 0; kf < 4; kf++) {
            const int krow = kf * 16 + l15;
            const int kcol = lg * 8;
            bf16x8 b1h = ldb(&Kh[krow][kcol]),      b1l = ldb(&Kl[krow][kcol]);
            bf16x8 b2h = ldb(&Kh[krow][32 + kcol]), b2l = ldb(&Kl[krow][32 + kcol]);
            f32x4 s1 = {}, s2 = {};
            s1 = MFMA16(__builtin_bit_cast(bf16x8, ql[0]), b1h, s1);
            s1 = MFMA16(__builtin_bit_cast(bf16x8, qh[0]), b1l, s1);
            s1 = MFMA16(__builtin_bit_cast(bf16x8, qh[0]), b1h, s1);
            s2 = MFMA16(__builtin_bit_cast(bf16x8, ql[1]), b2h, s2);
            s2 = MFMA16(__builtin_bit_cast(bf16x8, qh[1]), b2l, s2);
            s2 = MFMA16(__builtin_bit_cast(bf16x8, qh[1]), b2h, s2);
#pragma unroll
            for (int r = 0; r < 4; r++) {
                int pq = (qc * 64 + dq0 + r) >> 2;
                if (kpos <= pq) {
                    z1r[r] += __expf(fabsf(s1[r] * SCALING));
                    z2r[r] += __expf(fabsf(s2[r] * SCALING));
                }
            }
        }
    }
#pragma unroll
    for (int r = 0; r < 4; r++) {
        float a = z1r[r];
        a += __shfl_xor(a, 1); a += __shfl_xor(a, 2);
        a += __shfl_xor(a, 4); a += __shfl_xor(a, 8);
        float c = z2r[r];
        c += __shfl_xor(c, 1); c += __shfl_xor(c, 2);
        c += __shfl_xor(c, 4); c += __shfl_xor(c, 8);
        if (l15 == 0) {
            int s2i = qc * 64 + dq0 + r;
            f32x2 zz; zz[0] = a; zz[1] = c;
            *(f32x2*)(MZ + (((size_t)(b * 16 + h) << 10) + s2i) * 2) = zz;
        }
    }
}

// =====================================================================
// pass_1: weights + G colsums + AV only (Z read from MZ). 512 blocks
// heavy-first, pipelined K+V staging, wave-private W tiles (no barrier
// between weight-write and AV), per-wave Gacc slices. RoPE(Q) fused.
// =====================================================================
__global__ __launch_bounds__(256) void pass_1(const float* __restrict__ Yq,
                                              const float* __restrict__ fc,
                                              const unsigned short* __restrict__ KhG,
                                              const unsigned short* __restrict__ KlG,
                                              const unsigned short* __restrict__ VtH,
                                              const unsigned short* __restrict__ VtL,
                                              const float* __restrict__ MZ,
                                              const float* __restrict__ lamp,
                                              float* __restrict__ G,
                                              float* __restrict__ AOp) {
    const int blk = blockIdx.x;
    const int qc = 15 - (blk >> 5);
    const int h  = blk & 15;
    const int b  = (blk >> 4) & 1;
    const int t = threadIdx.x;
    const int lane = t & 63, w = t >> 6;
    const int l15 = lane & 15, lg = lane >> 4;

    __shared__ __align__(16) unsigned short Kh[64][72];
    __shared__ __align__(16) unsigned short Kl[64][72];
    __shared__ __align__(16) unsigned short Vth[64][72];
    __shared__ __align__(16) unsigned short Vtl[64][72];
    __shared__ __align__(16) unsigned short Wh[64][72];
    __shared__ __align__(16) unsigned short Wl[64][72];
    __shared__ float Gacc[4][1024];

    for (int i = t; i < 4096; i += 256) ((float*)Gacc)[i] = 0.f;

    us8v qh[2], ql[2];
    {
        const int srq = qc * 64 + w * 16 + l15;
        const int p = srq >> 2;
        const float* qp = Yq + ((size_t)(b * 1024 + srq) << 10) + h * 64 + lg * 8;
#pragma unroll
        for (int H = 0; H < 2; H++) {
            int dd = lg * 8 + H * 32;
            f32x4 a = rope4(*(const f32x4*)(qp + H * 32), fc, p, dd);
            f32x4 c = rope4(*(const f32x4*)(qp + H * 32 + 4), fc, p, dd + 4);
            split8(a, c, qh[H], ql[H]);
        }
    }
    const int dq0 = w * 16 + (lg << 2);

    // Z from pass_0 (raw sums), inverted exactly as before
    float z1r[4], z2r[4];
#pragma unroll
    for (int r = 0; r < 4; r++) {
        int s2i = qc * 64 + dq0 + r;
        f32x2 zz = *(const f32x2*)(MZ + (((size_t)(b * 16 + h) << 10) + s2i) * 2);
        z1r[r] = 1.f / fmaxf(zz[0], 1e-20f);
        z2r[r] = 1.f / fmaxf(zz[1], 1e-20f);
    }

    const int srow = t >> 2, ssub = t & 3;
    const int ptk = 4 * (srow & 15) + (srow >> 4);
    const unsigned short* KhB = KhG + ((size_t)(b * 1024) << 10) + h * 64;
    const unsigned short* KlB = KlG + ((size_t)(b * 1024) << 10) + h * 64;
    const unsigned short* VhB = VtH + (((size_t)(b * 16 + h) * 64 + srow) << 10) + ssub * 256;
    const unsigned short* VlB = VtL + (((size_t)(b * 16 + h) * 64 + srow) << 10) + ssub * 256;
    const float lam = *lamp;

    f32x4 ao[4] = {};

    us8v rkh0, rkh1, rkl0, rkl1, rvh0, rvh1, rvl0, rvl1;
    {
        const unsigned short* kh = KhB + ((size_t)ptk << 10) + ssub * 16;
        const unsigned short* kl = KlB + ((size_t)ptk << 10) + ssub * 16;
        rkh0 = *(const us8v*)kh; rkh1 = *(const us8v*)(kh + 8);
        rkl0 = *(const us8v*)kl; rkl1 = *(const us8v*)(kl + 8);
        rvh0 = *(const us8v*)VhB; rvh1 = *(const us8v*)(VhB + 8);
        rvl0 = *(const us8v*)VlB; rvl1 = *(const us8v*)(VlB + 8);
    }
    for (int kc = 0; kc <= qc; kc++) {
        __syncthreads();
        *(us8v*)&Kh[srow][ssub * 16]      = rkh0;
        *(us8v*)&Kh[srow][ssub * 16 + 8]  = rkh1;
        *(us8v*)&Kl[srow][ssub * 16]      = rkl0;
        *(us8v*)&Kl[srow][ssub * 16 + 8]  = rkl1;
        *(us8v*)&Vth[srow][ssub * 16]     = rvh0;
        *(us8v*)&Vth[srow][ssub * 16 + 8] = rvh1;
        *(us8v*)&Vtl[srow][ssub * 16]     = rvl0;
        *(us8v*)&Vtl[srow][ssub * 16 + 8] = rvl1;
        __syncthreads();
        if (kc < qc) {
            const unsigned short* kh = KhB + ((size_t)((kc + 1) * 64 + ptk) << 10) + ssub * 16;
            const unsigned short* kl = KlB + ((size_t)((kc + 1) * 64 + ptk) << 10) + ssub * 16;
            rkh0 = *(const us8v*)kh; rkh1 = *(const us8v*)(kh + 8);
            rkl0 = *(const us8v*)kl; rkl1 = *(const us8v*)(kl + 8);
            const unsigned short* vh = VhB + (kc + 1) * 16;
            const unsigned short* vl = VlB + (kc + 1) * 16;
            rvh0 = *(const us8v*)vh; rvh1 = *(const us8v*)(vh + 8);
            rvl0 = *(const us8v*)vl; rvl1 = *(const us8v*)(vl + 8);
        }
        const int kpos = kc * 16 + l15;
#pragma unroll
        for (int kf = 0; kf < 4; kf++) {
            const int krow = kf * 16 + l15;
            const int kcol = lg * 8;
            bf16x8 b1h = ldb(&Kh[krow][kcol]),      b1l = ldb(&Kl[krow][kcol]);
            bf16x8 b2h = ldb(&Kh[krow][32 + kcol]), b2l = ldb(&Kl[krow][32 + kcol]);
            f32x4 s1 = {}, s2 = {};
            s1 = MFMA16(__builtin_bit_cast(bf16x8, ql[0]), b1h, s1);
            s1 = MFMA16(__builtin_bit_cast(bf16x8, qh[0]), b1l, s1);
            s1 = MFMA16(__builtin_bit_cast(bf16x8, qh[0]), b1h, s1);
            s2 = MFMA16(__builtin_bit_cast(bf16x8, ql[1]), b2h, s2);
            s2 = MFMA16(__builtin_bit_cast(bf16x8, qh[1]), b2l, s2);
            s2 = MFMA16(__builtin_bit_cast(bf16x8, qh[1]), b2h, s2);
            const int kli = kf * 16 + l15;
            float colsum = 0.f;
#pragma unroll
            for (int r = 0; r < 4; r++) {
                int pq = (qc * 64 + dq0 + r) >> 2;
                float wv = 0.f, a1 = 0.f;
                if (kpos <= pq) {
                    float t1 = s1[r] * SCALING, t2 = s2[r] * SCALING;
                    float sg1 = (t1 > 0.f) ? 1.f : ((t1 < 0.f) ? -1.f : 0.f);
                    float sg2 = (t2 > 0.f) ? 1.f : ((t2 < 0.f) ? -1.f : 0.f);
                    a1 = sg1 * __expf(fabsf(t1)) * z1r[r];
                    wv = a1 - lam * (sg2 * __expf(fabsf(t2)) * z2r[r]);
                }
                colsum += a1;
                unsigned short hh = f2bf(wv);
                Wh[dq0 + r][kli] = hh;
                Wl[dq0 + r][kli] = f2bf(wv - bf2f(hh));
            }
            colsum += __shfl_xor(colsum, 16);
            colsum += __shfl_xor(colsum, 32);
            if (lane < 16) Gacc[w][kf * 256 + kc * 16 + lane] = colsum;
        }
        // No barrier: Wh/Wl rows [w*16, w*16+16) are wave-private.
#pragma unroll
        for (int kh2 = 0; kh2 < 2; kh2++) {
            bf16x8 wah = ldb(&Wh[w * 16 + l15][kh2 * 32 + lg * 8]);
            bf16x8 wal = ldb(&Wl[w * 16 + l15][kh2 * 32 + lg * 8]);
#pragma unroll
            for (int df = 0; df < 4; df++) {
                bf16x8 vbh = ldb(&Vth[df * 16 + l15][kh2 * 32 + lg * 8]);
                bf16x8 vbl = ldb(&Vtl[df * 16 + l15][kh2 * 32 + lg * 8]);
                ao[df] = MFMA16(wah, vbl, ao[df]);
                ao[df] = MFMA16(wal, vbh, ao[df]);
                ao[df] = MFMA16(wah, vbh, ao[df]);
            }
        }
    }

#pragma unroll
    for (int df = 0; df < 4; df++) {
#pragma unroll
        for (int r = 0; r < 4; r++) {
            int tq = qc * 64 + dq0 + r;
            int qrow = ((tq & 3) << 8) + (tq >> 2);
            AOp[((((size_t)(b * 16 + h)) << 10) + qrow) * 64 + df * 16 + l15] = ao[df][r];
        }
    }

    __syncthreads();
    float* Gb = G + ((size_t)(b * 16 + h) << 10);
    const int limp = (qc + 1) << 4;
    for (int idx = t; idx < 1024; idx += 256) {
        if ((idx & 255) < limp) {
            float s = Gacc[0][idx] + Gacc[1][idx] + Gacc[2][idx] + Gacc[3][idx];
            atomicAdd(&Gb[idx], s);
        }
    }
}

// -------- pass_2a: per (b,h) masked prefix GV[p][d] = sum_{pos<=p} G.v --------
__global__ __launch_bounds__(256) void pass_2a(const float* __restrict__ G,
                                               const float* __restrict__ Yv,
                                               float* __restrict__ GVpre) {
    const int h = blockIdx.x, b = blockIdx.y;
    const int t = threadIdx.x;
    __shared__ float Gl[1024];
    __shared__ float S[256][64];
    __shared__ float segsum[4][64];
    for (int i = t; i < 1024; i += 256) Gl[i] = G[((size_t)(b * 16 + h) << 10) + i];
    __syncthreads();
    const int d = t & 63, pg = t >> 6;
    const float* Yvb = Yv + ((size_t)b << 20) + h * 64 + d;
    for (int p0 = 0; p0 < 64; p0++) {
        int pos = pg * 64 + p0;
        float s = 0.f;
#pragma unroll
        for (int sq = 0; sq < 4; sq++) {
            int j = (sq << 8) + pos;
            s += Gl[j] * Yvb[(size_t)j << 10];
        }
        S[pos][d] = s;
    }
    __syncthreads();
    float acc = 0.f;
    for (int p0 = 0; p0 < 64; p0++) {
        int pos = pg * 64 + p0;
        acc += S[pos][d];
        S[pos][d] = acc;
    }
    segsum[pg][d] = acc;
    __syncthreads();
    float off = 0.f;
    for (int g = 0; g < pg; g++) off += segsum[g][d];
    float* gv = GVpre + (((size_t)(b * 16 + h)) << 14) + d;
    for (int p0 = 0; p0 < 64; p0++) {
        int pos = pg * 64 + p0;
        gv[pos << 6] = S[pos][d] + off;
    }
}

// -------- pass_2b: ao = AOp + (lam/1024)*GV[pq]; RMS; bf16 store --------
__global__ __launch_bounds__(256) void pass_2b(const float* __restrict__ AOp,
                                               const float* __restrict__ GVpre,
                                               const float* __restrict__ lamp,
                                               const float* __restrict__ wan,
                                               unsigned short* __restrict__ aoS) {
    const int qg = blockIdx.x;
    const int h = blockIdx.y, b = blockIdx.z;
    const int t = threadIdx.x;
    const int d = t & 63, rg = t >> 6;
    const float lamg = (*lamp) * (1.f / 1024.f);
    const float wv = wan[d];
    const float* aob = AOp + ((((size_t)(b * 16 + h)) << 10) + (qg << 8)) * 64 + d;
    const float* gvb = GVpre + (((size_t)(b * 16 + h)) << 14) + d;
    unsigned short* ob = aoS + ((size_t)b << 20) + ((size_t)h << 16) + ((size_t)(qg << 8) << 6) + d;
    for (int p0 = 0; p0 < 64; p0++) {
        int pq = p0 * 4 + rg;
        float ao = aob[(size_t)pq << 6] + lamg * gvb[(size_t)pq << 6];
        float ss = ao * ao;
#pragma unroll
        for (int o = 1; o < 64; o <<= 1) ss += __shfl_xor(ss, o);
        float rr_ = rsqrtf(ss * (1.f / 64.f) + EPS_ATTN);
        ob[(size_t)pq << 6] = f2bf(ao * rr_ * wv);
    }
}

extern "C" void kernel_launch(void* const* d_in, const int* in_sizes, int n_in,
                              void* d_out, int out_size, void* d_ws, size_t ws_size,
                              hipStream_t stream) {
    const float* x    = (const float*)d_in[0];
    const float* fc   = (const float*)d_in[1];
    const float* w1   = (const float*)d_in[2];
    const float* w2   = (const float*)d_in[3];
    const float* Wq   = (const float*)d_in[4];
    const float* bq   = (const float*)d_in[5];
    const float* Wk   = (const float*)d_in[6];
    const float* bk   = (const float*)d_in[7];
    const float* Wv   = (const float*)d_in[8];
    const float* bv   = (const float*)d_in[9];
    const float* Wo   = (const float*)d_in[10];
    const float* bo   = (const float*)d_in[11];
    const float* lq1  = (const float*)d_in[12];
    const float* lk1  = (const float*)d_in[13];
    const float* lq2  = (const float*)d_in[14];
    const float* lk2  = (const float*)d_in[15];
    const float* wan  = (const float*)d_in[16];
    const float* Wg   = (const float*)d_in[17];
    const float* bg   = (const float*)d_in[18];
    const float* Wout = (const float*)d_in[19];
    const float* bout = (const float*)d_in[20];

    char* ws = (char*)d_ws;
    const size_t MB = 1024 * 1024;
    // Layout (peak 49 MB):
    float* G    = (float*)(ws);                     // [0, 128K)
    float* lam  = (float*)(ws + 256 * 1024);        // 4 B
    float* MZ   = (float*)(ws + 384 * 1024);        // [384K, 640K) raw Z1/Z2 per row
    unsigned short* hH = (unsigned short*)(ws + 1 * MB);   // [1,5)  (dead after QKV)
    unsigned short* hL = (unsigned short*)(ws + 5 * MB);   // [5,9)
    float* Yq   = (float*)(ws + 9 * MB);            // [9,17)  (un-roped; rope fused into pass_0/1)
    float* Yk   = (float*)(ws + 17 * MB);           // [17,25) (dead after rope_split_k)
    float* Yv   = (float*)(ws + 25 * MB);           // [25,33) (dead after pass_2a)
    unsigned short* WqH = (unsigned short*)(ws + 33 * MB); // [33,35) (dead after QKV)
    unsigned short* WqL = (unsigned short*)(ws + 35 * MB); // [35,37)
    unsigned short* WkH = (unsigned short*)(ws + 37 * MB); // [37,39)
    unsigned short* WkL = (unsigned short*)(ws + 39 * MB); // [39,41)
    unsigned short* WvH = (unsigned short*)(ws + 41 * MB); // [41,43)
    unsigned short* WvL = (unsigned short*)(ws + 43 * MB); // [43,45)
    float* AOp  = (float*)(ws + 33 * MB);           // reuse [33,41) after QKV
    float* GVpre= (float*)(ws + 41 * MB);           // reuse [41,43) after QKV
    unsigned short* WoB = (unsigned short*)(ws + 43 * MB); // reuse [43,45) after QKV
    unsigned short* KhG = (unsigned short*)(ws + 1 * MB);  // reuse [1,5)  (hH dead)
    unsigned short* KlG = (unsigned short*)(ws + 5 * MB);  // reuse [5,9)  (hL dead)
    unsigned short* VtH = (unsigned short*)(ws + 17 * MB); // reuse [17,21) (Yk dead)
    unsigned short* VtL = (unsigned short*)(ws + 21 * MB); // reuse [21,25)
    unsigned short* aoS = (unsigned short*)(ws + 1 * MB);  // reuse [1,5)  (KhG dead after pass_1)
    float* X1           = (float*)(ws + 9 * MB);           // reuse [9,17) (Yq dead after pass_1)
    unsigned short* h2b = (unsigned short*)(ws + 5 * MB);  // reuse [5,9)  (KlG dead)
    unsigned short* mlp = (unsigned short*)(ws + 17 * MB); // reuse [17,33) (VtH/L, Yv dead)
    unsigned short* WuB = (unsigned short*)(ws + 33 * MB); // reuse [33,41) after pass_2b (AOp dead)
    unsigned short* WvB2= (unsigned short*)(ws + 41 * MB); // reuse [41,49) after Wo gemm
    unsigned short* WoutB=(unsigned short*)(ws + 33 * MB); // reuse [33,41) after gate (WuB dead)

    prep<<<32, 256, 0, stream>>>(G, lam, lq1, lk1, lq2, lk2);
    rms_split<<<2048, 256, 0, stream>>>(x, w1, hH, hL, EPS_DEF);
    cvt_split3<<<dim3(1024, 3), 256, 0, stream>>>(Wq, Wk, Wv, WqH, WqL, WkH, WkL, WvH, WvL, 262144);
    gemm_qkv_ps<<<dim3(32, 16, 3), 256, 0, stream>>>(hH, hL, WqH, WqL, WkH, WkL, WvH, WvL,
                                                     bq, bk, bv, Yq, Yk, Yv);
    cvt_bf16<<<1024, 256, 0, stream>>>(Wo, WoB, 262144);   // [43,45): WvL dead after QKV
    rope_split_k<<<2048, 256, 0, stream>>>(Yk, fc, KhG, KlG);
    v_split_t<<<dim3(16, 16, 2), 256, 0, stream>>>(Yv, VtH, VtL);
    pass_0<<<512, 256, 0, stream>>>(Yq, fc, KhG, KlG, MZ);
    pass_1<<<512, 256, 0, stream>>>(Yq, fc, KhG, KlG, VtH, VtL, MZ, lam, G, AOp);
    pass_2a<<<dim3(16, 2), 256, 0, stream>>>(G, Yv, GVpre);
    pass_2b<<<dim3(4, 16, 2), 256, 0, stream>>>(AOp, GVpre, lam, wan, aoS);
    dim3 gmf(32, 16);
    gemm_mfma_wb<<<gmf, 256, 0, stream>>>(aoS, WoB, bo, x, X1, 2048, 1024, 1024);
    // Pre-convert gate weights (AOp/GVpre/WoB regions now dead).
    cvt_bf16<<<4096, 256, 0, stream>>>(Wg, WuB, 1048576);
    cvt_bf16<<<4096, 256, 0, stream>>>(Wg + 4194304, WvB2, 1048576);
    rms_kernel<1><<<2048, 256, 0, stream>>>(X1, w2, h2b, EPS_DEF);
    gemm_gate_wb<<<dim3(16, 64), 256, 0, stream>>>(h2b, WuB, WvB2, bg, mlp);
    // Pre-convert Wout into [33,41) (WuB dead after gate).
    cvt_bf16<<<4096, 256, 0, stream>>>(Wout, WoutB, 1048576);
    // FINAL OUTPUT IS FP32.
    gemm_mfma_wb<<<gmf, 256, 0, stream>>>(mlp, WoutB, bout, X1, (float*)d_out, 2048, 1024, 4096);
}

// Round 14
// 414.885 us; speedup vs baseline: 8.9174x; 1.0172x over previous
//
#include <hip/hip_runtime.h>

#define LAMBDA_INIT 0.2f
#define SCALING 0.17677669529663687f   // 1/sqrt(32)
#define EPS_DEF 1.1920928955078125e-07f
#define EPS_ATTN 1e-5f

typedef unsigned short us4 __attribute__((ext_vector_type(4)));
typedef unsigned short us8v __attribute__((ext_vector_type(8)));
typedef float f32x4 __attribute__((ext_vector_type(4)));
typedef float f32x2 __attribute__((ext_vector_type(2)));
typedef __bf16 bf16x8 __attribute__((ext_vector_type(8)));

#define MFMA16(a, b, c) __builtin_amdgcn_mfma_f32_16x16x32_bf16((a), (b), (c), 0, 0, 0)

__device__ __forceinline__ float bf2f(unsigned short u) {
    unsigned int x = ((unsigned int)u) << 16;
    return __builtin_bit_cast(float, x);
}
__device__ __forceinline__ unsigned short f2bf(float f) {
    unsigned int x = __builtin_bit_cast(unsigned int, f);
    x += 0x7fffu + ((x >> 16) & 1u);
    return (unsigned short)(x >> 16);
}
// split a pair of f32x4 into hi/lo bf16 (x ~= hi + lo, residual ~2^-18 rel)
__device__ __forceinline__ void split8(f32x4 a, f32x4 b, us8v& hi, us8v& lo) {
#pragma unroll
    for (int u = 0; u < 4; u++) {
        unsigned short h = f2bf(a[u]);
        hi[u] = h; lo[u] = f2bf(a[u] - bf2f(h));
        unsigned short h2 = f2bf(b[u]);
        hi[4 + u] = h2; lo[4 + u] = f2bf(b[u] - bf2f(h2));
    }
}
__device__ __forceinline__ bf16x8 ldb(const unsigned short* p) {
    return __builtin_bit_cast(bf16x8, *(const us8v*)p);
}
// RoPE on 4 consecutive dims starting at dd (within head)
__device__ __forceinline__ f32x4 rope4(f32x4 v, const float* __restrict__ fc, int p, int dd) {
    if (p == 0) return v;
    int d4 = (dd & 31) >> 1;
    f32x4 f = *(const f32x4*)(fc + ((size_t)(p - 1) * 16 + d4) * 2);
    f32x4 o;
    o[0] = v[0] * f[0] - v[1] * f[1];
    o[1] = v[0] * f[1] + v[1] * f[0];
    o[2] = v[2] * f[2] - v[3] * f[3];
    o[3] = v[2] * f[3] + v[3] * f[2];
    return o;
}

__device__ __forceinline__ float wave_sum(float v) {
#pragma unroll
    for (int o = 32; o > 0; o >>= 1) v += __shfl_down(v, o);
    return v;
}
__device__ __forceinline__ float block_sum(float v, float* red4) {
    int wv = threadIdx.x >> 6;
    float w = wave_sum(v);
    __syncthreads();
    if ((threadIdx.x & 63) == 0) red4[wv] = w;
    __syncthreads();
    return red4[0] + red4[1] + red4[2] + red4[3];
}

// ---------------- prep: zero G, compute lambda ----------------
__global__ __launch_bounds__(256) void prep(float* __restrict__ G, float* __restrict__ lamp,
                                            const float* lq1, const float* lk1,
                                            const float* lq2, const float* lk2) {
    int i = (blockIdx.x * 256 + threadIdx.x) * 4;
    G[i] = 0.f; G[i + 1] = 0.f; G[i + 2] = 0.f; G[i + 3] = 0.f;
    if (blockIdx.x == 0 && threadIdx.x == 0) {
        float a = 0.f, c = 0.f;
        for (int d = 0; d < 32; d++) {
            a += lq1[d] * lk1[d];
            c += lq2[d] * lk2[d];
        }
        *lamp = expf(a) - expf(c) + LAMBDA_INIT;
    }
}

// ------- QKV weight hi/lo splits + Wo plain bf16, one fused launch -------
__global__ __launch_bounds__(256) void cvt_wsplit(
        const float* __restrict__ s0, const float* __restrict__ s1,
        const float* __restrict__ s2, const float* __restrict__ s3,
        unsigned short* __restrict__ h0, unsigned short* __restrict__ l0,
        unsigned short* __restrict__ h1p, unsigned short* __restrict__ l1p,
        unsigned short* __restrict__ h2p, unsigned short* __restrict__ l2p,
        unsigned short* __restrict__ d3, int n4) {
    const int z = blockIdx.y;
    int i = blockIdx.x * 256 + threadIdx.x;
    if (i >= n4) return;
    if (z == 3) {   // plain bf16 convert (Wo)
        f32x4 v = ((const f32x4*)s3)[i];
        us4 o;
#pragma unroll
        for (int u = 0; u < 4; u++) o[u] = f2bf(v[u]);
        ((us4*)d3)[i] = o;
        return;
    }
    const float* s = (z == 0) ? s0 : (z == 1) ? s1 : s2;
    unsigned short* hi = (z == 0) ? h0 : (z == 1) ? h1p : h2p;
    unsigned short* lo = (z == 0) ? l0 : (z == 1) ? l1p : l2p;
    f32x4 v = ((const f32x4*)s)[i];
    us4 h, l;
#pragma unroll
    for (int u = 0; u < 4; u++) {
        h[u] = f2bf(v[u]);
        l[u] = f2bf(v[u] - bf2f(h[u]));
    }
    ((us4*)hi)[i] = h;
    ((us4*)lo)[i] = l;
}

// ------- gate weights (Wu | Wv) bf16 conversion, one fused launch -------
__global__ __launch_bounds__(256) void cvt_gate2(const float* __restrict__ Wg,
                                                 unsigned short* __restrict__ WuB,
                                                 unsigned short* __restrict__ WvB, int n4) {
    const int z = blockIdx.y;
    const float* s = Wg + (size_t)z * 4194304;
    unsigned short* d = z ? WvB : WuB;
    int i = blockIdx.x * 256 + threadIdx.x;
    if (i >= n4) return;
    f32x4 v = ((const f32x4*)s)[i];
    us4 o;
#pragma unroll
    for (int u = 0; u < 4; u++) o[u] = f2bf(v[u]);
    ((us4*)d)[i] = o;
}

// ---------------- fp32 -> bf16 conversion ----------------
__global__ __launch_bounds__(256) void cvt_bf16(const float* __restrict__ s,
                                                unsigned short* __restrict__ d, int n4) {
    int i = blockIdx.x * 256 + threadIdx.x;
    if (i >= n4) return;
    f32x4 v = ((const f32x4*)s)[i];
    us4 o;
#pragma unroll
    for (int u = 0; u < 4; u++) o[u] = f2bf(v[u]);
    ((us4*)d)[i] = o;
}

// ---------------- RMSNorm: fp32 in, fp32 weight, bf16/fp32 out ----------------
template <int OUTBF>
__global__ __launch_bounds__(256) void rms_kernel(const float* __restrict__ x,
                                                  const float* __restrict__ w,
                                                  void* __restrict__ out, float eps) {
    int row = blockIdx.x;
    int tid = threadIdx.x;
    size_t base = (size_t)row * 1024 + tid * 4;
    f32x4 v = *(const f32x4*)(x + base);
    float ss = v[0]*v[0] + v[1]*v[1] + v[2]*v[2] + v[3]*v[3];
    __shared__ float red4[4];
    float tot = block_sum(ss, red4);
    float r = rsqrtf(tot * (1.0f / 1024.f) + eps);
    f32x4 wv = *(const f32x4*)(w + tid * 4);
    if (OUTBF) {
        us4 o;
#pragma unroll
        for (int i = 0; i < 4; i++) o[i] = f2bf(v[i] * r * wv[i]);
        *(us4*)((unsigned short*)out + base) = o;
    } else {
        f32x4 o;
#pragma unroll
        for (int i = 0; i < 4; i++) o[i] = v[i] * r * wv[i];
        *(f32x4*)((float*)out + base) = o;
    }
}

// ---------------- RMSNorm with hi/lo split output ----------------
__global__ __launch_bounds__(256) void rms_split(const float* __restrict__ x,
                                                 const float* __restrict__ w,
                                                 unsigned short* __restrict__ hh,
                                                 unsigned short* __restrict__ hl, float eps) {
    int row = blockIdx.x;
    int tid = threadIdx.x;
    size_t base = (size_t)row * 1024 + tid * 4;
    f32x4 v = *(const f32x4*)(x + base);
    float ss = v[0]*v[0] + v[1]*v[1] + v[2]*v[2] + v[3]*v[3];
    __shared__ float red4[4];
    float tot = block_sum(ss, red4);
    float r = rsqrtf(tot * (1.0f / 1024.f) + eps);
    f32x4 wv = *(const f32x4*)(w + tid * 4);
    us4 oh, ol;
#pragma unroll
    for (int i = 0; i < 4; i++) {
        float val = v[i] * r * wv[i];
        oh[i] = f2bf(val);
        ol[i] = f2bf(val - bf2f(oh[i]));
    }
    *(us4*)(hh + base) = oh;
    *(us4*)(hl + base) = ol;
}

// =====================================================================
// QKV split-bf16 MFMA GEMM, PRE-SPLIT operands, SOFTWARE-PIPELINED.
// BM=64, BN=64, BK=64, 4 waves (2x2). Grid (32,16,3).
// =====================================================================
__global__ __launch_bounds__(256) void gemm_qkv_ps(
        const unsigned short* __restrict__ AH, const unsigned short* __restrict__ AL,
        const unsigned short* __restrict__ WqH, const unsigned short* __restrict__ WqL,
        const unsigned short* __restrict__ WkH, const unsigned short* __restrict__ WkL,
        const unsigned short* __restrict__ WvH, const unsigned short* __restrict__ WvL,
        const float* __restrict__ bq, const float* __restrict__ bk, const float* __restrict__ bv,
        float* __restrict__ Yq, float* __restrict__ Yk, float* __restrict__ Yv) {
    const int z = blockIdx.z;
    const unsigned short* BH = (z == 0) ? WqH : (z == 1) ? WkH : WvH;
    const unsigned short* BL = (z == 0) ? WqL : (z == 1) ? WkL : WvL;
    const float* bias = (z == 0) ? bq : (z == 1) ? bk : bv;
    float* out        = (z == 0) ? Yq : (z == 1) ? Yk : Yv;
    const int K = 1024, N = 1024;
    __shared__ __align__(16) unsigned short Ah[64][72];
    __shared__ __align__(16) unsigned short Al[64][72];
    __shared__ __align__(16) unsigned short Bh[64][72];
    __shared__ __align__(16) unsigned short Bl[64][72];
    const int t = threadIdx.x;
    const int bm = blockIdx.x, bn = blockIdx.y;
    const int lane = t & 63, w = t >> 6;
    const int wr = w >> 1, wc = w & 1;
    const int l15 = lane & 15, lg = lane >> 4;
    const int sr = t >> 2, sc = (t & 3) * 16;

    const unsigned short* AgH = AH + (size_t)(bm * 64 + sr) * K + sc;
    const unsigned short* AgL = AL + (size_t)(bm * 64 + sr) * K + sc;
    const unsigned short* BgH = BH + (size_t)(bn * 64 + sr) * K + sc;
    const unsigned short* BgL = BL + (size_t)(bn * 64 + sr) * K + sc;

    f32x4 acc[2][2] = {};

    us8v ah0 = *(const us8v*)AgH, ah1 = *(const us8v*)(AgH + 8);
    us8v al0 = *(const us8v*)AgL, al1 = *(const us8v*)(AgL + 8);
    us8v bh0 = *(const us8v*)BgH, bh1 = *(const us8v*)(BgH + 8);
    us8v bl0 = *(const us8v*)BgL, bl1 = *(const us8v*)(BgL + 8);

    for (int k0 = 0; k0 < K; k0 += 64) {
        __syncthreads();
        *(us8v*)&Ah[sr][sc] = ah0; *(us8v*)&Ah[sr][sc + 8] = ah1;
        *(us8v*)&Al[sr][sc] = al0; *(us8v*)&Al[sr][sc + 8] = al1;
        *(us8v*)&Bh[sr][sc] = bh0; *(us8v*)&Bh[sr][sc + 8] = bh1;
        *(us8v*)&Bl[sr][sc] = bl0; *(us8v*)&Bl[sr][sc + 8] = bl1;
        __syncthreads();
        if (k0 + 64 < K) {
            const int kn = k0 + 64;
            ah0 = *(const us8v*)(AgH + kn); ah1 = *(const us8v*)(AgH + kn + 8);
            al0 = *(const us8v*)(AgL + kn); al1 = *(const us8v*)(AgL + kn + 8);
            bh0 = *(const us8v*)(BgH + kn); bh1 = *(const us8v*)(BgH + kn + 8);
            bl0 = *(const us8v*)(BgL + kn); bl1 = *(const us8v*)(BgL + kn + 8);
        }
#pragma unroll
        for (int kk = 0; kk < 2; kk++) {
            bf16x8 afh[2], afl[2], bfh[2], bfl[2];
#pragma unroll
            for (int mi = 0; mi < 2; mi++) {
                afh[mi] = ldb(&Ah[wr * 32 + mi * 16 + l15][kk * 32 + lg * 8]);
                afl[mi] = ldb(&Al[wr * 32 + mi * 16 + l15][kk * 32 + lg * 8]);
            }
#pragma unroll
            for (int ni = 0; ni < 2; ni++) {
                bfh[ni] = ldb(&Bh[wc * 32 + ni * 16 + l15][kk * 32 + lg * 8]);
                bfl[ni] = ldb(&Bl[wc * 32 + ni * 16 + l15][kk * 32 + lg * 8]);
            }
#pragma unroll
            for (int mi = 0; mi < 2; mi++)
#pragma unroll
                for (int ni = 0; ni < 2; ni++) {
                    acc[mi][ni] = MFMA16(afl[mi], bfh[ni], acc[mi][ni]);
                    acc[mi][ni] = MFMA16(afh[mi], bfl[ni], acc[mi][ni]);
                    acc[mi][ni] = MFMA16(afh[mi], bfh[ni], acc[mi][ni]);
                }
        }
    }

    const int rbase = bm * 64 + wr * 32 + (lg << 2);
    const int cbase = bn * 64 + wc * 32 + l15;
#pragma unroll
    for (int mi = 0; mi < 2; mi++) {
#pragma unroll
        for (int ni = 0; ni < 2; ni++) {
            int col = cbase + ni * 16;
            float bb = bias[col];
#pragma unroll
            for (int r = 0; r < 4; r++) {
                int row = rbase + mi * 16 + r;
                out[(size_t)row * N + col] = acc[mi][ni][r] + bb;
            }
        }
    }
}

// =====================================================================
// bf16 MFMA GEMM, pre-converted bf16 B, SOFTWARE-PIPELINED, BK=128.
// BM=64, BN=64, 4 waves (2x2). K must be a multiple of 128.
// =====================================================================
__global__ __launch_bounds__(256) void gemm_mfma_wb(const unsigned short* __restrict__ A,
                                                    const unsigned short* __restrict__ Bt,
                                                    const float* __restrict__ bias,
                                                    const float* __restrict__ res,
                                                    float* __restrict__ out,
                                                    int M, int N, int K) {
    __shared__ __align__(16) unsigned short As[64][136];
    __shared__ __align__(16) unsigned short Bs[64][136];
    const int t = threadIdx.x;
    const int bm = blockIdx.x, bn = blockIdx.y;
    const int lane = t & 63, w = t >> 6;
    const int wr = w >> 1, wc = w & 1;
    const int l15 = lane & 15, lg = lane >> 4;
    const int sr = t >> 2, sc = (t & 3) * 32;

    const unsigned short* Ag = A + (size_t)(bm * 64 + sr) * K + sc;
    const unsigned short* Bg = Bt + (size_t)(bn * 64 + sr) * K + sc;

    f32x4 acc[2][2] = {};

    us8v a0 = *(const us8v*)Ag,        a1 = *(const us8v*)(Ag + 8);
    us8v a2 = *(const us8v*)(Ag + 16), a3 = *(const us8v*)(Ag + 24);
    us8v b0 = *(const us8v*)Bg,        b1 = *(const us8v*)(Bg + 8);
    us8v b2 = *(const us8v*)(Bg + 16), b3 = *(const us8v*)(Bg + 24);

    for (int k0 = 0; k0 < K; k0 += 128) {
        __syncthreads();
        *(us8v*)&As[sr][sc]      = a0;
        *(us8v*)&As[sr][sc + 8]  = a1;
        *(us8v*)&As[sr][sc + 16] = a2;
        *(us8v*)&As[sr][sc + 24] = a3;
        *(us8v*)&Bs[sr][sc]      = b0;
        *(us8v*)&Bs[sr][sc + 8]  = b1;
        *(us8v*)&Bs[sr][sc + 16] = b2;
        *(us8v*)&Bs[sr][sc + 24] = b3;
        __syncthreads();
        if (k0 + 128 < K) {
            const int kn = k0 + 128;
            a0 = *(const us8v*)(Ag + kn);      a1 = *(const us8v*)(Ag + kn + 8);
            a2 = *(const us8v*)(Ag + kn + 16); a3 = *(const us8v*)(Ag + kn + 24);
            b0 = *(const us8v*)(Bg + kn);      b1 = *(const us8v*)(Bg + kn + 8);
            b2 = *(const us8v*)(Bg + kn + 16); b3 = *(const us8v*)(Bg + kn + 24);
        }
#pragma unroll
        for (int kk = 0; kk < 4; kk++) {
            bf16x8 af[2], bf[2];
#pragma unroll
            for (int mi = 0; mi < 2; mi++)
                af[mi] = ldb(&As[wr * 32 + mi * 16 + l15][kk * 32 + lg * 8]);
#pragma unroll
            for (int ni = 0; ni < 2; ni++)
                bf[ni] = ldb(&Bs[wc * 32 + ni * 16 + l15][kk * 32 + lg * 8]);
#pragma unroll
            for (int mi = 0; mi < 2; mi++)
#pragma unroll
                for (int ni = 0; ni < 2; ni++)
                    acc[mi][ni] = MFMA16(af[mi], bf[ni], acc[mi][ni]);
        }
    }

    const int rbase = bm * 64 + wr * 32 + (lg << 2);
    const int cbase = bn * 64 + wc * 32 + l15;
#pragma unroll
    for (int mi = 0; mi < 2; mi++) {
#pragma unroll
        for (int ni = 0; ni < 2; ni++) {
            int col = cbase + ni * 16;
            float bb = bias[col];
#pragma unroll
            for (int r = 0; r < 4; r++) {
                int row = rbase + mi * 16 + r;
                size_t oi = (size_t)row * N + col;
                out[oi] = acc[mi][ni][r] + bb + res[oi];
            }
        }
    }
}

// ------- fused gate GEMM, PRE-CONVERTED bf16 weights, PIPELINED -------
__global__ __launch_bounds__(256) void gemm_gate_wb(const unsigned short* __restrict__ A,
                                                    const unsigned short* __restrict__ WuB,
                                                    const unsigned short* __restrict__ WvB,
                                                    const float* __restrict__ bg,
                                                    unsigned short* __restrict__ mlp) {
    __shared__ __align__(16) unsigned short As[128][72];
    __shared__ __align__(16) unsigned short BsU[64][72];
    __shared__ __align__(16) unsigned short BsV[64][72];
    const int t = threadIdx.x;
    const int bm = blockIdx.x, bn = blockIdx.y;
    const int lane = t & 63, w = t >> 6;
    const int wr = w >> 1, wc = w & 1;
    const int l15 = lane & 15, lg = lane >> 4;
    const int sr = t >> 2, sc = (t & 3) * 16;

    const unsigned short* Ag  = A + (size_t)(bm * 128 + sr) * 1024 + sc;
    const unsigned short* Ag2 = Ag + (size_t)64 * 1024;
    const unsigned short* BgU = WuB + (size_t)(bn * 64 + sr) * 1024 + sc;
    const unsigned short* BgV = WvB + (size_t)(bn * 64 + sr) * 1024 + sc;

    f32x4 accU[4][2] = {};
    f32x4 accV[4][2] = {};

    us8v a0 = *(const us8v*)Ag,  a1 = *(const us8v*)(Ag + 8);
    us8v a2 = *(const us8v*)Ag2, a3 = *(const us8v*)(Ag2 + 8);
    us8v u0 = *(const us8v*)BgU, u1 = *(const us8v*)(BgU + 8);
    us8v v0 = *(const us8v*)BgV, v1 = *(const us8v*)(BgV + 8);

    for (int k0 = 0; k0 < 1024; k0 += 64) {
        __syncthreads();
        *(us8v*)&As[sr][sc]          = a0;
        *(us8v*)&As[sr][sc + 8]      = a1;
        *(us8v*)&As[sr + 64][sc]     = a2;
        *(us8v*)&As[sr + 64][sc + 8] = a3;
        *(us8v*)&BsU[sr][sc]         = u0;
        *(us8v*)&BsU[sr][sc + 8]     = u1;
        *(us8v*)&BsV[sr][sc]         = v0;
        *(us8v*)&BsV[sr][sc + 8]     = v1;
        __syncthreads();
        if (k0 + 64 < 1024) {
            const int kn = k0 + 64;
            a0 = *(const us8v*)(Ag + kn);  a1 = *(const us8v*)(Ag + kn + 8);
            a2 = *(const us8v*)(Ag2 + kn); a3 = *(const us8v*)(Ag2 + kn + 8);
            u0 = *(const us8v*)(BgU + kn); u1 = *(const us8v*)(BgU + kn + 8);
            v0 = *(const us8v*)(BgV + kn); v1 = *(const us8v*)(BgV + kn + 8);
        }
#pragma unroll
        for (int kk = 0; kk < 2; kk++) {
            bf16x8 af[4], bu[2], bv2[2];
#pragma unroll
            for (int mi = 0; mi < 4; mi++)
                af[mi] = ldb(&As[wr * 64 + mi * 16 + l15][kk * 32 + lg * 8]);
#pragma unroll
            for (int ni = 0; ni < 2; ni++) {
                bu[ni]  = ldb(&BsU[wc * 32 + ni * 16 + l15][kk * 32 + lg * 8]);
                bv2[ni] = ldb(&BsV[wc * 32 + ni * 16 + l15][kk * 32 + lg * 8]);
            }
#pragma unroll
            for (int mi = 0; mi < 4; mi++)
#pragma unroll
                for (int ni = 0; ni < 2; ni++) {
                    accU[mi][ni] = MFMA16(af[mi], bu[ni], accU[mi][ni]);
                    accV[mi][ni] = MFMA16(af[mi], bv2[ni], accV[mi][ni]);
                }
        }
    }

    const int rbase = bm * 128 + wr * 64 + (lg << 2);
    const int cbase = bn * 64 + wc * 32 + l15;
#pragma unroll
    for (int mi = 0; mi < 4; mi++) {
#pragma unroll
        for (int ni = 0; ni < 2; ni++) {
            int col = cbase + ni * 16;
            float bu_ = bg[col], bv_ = bg[4096 + col];
#pragma unroll
            for (int r = 0; r < 4; r++) {
                int row = rbase + mi * 16 + r;
                float u = accU[mi][ni][r] + bu_;
                float v = accV[mi][ni][r] + bv_;
                float s = v / (1.f + __expf(-v));
                mlp[(size_t)row * 4096 + col] = f2bf(u * s);
            }
        }
    }
}

// ------- RoPE(K) + hi/lo bf16 split, token-order output -------
__global__ __launch_bounds__(256) void rope_split_k(const float* __restrict__ Yk,
                                                    const float* __restrict__ fc,
                                                    unsigned short* __restrict__ KhG,
                                                    unsigned short* __restrict__ KlG) {
    int t = blockIdx.x;           // b*1024 + s
    int s = t & 1023;
    int p = s >> 2;
    int c0 = threadIdx.x * 4;
    const float* y = Yk + (size_t)t * 1024 + c0;
    float v0 = y[0], v1 = y[1], v2 = y[2], v3 = y[3];
    if (p > 0) {
        int d4 = (c0 & 31) >> 1;
        f32x4 f = *(const f32x4*)(fc + ((size_t)(p - 1) * 16 + d4) * 2);
        float w0 = v0 * f[0] - v1 * f[1];
        float w1 = v0 * f[1] + v1 * f[0];
        float w2 = v2 * f[2] - v3 * f[3];
        float w3 = v2 * f[3] + v3 * f[2];
        v0 = w0; v1 = w1; v2 = w2; v3 = w3;
    }
    us4 hi, lo;
    hi[0] = f2bf(v0); lo[0] = f2bf(v0 - bf2f(hi[0]));
    hi[1] = f2bf(v1); lo[1] = f2bf(v1 - bf2f(hi[1]));
    hi[2] = f2bf(v2); lo[2] = f2bf(v2 - bf2f(hi[2]));
    hi[3] = f2bf(v3); lo[3] = f2bf(v3 - bf2f(hi[3]));
    *(us4*)(KhG + (size_t)t * 1024 + c0) = hi;
    *(us4*)(KlG + (size_t)t * 1024 + c0) = lo;
}

// ------- V transpose + hi/lo split: Vt[(b,h)][d (64)][j (1024)] -------
__global__ __launch_bounds__(256) void v_split_t(const float* __restrict__ Yv,
                                                 unsigned short* __restrict__ VtH,
                                                 unsigned short* __restrict__ VtL) {
    const int jc = blockIdx.x, h = blockIdx.y, b = blockIdx.z;   // (16,16,2)
    __shared__ float tile[64][65];
    const int t = threadIdx.x;
    {
        const int jr = t >> 2, dc = (t & 3) * 16;
        const float* src = Yv + ((size_t)(b * 1024 + jc * 64 + jr) << 10) + h * 64 + dc;
        *(f32x4*)&tile[jr][dc]      = *(const f32x4*)src;
        *(f32x4*)&tile[jr][dc + 4]  = *(const f32x4*)(src + 4);
        *(f32x4*)&tile[jr][dc + 8]  = *(const f32x4*)(src + 8);
        *(f32x4*)&tile[jr][dc + 12] = *(const f32x4*)(src + 12);
    }
    __syncthreads();
    const int d = t >> 2, js = (t & 3) * 16;
    us8v h0, h1, l0, l1;
#pragma unroll
    for (int n = 0; n < 16; n++) {
        float val = tile[js + n][d];
        unsigned short hh = f2bf(val);
        unsigned short ll = f2bf(val - bf2f(hh));
        if (n < 8) { h0[n] = hh; l0[n] = ll; }
        else       { h1[n - 8] = hh; l1[n - 8] = ll; }
    }
    size_t ob = (((size_t)(b * 16 + h) * 64 + d) << 10) + jc * 64 + js;
    *(us8v*)(VtH + ob) = h0; *(us8v*)(VtH + ob + 8) = h1;
    *(us8v*)(VtL + ob) = l0; *(us8v*)(VtL + ob + 8) = l1;
}

// =====================================================================
// pass_0: Z1/Z2 denominators only (K tiles in LDS, RoPE(Q) fused).
// =====================================================================
__global__ __launch_bounds__(256) void pass_0(const float* __restrict__ Yq,
                                              const float* __restrict__ fc,
                                              const unsigned short* __restrict__ KhG,
                                              const unsigned short* __restrict__ KlG,
                                              float* __restrict__ MZ) {
    const int blk = blockIdx.x;
    const int qc = 15 - (blk >> 5);
    const int h  = blk & 15;
    const int b  = (blk >> 4) & 1;
    const int t = threadIdx.x;
    const int lane = t & 63, w = t >> 6;
    const int l15 = lane & 15, lg = lane >> 4;

    __shared__ __align__(16) unsigned short Kh[64][72];
    __shared__ __align__(16) unsigned short Kl[64][72];

    us8v qh[2], ql[2];
    {
        const int srq = qc * 64 + w * 16 + l15;
        const int p = srq >> 2;
        const float* qp = Yq + ((size_t)(b * 1024 + srq) << 10) + h * 64 + lg * 8;
#pragma unroll
        for (int H = 0; H < 2; H++) {
            int dd = lg * 8 + H * 32;
            f32x4 a = rope4(*(const f32x4*)(qp + H * 32), fc, p, dd);
            f32x4 c = rope4(*(const f32x4*)(qp + H * 32 + 4), fc, p, dd + 4);
            split8(a, c, qh[H], ql[H]);
        }
    }
    const int dq0 = w * 16 + (lg << 2);

    const int srow = t >> 2, ssub = t & 3;
    const int ptk = 4 * (srow & 15) + (srow >> 4);
    const unsigned short* KhB = KhG + ((size_t)(b * 1024) << 10) + h * 64;
    const unsigned short* KlB = KlG + ((size_t)(b * 1024) << 10) + h * 64;

    float z1r[4] = {0.f, 0.f, 0.f, 0.f};
    float z2r[4] = {0.f, 0.f, 0.f, 0.f};

    us8v rkh0, rkh1, rkl0, rkl1;
    {
        const unsigned short* kh = KhB + ((size_t)ptk << 10) + ssub * 16;
        const unsigned short* kl = KlB + ((size_t)ptk << 10) + ssub * 16;
        rkh0 = *(const us8v*)kh; rkh1 = *(const us8v*)(kh + 8);
        rkl0 = *(const us8v*)kl; rkl1 = *(const us8v*)(kl + 8);
    }
    for (int kc = 0; kc <= qc; kc++) {
        __syncthreads();
        *(us8v*)&Kh[srow][ssub * 16]     = rkh0;
        *(us8v*)&Kh[srow][ssub * 16 + 8] = rkh1;
        *(us8v*)&Kl[srow][ssub * 16]     = rkl0;
        *(us8v*)&Kl[srow][ssub * 16 + 8] = rkl1;
        __syncthreads();
        if (kc < qc) {
            const unsigned short* kh = KhB + ((size_t)((kc + 1) * 64 + ptk) << 10) + ssub * 16;
            const unsigned short* kl = KlB + ((size_t)((kc + 1) * 64 + ptk) << 10) + ssub * 16;
            rkh0 = *(const us8v*)kh; rkh1 = *(const us8v*)(kh + 8);
            rkl0 = *(const us8v*)kl; rkl1 = *(const us8v*)(kl + 8);
        }
        const int kpos = kc * 16 + l15;
#pragma unroll
        for (int kf = 0; kf < 4; kf++) {
            const int krow = kf * 16 + l15;
            const int kcol = lg * 8;
            bf16x8 b1h = ldb(&Kh[krow][kcol]),      b1l = ldb(&Kl[krow][kcol]);
            bf16x8 b2h = ldb(&Kh[krow][32 + kcol]), b2l = ldb(&Kl[krow][32 + kcol]);
            f32x4 s1 = {}, s2 = {};
            s1 = MFMA16(__builtin_bit_cast(bf16x8, ql[0]), b1h, s1);
            s1 = MFMA16(__builtin_bit_cast(bf16x8, qh[0]), b1l, s1);
            s1 = MFMA16(__builtin_bit_cast(bf16x8, qh[0]), b1h, s1);
            s2 = MFMA16(__builtin_bit_cast(bf16x8, ql[1]), b2h, s2);
            s2 = MFMA16(__builtin_bit_cast(bf16x8, qh[1]), b2l, s2);
            s2 = MFMA16(__builtin_bit_cast(bf16x8, qh[1]), b2h, s2);
#pragma unroll
            for (int r = 0; r < 4; r++) {
                int pq = (qc * 64 + dq0 + r) >> 2;
                if (kpos <= pq) {
                    z1r[r] += __expf(fabsf(s1[r] * SCALING));
                    z2r[r] += __expf(fabsf(s2[r] * SCALING));
                }
            }
        }
    }
#pragma unroll
    for (int r = 0; r < 4; r++) {
        float a = z1r[r];
        a += __shfl_xor(a, 1); a += __shfl_xor(a, 2);
        a += __shfl_xor(a, 4); a += __shfl_xor(a, 8);
        float c = z2r[r];
        c += __shfl_xor(c, 1); c += __shfl_xor(c, 2);
        c += __shfl_xor(c, 4); c += __shfl_xor(c, 8);
        if (l15 == 0) {
            int s2i = qc * 64 + dq0 + r;
            f32x2 zz; zz[0] = a; zz[1] = c;
            *(f32x2*)(MZ + (((size_t)(b * 16 + h) << 10) + s2i) * 2) = zz;
        }
    }
}

// =====================================================================
// pass_1: weights + G colsums + AV (Z from MZ). Pipelined K+V staging,
// wave-private W tiles, per-wave Gacc slices, RoPE(Q) fused.
// =====================================================================
__global__ __launch_bounds__(256) void pass_1(const float* __restrict__ Yq,
                                              const float* __restrict__ fc,
                                              const unsigned short* __restrict__ KhG,
                                              const unsigned short* __restrict__ KlG,
                                              const unsigned short* __restrict__ VtH,
                                              const unsigned short* __restrict__ VtL,
                                              const float* __restrict__ MZ,
                                              const float* __restrict__ lamp,
                                              float* __restrict__ G,
                                              float* __restrict__ AOp) {
    const int blk = blockIdx.x;
    const int qc = 15 - (blk >> 5);
    const int h  = blk & 15;
    const int b  = (blk >> 4) & 1;
    const int t = threadIdx.x;
    const int lane = t & 63, w = t >> 6;
    const int l15 = lane & 15, lg = lane >> 4;

    __shared__ __align__(16) unsigned short Kh[64][72];
    __shared__ __align__(16) unsigned short Kl[64][72];
    __shared__ __align__(16) unsigned short Vth[64][72];
    __shared__ __align__(16) unsigned short Vtl[64][72];
    __shared__ __align__(16) unsigned short Wh[64][72];
    __shared__ __align__(16) unsigned short Wl[64][72];
    __shared__ float Gacc[4][1024];

    for (int i = t; i < 4096; i += 256) ((float*)Gacc)[i] = 0.f;

    us8v qh[2], ql[2];
    {
        const int srq = qc * 64 + w * 16 + l15;
        const int p = srq >> 2;
        const float* qp = Yq + ((size_t)(b * 1024 + srq) << 10) + h * 64 + lg * 8;
#pragma unroll
        for (int H = 0; H < 2; H++) {
            int dd = lg * 8 + H * 32;
            f32x4 a = rope4(*(const f32x4*)(qp + H * 32), fc, p, dd);
            f32x4 c = rope4(*(const f32x4*)(qp + H * 32 + 4), fc, p, dd + 4);
            split8(a, c, qh[H], ql[H]);
        }
    }
    const int dq0 = w * 16 + (lg << 2);

    float z1r[4], z2r[4];
#pragma unroll
    for (int r = 0; r < 4; r++) {
        int s2i = qc * 64 + dq0 + r;
        f32x2 zz = *(const f32x2*)(MZ + (((size_t)(b * 16 + h) << 10) + s2i) * 2);
        z1r[r] = 1.f / fmaxf(zz[0], 1e-20f);
        z2r[r] = 1.f / fmaxf(zz[1], 1e-20f);
    }

    const int srow = t >> 2, ssub = t & 3;
    const int ptk = 4 * (srow & 15) + (srow >> 4);
    const unsigned short* KhB = KhG + ((size_t)(b * 1024) << 10) + h * 64;
    const unsigned short* KlB = KlG + ((size_t)(b * 1024) << 10) + h * 64;
    const unsigned short* VhB = VtH + (((size_t)(b * 16 + h) * 64 + srow) << 10) + ssub * 256;
    const unsigned short* VlB = VtL + (((size_t)(b * 16 + h) * 64 + srow) << 10) + ssub * 256;
    const float lam = *lamp;

    f32x4 ao[4] = {};

    us8v rkh0, rkh1, rkl0, rkl1, rvh0, rvh1, rvl0, rvl1;
    {
        const unsigned short* kh = KhB + ((size_t)ptk << 10) + ssub * 16;
        const unsigned short* kl = KlB + ((size_t)ptk << 10) + ssub * 16;
        rkh0 = *(const us8v*)kh; rkh1 = *(const us8v*)(kh + 8);
        rkl0 = *(const us8v*)kl; rkl1 = *(const us8v*)(kl + 8);
        rvh0 = *(const us8v*)VhB; rvh1 = *(const us8v*)(VhB + 8);
        rvl0 = *(const us8v*)VlB; rvl1 = *(const us8v*)(VlB + 8);
    }
    for (int kc = 0; kc <= qc; kc++) {
        __syncthreads();
        *(us8v*)&Kh[srow][ssub * 16]      = rkh0;
        *(us8v*)&Kh[srow][ssub * 16 + 8]  = rkh1;
        *(us8v*)&Kl[srow][ssub * 16]      = rkl0;
        *(us8v*)&Kl[srow][ssub * 16 + 8]  = rkl1;
        *(us8v*)&Vth[srow][ssub * 16]     = rvh0;
        *(us8v*)&Vth[srow][ssub * 16 + 8] = rvh1;
        *(us8v*)&Vtl[srow][ssub * 16]     = rvl0;
        *(us8v*)&Vtl[srow][ssub * 16 + 8] = rvl1;
        __syncthreads();
        if (kc < qc) {
            const unsigned short* kh = KhB + ((size_t)((kc + 1) * 64 + ptk) << 10) + ssub * 16;
            const unsigned short* kl = KlB + ((size_t)((kc + 1) * 64 + ptk) << 10) + ssub * 16;
            rkh0 = *(const us8v*)kh; rkh1 = *(const us8v*)(kh + 8);
            rkl0 = *(const us8v*)kl; rkl1 = *(const us8v*)(kl + 8);
            const unsigned short* vh = VhB + (kc + 1) * 16;
            const unsigned short* vl = VlB + (kc + 1) * 16;
            rvh0 = *(const us8v*)vh; rvh1 = *(const us8v*)(vh + 8);
            rvl0 = *(const us8v*)vl; rvl1 = *(const us8v*)(vl + 8);
        }
        const int kpos = kc * 16 + l15;
#pragma unroll
        for (int kf = 0; kf < 4; kf++) {
            const int krow = kf * 16 + l15;
            const int kcol = lg * 8;
            bf16x8 b1h = ldb(&Kh[krow][kcol]),      b1l = ldb(&Kl[krow][kcol]);
            bf16x8 b2h = ldb(&Kh[krow][32 + kcol]), b2l = ldb(&Kl[krow][32 + kcol]);
            f32x4 s1 = {}, s2 = {};
            s1 = MFMA16(__builtin_bit_cast(bf16x8, ql[0]), b1h, s1);
            s1 = MFMA16(__builtin_bit_cast(bf16x8, qh[0]), b1l, s1);
            s1 = MFMA16(__builtin_bit_cast(bf16x8, qh[0]), b1h, s1);
            s2 = MFMA16(__builtin_bit_cast(bf16x8, ql[1]), b2h, s2);
            s2 = MFMA16(__builtin_bit_cast(bf16x8, qh[1]), b2l, s2);
            s2 = MFMA16(__builtin_bit_cast(bf16x8, qh[1]), b2h, s2);
            const int kli = kf * 16 + l15;
            float colsum = 0.f;
#pragma unroll
            for (int r = 0; r < 4; r++) {
                int pq = (qc * 64 + dq0 + r) >> 2;
                float wv = 0.f, a1 = 0.f;
                if (kpos <= pq) {
                    float t1 = s1[r] * SCALING, t2 = s2[r] * SCALING;
                    float sg1 = (t1 > 0.f) ? 1.f : ((t1 < 0.f) ? -1.f : 0.f);
                    float sg2 = (t2 > 0.f) ? 1.f : ((t2 < 0.f) ? -1.f : 0.f);
                    a1 = sg1 * __expf(fabsf(t1)) * z1r[r];
                    wv = a1 - lam * (sg2 * __expf(fabsf(t2)) * z2r[r]);
                }
                colsum += a1;
                unsigned short hh = f2bf(wv);
                Wh[dq0 + r][kli] = hh;
                Wl[dq0 + r][kli] = f2bf(wv - bf2f(hh));
            }
            colsum += __shfl_xor(colsum, 16);
            colsum += __shfl_xor(colsum, 32);
            if (lane < 16) Gacc[w][kf * 256 + kc * 16 + lane] = colsum;
        }
        // No barrier: Wh/Wl rows [w*16, w*16+16) are wave-private.
#pragma unroll
        for (int kh2 = 0; kh2 < 2; kh2++) {
            bf16x8 wah = ldb(&Wh[w * 16 + l15][kh2 * 32 + lg * 8]);
            bf16x8 wal = ldb(&Wl[w * 16 + l15][kh2 * 32 + lg * 8]);
#pragma unroll
            for (int df = 0; df < 4; df++) {
                bf16x8 vbh = ldb(&Vth[df * 16 + l15][kh2 * 32 + lg * 8]);
                bf16x8 vbl = ldb(&Vtl[df * 16 + l15][kh2 * 32 + lg * 8]);
                ao[df] = MFMA16(wah, vbl, ao[df]);
                ao[df] = MFMA16(wal, vbh, ao[df]);
                ao[df] = MFMA16(wah, vbh, ao[df]);
            }
        }
    }

#pragma unroll
    for (int df = 0; df < 4; df++) {
#pragma unroll
        for (int r = 0; r < 4; r++) {
            int tq = qc * 64 + dq0 + r;
            int qrow = ((tq & 3) << 8) + (tq >> 2);
            AOp[((((size_t)(b * 16 + h)) << 10) + qrow) * 64 + df * 16 + l15] = ao[df][r];
        }
    }

    __syncthreads();
    float* Gb = G + ((size_t)(b * 16 + h) << 10);
    const int limp = (qc + 1) << 4;
    for (int idx = t; idx < 1024; idx += 256) {
        if ((idx & 255) < limp) {
            float s = Gacc[0][idx] + Gacc[1][idx] + Gacc[2][idx] + Gacc[3][idx];
            atomicAdd(&Gb[idx], s);
        }
    }
}

// -------- pass_2a: per (b,h) masked prefix GV[p][d] = sum_{pos<=p} G.v --------
__global__ __launch_bounds__(256) void pass_2a(const float* __restrict__ G,
                                               const float* __restrict__ Yv,
                                               float* __restrict__ GVpre) {
    const int h = blockIdx.x, b = blockIdx.y;
    const int t = threadIdx.x;
    __shared__ float Gl[1024];
    __shared__ float S[256][64];
    __shared__ float segsum[4][64];
    for (int i = t; i < 1024; i += 256) Gl[i] = G[((size_t)(b * 16 + h) << 10) + i];
    __syncthreads();
    const int d = t & 63, pg = t >> 6;
    const float* Yvb = Yv + ((size_t)b << 20) + h * 64 + d;
    for (int p0 = 0; p0 < 64; p0++) {
        int pos = pg * 64 + p0;
        float s = 0.f;
#pragma unroll
        for (int sq = 0; sq < 4; sq++) {
            int j = (sq << 8) + pos;
            s += Gl[j] * Yvb[(size_t)j << 10];
        }
        S[pos][d] = s;
    }
    __syncthreads();
    float acc = 0.f;
    for (int p0 = 0; p0 < 64; p0++) {
        int pos = pg * 64 + p0;
        acc += S[pos][d];
        S[pos][d] = acc;
    }
    segsum[pg][d] = acc;
    __syncthreads();
    float off = 0.f;
    for (int g = 0; g < pg; g++) off += segsum[g][d];
    float* gv = GVpre + (((size_t)(b * 16 + h)) << 14) + d;
    for (int p0 = 0; p0 < 64; p0++) {
        int pos = pg * 64 + p0;
        gv[pos << 6] = S[pos][d] + off;
    }
}

// -------- pass_2b: ao = AOp + (lam/1024)*GV[pq]; RMS; bf16 store --------
__global__ __launch_bounds__(256) void pass_2b(const float* __restrict__ AOp,
                                               const float* __restrict__ GVpre,
                                               const float* __restrict__ lamp,
                                               const float* __restrict__ wan,
                                               unsigned short* __restrict__ aoS) {
    const int qg = blockIdx.x;
    const int h = blockIdx.y, b = blockIdx.z;
    const int t = threadIdx.x;
    const int d = t & 63, rg = t >> 6;
    const float lamg = (*lamp) * (1.f / 1024.f);
    const float wv = wan[d];
    const float* aob = AOp + ((((size_t)(b * 16 + h)) << 10) + (qg << 8)) * 64 + d;
    const float* gvb = GVpre + (((size_t)(b * 16 + h)) << 14) + d;
    unsigned short* ob = aoS + ((size_t)b << 20) + ((size_t)h << 16) + ((size_t)(qg << 8) << 6) + d;
    for (int p0 = 0; p0 < 64; p0++) {
        int pq = p0 * 4 + rg;
        float ao = aob[(size_t)pq << 6] + lamg * gvb[(size_t)pq << 6];
        float ss = ao * ao;
#pragma unroll
        for (int o = 1; o < 64; o <<= 1) ss += __shfl_xor(ss, o);
        float rr_ = rsqrtf(ss * (1.f / 64.f) + EPS_ATTN);
        ob[(size_t)pq << 6] = f2bf(ao * rr_ * wv);
    }
}

extern "C" void kernel_launch(void* const* d_in, const int* in_sizes, int n_in,
                              void* d_out, int out_size, void* d_ws, size_t ws_size,
                              hipStream_t stream) {
    const float* x    = (const float*)d_in[0];
    const float* fc   = (const float*)d_in[1];
    const float* w1   = (const float*)d_in[2];
    const float* w2   = (const float*)d_in[3];
    const float* Wq   = (const float*)d_in[4];
    const float* bq   = (const float*)d_in[5];
    const float* Wk   = (const float*)d_in[6];
    const float* bk   = (const float*)d_in[7];
    const float* Wv   = (const float*)d_in[8];
    const float* bv   = (const float*)d_in[9];
    const float* Wo   = (const float*)d_in[10];
    const float* bo   = (const float*)d_in[11];
    const float* lq1  = (const float*)d_in[12];
    const float* lk1  = (const float*)d_in[13];
    const float* lq2  = (const float*)d_in[14];
    const float* lk2  = (const float*)d_in[15];
    const float* wan  = (const float*)d_in[16];
    const float* Wg   = (const float*)d_in[17];
    const float* bg   = (const float*)d_in[18];
    const float* Wout = (const float*)d_in[19];
    const float* bout = (const float*)d_in[20];

    char* ws = (char*)d_ws;
    const size_t MB = 1024 * 1024;
    // Layout (peak 49 MB):
    float* G    = (float*)(ws);                     // [0, 128K)
    float* lam  = (float*)(ws + 256 * 1024);        // 4 B
    float* MZ   = (float*)(ws + 384 * 1024);        // [384K, 640K) raw Z1/Z2 per row
    unsigned short* hH = (unsigned short*)(ws + 1 * MB);   // [1,5)  (dead after QKV)
    unsigned short* hL = (unsigned short*)(ws + 5 * MB);   // [5,9)
    float* Yq   = (float*)(ws + 9 * MB);            // [9,17)  (un-roped; rope fused)
    float* Yk   = (float*)(ws + 17 * MB);           // [17,25) (dead after rope_split_k)
    float* Yv   = (float*)(ws + 25 * MB);           // [25,33) (dead after pass_2a)
    unsigned short* WqH = (unsigned short*)(ws + 33 * MB); // [33,35) (dead after QKV)
    unsigned short* WqL = (unsigned short*)(ws + 35 * MB); // [35,37)
    unsigned short* WkH = (unsigned short*)(ws + 37 * MB); // [37,39)
    unsigned short* WkL = (unsigned short*)(ws + 39 * MB); // [39,41)
    unsigned short* WvH = (unsigned short*)(ws + 41 * MB); // [41,43)
    unsigned short* WvL = (unsigned short*)(ws + 43 * MB); // [43,45)
    unsigned short* WoB = (unsigned short*)(ws + 45 * MB); // [45,47) (converted pre-QKV; dead after Wo gemm)
    float* AOp  = (float*)(ws + 33 * MB);           // reuse [33,41) after QKV
    float* GVpre= (float*)(ws + 41 * MB);           // reuse [41,43) after QKV
    unsigned short* KhG = (unsigned short*)(ws + 1 * MB);  // reuse [1,5)  (hH dead)
    unsigned short* KlG = (unsigned short*)(ws + 5 * MB);  // reuse [5,9)  (hL dead)
    unsigned short* VtH = (unsigned short*)(ws + 17 * MB); // reuse [17,21) (Yk dead)
    unsigned short* VtL = (unsigned short*)(ws + 21 * MB); // reuse [21,25)
    unsigned short* aoS = (unsigned short*)(ws + 1 * MB);  // reuse [1,5)  (KhG dead after pass_1)
    float* X1           = (float*)(ws + 9 * MB);           // reuse [9,17) (Yq dead after pass_1)
    unsigned short* h2b = (unsigned short*)(ws + 5 * MB);  // reuse [5,9)  (KlG dead)
    unsigned short* mlp = (unsigned short*)(ws + 17 * MB); // reuse [17,33) (VtH/L, Yv dead)
    unsigned short* WuB = (unsigned short*)(ws + 33 * MB); // reuse [33,41) after pass_2b (AOp dead)
    unsigned short* WvB2= (unsigned short*)(ws + 41 * MB); // reuse [41,49) after Wo gemm (GVpre/WoB dead)
    unsigned short* WoutB=(unsigned short*)(ws + 33 * MB); // reuse [33,41) after gate (WuB dead)

    prep<<<32, 256, 0, stream>>>(G, lam, lq1, lk1, lq2, lk2);
    rms_split<<<2048, 256, 0, stream>>>(x, w1, hH, hL, EPS_DEF);
    // QKV weight splits + Wo plain convert, one fused launch.
    cvt_wsplit<<<dim3(1024, 4), 256, 0, stream>>>(Wq, Wk, Wv, Wo,
                                                  WqH, WqL, WkH, WkL, WvH, WvL, WoB, 262144);
    gemm_qkv_ps<<<dim3(32, 16, 3), 256, 0, stream>>>(hH, hL, WqH, WqL, WkH, WkL, WvH, WvL,
                                                     bq, bk, bv, Yq, Yk, Yv);
    rope_split_k<<<2048, 256, 0, stream>>>(Yk, fc, KhG, KlG);
    v_split_t<<<dim3(16, 16, 2), 256, 0, stream>>>(Yv, VtH, VtL);
    pass_0<<<512, 256, 0, stream>>>(Yq, fc, KhG, KlG, MZ);
    pass_1<<<512, 256, 0, stream>>>(Yq, fc, KhG, KlG, VtH, VtL, MZ, lam, G, AOp);
    pass_2a<<<dim3(16, 2), 256, 0, stream>>>(G, Yv, GVpre);
    pass_2b<<<dim3(4, 16, 2), 256, 0, stream>>>(AOp, GVpre, lam, wan, aoS);
    dim3 gmf(32, 16);
    gemm_mfma_wb<<<gmf, 256, 0, stream>>>(aoS, WoB, bo, x, X1, 2048, 1024, 1024);
    // Gate weights (both halves), one fused launch (AOp/GVpre/WoB dead).
    cvt_gate2<<<dim3(4096, 2), 256, 0, stream>>>(Wg, WuB, WvB2, 1048576);
    rms_kernel<1><<<2048, 256, 0, stream>>>(X1, w2, h2b, EPS_DEF);
    gemm_gate_wb<<<dim3(16, 64), 256, 0, stream>>>(h2b, WuB, WvB2, bg, mlp);
    // Pre-convert Wout into [33,41) (WuB dead after gate).
    cvt_bf16<<<4096, 256, 0, stream>>>(Wout, WoutB, 1048576);
    // FINAL OUTPUT IS FP32.
    gemm_mfma_wb<<<gmf, 256, 0, stream>>>(mlp, WoutB, bout, X1, (float*)d_out, 2048, 1024, 4096);
}